// Round 5
// baseline (3821.767 us; speedup 1.0000x reference)
//
#include <hip/hip_runtime.h>
#include <hip/hip_bf16.h>

typedef unsigned short ushort_t;

#define DEV __device__ __forceinline__

constexpr int Dd  = 64;
constexpr int VD  = 4525;
constexpr int VL  = 753;
constexpr int ND  = Dd * VD;     // 289600
constexpr int NLN = Dd * VL;     // 48192
constexpr int Hh  = 128;
constexpr int EMB = 10;
constexpr int TV  = 100;
constexpr int NH  = 8, HD = 16;
constexpr int L_ENC = 6, FF = 2048;
constexpr int GL  = 2;
constexpr int ED  = 32768, ET = 131072;
constexpr int KK  = 256;
constexpr int NCAND = (Dd - 1) * KK;       // 16128
constexpr int UCAP  = ET + NCAND;          // 147200
constexpr int NCANON = 35;
constexpr int NB_T = (UCAP + 255) / 256;   // 575 scan blocks (took CSR)
constexpr int NB_D = (NLN + 255) / 256;    // 189 scan blocks (did CSR)

DEV float bf(ushort_t u) { return __uint_as_float(((unsigned)u) << 16); }
DEV float bflo(unsigned u) { return __uint_as_float(u << 16); }
DEV float bfhi(unsigned u) { return __uint_as_float(u & 0xffff0000u); }
DEV ushort_t f2bf(float f) {
    unsigned u = __float_as_uint(f);
    u += 0x7fffu + ((u >> 16) & 1u);
    return (ushort_t)(u >> 16);
}

// ---------------------------------------------------------------------------
// dtype probe (fp32 vs packed bf16), flag=1 -> fp32.
__global__ __launch_bounds__(64)
void k_probe(const unsigned* __restrict__ w, int* __restrict__ flag)
{
    int tid = threadIdx.x;
    int c = 0;
    #pragma unroll
    for (int i = 0; i < 16; i++) c += (w[tid * 16 + i] >> 14) & 1;
    #pragma unroll
    for (int o = 32; o; o >>= 1) c += __shfl_xor(c, o);
    if (tid == 0) *flag = (c > 256) ? 1 : 0;
}

struct CanonDesc {
    const void* src[NCANON];
    int doff[NCANON];
    int bend[NCANON];
    int n[NCANON];
};

__global__ __launch_bounds__(256)
void k_canon(CanonDesc cd, float* __restrict__ dst, const int* __restrict__ flag)
{
    int b = blockIdx.x;
    int t = 0;
    while (t < NCANON && b >= cd.bend[t]) t++;
    if (t >= NCANON) return;
    int bstart = (t == 0) ? 0 : cd.bend[t - 1];
    int i = (b - bstart) * 256 + threadIdx.x;
    if (i >= cd.n[t]) return;
    float v = (*flag) ? ((const float*)cd.src[t])[i]
                      : bf(((const ushort_t*)cd.src[t])[i]);
    dst[cd.doff[t] + i] = v;
}

// ---------------------------------------------------------------------------
__global__ __launch_bounds__(256)
void k_mark(const int* __restrict__ took_dst, const int* __restrict__ cand,
            int* __restrict__ map)
{
    int g = blockIdx.x * 256 + threadIdx.x;
    if (g < ET) atomicOr(&map[took_dst[g]], 1);
    if (g < NCAND) {
        int d = g >> 8;
        atomicOr(&map[d * VD + cand[g]], 2);
    }
}

__global__ __launch_bounds__(256)
void k_assign(int* __restrict__ map, int* __restrict__ ulist, int* __restrict__ blist,
              int* __restrict__ nUB)
{
    int g = blockIdx.x * 256 + threadIdx.x;
    if (g >= ND) return;
    int m = map[g];
    if (m) {
        int s = atomicAdd(&nUB[0], 1);
        ulist[s] = g;
        map[g] = (s << 2) | m;
        if (m & 2) {
            int b = atomicAdd(&nUB[1], 1);
            blist[b] = s;
        }
    }
}

__global__ __launch_bounds__(256)
void k_counts(const int* __restrict__ did_dst, const int* __restrict__ did_src,
              const int* __restrict__ took_dst, const int* __restrict__ took_src,
              const int* __restrict__ map,
              int* __restrict__ cnt_ld, int* __restrict__ cnt_a1,
              int* __restrict__ cnt_dc, int* __restrict__ cnt_a2)
{
    int g = blockIdx.x * 256 + threadIdx.x;
    if (g < ED) {
        atomicAdd(&cnt_ld[did_dst[g]], 1);
        atomicAdd(&cnt_a1[did_src[g]], 1);
    }
    if (g < ET) {
        atomicAdd(&cnt_dc[map[took_dst[g]] >> 2], 1);
        atomicAdd(&cnt_a2[took_src[g]], 1);
    }
}

// ---------------------------------------------------------------------------
// 3-kernel exclusive scan (256 elems/block; top level fits 1024 blocks)
__global__ __launch_bounds__(256)
void k_scan_blk(const int* __restrict__ cnt, int* __restrict__ excl,
                int* __restrict__ btot, int n)
{
    __shared__ int s[256];
    int tid = threadIdx.x;
    int g = blockIdx.x * 256 + tid;
    int v = (g < n) ? cnt[g] : 0;
    s[tid] = v;
    __syncthreads();
    for (int o = 1; o < 256; o <<= 1) {
        int t = (tid >= o) ? s[tid - o] : 0;
        __syncthreads();
        s[tid] += t;
        __syncthreads();
    }
    if (g < n) excl[g] = s[tid] - v;
    if (tid == 255) btot[blockIdx.x] = s[255];
}

__global__ __launch_bounds__(1024)
void k_scan_top(int* __restrict__ btot, int nb)
{
    __shared__ int s[1024];
    int tid = threadIdx.x;
    int v = (tid < nb) ? btot[tid] : 0;
    s[tid] = v;
    __syncthreads();
    for (int o = 1; o < 1024; o <<= 1) {
        int t = (tid >= o) ? s[tid - o] : 0;
        __syncthreads();
        s[tid] += t;
        __syncthreads();
    }
    if (tid < nb) btot[tid] = s[tid] - v;
}

__global__ __launch_bounds__(256)
void k_scan_add(int* __restrict__ roff, const int* __restrict__ btot, int n, int total)
{
    int g = blockIdx.x * 256 + threadIdx.x;
    if (g < n) roff[g] += btot[blockIdx.x];
    if (g == 0) roff[n] = total;
}

// fill CSR edge lists: elist packs (src << shift) | edge_id
__global__ __launch_bounds__(256)
void k_fill(const int* __restrict__ did_src, const int* __restrict__ did_dst,
            const int* __restrict__ took_src, const int* __restrict__ took_dst,
            const int* __restrict__ map,
            const int* __restrict__ roff_d, const int* __restrict__ roff_t,
            int* __restrict__ cur_d, int* __restrict__ cur_t,
            int* __restrict__ elist_d, int* __restrict__ elist_t)
{
    int g = blockIdx.x * 256 + threadIdx.x;
    if (g < ED) {
        int d = did_dst[g];
        int pos = roff_d[d] + atomicAdd(&cur_d[d], 1);
        elist_d[pos] = (did_src[g] << 15) | g;
    }
    if (g < ET) {
        int slot = map[took_dst[g]] >> 2;
        int pos = roff_t[slot] + atomicAdd(&cur_t[slot], 1);
        elist_t[pos] = (took_src[g] << 17) | g;
    }
}

// ---------------------------------------------------------------------------
// embedding + align projection (weights canonical fp32).
template<int NID, int NTOK, int NF, bool BF16OUT, bool INDIRECT>
__global__ __launch_bounds__(64)
void k_embed(void* __restrict__ out, int n_static, const int* __restrict__ n_dyn,
             const int* __restrict__ ulist,
             const int* __restrict__ id_idx, const float* __restrict__ id_emb,
             const int* __restrict__ tokens, const float* __restrict__ tok_emb,
             const float* __restrict__ floats_, const float* __restrict__ float_w,
             const float* __restrict__ alignf)
{
    constexpr int L = (NID + NTOK + 1) * EMB;
    int slot = blockIdx.x * 64 + threadIdx.x;
    int n = INDIRECT ? *n_dyn : n_static;
    if (slot >= n) return;
    int node = INDIRECT ? ulist[slot] : slot;

    float vec[L];
    int p = 0;
    if constexpr (NID != 0) {
        const float* pe = id_emb + (size_t)id_idx[node] * EMB;
        #pragma unroll
        for (int e = 0; e < EMB; e++) vec[p++] = pe[e];
    }
    #pragma unroll
    for (int t = 0; t < NTOK; t++) {
        const float* pe = tok_emb + ((size_t)t * TV + tokens[node * NTOK + t]) * EMB;
        #pragma unroll
        for (int e = 0; e < EMB; e++) vec[p++] = pe[e];
    }
    {
        float fv[NF];
        #pragma unroll
        for (int f = 0; f < NF; f++) fv[f] = floats_[node * NF + f];
        #pragma unroll
        for (int e = 0; e < EMB; e++) {
            float a = 0.f;
            #pragma unroll
            for (int f = 0; f < NF; f++) a = fmaf(fv[f], float_w[f * EMB + e], a);
            vec[p++] = a;
        }
    }

    #pragma unroll 1
    for (int j = 0; j < Hh; j += 4) {
        float a0 = 0.f, a1 = 0.f, a2 = 0.f, a3 = 0.f;
        #pragma unroll
        for (int i = 0; i < L; i++) {
            const float* w = alignf + i * Hh + j;
            a0 = fmaf(vec[i], w[0], a0);
            a1 = fmaf(vec[i], w[1], a1);
            a2 = fmaf(vec[i], w[2], a2);
            a3 = fmaf(vec[i], w[3], a3);
        }
        if constexpr (BF16OUT) {
            unsigned lo = (unsigned)f2bf(a0) | ((unsigned)f2bf(a1) << 16);
            unsigned hi = (unsigned)f2bf(a2) | ((unsigned)f2bf(a3) << 16);
            uint2 v; v.x = lo; v.y = hi;
            *reinterpret_cast<uint2*>((ushort_t*)out + (size_t)slot * Hh + j) = v;
        } else {
            float4 r4; r4.x = a0; r4.y = a1; r4.z = a2; r4.w = a3;
            *reinterpret_cast<float4*>((float*)out + (size_t)slot * Hh + j) = r4;
        }
    }
}

// ---------------------------------------------------------------------------
// admission-side accumulators (LDS acc, one global-atomic flush per block)
__global__ __launch_bounds__(256)
void k_adm_did(const int* __restrict__ src, const int* __restrict__ dst,
               const ushort_t* __restrict__ efeat, const ushort_t* __restrict__ x_l,
               float* __restrict__ S_a1, int epb)
{
    __shared__ float acc[Dd * Hh];
    int tid = threadIdx.x;
    for (int i = tid; i < Dd * Hh; i += 256) acc[i] = 0.f;
    __syncthreads();
    int j = tid & 127;
    int e0 = blockIdx.x * epb;
    for (int e = e0 + (tid >> 7); e < e0 + epb; e += 2) {
        int s = src[e], d = dst[e];
        atomicAdd(&acc[s * Hh + j], bf(x_l[(size_t)d * Hh + j]) + bf(efeat[(size_t)e * Hh + j]));
    }
    __syncthreads();
    for (int i = tid; i < Dd * Hh; i += 256) unsafeAtomicAdd(&S_a1[i], acc[i]);
}

__global__ __launch_bounds__(256)
void k_adm_took(const int* __restrict__ src, const int* __restrict__ dst,
                const ushort_t* __restrict__ efeat, const ushort_t* __restrict__ x_dc,
                const int* __restrict__ map, float* __restrict__ S_a2, int epb)
{
    __shared__ float acc[Dd * Hh];
    int tid = threadIdx.x;
    for (int i = tid; i < Dd * Hh; i += 256) acc[i] = 0.f;
    __syncthreads();
    int j = tid & 127;
    int e0 = blockIdx.x * epb;
    for (int e = e0 + (tid >> 7); e < e0 + epb; e += 2) {
        int s = src[e];
        int slot = map[dst[e]] >> 2;
        atomicAdd(&acc[s * Hh + j], bf(x_dc[(size_t)slot * Hh + j]) + bf(efeat[(size_t)e * Hh + j]));
    }
    __syncthreads();
    for (int i = tid; i < Dd * Hh; i += 256) unsafeAtomicAdd(&S_a2[i], acc[i]);
}

// ---------------------------------------------------------------------------
// Fused gather + mean + GNN update:
//   X[r,:] = relu?( X[r,:]@Wself + mean_{e in CSR(r)}(xa[src]+ef[e]) @ Wmsg )
template<bool INDIRECT>
__global__ __launch_bounds__(128)
void k_gup(ushort_t* __restrict__ X, const float* __restrict__ xa,
           const ushort_t* __restrict__ ef,
           const int* __restrict__ roff, const int* __restrict__ elist, int sshift,
           const int* __restrict__ rows_list, const int* __restrict__ n_dyn, int n_static,
           const float* __restrict__ Wself, const float* __restrict__ Wmsg,
           int do_relu)
{
    __shared__ float Xs[32 * 130];
    __shared__ float Ss[32 * 130];
    __shared__ int rowid[32];
    int tid = threadIdx.x;
    int r0 = blockIdx.x * 32;
    int n = n_dyn ? *n_dyn : n_static;
    if (tid < 32) {
        int row = r0 + tid;
        rowid[tid] = (row < n) ? (INDIRECT ? rows_list[row] : row) : -1;
    }
    __syncthreads();

    // stage X rows
    for (int idx = tid; idx < 32 * 128; idx += 128) {
        int r = idx >> 7, c = idx & 127;
        int rr = rowid[r];
        Xs[r * 130 + c] = (rr >= 0) ? bf(X[(size_t)rr * Hh + c]) : 0.f;
    }

    // gather edge means: wave w handles rows w, w+2, ... (2 cols/lane)
    int wid = tid >> 6, lane = tid & 63;
    int c0 = lane * 2;
    int emask = (1 << sshift) - 1;
    for (int r = wid; r < 32; r += 2) {
        int rr = rowid[r];
        float a0 = 0.f, a1 = 0.f, invd = 0.f;
        if (rr >= 0) {
            int e0 = roff[rr], e1 = roff[rr + 1];
            invd = 1.f / fmaxf((float)(e1 - e0), 1.f);
            for (int ei = e0; ei < e1; ei++) {
                int pk = elist[ei];
                int s = pk >> sshift, e = pk & emask;
                const float* xr = xa + s * Hh + c0;
                unsigned ee = *reinterpret_cast<const unsigned*>(ef + (size_t)e * Hh + c0);
                a0 += xr[0] + bflo(ee);
                a1 += xr[1] + bfhi(ee);
            }
        }
        Ss[r * 130 + c0]     = a0 * invd;
        Ss[r * 130 + c0 + 1] = a1 * invd;
    }
    __syncthreads();

    int jg = tid & 15, rg = tid >> 4;
    int j0 = jg * 8, rr0 = rg * 4;
    float acc[4][8];
    #pragma unroll
    for (int i = 0; i < 4; i++)
        #pragma unroll
        for (int c = 0; c < 8; c++) acc[i][c] = 0.f;

    #pragma unroll 2
    for (int k = 0; k < 128; k++) {
        float xv[4], sv[4];
        #pragma unroll
        for (int i = 0; i < 4; i++) {
            xv[i] = Xs[(rr0 + i) * 130 + k];
            sv[i] = Ss[(rr0 + i) * 130 + k];
        }
        const float* w1p = Wself + k * Hh + j0;
        const float* w2p = Wmsg  + k * Hh + j0;
        float4 w1a = *reinterpret_cast<const float4*>(w1p);
        float4 w1b = *reinterpret_cast<const float4*>(w1p + 4);
        float4 w2a = *reinterpret_cast<const float4*>(w2p);
        float4 w2b = *reinterpret_cast<const float4*>(w2p + 4);
        float w1[8] = {w1a.x, w1a.y, w1a.z, w1a.w, w1b.x, w1b.y, w1b.z, w1b.w};
        float w2[8] = {w2a.x, w2a.y, w2a.z, w2a.w, w2b.x, w2b.y, w2b.z, w2b.w};
        #pragma unroll
        for (int i = 0; i < 4; i++)
            #pragma unroll
            for (int c = 0; c < 8; c++)
                acc[i][c] = fmaf(xv[i], w1[c], fmaf(sv[i], w2[c], acc[i][c]));
    }

    #pragma unroll
    for (int i = 0; i < 4; i++) {
        int rr = rowid[rr0 + i];
        if (rr < 0) continue;
        float o[8];
        #pragma unroll
        for (int c = 0; c < 8; c++) {
            o[c] = acc[i][c];
            if (do_relu) o[c] = fmaxf(o[c], 0.f);
        }
        uint4 v;
        v.x = (unsigned)f2bf(o[0]) | ((unsigned)f2bf(o[1]) << 16);
        v.y = (unsigned)f2bf(o[2]) | ((unsigned)f2bf(o[3]) << 16);
        v.z = (unsigned)f2bf(o[4]) | ((unsigned)f2bf(o[5]) << 16);
        v.w = (unsigned)f2bf(o[6]) | ((unsigned)f2bf(o[7]) << 16);
        *reinterpret_cast<uint4*>(X + (size_t)rr * Hh + j0) = v;
    }
}

// ---------------------------------------------------------------------------
__global__ __launch_bounds__(128)
void k_xa(float* __restrict__ x_a, const float* __restrict__ S_a1, const float* __restrict__ S_a2,
          const int* __restrict__ c1, const int* __restrict__ c2,
          const float* __restrict__ Wself, const float* __restrict__ Wm1,
          const float* __restrict__ Wm2, int do_relu)
{
    int r = blockIdx.x, tid = threadIdx.x;
    __shared__ float xr[128], a1[128], a2[128];
    float i1 = 1.f / fmaxf((float)c1[r], 1.f);
    float i2 = 1.f / fmaxf((float)c2[r], 1.f);
    xr[tid] = x_a[r * Hh + tid];
    a1[tid] = S_a1[r * Hh + tid] * i1;
    a2[tid] = S_a2[r * Hh + tid] * i2;
    __syncthreads();
    float acc = 0.f;
    for (int k = 0; k < 128; k++) {
        acc = fmaf(xr[k], Wself[k * Hh + tid], acc);
        acc = fmaf(a1[k], Wm1[k * Hh + tid], acc);
        acc = fmaf(a2[k], Wm2[k * Hh + tid], acc);
    }
    if (do_relu) acc = fmaxf(acc, 0.f);
    x_a[r * Hh + tid] = acc;
}

// ---------------------------------------------------------------------------
// Transformer (D=64, H=128), fp32; 3 kernels/layer.
__global__ __launch_bounds__(128)
void k_qkv(const float* __restrict__ h, float* __restrict__ qkv,
           const float* __restrict__ W, const float* __restrict__ b)
{
    int r = blockIdx.x, tid = threadIdx.x;
    __shared__ float hr[128];
    hr[tid] = h[r * Hh + tid];
    __syncthreads();
    #pragma unroll
    for (int c0 = 0; c0 < 3; c0++) {
        int c = c0 * 128 + tid;
        float acc = b[c];
        for (int k = 0; k < 128; k++) acc = fmaf(hr[k], W[k * 384 + c], acc);
        qkv[r * 384 + c] = acc;
    }
}

DEV float blocksum128(float v, float* red)
{
    #pragma unroll
    for (int o = 32; o; o >>= 1) v += __shfl_xor(v, o);
    int wid = threadIdx.x >> 6;
    __syncthreads();
    if ((threadIdx.x & 63) == 0) red[wid] = v;
    __syncthreads();
    return red[0] + red[1];
}

DEV float blocksum256(float v, float* red)
{
    #pragma unroll
    for (int o = 32; o; o >>= 1) v += __shfl_xor(v, o);
    int wid = threadIdx.x >> 6;
    __syncthreads();
    if ((threadIdx.x & 63) == 0) red[wid] = v;
    __syncthreads();
    return red[0] + red[1] + red[2] + red[3];
}

// fused attention + out-proj + residual + LN1; block per query row.
__global__ __launch_bounds__(128)
void k_attn_out(const float* __restrict__ qkv, float* __restrict__ h,
                const float* __restrict__ Wout, const float* __restrict__ bout,
                const float* __restrict__ ln)
{
    int q = blockIdx.x, tid = threadIdx.x;
    __shared__ float sc[NH * Dd];
    __shared__ float o_r[128];
    __shared__ float red[2];
    int hh = tid >> 4;
    int k0 = (tid & 15) * 4;
    const float* qrow = qkv + q * 384 + hh * HD;
    #pragma unroll
    for (int kk = k0; kk < k0 + 4; kk++) {
        const float* krow = qkv + kk * 384 + 128 + hh * HD;
        float s = 0.f;
        #pragma unroll
        for (int d = 0; d < HD; d++) s = fmaf(qrow[d], krow[d], s);
        sc[hh * Dd + kk] = s * 0.25f + (kk <= q ? 0.f : -1e9f);
    }
    __syncthreads();
    float m = -1e30f;
    for (int k = 0; k < Dd; k++) m = fmaxf(m, sc[hh * Dd + k]);
    float l = 0.f;
    for (int k = 0; k < Dd; k++) l += __expf(sc[hh * Dd + k] - m);
    float inv_l = 1.f / l;
    int d = tid & 15;
    float o = 0.f;
    for (int k = 0; k < Dd; k++)
        o = fmaf(__expf(sc[hh * Dd + k] - m) * inv_l, qkv[k * 384 + 256 + hh * HD + d], o);
    o_r[hh * HD + d] = o;
    __syncthreads();
    float acc = bout[tid];
    for (int k = 0; k < 128; k++) acc = fmaf(o_r[k], Wout[k * Hh + tid], acc);
    float x = h[q * Hh + tid] + acc;
    float mu = blocksum128(x, red) * (1.f / 128.f);
    float dx = x - mu;
    float var = blocksum128(dx * dx, red) * (1.f / 128.f);
    h[q * Hh + tid] = ln[tid] * dx * (1.f / sqrtf(var + 1e-5f)) + ln[128 + tid];
}

// fused ff1+relu+ff2 + residual + LN2; block per row, 256 threads.
__global__ __launch_bounds__(256)
void k_ffln(float* __restrict__ h,
            const float* __restrict__ W1, const float* __restrict__ b1,
            const float* __restrict__ W2, const float* __restrict__ b2,
            const float* __restrict__ ln)
{
    int r = blockIdx.x, tid = threadIdx.x;
    __shared__ float hr[128];
    __shared__ float f[FF];
    __shared__ float pp[256];
    __shared__ float red[4];
    if (tid < 128) hr[tid] = h[r * Hh + tid];
    __syncthreads();
    #pragma unroll 1
    for (int i = 0; i < 8; i++) {
        int c = i * 256 + tid;
        float a = b1[c];
        for (int k = 0; k < 128; k++) a = fmaf(hr[k], W1[(size_t)k * FF + c], a);
        f[c] = fmaxf(a, 0.f);
    }
    __syncthreads();
    int c = tid & 127, half = tid >> 7;
    float a = 0.f;
    int kb = half * (FF / 2);
    for (int k = kb; k < kb + FF / 2; k++)
        a = fmaf(f[k], W2[(size_t)k * Hh + c], a);
    pp[tid] = a;
    __syncthreads();
    float x = 0.f;
    if (tid < 128) x = hr[tid] + b2[tid] + pp[tid] + pp[tid + 128];
    float mu = blocksum256(x, red) * (1.f / 128.f);
    float dx = (tid < 128) ? (x - mu) : 0.f;
    float var = blocksum256(dx * dx, red) * (1.f / 128.f);
    if (tid < 128)
        h[r * Hh + tid] = ln[tid] * dx * (1.f / sqrtf(var + 1e-5f)) + ln[128 + tid];
}

// ---------------------------------------------------------------------------
__global__ __launch_bounds__(256)
void k_logits(const ushort_t* __restrict__ x_dc, const int* __restrict__ map,
              const float* __restrict__ h, const float* __restrict__ lp,
              const int* __restrict__ cand, float* __restrict__ out)
{
    int d = blockIdx.x;
    int tid = threadIdx.x, lane = tid & 63, w = tid >> 6;
    __shared__ float wv[128];
    if (tid < 128) wv[tid] = h[d * Hh + tid] * lp[tid];
    __syncthreads();
    for (int k = w; k < KK; k += 4) {
        int slot = map[d * VD + cand[d * KK + k]] >> 2;
        const ushort_t* row = x_dc + (size_t)slot * Hh;
        float v = bf(row[lane]) * wv[lane] + bf(row[lane + 64]) * wv[lane + 64];
        #pragma unroll
        for (int o = 32; o; o >>= 1) v += __shfl_xor(v, o);
        if (lane == 0) out[d * KK + k] = v;
    }
}

// ---------------------------------------------------------------------------
extern "C" void kernel_launch(void* const* d_in, const int* in_sizes, int n_in,
                              void* d_out, int out_size, void* d_ws, size_t ws_size,
                              hipStream_t stream)
{
    (void)in_sizes; (void)n_in; (void)out_size; (void)ws_size;

    const int* drug_tokens  = (const int*)d_in[0];
    const int* drug_node_id = (const int*)d_in[1];
    const int* lab_tokens   = (const int*)d_in[3];
    const int* lab_node_id  = (const int*)d_in[4];
    const int* adm_tokens   = (const int*)d_in[6];
    const int* did_tokens   = (const int*)d_in[8];
    const int* did_src      = (const int*)d_in[10];
    const int* did_dst      = (const int*)d_in[11];
    const int* took_tokens  = (const int*)d_in[12];
    const int* took_src     = (const int*)d_in[14];
    const int* took_dst     = (const int*)d_in[15];
    const int* cand_idx     = (const int*)d_in[16];

    const int cidx[NCANON] = {2,5,7,9,13, 17,18,19,20,21,22,23, 24,25,26,27,28,
                              29,30,31,32,33, 34,35, 36,37,38,39,40,41,42,43,44,45,46};
    const int cn[NCANON] = {
        ND*2, NLN*1, Dd*3, ED*2, ET*1,
        VD*EMB, VL*EMB, 3*TV*EMB, 2*TV*EMB, 4*TV*EMB, 2*TV*EMB, 2*TV*EMB,
        2*EMB, 1*EMB, 3*EMB, 2*EMB, 1*EMB,
        5*EMB*Hh, 4*EMB*Hh, 5*EMB*Hh, 3*EMB*Hh, 3*EMB*Hh,
        GL*4*Hh*Hh, GL*3*Hh*Hh,
        L_ENC*Hh*3*Hh, L_ENC*3*Hh, L_ENC*Hh*Hh, L_ENC*Hh, L_ENC*2*Hh,
        L_ENC*Hh*FF, L_ENC*FF, L_ENC*FF*Hh, L_ENC*Hh, L_ENC*2*Hh, Hh
    };
    CanonDesc cd;
    int eoff[NCANON + 1];
    int btot_blocks = 0;
    {
        int e = 0;
        for (int t = 0; t < NCANON; t++) {
            cd.src[t] = d_in[cidx[t]];
            cd.n[t] = cn[t];
            eoff[t] = e;
            cd.doff[t] = e;
            e = (e + cn[t] + 7) & ~7;
            btot_blocks += (cn[t] + 255) / 256;
            cd.bend[t] = btot_blocks;
        }
        eoff[NCANON] = e;
    }

    // ---- workspace carve ----
    char* p = (char*)d_ws;
    auto alloc_f = [&](size_t n) -> float*    { float* r = (float*)p;    p += n * sizeof(float); return r; };
    auto alloc_h = [&](size_t n) -> ushort_t* { ushort_t* r = (ushort_t*)p; p += n * sizeof(ushort_t); return r; };
    auto alloc_i = [&](size_t n) -> int*      { int* r = (int*)p;        p += n * sizeof(int); return r; };

    // zero-once block (one memset)
    int* map    = alloc_i(ND);
    int* cnt_dc = alloc_i(UCAP);
    int* cnt_ld = alloc_i(NLN);
    int* cnt_a1 = alloc_i(64);
    int* cnt_a2 = alloc_i(64);
    int* nUB    = alloc_i(8);
    int* cur_t  = alloc_i(UCAP);
    int* cur_d  = alloc_i(NLN);
    const size_t ZBLOCK = (size_t)ND + UCAP + NLN + 64 + 64 + 8 + UCAP + NLN;
    // per-layer zero block (S_a1 | S_a2 contiguous)
    float* S_a1 = alloc_f((size_t)Dd * Hh);
    float* S_a2 = alloc_f((size_t)Dd * Hh);
    // CSR
    int* roff_t  = alloc_i(UCAP + 8);
    int* roff_d  = alloc_i(NLN + 8);
    int* bscr    = alloc_i(1024);
    int* ulist   = alloc_i(UCAP);
    int* blist   = alloc_i(NCAND);
    int* elist_t = alloc_i(ET);
    int* elist_d = alloc_i(ED);
    // features
    ushort_t* x_dc   = alloc_h((size_t)UCAP * Hh);
    ushort_t* x_l    = alloc_h((size_t)NLN * Hh);
    float*    x_a    = alloc_f((size_t)Dd * Hh);
    ushort_t* e_did  = alloc_h((size_t)ED * Hh);
    ushort_t* e_took = alloc_h((size_t)ET * Hh);
    float*    qkvb   = alloc_f((size_t)Dd * 384);
    float*    cf     = alloc_f((size_t)eoff[NCANON]);
    int*      dflag  = alloc_i(8);

    const float* c_drug_floats  = cf + eoff[0];
    const float* c_lab_floats   = cf + eoff[1];
    const float* c_adm_floats   = cf + eoff[2];
    const float* c_did_floats   = cf + eoff[3];
    const float* c_took_floats  = cf + eoff[4];
    const float* c_drug_id_emb  = cf + eoff[5];
    const float* c_lab_id_emb   = cf + eoff[6];
    const float* c_drug_tok_emb = cf + eoff[7];
    const float* c_lab_tok_emb  = cf + eoff[8];
    const float* c_adm_tok_emb  = cf + eoff[9];
    const float* c_did_tok_emb  = cf + eoff[10];
    const float* c_took_tok_emb = cf + eoff[11];
    const float* c_drug_float_w = cf + eoff[12];
    const float* c_lab_float_w  = cf + eoff[13];
    const float* c_adm_float_w  = cf + eoff[14];
    const float* c_did_float_w  = cf + eoff[15];
    const float* c_took_float_w = cf + eoff[16];
    const float* c_drug_align   = cf + eoff[17];
    const float* c_lab_align    = cf + eoff[18];
    const float* c_adm_align    = cf + eoff[19];
    const float* c_did_align    = cf + eoff[20];
    const float* c_took_align   = cf + eoff[21];
    const float* c_gnn_msg      = cf + eoff[22];
    const float* c_gnn_self     = cf + eoff[23];
    const float* c_qkv_w        = cf + eoff[24];
    const float* c_qkv_b        = cf + eoff[25];
    const float* c_out_w        = cf + eoff[26];
    const float* c_out_b        = cf + eoff[27];
    const float* c_ln1          = cf + eoff[28];
    const float* c_ff1_w        = cf + eoff[29];
    const float* c_ff1_b        = cf + eoff[30];
    const float* c_ff2_w        = cf + eoff[31];
    const float* c_ff2_b        = cf + eoff[32];
    const float* c_ln2          = cf + eoff[33];
    const float* c_lp_w         = cf + eoff[34];

    // ---- canonicalize + graph prep ----
    k_probe<<<1, 64, 0, stream>>>((const unsigned*)d_in[41], dflag);
    k_canon<<<btot_blocks, 256, 0, stream>>>(cd, cf, dflag);
    hipMemsetAsync(map, 0, ZBLOCK * sizeof(int), stream);
    k_mark<<<ET / 256, 256, 0, stream>>>(took_dst, cand_idx, map);
    k_assign<<<(ND + 255) / 256, 256, 0, stream>>>(map, ulist, blist, nUB);
    k_counts<<<ET / 256, 256, 0, stream>>>(did_dst, did_src, took_dst, took_src, map,
                                           cnt_ld, cnt_a1, cnt_dc, cnt_a2);
    // CSR scans
    k_scan_blk<<<NB_T, 256, 0, stream>>>(cnt_dc, roff_t, bscr, UCAP);
    k_scan_top<<<1, 1024, 0, stream>>>(bscr, NB_T);
    k_scan_add<<<NB_T, 256, 0, stream>>>(roff_t, bscr, UCAP, ET);
    k_scan_blk<<<NB_D, 256, 0, stream>>>(cnt_ld, roff_d, bscr, NLN);
    k_scan_top<<<1, 1024, 0, stream>>>(bscr, NB_D);
    k_scan_add<<<NB_D, 256, 0, stream>>>(roff_d, bscr, NLN, ED);
    k_fill<<<ET / 256, 256, 0, stream>>>(did_src, did_dst, took_src, took_dst, map,
                                         roff_d, roff_t, cur_d, cur_t, elist_d, elist_t);

    // ---- embeddings ----
    k_embed<1,3,2,true,true><<<UCAP / 64, 64, 0, stream>>>(x_dc, 0, nUB, ulist,
        drug_node_id, c_drug_id_emb, drug_tokens, c_drug_tok_emb, c_drug_floats, c_drug_float_w, c_drug_align);
    k_embed<1,2,1,true,false><<<NLN / 64, 64, 0, stream>>>(x_l, NLN, nullptr, nullptr,
        lab_node_id, c_lab_id_emb, lab_tokens, c_lab_tok_emb, c_lab_floats, c_lab_float_w, c_lab_align);
    k_embed<0,4,3,false,false><<<1, 64, 0, stream>>>(x_a, Dd, nullptr, nullptr,
        nullptr, nullptr, adm_tokens, c_adm_tok_emb, c_adm_floats, c_adm_float_w, c_adm_align);
    k_embed<0,2,2,true,false><<<ED / 64, 64, 0, stream>>>(e_did, ED, nullptr, nullptr,
        nullptr, nullptr, did_tokens, c_did_tok_emb, c_did_floats, c_did_float_w, c_did_align);
    k_embed<0,2,1,true,false><<<ET / 64, 64, 0, stream>>>(e_took, ET, nullptr, nullptr,
        nullptr, nullptr, took_tokens, c_took_tok_emb, c_took_floats, c_took_float_w, c_took_align);

    const size_t HH = (size_t)Hh * Hh;

    // ---- GNN layer 1 (relu) ----
    hipMemsetAsync(S_a1, 0, 2 * (size_t)Dd * Hh * sizeof(float), stream);
    k_adm_did<<<128, 256, 0, stream>>>(did_src, did_dst, e_did, x_l, S_a1, ED / 128);
    k_adm_took<<<256, 256, 0, stream>>>(took_src, took_dst, e_took, x_dc, map, S_a2, ET / 256);
    k_gup<false><<<UCAP / 32, 128, 0, stream>>>(x_dc, x_a, e_took, roff_t, elist_t, 17,
        nullptr, nUB, 0, c_gnn_self + 1 * HH, c_gnn_msg + 1 * HH, 1);
    k_gup<false><<<NLN / 32, 128, 0, stream>>>(x_l, x_a, e_did, roff_d, elist_d, 15,
        nullptr, nullptr, NLN, c_gnn_self + 2 * HH, c_gnn_msg + 0 * HH, 1);
    k_xa<<<Dd, 128, 0, stream>>>(x_a, S_a1, S_a2, cnt_a1, cnt_a2,
        c_gnn_self + 0 * HH, c_gnn_msg + 2 * HH, c_gnn_msg + 3 * HH, 1);

    // ---- GNN layer 2 (no relu; lab update dead; drug update over B rows) ----
    const float* Ws1 = c_gnn_self + 3 * HH;
    const float* Wm1 = c_gnn_msg + 4 * HH;
    hipMemsetAsync(S_a1, 0, 2 * (size_t)Dd * Hh * sizeof(float), stream);
    k_adm_did<<<128, 256, 0, stream>>>(did_src, did_dst, e_did, x_l, S_a1, ED / 128);
    k_adm_took<<<256, 256, 0, stream>>>(took_src, took_dst, e_took, x_dc, map, S_a2, ET / 256);
    k_gup<true><<<(NCAND + 31) / 32, 128, 0, stream>>>(x_dc, x_a, e_took, roff_t, elist_t, 17,
        blist, nUB + 1, 0, Ws1 + 1 * HH, Wm1 + 1 * HH, 0);
    k_xa<<<Dd, 128, 0, stream>>>(x_a, S_a1, S_a2, cnt_a1, cnt_a2,
        Ws1 + 0 * HH, Wm1 + 2 * HH, Wm1 + 3 * HH, 0);

    // ---- transformer encoder on x_a ----
    for (int i = 0; i < L_ENC; i++) {
        k_qkv<<<Dd, 128, 0, stream>>>(x_a, qkvb, c_qkv_w + (size_t)i * Hh * 384, c_qkv_b + (size_t)i * 384);
        k_attn_out<<<Dd, 128, 0, stream>>>(qkvb, x_a, c_out_w + (size_t)i * HH,
                                           c_out_b + (size_t)i * Hh, c_ln1 + (size_t)i * 2 * Hh);
        k_ffln<<<Dd, 256, 0, stream>>>(x_a, c_ff1_w + (size_t)i * Hh * FF, c_ff1_b + (size_t)i * FF,
                                       c_ff2_w + (size_t)i * FF * Hh, c_ff2_b + (size_t)i * Hh,
                                       c_ln2 + (size_t)i * 2 * Hh);
    }

    // ---- logits ----
    k_logits<<<Dd - 1, 256, 0, stream>>>(x_dc, map, x_a, c_lp_w, cand_idx, (float*)d_out);
}

// Round 6
// 2191.542 us; speedup vs baseline: 1.7439x; 1.7439x over previous
//
#include <hip/hip_runtime.h>
#include <hip/hip_bf16.h>

typedef unsigned short ushort_t;

#define DEV __device__ __forceinline__

constexpr int Dd  = 64;
constexpr int VD  = 4525;
constexpr int VL  = 753;
constexpr int ND  = Dd * VD;     // 289600
constexpr int NLN = Dd * VL;     // 48192
constexpr int Hh  = 128;
constexpr int EMB = 10;
constexpr int TV  = 100;
constexpr int NH  = 8, HD = 16;
constexpr int L_ENC = 6, FF = 2048;
constexpr int GL  = 2;
constexpr int ED  = 32768, ET = 131072;
constexpr int KK  = 256;
constexpr int NCAND = (Dd - 1) * KK;       // 16128
constexpr int UCAP  = ET + NCAND;          // 147200
constexpr int NCANON = 35;
constexpr int NB_T = (UCAP + 255) / 256;
constexpr int NB_D = (NLN + 255) / 256;

DEV float bf(ushort_t u) { return __uint_as_float(((unsigned)u) << 16); }
DEV float bflo(unsigned u) { return __uint_as_float(u << 16); }
DEV float bfhi(unsigned u) { return __uint_as_float(u & 0xffff0000u); }
DEV ushort_t f2bf(float f) {
    unsigned u = __float_as_uint(f);
    u += 0x7fffu + ((u >> 16) & 1u);
    return (ushort_t)(u >> 16);
}

// ---------------------------------------------------------------------------
__global__ __launch_bounds__(64)
void k_probe(const unsigned* __restrict__ w, int* __restrict__ flag)
{
    int tid = threadIdx.x;
    int c = 0;
    #pragma unroll
    for (int i = 0; i < 16; i++) c += (w[tid * 16 + i] >> 14) & 1;
    #pragma unroll
    for (int o = 32; o; o >>= 1) c += __shfl_xor(c, o);
    if (tid == 0) *flag = (c > 256) ? 1 : 0;
}

struct CanonDesc {
    const void* src[NCANON];
    int doff[NCANON];
    int bend[NCANON];
    int n[NCANON];
};

__global__ __launch_bounds__(256)
void k_canon(CanonDesc cd, float* __restrict__ dst, const int* __restrict__ flag)
{
    int b = blockIdx.x;
    int t = 0;
    while (t < NCANON && b >= cd.bend[t]) t++;
    if (t >= NCANON) return;
    int bstart = (t == 0) ? 0 : cd.bend[t - 1];
    int i = (b - bstart) * 256 + threadIdx.x;
    if (i >= cd.n[t]) return;
    float v = (*flag) ? ((const float*)cd.src[t])[i]
                      : bf(((const ushort_t*)cd.src[t])[i]);
    dst[cd.doff[t] + i] = v;
}

// ---------------------------------------------------------------------------
__global__ __launch_bounds__(256)
void k_mark(const int* __restrict__ took_dst, const int* __restrict__ cand,
            int* __restrict__ map)
{
    int g = blockIdx.x * 256 + threadIdx.x;
    if (g < ET) atomicOr(&map[took_dst[g]], 1);
    if (g < NCAND) {
        int d = g >> 8;
        atomicOr(&map[d * VD + cand[g]], 2);
    }
}

__global__ __launch_bounds__(256)
void k_assign(int* __restrict__ map, int* __restrict__ ulist, int* __restrict__ blist,
              int* __restrict__ nUB)
{
    int g = blockIdx.x * 256 + threadIdx.x;
    if (g >= ND) return;
    int m = map[g];
    if (m) {
        int s = atomicAdd(&nUB[0], 1);
        ulist[s] = g;
        map[g] = (s << 2) | m;
        if (m & 2) {
            int b = atomicAdd(&nUB[1], 1);
            blist[b] = s;
        }
    }
}

__global__ __launch_bounds__(256)
void k_counts(const int* __restrict__ did_dst, const int* __restrict__ did_src,
              const int* __restrict__ took_dst, const int* __restrict__ took_src,
              const int* __restrict__ map,
              int* __restrict__ cnt_ld, int* __restrict__ cnt_a1,
              int* __restrict__ cnt_dc, int* __restrict__ cnt_a2)
{
    int g = blockIdx.x * 256 + threadIdx.x;
    if (g < ED) {
        atomicAdd(&cnt_ld[did_dst[g]], 1);
        atomicAdd(&cnt_a1[did_src[g]], 1);
    }
    if (g < ET) {
        atomicAdd(&cnt_dc[map[took_dst[g]] >> 2], 1);
        atomicAdd(&cnt_a2[took_src[g]], 1);
    }
}

// ---------------------------------------------------------------------------
// scans
__global__ __launch_bounds__(256)
void k_scan_blk(const int* __restrict__ cnt, int* __restrict__ excl,
                int* __restrict__ btot, int n)
{
    __shared__ int s[256];
    int tid = threadIdx.x;
    int g = blockIdx.x * 256 + tid;
    int v = (g < n) ? cnt[g] : 0;
    s[tid] = v;
    __syncthreads();
    for (int o = 1; o < 256; o <<= 1) {
        int t = (tid >= o) ? s[tid - o] : 0;
        __syncthreads();
        s[tid] += t;
        __syncthreads();
    }
    if (g < n) excl[g] = s[tid] - v;
    if (tid == 255) btot[blockIdx.x] = s[255];
}

__global__ __launch_bounds__(1024)
void k_scan_top(int* __restrict__ btot, int nb)
{
    __shared__ int s[1024];
    int tid = threadIdx.x;
    int v = (tid < nb) ? btot[tid] : 0;
    s[tid] = v;
    __syncthreads();
    for (int o = 1; o < 1024; o <<= 1) {
        int t = (tid >= o) ? s[tid - o] : 0;
        __syncthreads();
        s[tid] += t;
        __syncthreads();
    }
    if (tid < nb) btot[tid] = s[tid] - v;
}

__global__ __launch_bounds__(256)
void k_scan_add(int* __restrict__ roff, const int* __restrict__ btot, int n, int total)
{
    int g = blockIdx.x * 256 + threadIdx.x;
    if (g < n) roff[g] += btot[blockIdx.x];
    if (g == 0) roff[n] = total;
}

// 64-entry exclusive scans for admission src offsets
__global__ __launch_bounds__(64)
void k_scan64(const int* __restrict__ c1, const int* __restrict__ c2,
              int* __restrict__ r1, int* __restrict__ r2)
{
    int tid = threadIdx.x;
    int v1 = c1[tid], v2 = c2[tid];
    int s1 = v1, s2 = v2;
    for (int o = 1; o < 64; o <<= 1) {
        int t1 = __shfl_up(s1, o), t2 = __shfl_up(s2, o);
        if (tid >= o) { s1 += t1; s2 += t2; }
    }
    r1[tid] = s1 - v1;
    r2[tid] = s2 - v2;
}

// fill all edge lists
__global__ __launch_bounds__(256)
void k_fill(const int* __restrict__ did_src, const int* __restrict__ did_dst,
            const int* __restrict__ took_src, const int* __restrict__ took_dst,
            const int* __restrict__ map,
            const int* __restrict__ roff_d, const int* __restrict__ roff_t,
            const int* __restrict__ roff_a1, const int* __restrict__ roff_a2,
            int* __restrict__ cur_d, int* __restrict__ cur_t,
            int* __restrict__ cur_a1, int* __restrict__ cur_a2,
            int* __restrict__ elist_d, int* __restrict__ elist_t,
            int* __restrict__ didA, int* __restrict__ didB,
            int* __restrict__ tookA, int* __restrict__ tookB)
{
    int g = blockIdx.x * 256 + threadIdx.x;
    if (g < ED) {
        int d = did_dst[g], s = did_src[g];
        int pos = roff_d[d] + atomicAdd(&cur_d[d], 1);
        elist_d[pos] = (s << 15) | g;
        int pa = roff_a1[s] + atomicAdd(&cur_a1[s], 1);
        didA[pa] = (s << 16) | d;
        didB[pa] = g;
    }
    if (g < ET) {
        int s = took_src[g];
        int slot = map[took_dst[g]] >> 2;
        int pos = roff_t[slot] + atomicAdd(&cur_t[slot], 1);
        elist_t[pos] = (s << 17) | g;
        int pa = roff_a2[s] + atomicAdd(&cur_a2[s], 1);
        tookA[pa] = (s << 18) | slot;
        tookB[pa] = g;
    }
}

// ---------------------------------------------------------------------------
// segmented src-sum over sorted edge list. lane j handles cols 2j,2j+1.
// DUAL: also accumulate e-feature rows into Se.
template<bool DUAL>
__global__ __launch_bounds__(64)
void k_srcsum(const int* __restrict__ lA, const int* __restrict__ lB,
              const ushort_t* __restrict__ xrows, const ushort_t* __restrict__ erows,
              int shift, float* __restrict__ Sx, float* __restrict__ Se, int nedge)
{
    int lane = threadIdx.x;
    int c0 = lane * 2;
    int base = blockIdx.x * 256;
    int end = min(base + 256, nedge);
    int mask = (1 << shift) - 1;
    float ax0 = 0.f, ax1 = 0.f, ae0 = 0.f, ae1 = 0.f;
    int cur = -1;
    for (int i = base; i < end; i++) {
        int pk = lA[i];
        int s = pk >> shift, row = pk & mask;
        if (s != cur) {
            if (cur >= 0) {
                unsafeAtomicAdd(&Sx[cur * Hh + c0], ax0);
                unsafeAtomicAdd(&Sx[cur * Hh + c0 + 1], ax1);
                if (DUAL) {
                    unsafeAtomicAdd(&Se[cur * Hh + c0], ae0);
                    unsafeAtomicAdd(&Se[cur * Hh + c0 + 1], ae1);
                }
            }
            cur = s; ax0 = ax1 = ae0 = ae1 = 0.f;
        }
        unsigned xx = *reinterpret_cast<const unsigned*>(xrows + (size_t)row * Hh + c0);
        ax0 += bflo(xx); ax1 += bfhi(xx);
        if (DUAL) {
            int e = lB[i];
            unsigned ee = *reinterpret_cast<const unsigned*>(erows + (size_t)e * Hh + c0);
            ae0 += bflo(ee); ae1 += bfhi(ee);
        }
    }
    if (cur >= 0) {
        unsafeAtomicAdd(&Sx[cur * Hh + c0], ax0);
        unsafeAtomicAdd(&Sx[cur * Hh + c0 + 1], ax1);
        if (DUAL) {
            unsafeAtomicAdd(&Se[cur * Hh + c0], ae0);
            unsafeAtomicAdd(&Se[cur * Hh + c0 + 1], ae1);
        }
    }
}

// ---------------------------------------------------------------------------
template<int NID, int NTOK, int NF, bool BF16OUT, bool INDIRECT>
__global__ __launch_bounds__(64)
void k_embed(void* __restrict__ out, int n_static, const int* __restrict__ n_dyn,
             const int* __restrict__ ulist,
             const int* __restrict__ id_idx, const float* __restrict__ id_emb,
             const int* __restrict__ tokens, const float* __restrict__ tok_emb,
             const float* __restrict__ floats_, const float* __restrict__ float_w,
             const float* __restrict__ alignf)
{
    constexpr int L = (NID + NTOK + 1) * EMB;
    int slot = blockIdx.x * 64 + threadIdx.x;
    int n = INDIRECT ? *n_dyn : n_static;
    if (slot >= n) return;
    int node = INDIRECT ? ulist[slot] : slot;

    float vec[L];
    int p = 0;
    if constexpr (NID != 0) {
        const float* pe = id_emb + (size_t)id_idx[node] * EMB;
        #pragma unroll
        for (int e = 0; e < EMB; e++) vec[p++] = pe[e];
    }
    #pragma unroll
    for (int t = 0; t < NTOK; t++) {
        const float* pe = tok_emb + ((size_t)t * TV + tokens[node * NTOK + t]) * EMB;
        #pragma unroll
        for (int e = 0; e < EMB; e++) vec[p++] = pe[e];
    }
    {
        float fv[NF];
        #pragma unroll
        for (int f = 0; f < NF; f++) fv[f] = floats_[node * NF + f];
        #pragma unroll
        for (int e = 0; e < EMB; e++) {
            float a = 0.f;
            #pragma unroll
            for (int f = 0; f < NF; f++) a = fmaf(fv[f], float_w[f * EMB + e], a);
            vec[p++] = a;
        }
    }

    #pragma unroll 1
    for (int j = 0; j < Hh; j += 4) {
        float a0 = 0.f, a1 = 0.f, a2 = 0.f, a3 = 0.f;
        #pragma unroll
        for (int i = 0; i < L; i++) {
            const float* w = alignf + i * Hh + j;
            a0 = fmaf(vec[i], w[0], a0);
            a1 = fmaf(vec[i], w[1], a1);
            a2 = fmaf(vec[i], w[2], a2);
            a3 = fmaf(vec[i], w[3], a3);
        }
        if constexpr (BF16OUT) {
            unsigned lo = (unsigned)f2bf(a0) | ((unsigned)f2bf(a1) << 16);
            unsigned hi = (unsigned)f2bf(a2) | ((unsigned)f2bf(a3) << 16);
            uint2 v; v.x = lo; v.y = hi;
            *reinterpret_cast<uint2*>((ushort_t*)out + (size_t)slot * Hh + j) = v;
        } else {
            float4 r4; r4.x = a0; r4.y = a1; r4.z = a2; r4.w = a3;
            *reinterpret_cast<float4*>((float*)out + (size_t)slot * Hh + j) = r4;
        }
    }
}

// ---------------------------------------------------------------------------
// Fused gather + mean + GNN update
template<bool INDIRECT>
__global__ __launch_bounds__(128)
void k_gup(ushort_t* __restrict__ X, const float* __restrict__ xa,
           const ushort_t* __restrict__ ef,
           const int* __restrict__ roff, const int* __restrict__ elist, int sshift,
           const int* __restrict__ rows_list, const int* __restrict__ n_dyn, int n_static,
           const float* __restrict__ Wself, const float* __restrict__ Wmsg,
           int do_relu)
{
    __shared__ float Xs[32 * 130];
    __shared__ float Ss[32 * 130];
    __shared__ int rowid[32];
    int tid = threadIdx.x;
    int r0 = blockIdx.x * 32;
    int n = n_dyn ? *n_dyn : n_static;
    if (tid < 32) {
        int row = r0 + tid;
        rowid[tid] = (row < n) ? (INDIRECT ? rows_list[row] : row) : -1;
    }
    __syncthreads();

    for (int idx = tid; idx < 32 * 128; idx += 128) {
        int r = idx >> 7, c = idx & 127;
        int rr = rowid[r];
        Xs[r * 130 + c] = (rr >= 0) ? bf(X[(size_t)rr * Hh + c]) : 0.f;
    }

    int wid = tid >> 6, lane = tid & 63;
    int c0 = lane * 2;
    int emask = (1 << sshift) - 1;
    for (int r = wid; r < 32; r += 2) {
        int rr = rowid[r];
        float a0 = 0.f, a1 = 0.f, invd = 0.f;
        if (rr >= 0) {
            int e0 = roff[rr], e1 = roff[rr + 1];
            invd = 1.f / fmaxf((float)(e1 - e0), 1.f);
            for (int ei = e0; ei < e1; ei++) {
                int pk = elist[ei];
                int s = pk >> sshift, e = pk & emask;
                const float* xr = xa + s * Hh + c0;
                unsigned ee = *reinterpret_cast<const unsigned*>(ef + (size_t)e * Hh + c0);
                a0 += xr[0] + bflo(ee);
                a1 += xr[1] + bfhi(ee);
            }
        }
        Ss[r * 130 + c0]     = a0 * invd;
        Ss[r * 130 + c0 + 1] = a1 * invd;
    }
    __syncthreads();

    int jg = tid & 15, rg = tid >> 4;
    int j0 = jg * 8, rr0 = rg * 4;
    float acc[4][8];
    #pragma unroll
    for (int i = 0; i < 4; i++)
        #pragma unroll
        for (int c = 0; c < 8; c++) acc[i][c] = 0.f;

    #pragma unroll 2
    for (int k = 0; k < 128; k++) {
        float xv[4], sv[4];
        #pragma unroll
        for (int i = 0; i < 4; i++) {
            xv[i] = Xs[(rr0 + i) * 130 + k];
            sv[i] = Ss[(rr0 + i) * 130 + k];
        }
        const float* w1p = Wself + k * Hh + j0;
        const float* w2p = Wmsg  + k * Hh + j0;
        float4 w1a = *reinterpret_cast<const float4*>(w1p);
        float4 w1b = *reinterpret_cast<const float4*>(w1p + 4);
        float4 w2a = *reinterpret_cast<const float4*>(w2p);
        float4 w2b = *reinterpret_cast<const float4*>(w2p + 4);
        float w1[8] = {w1a.x, w1a.y, w1a.z, w1a.w, w1b.x, w1b.y, w1b.z, w1b.w};
        float w2[8] = {w2a.x, w2a.y, w2a.z, w2a.w, w2b.x, w2b.y, w2b.z, w2b.w};
        #pragma unroll
        for (int i = 0; i < 4; i++)
            #pragma unroll
            for (int c = 0; c < 8; c++)
                acc[i][c] = fmaf(xv[i], w1[c], fmaf(sv[i], w2[c], acc[i][c]));
    }

    #pragma unroll
    for (int i = 0; i < 4; i++) {
        int rr = rowid[rr0 + i];
        if (rr < 0) continue;
        float o[8];
        #pragma unroll
        for (int c = 0; c < 8; c++) {
            o[c] = acc[i][c];
            if (do_relu) o[c] = fmaxf(o[c], 0.f);
        }
        uint4 v;
        v.x = (unsigned)f2bf(o[0]) | ((unsigned)f2bf(o[1]) << 16);
        v.y = (unsigned)f2bf(o[2]) | ((unsigned)f2bf(o[3]) << 16);
        v.z = (unsigned)f2bf(o[4]) | ((unsigned)f2bf(o[5]) << 16);
        v.w = (unsigned)f2bf(o[6]) | ((unsigned)f2bf(o[7]) << 16);
        *reinterpret_cast<uint4*>(X + (size_t)rr * Hh + j0) = v;
    }
}

// ---------------------------------------------------------------------------
__global__ __launch_bounds__(128)
void k_xa(float* __restrict__ x_a,
          const float* __restrict__ Sx1, const float* __restrict__ E1,
          const float* __restrict__ Sx2, const float* __restrict__ E2,
          const int* __restrict__ c1, const int* __restrict__ c2,
          const float* __restrict__ Wself, const float* __restrict__ Wm1,
          const float* __restrict__ Wm2, int do_relu)
{
    int r = blockIdx.x, tid = threadIdx.x;
    __shared__ float xr[128], a1[128], a2[128];
    float i1 = 1.f / fmaxf((float)c1[r], 1.f);
    float i2 = 1.f / fmaxf((float)c2[r], 1.f);
    xr[tid] = x_a[r * Hh + tid];
    a1[tid] = (Sx1[r * Hh + tid] + E1[r * Hh + tid]) * i1;
    a2[tid] = (Sx2[r * Hh + tid] + E2[r * Hh + tid]) * i2;
    __syncthreads();
    float acc = 0.f;
    for (int k = 0; k < 128; k++) {
        acc = fmaf(xr[k], Wself[k * Hh + tid], acc);
        acc = fmaf(a1[k], Wm1[k * Hh + tid], acc);
        acc = fmaf(a2[k], Wm2[k * Hh + tid], acc);
    }
    if (do_relu) acc = fmaxf(acc, 0.f);
    x_a[r * Hh + tid] = acc;
}

// ---------------------------------------------------------------------------
// Transformer
__global__ __launch_bounds__(128)
void k_qkv(const float* __restrict__ h, float* __restrict__ qkv,
           const float* __restrict__ W, const float* __restrict__ b)
{
    int r = blockIdx.x, tid = threadIdx.x;
    __shared__ float hr[128];
    hr[tid] = h[r * Hh + tid];
    __syncthreads();
    #pragma unroll
    for (int c0 = 0; c0 < 3; c0++) {
        int c = c0 * 128 + tid;
        float acc = b[c];
        for (int k = 0; k < 128; k++) acc = fmaf(hr[k], W[k * 384 + c], acc);
        qkv[r * 384 + c] = acc;
    }
}

DEV float blocksum128(float v, float* red)
{
    #pragma unroll
    for (int o = 32; o; o >>= 1) v += __shfl_xor(v, o);
    int wid = threadIdx.x >> 6;
    __syncthreads();
    if ((threadIdx.x & 63) == 0) red[wid] = v;
    __syncthreads();
    return red[0] + red[1];
}

// fused attention + out-proj + residual + LN1
__global__ __launch_bounds__(128)
void k_attn_out(const float* __restrict__ qkv, float* __restrict__ h,
                const float* __restrict__ Wout, const float* __restrict__ bout,
                const float* __restrict__ ln)
{
    int q = blockIdx.x, tid = threadIdx.x;
    __shared__ float sc[NH * Dd];
    __shared__ float o_r[128];
    __shared__ float red[2];
    int hh = tid >> 4;
    int k0 = (tid & 15) * 4;
    const float* qrow = qkv + q * 384 + hh * HD;
    #pragma unroll
    for (int kk = k0; kk < k0 + 4; kk++) {
        const float* krow = qkv + kk * 384 + 128 + hh * HD;
        float s = 0.f;
        #pragma unroll
        for (int d = 0; d < HD; d++) s = fmaf(qrow[d], krow[d], s);
        sc[hh * Dd + kk] = s * 0.25f + (kk <= q ? 0.f : -1e9f);
    }
    __syncthreads();
    float m = -1e30f;
    for (int k = 0; k < Dd; k++) m = fmaxf(m, sc[hh * Dd + k]);
    float l = 0.f;
    for (int k = 0; k < Dd; k++) l += __expf(sc[hh * Dd + k] - m);
    float inv_l = 1.f / l;
    __syncthreads();
    #pragma unroll
    for (int kk = k0; kk < k0 + 4; kk++)
        sc[hh * Dd + kk] = __expf(sc[hh * Dd + kk] - m) * inv_l;
    __syncthreads();
    int d = tid & 15;
    float o0 = 0.f, o1 = 0.f, o2 = 0.f, o3 = 0.f;
    for (int k = 0; k < Dd; k += 4) {
        o0 = fmaf(sc[hh * Dd + k],     qkv[(k)     * 384 + 256 + hh * HD + d], o0);
        o1 = fmaf(sc[hh * Dd + k + 1], qkv[(k + 1) * 384 + 256 + hh * HD + d], o1);
        o2 = fmaf(sc[hh * Dd + k + 2], qkv[(k + 2) * 384 + 256 + hh * HD + d], o2);
        o3 = fmaf(sc[hh * Dd + k + 3], qkv[(k + 3) * 384 + 256 + hh * HD + d], o3);
    }
    o_r[hh * HD + d] = (o0 + o1) + (o2 + o3);
    __syncthreads();
    float a0 = bout[tid], a1 = 0.f, a2 = 0.f, a3 = 0.f;
    for (int k = 0; k < 128; k += 4) {
        a0 = fmaf(o_r[k],     Wout[(k)     * Hh + tid], a0);
        a1 = fmaf(o_r[k + 1], Wout[(k + 1) * Hh + tid], a1);
        a2 = fmaf(o_r[k + 2], Wout[(k + 2) * Hh + tid], a2);
        a3 = fmaf(o_r[k + 3], Wout[(k + 3) * Hh + tid], a3);
    }
    float x = h[q * Hh + tid] + (a0 + a1) + (a2 + a3);
    float mu = blocksum128(x, red) * (1.f / 128.f);
    float dx = x - mu;
    float var = blocksum128(dx * dx, red) * (1.f / 128.f);
    h[q * Hh + tid] = ln[tid] * dx * (1.f / sqrtf(var + 1e-5f)) + ln[128 + tid];
}

// ff1: grid (Dd, 2), 256 thr; thread computes 4 cols via float4, ILP 4.
__global__ __launch_bounds__(256)
void k_ff1(const float* __restrict__ h, float* __restrict__ fbuf,
           const float* __restrict__ W1, const float* __restrict__ b1)
{
    int r = blockIdx.x;
    int c0 = blockIdx.y * 1024 + threadIdx.x * 4;
    __shared__ float hr[128];
    if (threadIdx.x < 128) hr[threadIdx.x] = h[r * Hh + threadIdx.x];
    __syncthreads();
    float4 bb = *reinterpret_cast<const float4*>(b1 + c0);
    float a0 = bb.x, a1 = bb.y, a2 = bb.z, a3 = bb.w;
    #pragma unroll 4
    for (int k = 0; k < 128; k++) {
        float hk = hr[k];
        float4 w = *reinterpret_cast<const float4*>(W1 + (size_t)k * FF + c0);
        a0 = fmaf(hk, w.x, a0);
        a1 = fmaf(hk, w.y, a1);
        a2 = fmaf(hk, w.z, a2);
        a3 = fmaf(hk, w.w, a3);
    }
    float4 o;
    o.x = fmaxf(a0, 0.f); o.y = fmaxf(a1, 0.f);
    o.z = fmaxf(a2, 0.f); o.w = fmaxf(a3, 0.f);
    *reinterpret_cast<float4*>(fbuf + (size_t)r * FF + c0) = o;
}

// ff2 partial: grid (Dd, 16), 128 thr; K-chunk of 128 per block.
__global__ __launch_bounds__(128)
void k_ff2p(const float* __restrict__ fbuf, float* __restrict__ part,
            const float* __restrict__ W2)
{
    int r = blockIdx.x, pi = blockIdx.y, tid = threadIdx.x;
    int kc = pi * 128;
    const float* f = fbuf + (size_t)r * FF + kc;
    float a0 = 0.f, a1 = 0.f, a2 = 0.f, a3 = 0.f;
    for (int k = 0; k < 128; k += 4) {
        a0 = fmaf(f[k],     W2[(size_t)(kc + k)     * Hh + tid], a0);
        a1 = fmaf(f[k + 1], W2[(size_t)(kc + k + 1) * Hh + tid], a1);
        a2 = fmaf(f[k + 2], W2[(size_t)(kc + k + 2) * Hh + tid], a2);
        a3 = fmaf(f[k + 3], W2[(size_t)(kc + k + 3) * Hh + tid], a3);
    }
    part[(size_t)(r * 16 + pi) * Hh + tid] = (a0 + a1) + (a2 + a3);
}

__global__ __launch_bounds__(128)
void k_ln2(float* __restrict__ h, const float* __restrict__ part,
           const float* __restrict__ b2, const float* __restrict__ ln)
{
    int r = blockIdx.x, tid = threadIdx.x;
    __shared__ float red[2];
    float acc = b2[tid];
    #pragma unroll
    for (int pi = 0; pi < 16; pi++) acc += part[(size_t)(r * 16 + pi) * Hh + tid];
    float x = h[r * Hh + tid] + acc;
    float mu = blocksum128(x, red) * (1.f / 128.f);
    float dx = x - mu;
    float var = blocksum128(dx * dx, red) * (1.f / 128.f);
    h[r * Hh + tid] = ln[tid] * dx * (1.f / sqrtf(var + 1e-5f)) + ln[128 + tid];
}

// ---------------------------------------------------------------------------
__global__ __launch_bounds__(256)
void k_logits(const ushort_t* __restrict__ x_dc, const int* __restrict__ map,
              const float* __restrict__ h, const float* __restrict__ lp,
              const int* __restrict__ cand, float* __restrict__ out)
{
    int d = blockIdx.x;
    int tid = threadIdx.x, lane = tid & 63, w = tid >> 6;
    __shared__ float wv[128];
    if (tid < 128) wv[tid] = h[d * Hh + tid] * lp[tid];
    __syncthreads();
    for (int k = w; k < KK; k += 4) {
        int slot = map[d * VD + cand[d * KK + k]] >> 2;
        const ushort_t* row = x_dc + (size_t)slot * Hh;
        float v = bf(row[lane]) * wv[lane] + bf(row[lane + 64]) * wv[lane + 64];
        #pragma unroll
        for (int o = 32; o; o >>= 1) v += __shfl_xor(v, o);
        if (lane == 0) out[d * KK + k] = v;
    }
}

// ---------------------------------------------------------------------------
extern "C" void kernel_launch(void* const* d_in, const int* in_sizes, int n_in,
                              void* d_out, int out_size, void* d_ws, size_t ws_size,
                              hipStream_t stream)
{
    (void)in_sizes; (void)n_in; (void)out_size; (void)ws_size;

    const int* drug_tokens  = (const int*)d_in[0];
    const int* drug_node_id = (const int*)d_in[1];
    const int* lab_tokens   = (const int*)d_in[3];
    const int* lab_node_id  = (const int*)d_in[4];
    const int* adm_tokens   = (const int*)d_in[6];
    const int* did_tokens   = (const int*)d_in[8];
    const int* did_src      = (const int*)d_in[10];
    const int* did_dst      = (const int*)d_in[11];
    const int* took_tokens  = (const int*)d_in[12];
    const int* took_src     = (const int*)d_in[14];
    const int* took_dst     = (const int*)d_in[15];
    const int* cand_idx     = (const int*)d_in[16];

    const int cidx[NCANON] = {2,5,7,9,13, 17,18,19,20,21,22,23, 24,25,26,27,28,
                              29,30,31,32,33, 34,35, 36,37,38,39,40,41,42,43,44,45,46};
    const int cn[NCANON] = {
        ND*2, NLN*1, Dd*3, ED*2, ET*1,
        VD*EMB, VL*EMB, 3*TV*EMB, 2*TV*EMB, 4*TV*EMB, 2*TV*EMB, 2*TV*EMB,
        2*EMB, 1*EMB, 3*EMB, 2*EMB, 1*EMB,
        5*EMB*Hh, 4*EMB*Hh, 5*EMB*Hh, 3*EMB*Hh, 3*EMB*Hh,
        GL*4*Hh*Hh, GL*3*Hh*Hh,
        L_ENC*Hh*3*Hh, L_ENC*3*Hh, L_ENC*Hh*Hh, L_ENC*Hh, L_ENC*2*Hh,
        L_ENC*Hh*FF, L_ENC*FF, L_ENC*FF*Hh, L_ENC*Hh, L_ENC*2*Hh, Hh
    };
    CanonDesc cd;
    int eoff[NCANON + 1];
    int btot_blocks = 0;
    {
        int e = 0;
        for (int t = 0; t < NCANON; t++) {
            cd.src[t] = d_in[cidx[t]];
            cd.n[t] = cn[t];
            eoff[t] = e;
            cd.doff[t] = e;
            e = (e + cn[t] + 7) & ~7;
            btot_blocks += (cn[t] + 255) / 256;
            cd.bend[t] = btot_blocks;
        }
        eoff[NCANON] = e;
    }

    // ---- workspace carve ----
    char* p = (char*)d_ws;
    auto alloc_f = [&](size_t n) -> float*    { float* r = (float*)p;    p += n * sizeof(float); return r; };
    auto alloc_h = [&](size_t n) -> ushort_t* { ushort_t* r = (ushort_t*)p; p += n * sizeof(ushort_t); return r; };
    auto alloc_i = [&](size_t n) -> int*      { int* r = (int*)p;        p += n * sizeof(int); return r; };

    // zero-once block
    int* map    = alloc_i(ND);
    int* cnt_dc = alloc_i(UCAP);
    int* cnt_ld = alloc_i(NLN);
    int* cnt_a1 = alloc_i(64);
    int* cnt_a2 = alloc_i(64);
    int* nUB    = alloc_i(8);
    int* cur_t  = alloc_i(UCAP);
    int* cur_d  = alloc_i(NLN);
    int* cur_a1 = alloc_i(64);
    int* cur_a2 = alloc_i(64);
    float* E_did  = alloc_f((size_t)Dd * Hh);
    float* E_took = alloc_f((size_t)Dd * Hh);
    const size_t ZBLOCK = (size_t)ND + UCAP + NLN + 64 + 64 + 8 + UCAP + NLN + 64 + 64
                        + (size_t)Dd * Hh * 2;
    // per-layer zero block
    float* Sx_did  = alloc_f((size_t)Dd * Hh);
    float* Sx_took = alloc_f((size_t)Dd * Hh);
    // CSR
    int* roff_t  = alloc_i(UCAP + 8);
    int* roff_d  = alloc_i(NLN + 8);
    int* roff_a1 = alloc_i(72);
    int* roff_a2 = alloc_i(72);
    int* bscr    = alloc_i(1024);
    int* ulist   = alloc_i(UCAP);
    int* blist   = alloc_i(NCAND);
    int* elist_t = alloc_i(ET);
    int* elist_d = alloc_i(ED);
    int* tookA   = alloc_i(ET);
    int* tookB   = alloc_i(ET);
    int* didA    = alloc_i(ED);
    int* didB    = alloc_i(ED);
    // features
    ushort_t* x_dc   = alloc_h((size_t)UCAP * Hh);
    ushort_t* x_l    = alloc_h((size_t)NLN * Hh);
    float*    x_a    = alloc_f((size_t)Dd * Hh);
    ushort_t* e_did  = alloc_h((size_t)ED * Hh);
    ushort_t* e_took = alloc_h((size_t)ET * Hh);
    float*    qkvb   = alloc_f((size_t)Dd * 384);
    float*    fbuf   = alloc_f((size_t)Dd * FF);
    float*    part   = alloc_f((size_t)Dd * 16 * Hh);
    float*    cf     = alloc_f((size_t)eoff[NCANON]);
    int*      dflag  = alloc_i(8);

    const float* c_drug_floats  = cf + eoff[0];
    const float* c_lab_floats   = cf + eoff[1];
    const float* c_adm_floats   = cf + eoff[2];
    const float* c_did_floats   = cf + eoff[3];
    const float* c_took_floats  = cf + eoff[4];
    const float* c_drug_id_emb  = cf + eoff[5];
    const float* c_lab_id_emb   = cf + eoff[6];
    const float* c_drug_tok_emb = cf + eoff[7];
    const float* c_lab_tok_emb  = cf + eoff[8];
    const float* c_adm_tok_emb  = cf + eoff[9];
    const float* c_did_tok_emb  = cf + eoff[10];
    const float* c_took_tok_emb = cf + eoff[11];
    const float* c_drug_float_w = cf + eoff[12];
    const float* c_lab_float_w  = cf + eoff[13];
    const float* c_adm_float_w  = cf + eoff[14];
    const float* c_did_float_w  = cf + eoff[15];
    const float* c_took_float_w = cf + eoff[16];
    const float* c_drug_align   = cf + eoff[17];
    const float* c_lab_align    = cf + eoff[18];
    const float* c_adm_align    = cf + eoff[19];
    const float* c_did_align    = cf + eoff[20];
    const float* c_took_align   = cf + eoff[21];
    const float* c_gnn_msg      = cf + eoff[22];
    const float* c_gnn_self     = cf + eoff[23];
    const float* c_qkv_w        = cf + eoff[24];
    const float* c_qkv_b        = cf + eoff[25];
    const float* c_out_w        = cf + eoff[26];
    const float* c_out_b        = cf + eoff[27];
    const float* c_ln1          = cf + eoff[28];
    const float* c_ff1_w        = cf + eoff[29];
    const float* c_ff1_b        = cf + eoff[30];
    const float* c_ff2_w        = cf + eoff[31];
    const float* c_ff2_b        = cf + eoff[32];
    const float* c_ln2          = cf + eoff[33];
    const float* c_lp_w         = cf + eoff[34];

    // ---- canonicalize + graph prep ----
    k_probe<<<1, 64, 0, stream>>>((const unsigned*)d_in[41], dflag);
    k_canon<<<btot_blocks, 256, 0, stream>>>(cd, cf, dflag);
    hipMemsetAsync(map, 0, ZBLOCK * sizeof(int), stream);
    k_mark<<<ET / 256, 256, 0, stream>>>(took_dst, cand_idx, map);
    k_assign<<<(ND + 255) / 256, 256, 0, stream>>>(map, ulist, blist, nUB);
    k_counts<<<ET / 256, 256, 0, stream>>>(did_dst, did_src, took_dst, took_src, map,
                                           cnt_ld, cnt_a1, cnt_dc, cnt_a2);
    k_scan_blk<<<NB_T, 256, 0, stream>>>(cnt_dc, roff_t, bscr, UCAP);
    k_scan_top<<<1, 1024, 0, stream>>>(bscr, NB_T);
    k_scan_add<<<NB_T, 256, 0, stream>>>(roff_t, bscr, UCAP, ET);
    k_scan_blk<<<NB_D, 256, 0, stream>>>(cnt_ld, roff_d, bscr, NLN);
    k_scan_top<<<1, 1024, 0, stream>>>(bscr, NB_D);
    k_scan_add<<<NB_D, 256, 0, stream>>>(roff_d, bscr, NLN, ED);
    k_scan64<<<1, 64, 0, stream>>>(cnt_a1, cnt_a2, roff_a1, roff_a2);
    k_fill<<<ET / 256, 256, 0, stream>>>(did_src, did_dst, took_src, took_dst, map,
                                         roff_d, roff_t, roff_a1, roff_a2,
                                         cur_d, cur_t, cur_a1, cur_a2,
                                         elist_d, elist_t, didA, didB, tookA, tookB);

    // ---- embeddings ----
    k_embed<1,3,2,true,true><<<UCAP / 64, 64, 0, stream>>>(x_dc, 0, nUB, ulist,
        drug_node_id, c_drug_id_emb, drug_tokens, c_drug_tok_emb, c_drug_floats, c_drug_float_w, c_drug_align);
    k_embed<1,2,1,true,false><<<NLN / 64, 64, 0, stream>>>(x_l, NLN, nullptr, nullptr,
        lab_node_id, c_lab_id_emb, lab_tokens, c_lab_tok_emb, c_lab_floats, c_lab_float_w, c_lab_align);
    k_embed<0,4,3,false,false><<<1, 64, 0, stream>>>(x_a, Dd, nullptr, nullptr,
        nullptr, nullptr, adm_tokens, c_adm_tok_emb, c_adm_floats, c_adm_float_w, c_adm_align);
    k_embed<0,2,2,true,false><<<ED / 64, 64, 0, stream>>>(e_did, ED, nullptr, nullptr,
        nullptr, nullptr, did_tokens, c_did_tok_emb, c_did_floats, c_did_float_w, c_did_align);
    k_embed<0,2,1,true,false><<<ET / 64, 64, 0, stream>>>(e_took, ET, nullptr, nullptr,
        nullptr, nullptr, took_tokens, c_took_tok_emb, c_took_floats, c_took_float_w, c_took_align);

    const size_t HH = (size_t)Hh * Hh;

    // ---- GNN layer 1 (relu) ----
    hipMemsetAsync(Sx_did, 0, 2 * (size_t)Dd * Hh * sizeof(float), stream);
    k_srcsum<true><<<(ED + 255) / 256, 64, 0, stream>>>(didA, didB, x_l, e_did, 16,
                                                        Sx_did, E_did, ED);
    k_srcsum<true><<<(ET + 255) / 256, 64, 0, stream>>>(tookA, tookB, x_dc, e_took, 18,
                                                        Sx_took, E_took, ET);
    k_gup<false><<<UCAP / 32, 128, 0, stream>>>(x_dc, x_a, e_took, roff_t, elist_t, 17,
        nullptr, nUB, 0, c_gnn_self + 1 * HH, c_gnn_msg + 1 * HH, 1);
    k_gup<false><<<NLN / 32, 128, 0, stream>>>(x_l, x_a, e_did, roff_d, elist_d, 15,
        nullptr, nullptr, NLN, c_gnn_self + 2 * HH, c_gnn_msg + 0 * HH, 1);
    k_xa<<<Dd, 128, 0, stream>>>(x_a, Sx_did, E_did, Sx_took, E_took, cnt_a1, cnt_a2,
        c_gnn_self + 0 * HH, c_gnn_msg + 2 * HH, c_gnn_msg + 3 * HH, 1);

    // ---- GNN layer 2 ----
    const float* Ws1 = c_gnn_self + 3 * HH;
    const float* Wm1 = c_gnn_msg + 4 * HH;
    hipMemsetAsync(Sx_did, 0, 2 * (size_t)Dd * Hh * sizeof(float), stream);
    k_srcsum<false><<<(ED + 255) / 256, 64, 0, stream>>>(didA, didB, x_l, nullptr, 16,
                                                         Sx_did, nullptr, ED);
    k_srcsum<false><<<(ET + 255) / 256, 64, 0, stream>>>(tookA, tookB, x_dc, nullptr, 18,
                                                         Sx_took, nullptr, ET);
    k_gup<true><<<(NCAND + 31) / 32, 128, 0, stream>>>(x_dc, x_a, e_took, roff_t, elist_t, 17,
        blist, nUB + 1, 0, Ws1 + 1 * HH, Wm1 + 1 * HH, 0);
    k_xa<<<Dd, 128, 0, stream>>>(x_a, Sx_did, E_did, Sx_took, E_took, cnt_a1, cnt_a2,
        Ws1 + 0 * HH, Wm1 + 2 * HH, Wm1 + 3 * HH, 0);

    // ---- transformer encoder ----
    for (int i = 0; i < L_ENC; i++) {
        k_qkv<<<Dd, 128, 0, stream>>>(x_a, qkvb, c_qkv_w + (size_t)i * Hh * 384, c_qkv_b + (size_t)i * 384);
        k_attn_out<<<Dd, 128, 0, stream>>>(qkvb, x_a, c_out_w + (size_t)i * HH,
                                           c_out_b + (size_t)i * Hh, c_ln1 + (size_t)i * 2 * Hh);
        k_ff1<<<dim3(Dd, 2), 256, 0, stream>>>(x_a, fbuf, c_ff1_w + (size_t)i * Hh * FF,
                                               c_ff1_b + (size_t)i * FF);
        k_ff2p<<<dim3(Dd, 16), 128, 0, stream>>>(fbuf, part, c_ff2_w + (size_t)i * FF * Hh);
        k_ln2<<<Dd, 128, 0, stream>>>(x_a, part, c_ff2_b + (size_t)i * Hh, c_ln2 + (size_t)i * 2 * Hh);
    }

    // ---- logits ----
    k_logits<<<Dd - 1, 256, 0, stream>>>(x_dc, map, x_a, c_lp_w, cand_idx, (float*)d_out);
}

// Round 7
// 2039.848 us; speedup vs baseline: 1.8736x; 1.0744x over previous
//
#include <hip/hip_runtime.h>
#include <hip/hip_bf16.h>

typedef unsigned short ushort_t;
typedef __attribute__((ext_vector_type(8))) short bf16x8;
typedef __attribute__((ext_vector_type(4))) float f32x4;

#define DEV __device__ __forceinline__

constexpr int Dd  = 64;
constexpr int VD  = 4525;
constexpr int VL  = 753;
constexpr int ND  = Dd * VD;     // 289600
constexpr int NLN = Dd * VL;     // 48192
constexpr int Hh  = 128;
constexpr int EMB = 10;
constexpr int TV  = 100;
constexpr int NH  = 8, HD = 16;
constexpr int L_ENC = 6, FF = 2048;
constexpr int GL  = 2;
constexpr int ED  = 32768, ET = 131072;
constexpr int KK  = 256;
constexpr int NCAND = (Dd - 1) * KK;       // 16128
constexpr int UCAP  = ET + NCAND;          // 147200
constexpr int NCANON = 35;
constexpr int NB_T = (UCAP + 255) / 256;
constexpr int NB_D = (NLN + 255) / 256;

DEV float bf(ushort_t u) { return __uint_as_float(((unsigned)u) << 16); }
DEV float bflo(unsigned u) { return __uint_as_float(u << 16); }
DEV float bfhi(unsigned u) { return __uint_as_float(u & 0xffff0000u); }
DEV ushort_t f2bf(float f) {
    unsigned u = __float_as_uint(f);
    u += 0x7fffu + ((u >> 16) & 1u);
    return (ushort_t)(u >> 16);
}

// ---------------------------------------------------------------------------
__global__ __launch_bounds__(64)
void k_probe(const unsigned* __restrict__ w, int* __restrict__ flag)
{
    int tid = threadIdx.x;
    int c = 0;
    #pragma unroll
    for (int i = 0; i < 16; i++) c += (w[tid * 16 + i] >> 14) & 1;
    #pragma unroll
    for (int o = 32; o; o >>= 1) c += __shfl_xor(c, o);
    if (tid == 0) *flag = (c > 256) ? 1 : 0;
}

struct CanonDesc {
    const void* src[NCANON];
    int doff[NCANON];
    int bend[NCANON];
    int n[NCANON];
};

__global__ __launch_bounds__(256)
void k_canon(CanonDesc cd, float* __restrict__ dst, const int* __restrict__ flag)
{
    int b = blockIdx.x;
    int t = 0;
    while (t < NCANON && b >= cd.bend[t]) t++;
    if (t >= NCANON) return;
    int bstart = (t == 0) ? 0 : cd.bend[t - 1];
    int i = (b - bstart) * 256 + threadIdx.x;
    if (i >= cd.n[t]) return;
    float v = (*flag) ? ((const float*)cd.src[t])[i]
                      : bf(((const ushort_t*)cd.src[t])[i]);
    dst[cd.doff[t] + i] = v;
}

// pack [Wself;Wmsg] (256x128 fp32) into MFMA B-operand bf16 layout [32][128][8]
__global__ __launch_bounds__(128)
void k_wpack(const float* __restrict__ gself, const float* __restrict__ gmsg,
             ushort_t* __restrict__ wt)
{
    const int selfIdx[3] = {1, 2, 4};   // l1 drug, l1 lab, l2 drug
    const int msgIdx[3]  = {1, 0, 5};
    int pr = blockIdx.y, chunk = blockIdx.x, nn = threadIdx.x;
    const float* Ws = gself + (size_t)selfIdx[pr] * Hh * Hh;
    const float* Wm = gmsg  + (size_t)msgIdx[pr]  * Hh * Hh;
    ushort_t* dst = wt + (((size_t)pr * 32 + chunk) * 128 + nn) * 8;
    #pragma unroll
    for (int j = 0; j < 8; j++) {
        int k = chunk * 8 + j;
        float v = (k < 128) ? Ws[k * Hh + nn] : Wm[(k - 128) * Hh + nn];
        dst[j] = f2bf(v);
    }
}

// ---------------------------------------------------------------------------
__global__ __launch_bounds__(256)
void k_mark(const int* __restrict__ took_dst, const int* __restrict__ cand,
            int* __restrict__ map)
{
    int g = blockIdx.x * 256 + threadIdx.x;
    if (g < ET) atomicOr(&map[took_dst[g]], 1);
    if (g < NCAND) {
        int d = g >> 8;
        atomicOr(&map[d * VD + cand[g]], 2);
    }
}

__global__ __launch_bounds__(256)
void k_assign(int* __restrict__ map, int* __restrict__ ulist, int* __restrict__ blist,
              int* __restrict__ nUB)
{
    int g = blockIdx.x * 256 + threadIdx.x;
    if (g >= ND) return;
    int m = map[g];
    if (m) {
        int s = atomicAdd(&nUB[0], 1);
        ulist[s] = g;
        map[g] = (s << 2) | m;
        if (m & 2) {
            int b = atomicAdd(&nUB[1], 1);
            blist[b] = s;
        }
    }
}

__global__ __launch_bounds__(256)
void k_counts(const int* __restrict__ did_dst, const int* __restrict__ did_src,
              const int* __restrict__ took_dst, const int* __restrict__ took_src,
              const int* __restrict__ map,
              int* __restrict__ cnt_ld, int* __restrict__ cnt_a1,
              int* __restrict__ cnt_dc, int* __restrict__ cnt_a2)
{
    int g = blockIdx.x * 256 + threadIdx.x;
    if (g < ED) {
        atomicAdd(&cnt_ld[did_dst[g]], 1);
        atomicAdd(&cnt_a1[did_src[g]], 1);
    }
    if (g < ET) {
        atomicAdd(&cnt_dc[map[took_dst[g]] >> 2], 1);
        atomicAdd(&cnt_a2[took_src[g]], 1);
    }
}

// ---------------------------------------------------------------------------
__global__ __launch_bounds__(256)
void k_scan_blk(const int* __restrict__ cnt, int* __restrict__ excl,
                int* __restrict__ btot, int n)
{
    __shared__ int s[256];
    int tid = threadIdx.x;
    int g = blockIdx.x * 256 + tid;
    int v = (g < n) ? cnt[g] : 0;
    s[tid] = v;
    __syncthreads();
    for (int o = 1; o < 256; o <<= 1) {
        int t = (tid >= o) ? s[tid - o] : 0;
        __syncthreads();
        s[tid] += t;
        __syncthreads();
    }
    if (g < n) excl[g] = s[tid] - v;
    if (tid == 255) btot[blockIdx.x] = s[255];
}

__global__ __launch_bounds__(1024)
void k_scan_top(int* __restrict__ btot, int nb)
{
    __shared__ int s[1024];
    int tid = threadIdx.x;
    int v = (tid < nb) ? btot[tid] : 0;
    s[tid] = v;
    __syncthreads();
    for (int o = 1; o < 1024; o <<= 1) {
        int t = (tid >= o) ? s[tid - o] : 0;
        __syncthreads();
        s[tid] += t;
        __syncthreads();
    }
    if (tid < nb) btot[tid] = s[tid] - v;
}

__global__ __launch_bounds__(256)
void k_scan_add(int* __restrict__ roff, const int* __restrict__ btot, int n, int total)
{
    int g = blockIdx.x * 256 + threadIdx.x;
    if (g < n) roff[g] += btot[blockIdx.x];
    if (g == 0) roff[n] = total;
}

__global__ __launch_bounds__(64)
void k_scan64(const int* __restrict__ c1, const int* __restrict__ c2,
              int* __restrict__ r1, int* __restrict__ r2)
{
    int tid = threadIdx.x;
    int v1 = c1[tid], v2 = c2[tid];
    int s1 = v1, s2 = v2;
    for (int o = 1; o < 64; o <<= 1) {
        int t1 = __shfl_up(s1, o), t2 = __shfl_up(s2, o);
        if (tid >= o) { s1 += t1; s2 += t2; }
    }
    r1[tid] = s1 - v1;
    r2[tid] = s2 - v2;
}

__global__ __launch_bounds__(256)
void k_fill(const int* __restrict__ did_src, const int* __restrict__ did_dst,
            const int* __restrict__ took_src, const int* __restrict__ took_dst,
            const int* __restrict__ map,
            const int* __restrict__ roff_d, const int* __restrict__ roff_t,
            const int* __restrict__ roff_a1, const int* __restrict__ roff_a2,
            int* __restrict__ cur_d, int* __restrict__ cur_t,
            int* __restrict__ cur_a1, int* __restrict__ cur_a2,
            int* __restrict__ elist_d, int* __restrict__ elist_t,
            int* __restrict__ didA, int* __restrict__ didB,
            int* __restrict__ tookA, int* __restrict__ tookB)
{
    int g = blockIdx.x * 256 + threadIdx.x;
    if (g < ED) {
        int d = did_dst[g], s = did_src[g];
        int pos = roff_d[d] + atomicAdd(&cur_d[d], 1);
        elist_d[pos] = (s << 15) | g;
        int pa = roff_a1[s] + atomicAdd(&cur_a1[s], 1);
        didA[pa] = (s << 16) | d;
        didB[pa] = g;
    }
    if (g < ET) {
        int s = took_src[g];
        int slot = map[took_dst[g]] >> 2;
        int pos = roff_t[slot] + atomicAdd(&cur_t[slot], 1);
        elist_t[pos] = (s << 17) | g;
        int pa = roff_a2[s] + atomicAdd(&cur_a2[s], 1);
        tookA[pa] = (s << 18) | slot;
        tookB[pa] = g;
    }
}

// ---------------------------------------------------------------------------
// segmented src-sum over sorted edge list (epb edges/block)
template<bool DUAL>
__global__ __launch_bounds__(64)
void k_srcsum(const int* __restrict__ lA, const int* __restrict__ lB,
              const ushort_t* __restrict__ xrows, const ushort_t* __restrict__ erows,
              int shift, float* __restrict__ Sx, float* __restrict__ Se,
              int nedge, int epb)
{
    int lane = threadIdx.x;
    int c0 = lane * 2;
    int base = blockIdx.x * epb;
    int end = min(base + epb, nedge);
    int mask = (1 << shift) - 1;
    float ax0 = 0.f, ax1 = 0.f, ae0 = 0.f, ae1 = 0.f;
    int cur = -1;
    for (int i = base; i < end; i++) {
        int pk = lA[i];
        int s = pk >> shift, row = pk & mask;
        if (s != cur) {
            if (cur >= 0) {
                unsafeAtomicAdd(&Sx[cur * Hh + c0], ax0);
                unsafeAtomicAdd(&Sx[cur * Hh + c0 + 1], ax1);
                if (DUAL) {
                    unsafeAtomicAdd(&Se[cur * Hh + c0], ae0);
                    unsafeAtomicAdd(&Se[cur * Hh + c0 + 1], ae1);
                }
            }
            cur = s; ax0 = ax1 = ae0 = ae1 = 0.f;
        }
        unsigned xx = *reinterpret_cast<const unsigned*>(xrows + (size_t)row * Hh + c0);
        ax0 += bflo(xx); ax1 += bfhi(xx);
        if (DUAL) {
            int e = lB[i];
            unsigned ee = *reinterpret_cast<const unsigned*>(erows + (size_t)e * Hh + c0);
            ae0 += bflo(ee); ae1 += bfhi(ee);
        }
    }
    if (cur >= 0) {
        unsafeAtomicAdd(&Sx[cur * Hh + c0], ax0);
        unsafeAtomicAdd(&Sx[cur * Hh + c0 + 1], ax1);
        if (DUAL) {
            unsafeAtomicAdd(&Se[cur * Hh + c0], ae0);
            unsafeAtomicAdd(&Se[cur * Hh + c0 + 1], ae1);
        }
    }
}

// ---------------------------------------------------------------------------
template<int NID, int NTOK, int NF, bool BF16OUT, bool INDIRECT>
__global__ __launch_bounds__(64)
void k_embed(void* __restrict__ out, int n_static, const int* __restrict__ n_dyn,
             const int* __restrict__ ulist,
             const int* __restrict__ id_idx, const float* __restrict__ id_emb,
             const int* __restrict__ tokens, const float* __restrict__ tok_emb,
             const float* __restrict__ floats_, const float* __restrict__ float_w,
             const float* __restrict__ alignf)
{
    constexpr int L = (NID + NTOK + 1) * EMB;
    int slot = blockIdx.x * 64 + threadIdx.x;
    int n = INDIRECT ? *n_dyn : n_static;
    if (slot >= n) return;
    int node = INDIRECT ? ulist[slot] : slot;

    float vec[L];
    int p = 0;
    if constexpr (NID != 0) {
        const float* pe = id_emb + (size_t)id_idx[node] * EMB;
        #pragma unroll
        for (int e = 0; e < EMB; e++) vec[p++] = pe[e];
    }
    #pragma unroll
    for (int t = 0; t < NTOK; t++) {
        const float* pe = tok_emb + ((size_t)t * TV + tokens[node * NTOK + t]) * EMB;
        #pragma unroll
        for (int e = 0; e < EMB; e++) vec[p++] = pe[e];
    }
    {
        float fv[NF];
        #pragma unroll
        for (int f = 0; f < NF; f++) fv[f] = floats_[node * NF + f];
        #pragma unroll
        for (int e = 0; e < EMB; e++) {
            float a = 0.f;
            #pragma unroll
            for (int f = 0; f < NF; f++) a = fmaf(fv[f], float_w[f * EMB + e], a);
            vec[p++] = a;
        }
    }

    #pragma unroll 1
    for (int j = 0; j < Hh; j += 4) {
        float a0 = 0.f, a1 = 0.f, a2 = 0.f, a3 = 0.f;
        #pragma unroll
        for (int i = 0; i < L; i++) {
            const float* w = alignf + i * Hh + j;
            a0 = fmaf(vec[i], w[0], a0);
            a1 = fmaf(vec[i], w[1], a1);
            a2 = fmaf(vec[i], w[2], a2);
            a3 = fmaf(vec[i], w[3], a3);
        }
        if constexpr (BF16OUT) {
            unsigned lo = (unsigned)f2bf(a0) | ((unsigned)f2bf(a1) << 16);
            unsigned hi = (unsigned)f2bf(a2) | ((unsigned)f2bf(a3) << 16);
            uint2 v; v.x = lo; v.y = hi;
            *reinterpret_cast<uint2*>((ushort_t*)out + (size_t)slot * Hh + j) = v;
        } else {
            float4 r4; r4.x = a0; r4.y = a1; r4.z = a2; r4.w = a3;
            *reinterpret_cast<float4*>((float*)out + (size_t)slot * Hh + j) = r4;
        }
    }
}

// ---------------------------------------------------------------------------
// Fused gather + mean + GNN update, MFMA version.
//   X[r,:] = relu?( [X[r,:] | mean_edges] @ Wt )   (K=256, bf16 in, fp32 acc)
template<bool INDIRECT>
__global__ __launch_bounds__(128)
void k_gup(ushort_t* __restrict__ X, const float* __restrict__ xa,
           const ushort_t* __restrict__ ef,
           const int* __restrict__ roff, const int* __restrict__ elist, int sshift,
           const int* __restrict__ rows_list, const int* __restrict__ n_dyn, int n_static,
           const ushort_t* __restrict__ Wt, int do_relu)
{
    __shared__ ushort_t As[32 * 264];    // [row][k 0..255 (+8 pad)] bf16, 16.9 KB
    __shared__ int rowid[32];
    int tid = threadIdx.x;
    int r0 = blockIdx.x * 32;
    int n = n_dyn ? *n_dyn : n_static;
    if (tid < 32) {
        int row = r0 + tid;
        rowid[tid] = (row < n) ? (INDIRECT ? rows_list[row] : row) : -1;
    }
    __syncthreads();

    // stage X (raw bf16 copy, 16B chunks)
    for (int idx = tid; idx < 512; idx += 128) {
        int r = idx >> 4, c16 = idx & 15;
        int rr = rowid[r];
        uint4 v = make_uint4(0, 0, 0, 0);
        if (rr >= 0) v = *reinterpret_cast<const uint4*>(X + (size_t)rr * Hh + c16 * 8);
        *reinterpret_cast<uint4*>(&As[r * 264 + c16 * 8]) = v;
    }
    // gather edge means -> bf16 into k=128..255
    int wid = tid >> 6, lane = tid & 63;
    int c0 = lane * 2;
    int emask = (1 << sshift) - 1;
    for (int r = wid; r < 32; r += 2) {
        int rr = rowid[r];
        float a0 = 0.f, a1 = 0.f, invd = 0.f;
        if (rr >= 0) {
            int e0 = roff[rr], e1 = roff[rr + 1];
            invd = 1.f / fmaxf((float)(e1 - e0), 1.f);
            for (int ei = e0; ei < e1; ei++) {
                int pk = elist[ei];
                int s = pk >> sshift, e = pk & emask;
                const float* xr = xa + s * Hh + c0;
                unsigned ee = *reinterpret_cast<const unsigned*>(ef + (size_t)e * Hh + c0);
                a0 += xr[0] + bflo(ee);
                a1 += xr[1] + bfhi(ee);
            }
        }
        unsigned pk2 = (unsigned)f2bf(a0 * invd) | ((unsigned)f2bf(a1 * invd) << 16);
        *reinterpret_cast<unsigned*>(&As[r * 264 + 128 + c0]) = pk2;
    }
    __syncthreads();

    // MFMA: wave w computes rows 16w..16w+15 x all 128 cols
    int m = lane & 15, quad = lane >> 4;
    f32x4 acc[8];
    #pragma unroll
    for (int t = 0; t < 8; t++) acc[t] = (f32x4){0.f, 0.f, 0.f, 0.f};
    #pragma unroll
    for (int kc = 0; kc < 8; kc++) {
        bf16x8 a = *reinterpret_cast<const bf16x8*>(&As[(16 * wid + m) * 264 + kc * 32 + quad * 8]);
        #pragma unroll
        for (int nt = 0; nt < 8; nt++) {
            bf16x8 b = *reinterpret_cast<const bf16x8*>(Wt + (((kc * 4 + quad) * 128) + nt * 16 + m) * 8);
            acc[nt] = __builtin_amdgcn_mfma_f32_16x16x32_bf16(a, b, acc[nt], 0, 0, 0);
        }
    }
    __syncthreads();
    // stage D (reuse As as float[32][132])
    float* Ds = reinterpret_cast<float*>(As);
    #pragma unroll
    for (int nt = 0; nt < 8; nt++)
        #pragma unroll
        for (int reg = 0; reg < 4; reg++)
            Ds[(16 * wid + quad * 4 + reg) * 132 + nt * 16 + m] = acc[nt][reg];
    __syncthreads();
    // coalesced bf16 writeback
    for (int idx = tid; idx < 512; idx += 128) {
        int r = idx >> 4, c16 = idx & 15;
        int rr = rowid[r];
        if (rr < 0) continue;
        const float* dsrc = &Ds[r * 132 + c16 * 8];
        float o[8];
        #pragma unroll
        for (int c = 0; c < 8; c++) {
            o[c] = dsrc[c];
            if (do_relu) o[c] = fmaxf(o[c], 0.f);
        }
        uint4 v;
        v.x = (unsigned)f2bf(o[0]) | ((unsigned)f2bf(o[1]) << 16);
        v.y = (unsigned)f2bf(o[2]) | ((unsigned)f2bf(o[3]) << 16);
        v.z = (unsigned)f2bf(o[4]) | ((unsigned)f2bf(o[5]) << 16);
        v.w = (unsigned)f2bf(o[6]) | ((unsigned)f2bf(o[7]) << 16);
        *reinterpret_cast<uint4*>(X + (size_t)rr * Hh + c16 * 8) = v;
    }
}

// ---------------------------------------------------------------------------
__global__ __launch_bounds__(128)
void k_xa(float* __restrict__ x_a,
          const float* __restrict__ Sx1, const float* __restrict__ E1,
          const float* __restrict__ Sx2, const float* __restrict__ E2,
          const int* __restrict__ c1, const int* __restrict__ c2,
          const float* __restrict__ Wself, const float* __restrict__ Wm1,
          const float* __restrict__ Wm2, int do_relu)
{
    int r = blockIdx.x, tid = threadIdx.x;
    __shared__ float xr[128], a1[128], a2[128];
    float i1 = 1.f / fmaxf((float)c1[r], 1.f);
    float i2 = 1.f / fmaxf((float)c2[r], 1.f);
    xr[tid] = x_a[r * Hh + tid];
    a1[tid] = (Sx1[r * Hh + tid] + E1[r * Hh + tid]) * i1;
    a2[tid] = (Sx2[r * Hh + tid] + E2[r * Hh + tid]) * i2;
    __syncthreads();
    float acc = 0.f;
    for (int k = 0; k < 128; k++) {
        acc = fmaf(xr[k], Wself[k * Hh + tid], acc);
        acc = fmaf(a1[k], Wm1[k * Hh + tid], acc);
        acc = fmaf(a2[k], Wm2[k * Hh + tid], acc);
    }
    if (do_relu) acc = fmaxf(acc, 0.f);
    x_a[r * Hh + tid] = acc;
}

// ---------------------------------------------------------------------------
__global__ __launch_bounds__(128)
void k_qkv(const float* __restrict__ h, float* __restrict__ qkv,
           const float* __restrict__ W, const float* __restrict__ b)
{
    int r = blockIdx.x, tid = threadIdx.x;
    __shared__ float hr[128];
    hr[tid] = h[r * Hh + tid];
    __syncthreads();
    #pragma unroll
    for (int c0 = 0; c0 < 3; c0++) {
        int c = c0 * 128 + tid;
        float acc = b[c];
        for (int k = 0; k < 128; k++) acc = fmaf(hr[k], W[k * 384 + c], acc);
        qkv[r * 384 + c] = acc;
    }
}

DEV float blocksum128(float v, float* red)
{
    #pragma unroll
    for (int o = 32; o; o >>= 1) v += __shfl_xor(v, o);
    int wid = threadIdx.x >> 6;
    __syncthreads();
    if ((threadIdx.x & 63) == 0) red[wid] = v;
    __syncthreads();
    return red[0] + red[1];
}

DEV float blocksum256(float v, float* red)
{
    #pragma unroll
    for (int o = 32; o; o >>= 1) v += __shfl_xor(v, o);
    int wid = threadIdx.x >> 6;
    __syncthreads();
    if ((threadIdx.x & 63) == 0) red[wid] = v;
    __syncthreads();
    return red[0] + red[1] + red[2] + red[3];
}

// fused attention + out-proj + residual + LN1 + ff1 ; 256 thr, block per q row
__global__ __launch_bounds__(256)
void k_attn_ff1(const float* __restrict__ qkv, float* __restrict__ h,
                float* __restrict__ fbuf,
                const float* __restrict__ Wout, const float* __restrict__ bout,
                const float* __restrict__ ln,
                const float* __restrict__ W1, const float* __restrict__ b1)
{
    int q = blockIdx.x, tid = threadIdx.x;
    __shared__ float sc[NH * Dd];
    __shared__ float o_r[128];
    __shared__ float hr[128];
    __shared__ float red[4];
    int hh = tid >> 4;
    int k0 = (tid & 15) * 4;
    if (tid < 128) {
        const float* qrow = qkv + q * 384 + hh * HD;
        #pragma unroll
        for (int kk = k0; kk < k0 + 4; kk++) {
            const float* krow = qkv + kk * 384 + 128 + hh * HD;
            float s = 0.f;
            #pragma unroll
            for (int d = 0; d < HD; d++) s = fmaf(qrow[d], krow[d], s);
            sc[hh * Dd + kk] = s * 0.25f + (kk <= q ? 0.f : -1e9f);
        }
    }
    __syncthreads();
    float p0 = 0.f, p1 = 0.f, p2 = 0.f, p3 = 0.f;
    if (tid < 128) {
        float mm = -1e30f;
        for (int k = 0; k < Dd; k++) mm = fmaxf(mm, sc[hh * Dd + k]);
        float l = 0.f;
        for (int k = 0; k < Dd; k++) l += __expf(sc[hh * Dd + k] - mm);
        float inv_l = 1.f / l;
        p0 = __expf(sc[hh * Dd + k0]     - mm) * inv_l;
        p1 = __expf(sc[hh * Dd + k0 + 1] - mm) * inv_l;
        p2 = __expf(sc[hh * Dd + k0 + 2] - mm) * inv_l;
        p3 = __expf(sc[hh * Dd + k0 + 3] - mm) * inv_l;
    }
    __syncthreads();
    if (tid < 128) {
        sc[hh * Dd + k0] = p0; sc[hh * Dd + k0 + 1] = p1;
        sc[hh * Dd + k0 + 2] = p2; sc[hh * Dd + k0 + 3] = p3;
    }
    __syncthreads();
    if (tid < 128) {
        int d = tid & 15;
        float o0 = 0.f, o1 = 0.f, o2 = 0.f, o3 = 0.f;
        for (int k = 0; k < Dd; k += 4) {
            o0 = fmaf(sc[hh * Dd + k],     qkv[(k)     * 384 + 256 + hh * HD + d], o0);
            o1 = fmaf(sc[hh * Dd + k + 1], qkv[(k + 1) * 384 + 256 + hh * HD + d], o1);
            o2 = fmaf(sc[hh * Dd + k + 2], qkv[(k + 2) * 384 + 256 + hh * HD + d], o2);
            o3 = fmaf(sc[hh * Dd + k + 3], qkv[(k + 3) * 384 + 256 + hh * HD + d], o3);
        }
        o_r[hh * HD + d] = (o0 + o1) + (o2 + o3);
    }
    __syncthreads();
    float x = 0.f;
    if (tid < 128) {
        float a0 = bout[tid], a1 = 0.f, a2 = 0.f, a3 = 0.f;
        for (int k = 0; k < 128; k += 4) {
            a0 = fmaf(o_r[k],     Wout[(k)     * Hh + tid], a0);
            a1 = fmaf(o_r[k + 1], Wout[(k + 1) * Hh + tid], a1);
            a2 = fmaf(o_r[k + 2], Wout[(k + 2) * Hh + tid], a2);
            a3 = fmaf(o_r[k + 3], Wout[(k + 3) * Hh + tid], a3);
        }
        x = h[q * Hh + tid] + (a0 + a1) + (a2 + a3);
    }
    float mu = blocksum256(x, red) * (1.f / 128.f);
    float dx = (tid < 128) ? (x - mu) : 0.f;
    float var = blocksum256(dx * dx, red) * (1.f / 128.f);
    if (tid < 128) {
        float y = ln[tid] * dx * (1.f / sqrtf(var + 1e-5f)) + ln[128 + tid];
        hr[tid] = y;
        h[q * Hh + tid] = y;
    }
    __syncthreads();
    // ff1: 8 cols per thread
    #pragma unroll 1
    for (int i = 0; i < 8; i++) {
        int c = i * 256 + tid;
        float a = b1[c];
        #pragma unroll 4
        for (int k = 0; k < 128; k++) a = fmaf(hr[k], W1[(size_t)k * FF + c], a);
        fbuf[(size_t)q * FF + c] = fmaxf(a, 0.f);
    }
}

__global__ __launch_bounds__(128)
void k_ff2p(const float* __restrict__ fbuf, float* __restrict__ part,
            const float* __restrict__ W2)
{
    int r = blockIdx.x, pi = blockIdx.y, tid = threadIdx.x;
    int kc = pi * 128;
    const float* f = fbuf + (size_t)r * FF + kc;
    float a0 = 0.f, a1 = 0.f, a2 = 0.f, a3 = 0.f;
    for (int k = 0; k < 128; k += 4) {
        a0 = fmaf(f[k],     W2[(size_t)(kc + k)     * Hh + tid], a0);
        a1 = fmaf(f[k + 1], W2[(size_t)(kc + k + 1) * Hh + tid], a1);
        a2 = fmaf(f[k + 2], W2[(size_t)(kc + k + 2) * Hh + tid], a2);
        a3 = fmaf(f[k + 3], W2[(size_t)(kc + k + 3) * Hh + tid], a3);
    }
    part[(size_t)(r * 16 + pi) * Hh + tid] = (a0 + a1) + (a2 + a3);
}

// sum partials + residual + LN2 + next-layer qkv
__global__ __launch_bounds__(128)
void k_ln2qkv(float* __restrict__ h, const float* __restrict__ part,
              const float* __restrict__ b2, const float* __restrict__ ln,
              float* __restrict__ qkv, const float* __restrict__ Wq,
              const float* __restrict__ bq, int do_qkv)
{
    int r = blockIdx.x, tid = threadIdx.x;
    __shared__ float red[2];
    __shared__ float hr[128];
    float acc = b2[tid];
    #pragma unroll
    for (int pi = 0; pi < 16; pi++) acc += part[(size_t)(r * 16 + pi) * Hh + tid];
    float x = h[r * Hh + tid] + acc;
    float mu = blocksum128(x, red) * (1.f / 128.f);
    float dx = x - mu;
    float var = blocksum128(dx * dx, red) * (1.f / 128.f);
    float y = ln[tid] * dx * (1.f / sqrtf(var + 1e-5f)) + ln[128 + tid];
    hr[tid] = y;
    h[r * Hh + tid] = y;
    __syncthreads();
    if (do_qkv) {
        #pragma unroll
        for (int c0 = 0; c0 < 3; c0++) {
            int c = c0 * 128 + tid;
            float a = bq[c];
            for (int k = 0; k < 128; k++) a = fmaf(hr[k], Wq[k * 384 + c], a);
            qkv[r * 384 + c] = a;
        }
    }
}

// ---------------------------------------------------------------------------
__global__ __launch_bounds__(256)
void k_logits(const ushort_t* __restrict__ x_dc, const int* __restrict__ map,
              const float* __restrict__ h, const float* __restrict__ lp,
              const int* __restrict__ cand, float* __restrict__ out)
{
    int d = blockIdx.x;
    int tid = threadIdx.x, lane = tid & 63, w = tid >> 6;
    __shared__ float wv[128];
    if (tid < 128) wv[tid] = h[d * Hh + tid] * lp[tid];
    __syncthreads();
    for (int k = w; k < KK; k += 4) {
        int slot = map[d * VD + cand[d * KK + k]] >> 2;
        const ushort_t* row = x_dc + (size_t)slot * Hh;
        float v = bf(row[lane]) * wv[lane] + bf(row[lane + 64]) * wv[lane + 64];
        #pragma unroll
        for (int o = 32; o; o >>= 1) v += __shfl_xor(v, o);
        if (lane == 0) out[d * KK + k] = v;
    }
}

// ---------------------------------------------------------------------------
extern "C" void kernel_launch(void* const* d_in, const int* in_sizes, int n_in,
                              void* d_out, int out_size, void* d_ws, size_t ws_size,
                              hipStream_t stream)
{
    (void)in_sizes; (void)n_in; (void)out_size; (void)ws_size;

    const int* drug_tokens  = (const int*)d_in[0];
    const int* drug_node_id = (const int*)d_in[1];
    const int* lab_tokens   = (const int*)d_in[3];
    const int* lab_node_id  = (const int*)d_in[4];
    const int* adm_tokens   = (const int*)d_in[6];
    const int* did_tokens   = (const int*)d_in[8];
    const int* did_src      = (const int*)d_in[10];
    const int* did_dst      = (const int*)d_in[11];
    const int* took_tokens  = (const int*)d_in[12];
    const int* took_src     = (const int*)d_in[14];
    const int* took_dst     = (const int*)d_in[15];
    const int* cand_idx     = (const int*)d_in[16];

    const int cidx[NCANON] = {2,5,7,9,13, 17,18,19,20,21,22,23, 24,25,26,27,28,
                              29,30,31,32,33, 34,35, 36,37,38,39,40,41,42,43,44,45,46};
    const int cn[NCANON] = {
        ND*2, NLN*1, Dd*3, ED*2, ET*1,
        VD*EMB, VL*EMB, 3*TV*EMB, 2*TV*EMB, 4*TV*EMB, 2*TV*EMB, 2*TV*EMB,
        2*EMB, 1*EMB, 3*EMB, 2*EMB, 1*EMB,
        5*EMB*Hh, 4*EMB*Hh, 5*EMB*Hh, 3*EMB*Hh, 3*EMB*Hh,
        GL*4*Hh*Hh, GL*3*Hh*Hh,
        L_ENC*Hh*3*Hh, L_ENC*3*Hh, L_ENC*Hh*Hh, L_ENC*Hh, L_ENC*2*Hh,
        L_ENC*Hh*FF, L_ENC*FF, L_ENC*FF*Hh, L_ENC*Hh, L_ENC*2*Hh, Hh
    };
    CanonDesc cd;
    int eoff[NCANON + 1];
    int btot_blocks = 0;
    {
        int e = 0;
        for (int t = 0; t < NCANON; t++) {
            cd.src[t] = d_in[cidx[t]];
            cd.n[t] = cn[t];
            eoff[t] = e;
            cd.doff[t] = e;
            e = (e + cn[t] + 7) & ~7;
            btot_blocks += (cn[t] + 255) / 256;
            cd.bend[t] = btot_blocks;
        }
        eoff[NCANON] = e;
    }

    // ---- workspace carve ----
    char* p = (char*)d_ws;
    auto alloc_f = [&](size_t n) -> float*    { float* r = (float*)p;    p += n * sizeof(float); return r; };
    auto alloc_h = [&](size_t n) -> ushort_t* { ushort_t* r = (ushort_t*)p; p += n * sizeof(ushort_t); return r; };
    auto alloc_i = [&](size_t n) -> int*      { int* r = (int*)p;        p += n * sizeof(int); return r; };

    int* map    = alloc_i(ND);
    int* cnt_dc = alloc_i(UCAP);
    int* cnt_ld = alloc_i(NLN);
    int* cnt_a1 = alloc_i(64);
    int* cnt_a2 = alloc_i(64);
    int* nUB    = alloc_i(8);
    int* cur_t  = alloc_i(UCAP);
    int* cur_d  = alloc_i(NLN);
    int* cur_a1 = alloc_i(64);
    int* cur_a2 = alloc_i(64);
    float* E_did  = alloc_f((size_t)Dd * Hh);
    float* E_took = alloc_f((size_t)Dd * Hh);
    const size_t ZBLOCK = (size_t)ND + UCAP + NLN + 64 + 64 + 8 + UCAP + NLN + 64 + 64
                        + (size_t)Dd * Hh * 2;
    float* Sx_did  = alloc_f((size_t)Dd * Hh);
    float* Sx_took = alloc_f((size_t)Dd * Hh);
    int* roff_t  = alloc_i(UCAP + 8);
    int* roff_d  = alloc_i(NLN + 8);
    int* roff_a1 = alloc_i(72);
    int* roff_a2 = alloc_i(72);
    int* bscr    = alloc_i(1024);
    int* ulist   = alloc_i(UCAP);
    int* blist   = alloc_i(NCAND);
    int* elist_t = alloc_i(ET);
    int* elist_d = alloc_i(ED);
    int* tookA   = alloc_i(ET);
    int* tookB   = alloc_i(ET);
    int* didA    = alloc_i(ED);
    int* didB    = alloc_i(ED);
    ushort_t* wt     = alloc_h(3 * 32768);           // packed MFMA weights
    ushort_t* x_dc   = alloc_h((size_t)UCAP * Hh);
    ushort_t* x_l    = alloc_h((size_t)NLN * Hh);
    float*    x_a    = alloc_f((size_t)Dd * Hh);
    ushort_t* e_did  = alloc_h((size_t)ED * Hh);
    ushort_t* e_took = alloc_h((size_t)ET * Hh);
    float*    qkvb   = alloc_f((size_t)Dd * 384);
    float*    fbuf   = alloc_f((size_t)Dd * FF);
    float*    part   = alloc_f((size_t)Dd * 16 * Hh);
    float*    cf     = alloc_f((size_t)eoff[NCANON]);
    int*      dflag  = alloc_i(8);

    const float* c_drug_floats  = cf + eoff[0];
    const float* c_lab_floats   = cf + eoff[1];
    const float* c_adm_floats   = cf + eoff[2];
    const float* c_did_floats   = cf + eoff[3];
    const float* c_took_floats  = cf + eoff[4];
    const float* c_drug_id_emb  = cf + eoff[5];
    const float* c_lab_id_emb   = cf + eoff[6];
    const float* c_drug_tok_emb = cf + eoff[7];
    const float* c_lab_tok_emb  = cf + eoff[8];
    const float* c_adm_tok_emb  = cf + eoff[9];
    const float* c_did_tok_emb  = cf + eoff[10];
    const float* c_took_tok_emb = cf + eoff[11];
    const float* c_drug_float_w = cf + eoff[12];
    const float* c_lab_float_w  = cf + eoff[13];
    const float* c_adm_float_w  = cf + eoff[14];
    const float* c_did_float_w  = cf + eoff[15];
    const float* c_took_float_w = cf + eoff[16];
    const float* c_drug_align   = cf + eoff[17];
    const float* c_lab_align    = cf + eoff[18];
    const float* c_adm_align    = cf + eoff[19];
    const float* c_did_align    = cf + eoff[20];
    const float* c_took_align   = cf + eoff[21];
    const float* c_gnn_msg      = cf + eoff[22];
    const float* c_gnn_self     = cf + eoff[23];
    const float* c_qkv_w        = cf + eoff[24];
    const float* c_qkv_b        = cf + eoff[25];
    const float* c_out_w        = cf + eoff[26];
    const float* c_out_b        = cf + eoff[27];
    const float* c_ln1          = cf + eoff[28];
    const float* c_ff1_w        = cf + eoff[29];
    const float* c_ff1_b        = cf + eoff[30];
    const float* c_ff2_w        = cf + eoff[31];
    const float* c_ff2_b        = cf + eoff[32];
    const float* c_ln2          = cf + eoff[33];
    const float* c_lp_w         = cf + eoff[34];

    // ---- canonicalize + graph prep ----
    k_probe<<<1, 64, 0, stream>>>((const unsigned*)d_in[41], dflag);
    k_canon<<<btot_blocks, 256, 0, stream>>>(cd, cf, dflag);
    k_wpack<<<dim3(32, 3), 128, 0, stream>>>(c_gnn_self, c_gnn_msg, wt);
    hipMemsetAsync(map, 0, ZBLOCK * sizeof(int), stream);
    k_mark<<<ET / 256, 256, 0, stream>>>(took_dst, cand_idx, map);
    k_assign<<<(ND + 255) / 256, 256, 0, stream>>>(map, ulist, blist, nUB);
    k_counts<<<ET / 256, 256, 0, stream>>>(did_dst, did_src, took_dst, took_src, map,
                                           cnt_ld, cnt_a1, cnt_dc, cnt_a2);
    k_scan_blk<<<NB_T, 256, 0, stream>>>(cnt_dc, roff_t, bscr, UCAP);
    k_scan_top<<<1, 1024, 0, stream>>>(bscr, NB_T);
    k_scan_add<<<NB_T, 256, 0, stream>>>(roff_t, bscr, UCAP, ET);
    k_scan_blk<<<NB_D, 256, 0, stream>>>(cnt_ld, roff_d, bscr, NLN);
    k_scan_top<<<1, 1024, 0, stream>>>(bscr, NB_D);
    k_scan_add<<<NB_D, 256, 0, stream>>>(roff_d, bscr, NLN, ED);
    k_scan64<<<1, 64, 0, stream>>>(cnt_a1, cnt_a2, roff_a1, roff_a2);
    k_fill<<<ET / 256, 256, 0, stream>>>(did_src, did_dst, took_src, took_dst, map,
                                         roff_d, roff_t, roff_a1, roff_a2,
                                         cur_d, cur_t, cur_a1, cur_a2,
                                         elist_d, elist_t, didA, didB, tookA, tookB);

    // ---- embeddings ----
    k_embed<1,3,2,true,true><<<UCAP / 64, 64, 0, stream>>>(x_dc, 0, nUB, ulist,
        drug_node_id, c_drug_id_emb, drug_tokens, c_drug_tok_emb, c_drug_floats, c_drug_float_w, c_drug_align);
    k_embed<1,2,1,true,false><<<NLN / 64, 64, 0, stream>>>(x_l, NLN, nullptr, nullptr,
        lab_node_id, c_lab_id_emb, lab_tokens, c_lab_tok_emb, c_lab_floats, c_lab_float_w, c_lab_align);
    k_embed<0,4,3,false,false><<<1, 64, 0, stream>>>(x_a, Dd, nullptr, nullptr,
        nullptr, nullptr, adm_tokens, c_adm_tok_emb, c_adm_floats, c_adm_float_w, c_adm_align);
    k_embed<0,2,2,true,false><<<ED / 64, 64, 0, stream>>>(e_did, ED, nullptr, nullptr,
        nullptr, nullptr, did_tokens, c_did_tok_emb, c_did_floats, c_did_float_w, c_did_align);
    k_embed<0,2,1,true,false><<<ET / 64, 64, 0, stream>>>(e_took, ET, nullptr, nullptr,
        nullptr, nullptr, took_tokens, c_took_tok_emb, c_took_floats, c_took_float_w, c_took_align);

    const size_t HH = (size_t)Hh * Hh;

    // ---- GNN layer 1 (relu) ----
    hipMemsetAsync(Sx_did, 0, 2 * (size_t)Dd * Hh * sizeof(float), stream);
    k_srcsum<true><<<(ED + 31) / 32, 64, 0, stream>>>(didA, didB, x_l, e_did, 16,
                                                      Sx_did, E_did, ED, 32);
    k_srcsum<true><<<(ET + 31) / 32, 64, 0, stream>>>(tookA, tookB, x_dc, e_took, 18,
                                                      Sx_took, E_took, ET, 32);
    k_gup<false><<<UCAP / 32, 128, 0, stream>>>(x_dc, x_a, e_took, roff_t, elist_t, 17,
        nullptr, nUB, 0, wt, 1);
    k_gup<false><<<NLN / 32, 128, 0, stream>>>(x_l, x_a, e_did, roff_d, elist_d, 15,
        nullptr, nullptr, NLN, wt + 32768, 1);
    k_xa<<<Dd, 128, 0, stream>>>(x_a, Sx_did, E_did, Sx_took, E_took, cnt_a1, cnt_a2,
        c_gnn_self + 0 * HH, c_gnn_msg + 2 * HH, c_gnn_msg + 3 * HH, 1);

    // ---- GNN layer 2 ----
    const float* Ws1 = c_gnn_self + 3 * HH;
    const float* Wm1 = c_gnn_msg + 4 * HH;
    hipMemsetAsync(Sx_did, 0, 2 * (size_t)Dd * Hh * sizeof(float), stream);
    k_srcsum<false><<<(ED + 31) / 32, 64, 0, stream>>>(didA, didB, x_l, nullptr, 16,
                                                       Sx_did, nullptr, ED, 32);
    k_srcsum<false><<<(ET + 31) / 32, 64, 0, stream>>>(tookA, tookB, x_dc, nullptr, 18,
                                                       Sx_took, nullptr, ET, 32);
    k_gup<true><<<(NCAND + 31) / 32, 128, 0, stream>>>(x_dc, x_a, e_took, roff_t, elist_t, 17,
        blist, nUB + 1, 0, wt + 65536, 0);
    k_xa<<<Dd, 128, 0, stream>>>(x_a, Sx_did, E_did, Sx_took, E_took, cnt_a1, cnt_a2,
        Ws1 + 0 * HH, Wm1 + 2 * HH, Wm1 + 3 * HH, 0);

    // ---- transformer encoder (3 launches/layer) ----
    k_qkv<<<Dd, 128, 0, stream>>>(x_a, qkvb, c_qkv_w, c_qkv_b);
    for (int i = 0; i < L_ENC; i++) {
        k_attn_ff1<<<Dd, 256, 0, stream>>>(qkvb, x_a, fbuf,
            c_out_w + (size_t)i * HH, c_out_b + (size_t)i * Hh, c_ln1 + (size_t)i * 2 * Hh,
            c_ff1_w + (size_t)i * Hh * FF, c_ff1_b + (size_t)i * FF);
        k_ff2p<<<dim3(Dd, 16), 128, 0, stream>>>(fbuf, part, c_ff2_w + (size_t)i * FF * Hh);
        int nx = (i + 1 < L_ENC) ? 1 : 0;
        k_ln2qkv<<<Dd, 128, 0, stream>>>(x_a, part, c_ff2_b + (size_t)i * Hh,
            c_ln2 + (size_t)i * 2 * Hh, qkvb,
            c_qkv_w + (size_t)(nx ? (i + 1) : 0) * Hh * 384,
            c_qkv_b + (size_t)(nx ? (i + 1) : 0) * 384, nx);
    }

    // ---- logits ----
    k_logits<<<Dd - 1, 256, 0, stream>>>(x_dc, map, x_a, c_lp_w, cand_idx, (float*)d_out);
}

// Round 8
// 1658.648 us; speedup vs baseline: 2.3041x; 1.2298x over previous
//
#include <hip/hip_runtime.h>
#include <hip/hip_bf16.h>

typedef unsigned short ushort_t;
typedef __attribute__((ext_vector_type(8))) short bf16x8;
typedef __attribute__((ext_vector_type(4))) float f32x4;

#define DEV __device__ __forceinline__

constexpr int Dd  = 64;
constexpr int VD  = 4525;
constexpr int VL  = 753;
constexpr int ND  = Dd * VD;     // 289600
constexpr int NLN = Dd * VL;     // 48192
constexpr int Hh  = 128;
constexpr int EMB = 10;
constexpr int TV  = 100;
constexpr int NH  = 8, HD = 16;
constexpr int L_ENC = 6, FF = 2048;
constexpr int GL  = 2;
constexpr int ED  = 32768, ET = 131072;
constexpr int KK  = 256;
constexpr int NCAND = (Dd - 1) * KK;       // 16128
constexpr int UCAP  = ET + NCAND;          // 147200
constexpr int NCANON = 35;
constexpr int NB_T = (UCAP + 255) / 256;
constexpr int NB_D = (NLN + 255) / 256;

DEV float bf(ushort_t u) { return __uint_as_float(((unsigned)u) << 16); }
DEV float bflo(unsigned u) { return __uint_as_float(u << 16); }
DEV float bfhi(unsigned u) { return __uint_as_float(u & 0xffff0000u); }
DEV ushort_t f2bf(float f) {
    unsigned u = __float_as_uint(f);
    u += 0x7fffu + ((u >> 16) & 1u);
    return (ushort_t)(u >> 16);
}

// ---------------------------------------------------------------------------
__global__ __launch_bounds__(64)
void k_probe(const unsigned* __restrict__ w, int* __restrict__ flag)
{
    int tid = threadIdx.x;
    int c = 0;
    #pragma unroll
    for (int i = 0; i < 16; i++) c += (w[tid * 16 + i] >> 14) & 1;
    #pragma unroll
    for (int o = 32; o; o >>= 1) c += __shfl_xor(c, o);
    if (tid == 0) *flag = (c > 256) ? 1 : 0;
}

struct CanonDesc {
    const void* src[NCANON];
    int doff[NCANON];
    int bend[NCANON];
    int n[NCANON];
};

__global__ __launch_bounds__(256)
void k_canon(CanonDesc cd, float* __restrict__ dst, const int* __restrict__ flag)
{
    int b = blockIdx.x;
    int t = 0;
    while (t < NCANON && b >= cd.bend[t]) t++;
    if (t >= NCANON) return;
    int bstart = (t == 0) ? 0 : cd.bend[t - 1];
    int i = (b - bstart) * 256 + threadIdx.x;
    if (i >= cd.n[t]) return;
    float v = (*flag) ? ((const float*)cd.src[t])[i]
                      : bf(((const ushort_t*)cd.src[t])[i]);
    dst[cd.doff[t] + i] = v;
}

// pack [Wself;Wmsg] (256x128 fp32) into MFMA B-operand bf16 layout [32][128][8]
__global__ __launch_bounds__(128)
void k_wpack(const float* __restrict__ gself, const float* __restrict__ gmsg,
             ushort_t* __restrict__ wt)
{
    const int selfIdx[3] = {1, 2, 4};   // l1 drug, l1 lab, l2 drug
    const int msgIdx[3]  = {1, 0, 5};
    int pr = blockIdx.y, chunk = blockIdx.x, nn = threadIdx.x;
    const float* Ws = gself + (size_t)selfIdx[pr] * Hh * Hh;
    const float* Wm = gmsg  + (size_t)msgIdx[pr]  * Hh * Hh;
    ushort_t* dst = wt + (((size_t)pr * 32 + chunk) * 128 + nn) * 8;
    #pragma unroll
    for (int j = 0; j < 8; j++) {
        int k = chunk * 8 + j;
        float v = (k < 128) ? Ws[k * Hh + nn] : Wm[(k - 128) * Hh + nn];
        dst[j] = f2bf(v);
    }
}

// ---------------------------------------------------------------------------
__global__ __launch_bounds__(256)
void k_mark(const int* __restrict__ took_dst, const int* __restrict__ cand,
            int* __restrict__ map)
{
    int g = blockIdx.x * 256 + threadIdx.x;
    if (g < ET) atomicOr(&map[took_dst[g]], 1);
    if (g < NCAND) {
        int d = g >> 8;
        atomicOr(&map[d * VD + cand[g]], 2);
    }
}

__global__ __launch_bounds__(256)
void k_assign(int* __restrict__ map, int* __restrict__ ulist, int* __restrict__ blist,
              int* __restrict__ nUB)
{
    int g = blockIdx.x * 256 + threadIdx.x;
    if (g >= ND) return;
    int m = map[g];
    if (m) {
        int s = atomicAdd(&nUB[0], 1);
        ulist[s] = g;
        map[g] = (s << 2) | m;
        if (m & 2) {
            int b = atomicAdd(&nUB[1], 1);
            blist[b] = s;
        }
    }
}

// edge-degree counts: LDS histograms for the 64-entry admission counters
// (device-scope same-address atomics are ~200cyc serialized -> was 210us).
// 128 blocks: 1024 took-edges + 256 did-edges each.
__global__ __launch_bounds__(256)
void k_counts(const int* __restrict__ did_dst, const int* __restrict__ did_src,
              const int* __restrict__ took_dst, const int* __restrict__ took_src,
              const int* __restrict__ map,
              int* __restrict__ cnt_ld, int* __restrict__ cnt_a1,
              int* __restrict__ cnt_dc, int* __restrict__ cnt_a2)
{
    __shared__ int h1[64], h2[64];
    int tid = threadIdx.x;
    if (tid < 64) { h1[tid] = 0; h2[tid] = 0; }
    __syncthreads();
    int tb = blockIdx.x * 1024;
    #pragma unroll
    for (int o = 0; o < 1024; o += 256) {
        int i = tb + o + tid;
        atomicAdd(&cnt_dc[map[took_dst[i]] >> 2], 1);
        atomicAdd(&h2[took_src[i]], 1);
    }
    {
        int i = blockIdx.x * 256 + tid;
        atomicAdd(&cnt_ld[did_dst[i]], 1);
        atomicAdd(&h1[did_src[i]], 1);
    }
    __syncthreads();
    if (tid < 64) {
        if (h1[tid]) atomicAdd(&cnt_a1[tid], h1[tid]);
        if (h2[tid]) atomicAdd(&cnt_a2[tid], h2[tid]);
    }
}

// ---------------------------------------------------------------------------
__global__ __launch_bounds__(256)
void k_scan_blk(const int* __restrict__ cnt, int* __restrict__ excl,
                int* __restrict__ btot, int n)
{
    __shared__ int s[256];
    int tid = threadIdx.x;
    int g = blockIdx.x * 256 + tid;
    int v = (g < n) ? cnt[g] : 0;
    s[tid] = v;
    __syncthreads();
    for (int o = 1; o < 256; o <<= 1) {
        int t = (tid >= o) ? s[tid - o] : 0;
        __syncthreads();
        s[tid] += t;
        __syncthreads();
    }
    if (g < n) excl[g] = s[tid] - v;
    if (tid == 255) btot[blockIdx.x] = s[255];
}

__global__ __launch_bounds__(1024)
void k_scan_top(int* __restrict__ btot, int nb)
{
    __shared__ int s[1024];
    int tid = threadIdx.x;
    int v = (tid < nb) ? btot[tid] : 0;
    s[tid] = v;
    __syncthreads();
    for (int o = 1; o < 1024; o <<= 1) {
        int t = (tid >= o) ? s[tid - o] : 0;
        __syncthreads();
        s[tid] += t;
        __syncthreads();
    }
    if (tid < nb) btot[tid] = s[tid] - v;
}

__global__ __launch_bounds__(256)
void k_scan_add(int* __restrict__ roff, const int* __restrict__ btot, int n, int total)
{
    int g = blockIdx.x * 256 + threadIdx.x;
    if (g < n) roff[g] += btot[blockIdx.x];
    if (g == 0) roff[n] = total;
}

__global__ __launch_bounds__(64)
void k_scan64(const int* __restrict__ c1, const int* __restrict__ c2,
              int* __restrict__ r1, int* __restrict__ r2)
{
    int tid = threadIdx.x;
    int v1 = c1[tid], v2 = c2[tid];
    int s1 = v1, s2 = v2;
    for (int o = 1; o < 64; o <<= 1) {
        int t1 = __shfl_up(s1, o), t2 = __shfl_up(s2, o);
        if (tid >= o) { s1 += t1; s2 += t2; }
    }
    r1[tid] = s1 - v1;
    r2[tid] = s2 - v2;
}

// fill edge lists. Admission lists use count->bulk-reserve->place to avoid
// 64-address device-atomic contention; grouping by src is preserved because
// each src's global region holds only that src (order within is free).
__global__ __launch_bounds__(256)
void k_fill(const int* __restrict__ did_src, const int* __restrict__ did_dst,
            const int* __restrict__ took_src, const int* __restrict__ took_dst,
            const int* __restrict__ map,
            const int* __restrict__ roff_d, const int* __restrict__ roff_t,
            const int* __restrict__ roff_a1, const int* __restrict__ roff_a2,
            int* __restrict__ cur_d, int* __restrict__ cur_t,
            int* __restrict__ cur_a1, int* __restrict__ cur_a2,
            int* __restrict__ elist_d, int* __restrict__ elist_t,
            int* __restrict__ didA, int* __restrict__ didB,
            int* __restrict__ tookA, int* __restrict__ tookB)
{
    __shared__ int h1[64], h2[64], b1[64], b2[64];
    int tid = threadIdx.x;
    if (tid < 64) { h1[tid] = 0; h2[tid] = 0; }
    __syncthreads();
    int tb = blockIdx.x * 1024;
    int db = blockIdx.x * 256;
    #pragma unroll
    for (int o = 0; o < 1024; o += 256)
        atomicAdd(&h2[took_src[tb + o + tid]], 1);
    atomicAdd(&h1[did_src[db + tid]], 1);
    __syncthreads();
    if (tid < 64) {
        b1[tid] = h1[tid] ? atomicAdd(&cur_a1[tid], h1[tid]) : 0;
        b2[tid] = h2[tid] ? atomicAdd(&cur_a2[tid], h2[tid]) : 0;
        h1[tid] = 0; h2[tid] = 0;
    }
    __syncthreads();
    #pragma unroll
    for (int o = 0; o < 1024; o += 256) {
        int i = tb + o + tid;
        int s = took_src[i];
        int slot = map[took_dst[i]] >> 2;
        int pos = roff_t[slot] + atomicAdd(&cur_t[slot], 1);
        elist_t[pos] = (s << 17) | i;
        int pa = roff_a2[s] + b2[s] + atomicAdd(&h2[s], 1);
        tookA[pa] = (s << 18) | slot;
        tookB[pa] = i;
    }
    {
        int i = db + tid;
        int d = did_dst[i], s = did_src[i];
        int pos = roff_d[d] + atomicAdd(&cur_d[d], 1);
        elist_d[pos] = (s << 15) | i;
        int pa = roff_a1[s] + b1[s] + atomicAdd(&h1[s], 1);
        didA[pa] = (s << 16) | d;
        didB[pa] = i;
    }
}

// ---------------------------------------------------------------------------
// segmented src-sum over sorted edge list (epb edges/block)
template<bool DUAL>
__global__ __launch_bounds__(64)
void k_srcsum(const int* __restrict__ lA, const int* __restrict__ lB,
              const ushort_t* __restrict__ xrows, const ushort_t* __restrict__ erows,
              int shift, float* __restrict__ Sx, float* __restrict__ Se,
              int nedge, int epb)
{
    int lane = threadIdx.x;
    int c0 = lane * 2;
    int base = blockIdx.x * epb;
    int end = min(base + epb, nedge);
    int mask = (1 << shift) - 1;
    float ax0 = 0.f, ax1 = 0.f, ae0 = 0.f, ae1 = 0.f;
    int cur = -1;
    for (int i = base; i < end; i++) {
        int pk = lA[i];
        int s = pk >> shift, row = pk & mask;
        if (s != cur) {
            if (cur >= 0) {
                unsafeAtomicAdd(&Sx[cur * Hh + c0], ax0);
                unsafeAtomicAdd(&Sx[cur * Hh + c0 + 1], ax1);
                if (DUAL) {
                    unsafeAtomicAdd(&Se[cur * Hh + c0], ae0);
                    unsafeAtomicAdd(&Se[cur * Hh + c0 + 1], ae1);
                }
            }
            cur = s; ax0 = ax1 = ae0 = ae1 = 0.f;
        }
        unsigned xx = *reinterpret_cast<const unsigned*>(xrows + (size_t)row * Hh + c0);
        ax0 += bflo(xx); ax1 += bfhi(xx);
        if (DUAL) {
            int e = lB[i];
            unsigned ee = *reinterpret_cast<const unsigned*>(erows + (size_t)e * Hh + c0);
            ae0 += bflo(ee); ae1 += bfhi(ee);
        }
    }
    if (cur >= 0) {
        unsafeAtomicAdd(&Sx[cur * Hh + c0], ax0);
        unsafeAtomicAdd(&Sx[cur * Hh + c0 + 1], ax1);
        if (DUAL) {
            unsafeAtomicAdd(&Se[cur * Hh + c0], ae0);
            unsafeAtomicAdd(&Se[cur * Hh + c0 + 1], ae1);
        }
    }
}

// ---------------------------------------------------------------------------
template<int NID, int NTOK, int NF, bool BF16OUT, bool INDIRECT>
__global__ __launch_bounds__(64)
void k_embed(void* __restrict__ out, int n_static, const int* __restrict__ n_dyn,
             const int* __restrict__ ulist,
             const int* __restrict__ id_idx, const float* __restrict__ id_emb,
             const int* __restrict__ tokens, const float* __restrict__ tok_emb,
             const float* __restrict__ floats_, const float* __restrict__ float_w,
             const float* __restrict__ alignf)
{
    constexpr int L = (NID + NTOK + 1) * EMB;
    int slot = blockIdx.x * 64 + threadIdx.x;
    int n = INDIRECT ? *n_dyn : n_static;
    if (slot >= n) return;
    int node = INDIRECT ? ulist[slot] : slot;

    float vec[L];
    int p = 0;
    if constexpr (NID != 0) {
        const float* pe = id_emb + (size_t)id_idx[node] * EMB;
        #pragma unroll
        for (int e = 0; e < EMB; e++) vec[p++] = pe[e];
    }
    #pragma unroll
    for (int t = 0; t < NTOK; t++) {
        const float* pe = tok_emb + ((size_t)t * TV + tokens[node * NTOK + t]) * EMB;
        #pragma unroll
        for (int e = 0; e < EMB; e++) vec[p++] = pe[e];
    }
    {
        float fv[NF];
        #pragma unroll
        for (int f = 0; f < NF; f++) fv[f] = floats_[node * NF + f];
        #pragma unroll
        for (int e = 0; e < EMB; e++) {
            float a = 0.f;
            #pragma unroll
            for (int f = 0; f < NF; f++) a = fmaf(fv[f], float_w[f * EMB + e], a);
            vec[p++] = a;
        }
    }

    #pragma unroll 1
    for (int j = 0; j < Hh; j += 4) {
        float a0 = 0.f, a1 = 0.f, a2 = 0.f, a3 = 0.f;
        #pragma unroll
        for (int i = 0; i < L; i++) {
            const float* w = alignf + i * Hh + j;
            a0 = fmaf(vec[i], w[0], a0);
            a1 = fmaf(vec[i], w[1], a1);
            a2 = fmaf(vec[i], w[2], a2);
            a3 = fmaf(vec[i], w[3], a3);
        }
        if constexpr (BF16OUT) {
            unsigned lo = (unsigned)f2bf(a0) | ((unsigned)f2bf(a1) << 16);
            unsigned hi = (unsigned)f2bf(a2) | ((unsigned)f2bf(a3) << 16);
            uint2 v; v.x = lo; v.y = hi;
            *reinterpret_cast<uint2*>((ushort_t*)out + (size_t)slot * Hh + j) = v;
        } else {
            float4 r4; r4.x = a0; r4.y = a1; r4.z = a2; r4.w = a3;
            *reinterpret_cast<float4*>((float*)out + (size_t)slot * Hh + j) = r4;
        }
    }
}

// ---------------------------------------------------------------------------
// Fused gather + mean + GNN update, MFMA version.
template<bool INDIRECT>
__global__ __launch_bounds__(128)
void k_gup(ushort_t* __restrict__ X, const float* __restrict__ xa,
           const ushort_t* __restrict__ ef,
           const int* __restrict__ roff, const int* __restrict__ elist, int sshift,
           const int* __restrict__ rows_list, const int* __restrict__ n_dyn, int n_static,
           const ushort_t* __restrict__ Wt, int do_relu)
{
    __shared__ ushort_t As[32 * 264];
    __shared__ int rowid[32];
    int tid = threadIdx.x;
    int r0 = blockIdx.x * 32;
    int n = n_dyn ? *n_dyn : n_static;
    if (tid < 32) {
        int row = r0 + tid;
        rowid[tid] = (row < n) ? (INDIRECT ? rows_list[row] : row) : -1;
    }
    __syncthreads();

    for (int idx = tid; idx < 512; idx += 128) {
        int r = idx >> 4, c16 = idx & 15;
        int rr = rowid[r];
        uint4 v = make_uint4(0, 0, 0, 0);
        if (rr >= 0) v = *reinterpret_cast<const uint4*>(X + (size_t)rr * Hh + c16 * 8);
        *reinterpret_cast<uint4*>(&As[r * 264 + c16 * 8]) = v;
    }
    int wid = tid >> 6, lane = tid & 63;
    int c0 = lane * 2;
    int emask = (1 << sshift) - 1;
    for (int r = wid; r < 32; r += 2) {
        int rr = rowid[r];
        float a0 = 0.f, a1 = 0.f, invd = 0.f;
        if (rr >= 0) {
            int e0 = roff[rr], e1 = roff[rr + 1];
            invd = 1.f / fmaxf((float)(e1 - e0), 1.f);
            for (int ei = e0; ei < e1; ei++) {
                int pk = elist[ei];
                int s = pk >> sshift, e = pk & emask;
                const float* xr = xa + s * Hh + c0;
                unsigned ee = *reinterpret_cast<const unsigned*>(ef + (size_t)e * Hh + c0);
                a0 += xr[0] + bflo(ee);
                a1 += xr[1] + bfhi(ee);
            }
        }
        unsigned pk2 = (unsigned)f2bf(a0 * invd) | ((unsigned)f2bf(a1 * invd) << 16);
        *reinterpret_cast<unsigned*>(&As[r * 264 + 128 + c0]) = pk2;
    }
    __syncthreads();

    int m = lane & 15, quad = lane >> 4;
    f32x4 acc[8];
    #pragma unroll
    for (int t = 0; t < 8; t++) acc[t] = (f32x4){0.f, 0.f, 0.f, 0.f};
    #pragma unroll
    for (int kc = 0; kc < 8; kc++) {
        bf16x8 a = *reinterpret_cast<const bf16x8*>(&As[(16 * wid + m) * 264 + kc * 32 + quad * 8]);
        #pragma unroll
        for (int nt = 0; nt < 8; nt++) {
            bf16x8 b = *reinterpret_cast<const bf16x8*>(Wt + (((kc * 4 + quad) * 128) + nt * 16 + m) * 8);
            acc[nt] = __builtin_amdgcn_mfma_f32_16x16x32_bf16(a, b, acc[nt], 0, 0, 0);
        }
    }
    __syncthreads();
    float* Ds = reinterpret_cast<float*>(As);
    #pragma unroll
    for (int nt = 0; nt < 8; nt++)
        #pragma unroll
        for (int reg = 0; reg < 4; reg++)
            Ds[(16 * wid + quad * 4 + reg) * 132 + nt * 16 + m] = acc[nt][reg];
    __syncthreads();
    for (int idx = tid; idx < 512; idx += 128) {
        int r = idx >> 4, c16 = idx & 15;
        int rr = rowid[r];
        if (rr < 0) continue;
        const float* dsrc = &Ds[r * 132 + c16 * 8];
        float o[8];
        #pragma unroll
        for (int c = 0; c < 8; c++) {
            o[c] = dsrc[c];
            if (do_relu) o[c] = fmaxf(o[c], 0.f);
        }
        uint4 v;
        v.x = (unsigned)f2bf(o[0]) | ((unsigned)f2bf(o[1]) << 16);
        v.y = (unsigned)f2bf(o[2]) | ((unsigned)f2bf(o[3]) << 16);
        v.z = (unsigned)f2bf(o[4]) | ((unsigned)f2bf(o[5]) << 16);
        v.w = (unsigned)f2bf(o[6]) | ((unsigned)f2bf(o[7]) << 16);
        *reinterpret_cast<uint4*>(X + (size_t)rr * Hh + c16 * 8) = v;
    }
}

// ---------------------------------------------------------------------------
__global__ __launch_bounds__(128)
void k_xa(float* __restrict__ x_a,
          const float* __restrict__ Sx1, const float* __restrict__ E1,
          const float* __restrict__ Sx2, const float* __restrict__ E2,
          const int* __restrict__ c1, const int* __restrict__ c2,
          const float* __restrict__ Wself, const float* __restrict__ Wm1,
          const float* __restrict__ Wm2, int do_relu)
{
    int r = blockIdx.x, tid = threadIdx.x;
    __shared__ float xr[128], a1[128], a2[128];
    float i1 = 1.f / fmaxf((float)c1[r], 1.f);
    float i2 = 1.f / fmaxf((float)c2[r], 1.f);
    xr[tid] = x_a[r * Hh + tid];
    a1[tid] = (Sx1[r * Hh + tid] + E1[r * Hh + tid]) * i1;
    a2[tid] = (Sx2[r * Hh + tid] + E2[r * Hh + tid]) * i2;
    __syncthreads();
    float acc = 0.f;
    for (int k = 0; k < 128; k++) {
        acc = fmaf(xr[k], Wself[k * Hh + tid], acc);
        acc = fmaf(a1[k], Wm1[k * Hh + tid], acc);
        acc = fmaf(a2[k], Wm2[k * Hh + tid], acc);
    }
    if (do_relu) acc = fmaxf(acc, 0.f);
    x_a[r * Hh + tid] = acc;
}

// ---------------------------------------------------------------------------
__global__ __launch_bounds__(128)
void k_qkv(const float* __restrict__ h, float* __restrict__ qkv,
           const float* __restrict__ W, const float* __restrict__ b)
{
    int r = blockIdx.x, tid = threadIdx.x;
    __shared__ float hr[128];
    hr[tid] = h[r * Hh + tid];
    __syncthreads();
    #pragma unroll
    for (int c0 = 0; c0 < 3; c0++) {
        int c = c0 * 128 + tid;
        float acc = b[c];
        for (int k = 0; k < 128; k++) acc = fmaf(hr[k], W[k * 384 + c], acc);
        qkv[r * 384 + c] = acc;
    }
}

DEV float blocksum128(float v, float* red)
{
    #pragma unroll
    for (int o = 32; o; o >>= 1) v += __shfl_xor(v, o);
    int wid = threadIdx.x >> 6;
    __syncthreads();
    if ((threadIdx.x & 63) == 0) red[wid] = v;
    __syncthreads();
    return red[0] + red[1];
}

DEV float blocksum256(float v, float* red)
{
    #pragma unroll
    for (int o = 32; o; o >>= 1) v += __shfl_xor(v, o);
    int wid = threadIdx.x >> 6;
    __syncthreads();
    if ((threadIdx.x & 63) == 0) red[wid] = v;
    __syncthreads();
    return red[0] + red[1] + red[2] + red[3];
}

// fused attention + out-proj + residual + LN1 + ff1 ; 256 thr, block per q row
__global__ __launch_bounds__(256)
void k_attn_ff1(const float* __restrict__ qkv, float* __restrict__ h,
                float* __restrict__ fbuf,
                const float* __restrict__ Wout, const float* __restrict__ bout,
                const float* __restrict__ ln,
                const float* __restrict__ W1, const float* __restrict__ b1)
{
    int q = blockIdx.x, tid = threadIdx.x;
    __shared__ float sc[NH * Dd];
    __shared__ float o_r[128];
    __shared__ float hr[128];
    __shared__ float red[4];
    int hh = tid >> 4;
    int k0 = (tid & 15) * 4;
    if (tid < 128) {
        const float* qrow = qkv + q * 384 + hh * HD;
        #pragma unroll
        for (int kk = k0; kk < k0 + 4; kk++) {
            const float* krow = qkv + kk * 384 + 128 + hh * HD;
            float s = 0.f;
            #pragma unroll
            for (int d = 0; d < HD; d++) s = fmaf(qrow[d], krow[d], s);
            sc[hh * Dd + kk] = s * 0.25f + (kk <= q ? 0.f : -1e9f);
        }
    }
    __syncthreads();
    float p0 = 0.f, p1 = 0.f, p2 = 0.f, p3 = 0.f;
    if (tid < 128) {
        float mm = -1e30f;
        for (int k = 0; k < Dd; k++) mm = fmaxf(mm, sc[hh * Dd + k]);
        float l = 0.f;
        for (int k = 0; k < Dd; k++) l += __expf(sc[hh * Dd + k] - mm);
        float inv_l = 1.f / l;
        p0 = __expf(sc[hh * Dd + k0]     - mm) * inv_l;
        p1 = __expf(sc[hh * Dd + k0 + 1] - mm) * inv_l;
        p2 = __expf(sc[hh * Dd + k0 + 2] - mm) * inv_l;
        p3 = __expf(sc[hh * Dd + k0 + 3] - mm) * inv_l;
    }
    __syncthreads();
    if (tid < 128) {
        sc[hh * Dd + k0] = p0; sc[hh * Dd + k0 + 1] = p1;
        sc[hh * Dd + k0 + 2] = p2; sc[hh * Dd + k0 + 3] = p3;
    }
    __syncthreads();
    if (tid < 128) {
        int d = tid & 15;
        float o0 = 0.f, o1 = 0.f, o2 = 0.f, o3 = 0.f;
        for (int k = 0; k < Dd; k += 4) {
            o0 = fmaf(sc[hh * Dd + k],     qkv[(k)     * 384 + 256 + hh * HD + d], o0);
            o1 = fmaf(sc[hh * Dd + k + 1], qkv[(k + 1) * 384 + 256 + hh * HD + d], o1);
            o2 = fmaf(sc[hh * Dd + k + 2], qkv[(k + 2) * 384 + 256 + hh * HD + d], o2);
            o3 = fmaf(sc[hh * Dd + k + 3], qkv[(k + 3) * 384 + 256 + hh * HD + d], o3);
        }
        o_r[hh * HD + d] = (o0 + o1) + (o2 + o3);
    }
    __syncthreads();
    float x = 0.f;
    if (tid < 128) {
        float a0 = bout[tid], a1 = 0.f, a2 = 0.f, a3 = 0.f;
        for (int k = 0; k < 128; k += 4) {
            a0 = fmaf(o_r[k],     Wout[(k)     * Hh + tid], a0);
            a1 = fmaf(o_r[k + 1], Wout[(k + 1) * Hh + tid], a1);
            a2 = fmaf(o_r[k + 2], Wout[(k + 2) * Hh + tid], a2);
            a3 = fmaf(o_r[k + 3], Wout[(k + 3) * Hh + tid], a3);
        }
        x = h[q * Hh + tid] + (a0 + a1) + (a2 + a3);
    }
    float mu = blocksum256(x, red) * (1.f / 128.f);
    float dx = (tid < 128) ? (x - mu) : 0.f;
    float var = blocksum256(dx * dx, red) * (1.f / 128.f);
    if (tid < 128) {
        float y = ln[tid] * dx * (1.f / sqrtf(var + 1e-5f)) + ln[128 + tid];
        hr[tid] = y;
        h[q * Hh + tid] = y;
    }
    __syncthreads();
    #pragma unroll 1
    for (int i = 0; i < 8; i++) {
        int c = i * 256 + tid;
        float a = b1[c];
        #pragma unroll 4
        for (int k = 0; k < 128; k++) a = fmaf(hr[k], W1[(size_t)k * FF + c], a);
        fbuf[(size_t)q * FF + c] = fmaxf(a, 0.f);
    }
}

__global__ __launch_bounds__(128)
void k_ff2p(const float* __restrict__ fbuf, float* __restrict__ part,
            const float* __restrict__ W2)
{
    int r = blockIdx.x, pi = blockIdx.y, tid = threadIdx.x;
    int kc = pi * 128;
    const float* f = fbuf + (size_t)r * FF + kc;
    float a0 = 0.f, a1 = 0.f, a2 = 0.f, a3 = 0.f;
    for (int k = 0; k < 128; k += 4) {
        a0 = fmaf(f[k],     W2[(size_t)(kc + k)     * Hh + tid], a0);
        a1 = fmaf(f[k + 1], W2[(size_t)(kc + k + 1) * Hh + tid], a1);
        a2 = fmaf(f[k + 2], W2[(size_t)(kc + k + 2) * Hh + tid], a2);
        a3 = fmaf(f[k + 3], W2[(size_t)(kc + k + 3) * Hh + tid], a3);
    }
    part[(size_t)(r * 16 + pi) * Hh + tid] = (a0 + a1) + (a2 + a3);
}

__global__ __launch_bounds__(128)
void k_ln2qkv(float* __restrict__ h, const float* __restrict__ part,
              const float* __restrict__ b2, const float* __restrict__ ln,
              float* __restrict__ qkv, const float* __restrict__ Wq,
              const float* __restrict__ bq, int do_qkv)
{
    int r = blockIdx.x, tid = threadIdx.x;
    __shared__ float red[2];
    __shared__ float hr[128];
    float acc = b2[tid];
    #pragma unroll
    for (int pi = 0; pi < 16; pi++) acc += part[(size_t)(r * 16 + pi) * Hh + tid];
    float x = h[r * Hh + tid] + acc;
    float mu = blocksum128(x, red) * (1.f / 128.f);
    float dx = x - mu;
    float var = blocksum128(dx * dx, red) * (1.f / 128.f);
    float y = ln[tid] * dx * (1.f / sqrtf(var + 1e-5f)) + ln[128 + tid];
    hr[tid] = y;
    h[r * Hh + tid] = y;
    __syncthreads();
    if (do_qkv) {
        #pragma unroll
        for (int c0 = 0; c0 < 3; c0++) {
            int c = c0 * 128 + tid;
            float a = bq[c];
            for (int k = 0; k < 128; k++) a = fmaf(hr[k], Wq[k * 384 + c], a);
            qkv[r * 384 + c] = a;
        }
    }
}

// ---------------------------------------------------------------------------
__global__ __launch_bounds__(256)
void k_logits(const ushort_t* __restrict__ x_dc, const int* __restrict__ map,
              const float* __restrict__ h, const float* __restrict__ lp,
              const int* __restrict__ cand, float* __restrict__ out)
{
    int d = blockIdx.x;
    int tid = threadIdx.x, lane = tid & 63, w = tid >> 6;
    __shared__ float wv[128];
    if (tid < 128) wv[tid] = h[d * Hh + tid] * lp[tid];
    __syncthreads();
    for (int k = w; k < KK; k += 4) {
        int slot = map[d * VD + cand[d * KK + k]] >> 2;
        const ushort_t* row = x_dc + (size_t)slot * Hh;
        float v = bf(row[lane]) * wv[lane] + bf(row[lane + 64]) * wv[lane + 64];
        #pragma unroll
        for (int o = 32; o; o >>= 1) v += __shfl_xor(v, o);
        if (lane == 0) out[d * KK + k] = v;
    }
}

// ---------------------------------------------------------------------------
extern "C" void kernel_launch(void* const* d_in, const int* in_sizes, int n_in,
                              void* d_out, int out_size, void* d_ws, size_t ws_size,
                              hipStream_t stream)
{
    (void)in_sizes; (void)n_in; (void)out_size; (void)ws_size;

    const int* drug_tokens  = (const int*)d_in[0];
    const int* drug_node_id = (const int*)d_in[1];
    const int* lab_tokens   = (const int*)d_in[3];
    const int* lab_node_id  = (const int*)d_in[4];
    const int* adm_tokens   = (const int*)d_in[6];
    const int* did_tokens   = (const int*)d_in[8];
    const int* did_src      = (const int*)d_in[10];
    const int* did_dst      = (const int*)d_in[11];
    const int* took_tokens  = (const int*)d_in[12];
    const int* took_src     = (const int*)d_in[14];
    const int* took_dst     = (const int*)d_in[15];
    const int* cand_idx     = (const int*)d_in[16];

    const int cidx[NCANON] = {2,5,7,9,13, 17,18,19,20,21,22,23, 24,25,26,27,28,
                              29,30,31,32,33, 34,35, 36,37,38,39,40,41,42,43,44,45,46};
    const int cn[NCANON] = {
        ND*2, NLN*1, Dd*3, ED*2, ET*1,
        VD*EMB, VL*EMB, 3*TV*EMB, 2*TV*EMB, 4*TV*EMB, 2*TV*EMB, 2*TV*EMB,
        2*EMB, 1*EMB, 3*EMB, 2*EMB, 1*EMB,
        5*EMB*Hh, 4*EMB*Hh, 5*EMB*Hh, 3*EMB*Hh, 3*EMB*Hh,
        GL*4*Hh*Hh, GL*3*Hh*Hh,
        L_ENC*Hh*3*Hh, L_ENC*3*Hh, L_ENC*Hh*Hh, L_ENC*Hh, L_ENC*2*Hh,
        L_ENC*Hh*FF, L_ENC*FF, L_ENC*FF*Hh, L_ENC*Hh, L_ENC*2*Hh, Hh
    };
    CanonDesc cd;
    int eoff[NCANON + 1];
    int btot_blocks = 0;
    {
        int e = 0;
        for (int t = 0; t < NCANON; t++) {
            cd.src[t] = d_in[cidx[t]];
            cd.n[t] = cn[t];
            eoff[t] = e;
            cd.doff[t] = e;
            e = (e + cn[t] + 7) & ~7;
            btot_blocks += (cn[t] + 255) / 256;
            cd.bend[t] = btot_blocks;
        }
        eoff[NCANON] = e;
    }

    // ---- workspace carve ----
    char* p = (char*)d_ws;
    auto alloc_f = [&](size_t n) -> float*    { float* r = (float*)p;    p += n * sizeof(float); return r; };
    auto alloc_h = [&](size_t n) -> ushort_t* { ushort_t* r = (ushort_t*)p; p += n * sizeof(ushort_t); return r; };
    auto alloc_i = [&](size_t n) -> int*      { int* r = (int*)p;        p += n * sizeof(int); return r; };

    int* map    = alloc_i(ND);
    int* cnt_dc = alloc_i(UCAP);
    int* cnt_ld = alloc_i(NLN);
    int* cnt_a1 = alloc_i(64);
    int* cnt_a2 = alloc_i(64);
    int* nUB    = alloc_i(8);
    int* cur_t  = alloc_i(UCAP);
    int* cur_d  = alloc_i(NLN);
    int* cur_a1 = alloc_i(64);
    int* cur_a2 = alloc_i(64);
    float* E_did  = alloc_f((size_t)Dd * Hh);
    float* E_took = alloc_f((size_t)Dd * Hh);
    const size_t ZBLOCK = (size_t)ND + UCAP + NLN + 64 + 64 + 8 + UCAP + NLN + 64 + 64
                        + (size_t)Dd * Hh * 2;
    float* Sx_did  = alloc_f((size_t)Dd * Hh);
    float* Sx_took = alloc_f((size_t)Dd * Hh);
    int* roff_t  = alloc_i(UCAP + 8);
    int* roff_d  = alloc_i(NLN + 8);
    int* roff_a1 = alloc_i(72);
    int* roff_a2 = alloc_i(72);
    int* bscr    = alloc_i(1024);
    int* ulist   = alloc_i(UCAP);
    int* blist   = alloc_i(NCAND);
    int* elist_t = alloc_i(ET);
    int* elist_d = alloc_i(ED);
    int* tookA   = alloc_i(ET);
    int* tookB   = alloc_i(ET);
    int* didA    = alloc_i(ED);
    int* didB    = alloc_i(ED);
    ushort_t* wt     = alloc_h(3 * 32768);
    ushort_t* x_dc   = alloc_h((size_t)UCAP * Hh);
    ushort_t* x_l    = alloc_h((size_t)NLN * Hh);
    float*    x_a    = alloc_f((size_t)Dd * Hh);
    ushort_t* e_did  = alloc_h((size_t)ED * Hh);
    ushort_t* e_took = alloc_h((size_t)ET * Hh);
    float*    qkvb   = alloc_f((size_t)Dd * 384);
    float*    fbuf   = alloc_f((size_t)Dd * FF);
    float*    part   = alloc_f((size_t)Dd * 16 * Hh);
    float*    cf     = alloc_f((size_t)eoff[NCANON]);
    int*      dflag  = alloc_i(8);

    const float* c_drug_floats  = cf + eoff[0];
    const float* c_lab_floats   = cf + eoff[1];
    const float* c_adm_floats   = cf + eoff[2];
    const float* c_did_floats   = cf + eoff[3];
    const float* c_took_floats  = cf + eoff[4];
    const float* c_drug_id_emb  = cf + eoff[5];
    const float* c_lab_id_emb   = cf + eoff[6];
    const float* c_drug_tok_emb = cf + eoff[7];
    const float* c_lab_tok_emb  = cf + eoff[8];
    const float* c_adm_tok_emb  = cf + eoff[9];
    const float* c_did_tok_emb  = cf + eoff[10];
    const float* c_took_tok_emb = cf + eoff[11];
    const float* c_drug_float_w = cf + eoff[12];
    const float* c_lab_float_w  = cf + eoff[13];
    const float* c_adm_float_w  = cf + eoff[14];
    const float* c_did_float_w  = cf + eoff[15];
    const float* c_took_float_w = cf + eoff[16];
    const float* c_drug_align   = cf + eoff[17];
    const float* c_lab_align    = cf + eoff[18];
    const float* c_adm_align    = cf + eoff[19];
    const float* c_did_align    = cf + eoff[20];
    const float* c_took_align   = cf + eoff[21];
    const float* c_gnn_msg      = cf + eoff[22];
    const float* c_gnn_self     = cf + eoff[23];
    const float* c_qkv_w        = cf + eoff[24];
    const float* c_qkv_b        = cf + eoff[25];
    const float* c_out_w        = cf + eoff[26];
    const float* c_out_b        = cf + eoff[27];
    const float* c_ln1          = cf + eoff[28];
    const float* c_ff1_w        = cf + eoff[29];
    const float* c_ff1_b        = cf + eoff[30];
    const float* c_ff2_w        = cf + eoff[31];
    const float* c_ff2_b        = cf + eoff[32];
    const float* c_ln2          = cf + eoff[33];
    const float* c_lp_w         = cf + eoff[34];

    // ---- canonicalize + graph prep ----
    k_probe<<<1, 64, 0, stream>>>((const unsigned*)d_in[41], dflag);
    k_canon<<<btot_blocks, 256, 0, stream>>>(cd, cf, dflag);
    k_wpack<<<dim3(32, 3), 128, 0, stream>>>(c_gnn_self, c_gnn_msg, wt);
    hipMemsetAsync(map, 0, ZBLOCK * sizeof(int), stream);
    k_mark<<<ET / 256, 256, 0, stream>>>(took_dst, cand_idx, map);
    k_assign<<<(ND + 255) / 256, 256, 0, stream>>>(map, ulist, blist, nUB);
    k_counts<<<128, 256, 0, stream>>>(did_dst, did_src, took_dst, took_src, map,
                                      cnt_ld, cnt_a1, cnt_dc, cnt_a2);
    k_scan_blk<<<NB_T, 256, 0, stream>>>(cnt_dc, roff_t, bscr, UCAP);
    k_scan_top<<<1, 1024, 0, stream>>>(bscr, NB_T);
    k_scan_add<<<NB_T, 256, 0, stream>>>(roff_t, bscr, UCAP, ET);
    k_scan_blk<<<NB_D, 256, 0, stream>>>(cnt_ld, roff_d, bscr, NLN);
    k_scan_top<<<1, 1024, 0, stream>>>(bscr, NB_D);
    k_scan_add<<<NB_D, 256, 0, stream>>>(roff_d, bscr, NLN, ED);
    k_scan64<<<1, 64, 0, stream>>>(cnt_a1, cnt_a2, roff_a1, roff_a2);
    k_fill<<<128, 256, 0, stream>>>(did_src, did_dst, took_src, took_dst, map,
                                    roff_d, roff_t, roff_a1, roff_a2,
                                    cur_d, cur_t, cur_a1, cur_a2,
                                    elist_d, elist_t, didA, didB, tookA, tookB);

    // ---- embeddings ----
    k_embed<1,3,2,true,true><<<UCAP / 64, 64, 0, stream>>>(x_dc, 0, nUB, ulist,
        drug_node_id, c_drug_id_emb, drug_tokens, c_drug_tok_emb, c_drug_floats, c_drug_float_w, c_drug_align);
    k_embed<1,2,1,true,false><<<NLN / 64, 64, 0, stream>>>(x_l, NLN, nullptr, nullptr,
        lab_node_id, c_lab_id_emb, lab_tokens, c_lab_tok_emb, c_lab_floats, c_lab_float_w, c_lab_align);
    k_embed<0,4,3,false,false><<<1, 64, 0, stream>>>(x_a, Dd, nullptr, nullptr,
        nullptr, nullptr, adm_tokens, c_adm_tok_emb, c_adm_floats, c_adm_float_w, c_adm_align);
    k_embed<0,2,2,true,false><<<ED / 64, 64, 0, stream>>>(e_did, ED, nullptr, nullptr,
        nullptr, nullptr, did_tokens, c_did_tok_emb, c_did_floats, c_did_float_w, c_did_align);
    k_embed<0,2,1,true,false><<<ET / 64, 64, 0, stream>>>(e_took, ET, nullptr, nullptr,
        nullptr, nullptr, took_tokens, c_took_tok_emb, c_took_floats, c_took_float_w, c_took_align);

    const size_t HH = (size_t)Hh * Hh;

    // ---- GNN layer 1 (relu) ----
    hipMemsetAsync(Sx_did, 0, 2 * (size_t)Dd * Hh * sizeof(float), stream);
    k_srcsum<true><<<(ED + 31) / 32, 64, 0, stream>>>(didA, didB, x_l, e_did, 16,
                                                      Sx_did, E_did, ED, 32);
    k_srcsum<true><<<(ET + 31) / 32, 64, 0, stream>>>(tookA, tookB, x_dc, e_took, 18,
                                                      Sx_took, E_took, ET, 32);
    k_gup<false><<<UCAP / 32, 128, 0, stream>>>(x_dc, x_a, e_took, roff_t, elist_t, 17,
        nullptr, nUB, 0, wt, 1);
    k_gup<false><<<NLN / 32, 128, 0, stream>>>(x_l, x_a, e_did, roff_d, elist_d, 15,
        nullptr, nullptr, NLN, wt + 32768, 1);
    k_xa<<<Dd, 128, 0, stream>>>(x_a, Sx_did, E_did, Sx_took, E_took, cnt_a1, cnt_a2,
        c_gnn_self + 0 * HH, c_gnn_msg + 2 * HH, c_gnn_msg + 3 * HH, 1);

    // ---- GNN layer 2 ----
    const float* Ws1 = c_gnn_self + 3 * HH;
    const float* Wm1 = c_gnn_msg + 4 * HH;
    hipMemsetAsync(Sx_did, 0, 2 * (size_t)Dd * Hh * sizeof(float), stream);
    k_srcsum<false><<<(ED + 31) / 32, 64, 0, stream>>>(didA, didB, x_l, nullptr, 16,
                                                       Sx_did, nullptr, ED, 32);
    k_srcsum<false><<<(ET + 31) / 32, 64, 0, stream>>>(tookA, tookB, x_dc, nullptr, 18,
                                                       Sx_took, nullptr, ET, 32);
    k_gup<true><<<(NCAND + 31) / 32, 128, 0, stream>>>(x_dc, x_a, e_took, roff_t, elist_t, 17,
        blist, nUB + 1, 0, wt + 65536, 0);
    k_xa<<<Dd, 128, 0, stream>>>(x_a, Sx_did, E_did, Sx_took, E_took, cnt_a1, cnt_a2,
        Ws1 + 0 * HH, Wm1 + 2 * HH, Wm1 + 3 * HH, 0);

    // ---- transformer encoder (3 launches/layer) ----
    k_qkv<<<Dd, 128, 0, stream>>>(x_a, qkvb, c_qkv_w, c_qkv_b);
    for (int i = 0; i < L_ENC; i++) {
        k_attn_ff1<<<Dd, 256, 0, stream>>>(qkvb, x_a, fbuf,
            c_out_w + (size_t)i * HH, c_out_b + (size_t)i * Hh, c_ln1 + (size_t)i * 2 * Hh,
            c_ff1_w + (size_t)i * Hh * FF, c_ff1_b + (size_t)i * FF);
        k_ff2p<<<dim3(Dd, 16), 128, 0, stream>>>(fbuf, part, c_ff2_w + (size_t)i * FF * Hh);
        int nx = (i + 1 < L_ENC) ? 1 : 0;
        k_ln2qkv<<<Dd, 128, 0, stream>>>(x_a, part, c_ff2_b + (size_t)i * Hh,
            c_ln2 + (size_t)i * 2 * Hh, qkvb,
            c_qkv_w + (size_t)(nx ? (i + 1) : 0) * Hh * 384,
            c_qkv_b + (size_t)(nx ? (i + 1) : 0) * 384, nx);
    }

    // ---- logits ----
    k_logits<<<Dd - 1, 256, 0, stream>>>(x_dc, map, x_a, c_lp_w, cand_idx, (float*)d_out);
}

// Round 9
// 1439.783 us; speedup vs baseline: 2.6544x; 1.1520x over previous
//
#include <hip/hip_runtime.h>
#include <hip/hip_bf16.h>

typedef unsigned short ushort_t;
typedef __attribute__((ext_vector_type(8))) short bf16x8;
typedef __attribute__((ext_vector_type(4))) float f32x4;

#define DEV __device__ __forceinline__

constexpr int Dd  = 64;
constexpr int VD  = 4525;
constexpr int VL  = 753;
constexpr int ND  = Dd * VD;     // 289600
constexpr int NLN = Dd * VL;     // 48192
constexpr int Hh  = 128;
constexpr int EMB = 10;
constexpr int TV  = 100;
constexpr int NH  = 8, HD = 16;
constexpr int L_ENC = 6, FF = 2048;
constexpr int GL  = 2;
constexpr int ED  = 32768, ET = 131072;
constexpr int KK  = 256;
constexpr int NCAND = (Dd - 1) * KK;       // 16128
constexpr int UCAP  = ET + NCAND;          // 147200
constexpr int NCANON = 35;
constexpr int NB_T = (UCAP + 255) / 256;
constexpr int NB_D = (NLN + 255) / 256;

DEV float bf(ushort_t u) { return __uint_as_float(((unsigned)u) << 16); }
DEV float bflo(unsigned u) { return __uint_as_float(u << 16); }
DEV float bfhi(unsigned u) { return __uint_as_float(u & 0xffff0000u); }
DEV ushort_t f2bf(float f) {
    unsigned u = __float_as_uint(f);
    u += 0x7fffu + ((u >> 16) & 1u);
    return (ushort_t)(u >> 16);
}

// ---------------------------------------------------------------------------
__global__ __launch_bounds__(64)
void k_probe(const unsigned* __restrict__ w, int* __restrict__ flag)
{
    int tid = threadIdx.x;
    int c = 0;
    #pragma unroll
    for (int i = 0; i < 16; i++) c += (w[tid * 16 + i] >> 14) & 1;
    #pragma unroll
    for (int o = 32; o; o >>= 1) c += __shfl_xor(c, o);
    if (tid == 0) *flag = (c > 256) ? 1 : 0;
}

struct CanonDesc {
    const void* src[NCANON];
    int doff[NCANON];
    int bend[NCANON];
    int n[NCANON];
};

__global__ __launch_bounds__(256)
void k_canon(CanonDesc cd, float* __restrict__ dst, const int* __restrict__ flag)
{
    int b = blockIdx.x;
    int t = 0;
    while (t < NCANON && b >= cd.bend[t]) t++;
    if (t >= NCANON) return;
    int bstart = (t == 0) ? 0 : cd.bend[t - 1];
    int i = (b - bstart) * 256 + threadIdx.x;
    if (i >= cd.n[t]) return;
    float v = (*flag) ? ((const float*)cd.src[t])[i]
                      : bf(((const ushort_t*)cd.src[t])[i]);
    dst[cd.doff[t] + i] = v;
}

// pack [Wself;Wmsg] (256x128 fp32) into MFMA B-operand bf16 layout
__global__ __launch_bounds__(128)
void k_wpack(const float* __restrict__ gself, const float* __restrict__ gmsg,
             ushort_t* __restrict__ wt)
{
    const int selfIdx[3] = {1, 2, 4};
    const int msgIdx[3]  = {1, 0, 5};
    int pr = blockIdx.y, chunk = blockIdx.x, nn = threadIdx.x;
    const float* Ws = gself + (size_t)selfIdx[pr] * Hh * Hh;
    const float* Wm = gmsg  + (size_t)msgIdx[pr]  * Hh * Hh;
    ushort_t* dst = wt + (((size_t)pr * 32 + chunk) * 128 + nn) * 8;
    #pragma unroll
    for (int j = 0; j < 8; j++) {
        int k = chunk * 8 + j;
        float v = (k < 128) ? Ws[k * Hh + nn] : Wm[(k - 128) * Hh + nn];
        dst[j] = f2bf(v);
    }
}

// pack an align matrix [L x 128] fp32 -> MFMA B layout bf16, K padded w/ zeros
__global__ __launch_bounds__(128)
void k_apack(const float* __restrict__ A, ushort_t* __restrict__ dst, int L)
{
    int c = blockIdx.x, nn = threadIdx.x;
    ushort_t* d = dst + ((size_t)c * 128 + nn) * 8;
    #pragma unroll
    for (int j = 0; j < 8; j++) {
        int k = c * 8 + j;
        d[j] = (k < L) ? f2bf(A[(size_t)k * Hh + nn]) : (ushort_t)0;
    }
}

// ---------------------------------------------------------------------------
__global__ __launch_bounds__(256)
void k_mark(const int* __restrict__ took_dst, const int* __restrict__ cand,
            int* __restrict__ map)
{
    int g = blockIdx.x * 256 + threadIdx.x;
    if (g < ET) atomicOr(&map[took_dst[g]], 1);
    if (g < NCAND) {
        int d = g >> 8;
        atomicOr(&map[d * VD + cand[g]], 2);
    }
}

__global__ __launch_bounds__(256)
void k_assign(int* __restrict__ map, int* __restrict__ ulist, int* __restrict__ blist,
              int* __restrict__ nUB)
{
    int g = blockIdx.x * 256 + threadIdx.x;
    if (g >= ND) return;
    int m = map[g];
    if (m) {
        int s = atomicAdd(&nUB[0], 1);
        ulist[s] = g;
        map[g] = (s << 2) | m;
        if (m & 2) {
            int b = atomicAdd(&nUB[1], 1);
            blist[b] = s;
        }
    }
}

__global__ __launch_bounds__(256)
void k_counts(const int* __restrict__ did_dst, const int* __restrict__ did_src,
              const int* __restrict__ took_dst, const int* __restrict__ took_src,
              const int* __restrict__ map,
              int* __restrict__ cnt_ld, int* __restrict__ cnt_a1,
              int* __restrict__ cnt_dc, int* __restrict__ cnt_a2)
{
    __shared__ int h1[64], h2[64];
    int tid = threadIdx.x;
    if (tid < 64) { h1[tid] = 0; h2[tid] = 0; }
    __syncthreads();
    int tb = blockIdx.x * 1024;
    #pragma unroll
    for (int o = 0; o < 1024; o += 256) {
        int i = tb + o + tid;
        atomicAdd(&cnt_dc[map[took_dst[i]] >> 2], 1);
        atomicAdd(&h2[took_src[i]], 1);
    }
    {
        int i = blockIdx.x * 256 + tid;
        atomicAdd(&cnt_ld[did_dst[i]], 1);
        atomicAdd(&h1[did_src[i]], 1);
    }
    __syncthreads();
    if (tid < 64) {
        if (h1[tid]) atomicAdd(&cnt_a1[tid], h1[tid]);
        if (h2[tid]) atomicAdd(&cnt_a2[tid], h2[tid]);
    }
}

// ---------------------------------------------------------------------------
__global__ __launch_bounds__(256)
void k_scan_blk(const int* __restrict__ cnt, int* __restrict__ excl,
                int* __restrict__ btot, int n)
{
    __shared__ int s[256];
    int tid = threadIdx.x;
    int g = blockIdx.x * 256 + tid;
    int v = (g < n) ? cnt[g] : 0;
    s[tid] = v;
    __syncthreads();
    for (int o = 1; o < 256; o <<= 1) {
        int t = (tid >= o) ? s[tid - o] : 0;
        __syncthreads();
        s[tid] += t;
        __syncthreads();
    }
    if (g < n) excl[g] = s[tid] - v;
    if (tid == 255) btot[blockIdx.x] = s[255];
}

__global__ __launch_bounds__(1024)
void k_scan_top(int* __restrict__ btot, int nb)
{
    __shared__ int s[1024];
    int tid = threadIdx.x;
    int v = (tid < nb) ? btot[tid] : 0;
    s[tid] = v;
    __syncthreads();
    for (int o = 1; o < 1024; o <<= 1) {
        int t = (tid >= o) ? s[tid - o] : 0;
        __syncthreads();
        s[tid] += t;
        __syncthreads();
    }
    if (tid < nb) btot[tid] = s[tid] - v;
}

__global__ __launch_bounds__(256)
void k_scan_add(int* __restrict__ roff, const int* __restrict__ btot, int n, int total)
{
    int g = blockIdx.x * 256 + threadIdx.x;
    if (g < n) roff[g] += btot[blockIdx.x];
    if (g == 0) roff[n] = total;
}

__global__ __launch_bounds__(64)
void k_scan64(const int* __restrict__ c1, const int* __restrict__ c2,
              int* __restrict__ r1, int* __restrict__ r2)
{
    int tid = threadIdx.x;
    int v1 = c1[tid], v2 = c2[tid];
    int s1 = v1, s2 = v2;
    for (int o = 1; o < 64; o <<= 1) {
        int t1 = __shfl_up(s1, o), t2 = __shfl_up(s2, o);
        if (tid >= o) { s1 += t1; s2 += t2; }
    }
    r1[tid] = s1 - v1;
    r2[tid] = s2 - v2;
}

__global__ __launch_bounds__(256)
void k_fill(const int* __restrict__ did_src, const int* __restrict__ did_dst,
            const int* __restrict__ took_src, const int* __restrict__ took_dst,
            const int* __restrict__ map,
            const int* __restrict__ roff_d, const int* __restrict__ roff_t,
            const int* __restrict__ roff_a1, const int* __restrict__ roff_a2,
            int* __restrict__ cur_d, int* __restrict__ cur_t,
            int* __restrict__ cur_a1, int* __restrict__ cur_a2,
            int* __restrict__ elist_d, int* __restrict__ elist_t,
            int* __restrict__ didA, int* __restrict__ didB,
            int* __restrict__ tookA, int* __restrict__ tookB)
{
    __shared__ int h1[64], h2[64], b1[64], b2[64];
    int tid = threadIdx.x;
    if (tid < 64) { h1[tid] = 0; h2[tid] = 0; }
    __syncthreads();
    int tb = blockIdx.x * 1024;
    int db = blockIdx.x * 256;
    #pragma unroll
    for (int o = 0; o < 1024; o += 256)
        atomicAdd(&h2[took_src[tb + o + tid]], 1);
    atomicAdd(&h1[did_src[db + tid]], 1);
    __syncthreads();
    if (tid < 64) {
        b1[tid] = h1[tid] ? atomicAdd(&cur_a1[tid], h1[tid]) : 0;
        b2[tid] = h2[tid] ? atomicAdd(&cur_a2[tid], h2[tid]) : 0;
        h1[tid] = 0; h2[tid] = 0;
    }
    __syncthreads();
    #pragma unroll
    for (int o = 0; o < 1024; o += 256) {
        int i = tb + o + tid;
        int s = took_src[i];
        int slot = map[took_dst[i]] >> 2;
        int pos = roff_t[slot] + atomicAdd(&cur_t[slot], 1);
        elist_t[pos] = (s << 17) | i;
        int pa = roff_a2[s] + b2[s] + atomicAdd(&h2[s], 1);
        tookA[pa] = (s << 18) | slot;
        tookB[pa] = i;
    }
    {
        int i = db + tid;
        int d = did_dst[i], s = did_src[i];
        int pos = roff_d[d] + atomicAdd(&cur_d[d], 1);
        elist_d[pos] = (s << 15) | i;
        int pa = roff_a1[s] + b1[s] + atomicAdd(&h1[s], 1);
        didA[pa] = (s << 16) | d;
        didB[pa] = i;
    }
}

// ---------------------------------------------------------------------------
template<bool DUAL>
__global__ __launch_bounds__(64)
void k_srcsum(const int* __restrict__ lA, const int* __restrict__ lB,
              const ushort_t* __restrict__ xrows, const ushort_t* __restrict__ erows,
              int shift, float* __restrict__ Sx, float* __restrict__ Se,
              int nedge, int epb)
{
    int lane = threadIdx.x;
    int c0 = lane * 2;
    int base = blockIdx.x * epb;
    int end = min(base + epb, nedge);
    int mask = (1 << shift) - 1;
    float ax0 = 0.f, ax1 = 0.f, ae0 = 0.f, ae1 = 0.f;
    int cur = -1;
    for (int i = base; i < end; i++) {
        int pk = lA[i];
        int s = pk >> shift, row = pk & mask;
        if (s != cur) {
            if (cur >= 0) {
                unsafeAtomicAdd(&Sx[cur * Hh + c0], ax0);
                unsafeAtomicAdd(&Sx[cur * Hh + c0 + 1], ax1);
                if (DUAL) {
                    unsafeAtomicAdd(&Se[cur * Hh + c0], ae0);
                    unsafeAtomicAdd(&Se[cur * Hh + c0 + 1], ae1);
                }
            }
            cur = s; ax0 = ax1 = ae0 = ae1 = 0.f;
        }
        unsigned xx = *reinterpret_cast<const unsigned*>(xrows + (size_t)row * Hh + c0);
        ax0 += bflo(xx); ax1 += bfhi(xx);
        if (DUAL) {
            int e = lB[i];
            unsigned ee = *reinterpret_cast<const unsigned*>(erows + (size_t)e * Hh + c0);
            ae0 += bflo(ee); ae1 += bfhi(ee);
        }
    }
    if (cur >= 0) {
        unsafeAtomicAdd(&Sx[cur * Hh + c0], ax0);
        unsafeAtomicAdd(&Sx[cur * Hh + c0 + 1], ax1);
        if (DUAL) {
            unsafeAtomicAdd(&Se[cur * Hh + c0], ae0);
            unsafeAtomicAdd(&Se[cur * Hh + c0 + 1], ae1);
        }
    }
}

// ---------------------------------------------------------------------------
// scalar embed (kept only for adm; 1 block)
template<int NID, int NTOK, int NF>
__global__ __launch_bounds__(64)
void k_embed(float* __restrict__ out, int n,
             const int* __restrict__ id_idx, const float* __restrict__ id_emb,
             const int* __restrict__ tokens, const float* __restrict__ tok_emb,
             const float* __restrict__ floats_, const float* __restrict__ float_w,
             const float* __restrict__ alignf)
{
    constexpr int L = (NID + NTOK + 1) * EMB;
    int node = blockIdx.x * 64 + threadIdx.x;
    if (node >= n) return;
    float vec[L];
    int p = 0;
    if constexpr (NID != 0) {
        const float* pe = id_emb + (size_t)id_idx[node] * EMB;
        #pragma unroll
        for (int e = 0; e < EMB; e++) vec[p++] = pe[e];
    }
    #pragma unroll
    for (int t = 0; t < NTOK; t++) {
        const float* pe = tok_emb + ((size_t)t * TV + tokens[node * NTOK + t]) * EMB;
        #pragma unroll
        for (int e = 0; e < EMB; e++) vec[p++] = pe[e];
    }
    {
        float fv[NF];
        #pragma unroll
        for (int f = 0; f < NF; f++) fv[f] = floats_[node * NF + f];
        #pragma unroll
        for (int e = 0; e < EMB; e++) {
            float a = 0.f;
            #pragma unroll
            for (int f = 0; f < NF; f++) a = fmaf(fv[f], float_w[f * EMB + e], a);
            vec[p++] = a;
        }
    }
    #pragma unroll 1
    for (int j = 0; j < Hh; j += 4) {
        float a0 = 0.f, a1 = 0.f, a2 = 0.f, a3 = 0.f;
        #pragma unroll
        for (int i = 0; i < L; i++) {
            const float* w = alignf + i * Hh + j;
            a0 = fmaf(vec[i], w[0], a0);
            a1 = fmaf(vec[i], w[1], a1);
            a2 = fmaf(vec[i], w[2], a2);
            a3 = fmaf(vec[i], w[3], a3);
        }
        float4 r4; r4.x = a0; r4.y = a1; r4.z = a2; r4.w = a3;
        *reinterpret_cast<float4*>(out + (size_t)node * Hh + j) = r4;
    }
}

// MFMA embed: 32 nodes/block; 128-thread parallel gather into bf16 LDS A-tile,
// then 32xK @ Kx128 MFMA with pre-packed align B.
template<int NID, int NTOK, int NF, int KCH, bool INDIRECT>
__global__ __launch_bounds__(128)
void k_embed_m(ushort_t* __restrict__ out, int n_static, const int* __restrict__ n_dyn,
               const int* __restrict__ ulist,
               const int* __restrict__ id_idx, const float* __restrict__ id_emb,
               const int* __restrict__ tokens, const float* __restrict__ tok_emb,
               const float* __restrict__ floats_, const float* __restrict__ float_w,
               const ushort_t* __restrict__ Bp)
{
    constexpr int NSEG = NID + NTOK + 1;
    constexpr int K = KCH * 32;
    constexpr int STR = K + 8;          // bf16 stride; *2B is a 16B multiple
    __shared__ ushort_t As[32 * 264];   // 16.9 KB, reused as Ds (float[32][132])
    __shared__ int nodeid[32];
    int tid = threadIdx.x;
    int r0 = blockIdx.x * 32;
    int n = INDIRECT ? *n_dyn : n_static;
    if (tid < 32) {
        int slot = r0 + tid;
        nodeid[tid] = (slot < n) ? (INDIRECT ? ulist[slot] : slot) : -1;
    }
    for (int i = tid; i < 32 * STR; i += 128) As[i] = 0;
    __syncthreads();

    for (int pi = tid; pi < 32 * NSEG; pi += 128) {
        int seg = pi >> 5, nl = pi & 31;
        int node = nodeid[nl];
        if (node < 0) continue;
        float v[EMB];
        if (NID != 0 && seg == 0) {
            const float* pe = id_emb + (size_t)id_idx[node] * EMB;
            #pragma unroll
            for (int e = 0; e < EMB; e++) v[e] = pe[e];
        } else if (seg < NID + NTOK) {
            int t = seg - NID;
            const float* pe = tok_emb + ((size_t)t * TV + tokens[node * NTOK + t]) * EMB;
            #pragma unroll
            for (int e = 0; e < EMB; e++) v[e] = pe[e];
        } else {
            float fv[NF];
            #pragma unroll
            for (int f = 0; f < NF; f++) fv[f] = floats_[node * NF + f];
            #pragma unroll
            for (int e = 0; e < EMB; e++) {
                float a = 0.f;
                #pragma unroll
                for (int f = 0; f < NF; f++) a = fmaf(fv[f], float_w[f * EMB + e], a);
                v[e] = a;
            }
        }
        ushort_t* dst = &As[nl * STR + seg * EMB];
        #pragma unroll
        for (int e = 0; e < EMB; e += 2) {
            unsigned pk = (unsigned)f2bf(v[e]) | ((unsigned)f2bf(v[e + 1]) << 16);
            *reinterpret_cast<unsigned*>(dst + e) = pk;
        }
    }
    __syncthreads();

    int wid = tid >> 6, lane = tid & 63;
    int m = lane & 15, quad = lane >> 4;
    f32x4 acc[8];
    #pragma unroll
    for (int t = 0; t < 8; t++) acc[t] = (f32x4){0.f, 0.f, 0.f, 0.f};
    #pragma unroll
    for (int kc = 0; kc < KCH; kc++) {
        bf16x8 a = *reinterpret_cast<const bf16x8*>(&As[(16 * wid + m) * STR + kc * 32 + quad * 8]);
        #pragma unroll
        for (int nt = 0; nt < 8; nt++) {
            bf16x8 b = *reinterpret_cast<const bf16x8*>(Bp + (((kc * 4 + quad) * 128) + nt * 16 + m) * 8);
            acc[nt] = __builtin_amdgcn_mfma_f32_16x16x32_bf16(a, b, acc[nt], 0, 0, 0);
        }
    }
    __syncthreads();
    float* Ds = reinterpret_cast<float*>(As);
    #pragma unroll
    for (int nt = 0; nt < 8; nt++)
        #pragma unroll
        for (int reg = 0; reg < 4; reg++)
            Ds[(16 * wid + quad * 4 + reg) * 132 + nt * 16 + m] = acc[nt][reg];
    __syncthreads();
    for (int idx = tid; idx < 512; idx += 128) {
        int r = idx >> 4, c16 = idx & 15;
        int slot = r0 + r;
        if (slot >= n) continue;
        const float* dsrc = &Ds[r * 132 + c16 * 8];
        uint4 v;
        v.x = (unsigned)f2bf(dsrc[0]) | ((unsigned)f2bf(dsrc[1]) << 16);
        v.y = (unsigned)f2bf(dsrc[2]) | ((unsigned)f2bf(dsrc[3]) << 16);
        v.z = (unsigned)f2bf(dsrc[4]) | ((unsigned)f2bf(dsrc[5]) << 16);
        v.w = (unsigned)f2bf(dsrc[6]) | ((unsigned)f2bf(dsrc[7]) << 16);
        *reinterpret_cast<uint4*>(out + (size_t)slot * Hh + c16 * 8) = v;
    }
}

// ---------------------------------------------------------------------------
// Fused gather + mean + GNN update, MFMA version.
template<bool INDIRECT>
__global__ __launch_bounds__(128)
void k_gup(ushort_t* __restrict__ X, const float* __restrict__ xa,
           const ushort_t* __restrict__ ef,
           const int* __restrict__ roff, const int* __restrict__ elist, int sshift,
           const int* __restrict__ rows_list, const int* __restrict__ n_dyn, int n_static,
           const ushort_t* __restrict__ Wt, int do_relu)
{
    __shared__ ushort_t As[32 * 264];
    __shared__ int rowid[32];
    int tid = threadIdx.x;
    int r0 = blockIdx.x * 32;
    int n = n_dyn ? *n_dyn : n_static;
    if (tid < 32) {
        int row = r0 + tid;
        rowid[tid] = (row < n) ? (INDIRECT ? rows_list[row] : row) : -1;
    }
    __syncthreads();

    for (int idx = tid; idx < 512; idx += 128) {
        int r = idx >> 4, c16 = idx & 15;
        int rr = rowid[r];
        uint4 v = make_uint4(0, 0, 0, 0);
        if (rr >= 0) v = *reinterpret_cast<const uint4*>(X + (size_t)rr * Hh + c16 * 8);
        *reinterpret_cast<uint4*>(&As[r * 264 + c16 * 8]) = v;
    }
    int wid = tid >> 6, lane = tid & 63;
    int c0 = lane * 2;
    int emask = (1 << sshift) - 1;
    for (int r = wid; r < 32; r += 2) {
        int rr = rowid[r];
        float a0 = 0.f, a1 = 0.f, invd = 0.f;
        if (rr >= 0) {
            int e0 = roff[rr], e1 = roff[rr + 1];
            invd = 1.f / fmaxf((float)(e1 - e0), 1.f);
            for (int ei = e0; ei < e1; ei++) {
                int pk = elist[ei];
                int s = pk >> sshift, e = pk & emask;
                const float* xr = xa + s * Hh + c0;
                unsigned ee = *reinterpret_cast<const unsigned*>(ef + (size_t)e * Hh + c0);
                a0 += xr[0] + bflo(ee);
                a1 += xr[1] + bfhi(ee);
            }
        }
        unsigned pk2 = (unsigned)f2bf(a0 * invd) | ((unsigned)f2bf(a1 * invd) << 16);
        *reinterpret_cast<unsigned*>(&As[r * 264 + 128 + c0]) = pk2;
    }
    __syncthreads();

    int m = lane & 15, quad = lane >> 4;
    f32x4 acc[8];
    #pragma unroll
    for (int t = 0; t < 8; t++) acc[t] = (f32x4){0.f, 0.f, 0.f, 0.f};
    #pragma unroll
    for (int kc = 0; kc < 8; kc++) {
        bf16x8 a = *reinterpret_cast<const bf16x8*>(&As[(16 * wid + m) * 264 + kc * 32 + quad * 8]);
        #pragma unroll
        for (int nt = 0; nt < 8; nt++) {
            bf16x8 b = *reinterpret_cast<const bf16x8*>(Wt + (((kc * 4 + quad) * 128) + nt * 16 + m) * 8);
            acc[nt] = __builtin_amdgcn_mfma_f32_16x16x32_bf16(a, b, acc[nt], 0, 0, 0);
        }
    }
    __syncthreads();
    float* Ds = reinterpret_cast<float*>(As);
    #pragma unroll
    for (int nt = 0; nt < 8; nt++)
        #pragma unroll
        for (int reg = 0; reg < 4; reg++)
            Ds[(16 * wid + quad * 4 + reg) * 132 + nt * 16 + m] = acc[nt][reg];
    __syncthreads();
    for (int idx = tid; idx < 512; idx += 128) {
        int r = idx >> 4, c16 = idx & 15;
        int rr = rowid[r];
        if (rr < 0) continue;
        const float* dsrc = &Ds[r * 132 + c16 * 8];
        float o[8];
        #pragma unroll
        for (int c = 0; c < 8; c++) {
            o[c] = dsrc[c];
            if (do_relu) o[c] = fmaxf(o[c], 0.f);
        }
        uint4 v;
        v.x = (unsigned)f2bf(o[0]) | ((unsigned)f2bf(o[1]) << 16);
        v.y = (unsigned)f2bf(o[2]) | ((unsigned)f2bf(o[3]) << 16);
        v.z = (unsigned)f2bf(o[4]) | ((unsigned)f2bf(o[5]) << 16);
        v.w = (unsigned)f2bf(o[6]) | ((unsigned)f2bf(o[7]) << 16);
        *reinterpret_cast<uint4*>(X + (size_t)rr * Hh + c16 * 8) = v;
    }
}

// ---------------------------------------------------------------------------
__global__ __launch_bounds__(128)
void k_xa(float* __restrict__ x_a,
          const float* __restrict__ Sx1, const float* __restrict__ E1,
          const float* __restrict__ Sx2, const float* __restrict__ E2,
          const int* __restrict__ c1, const int* __restrict__ c2,
          const float* __restrict__ Wself, const float* __restrict__ Wm1,
          const float* __restrict__ Wm2, int do_relu)
{
    int r = blockIdx.x, tid = threadIdx.x;
    __shared__ float xr[128], a1[128], a2[128];
    float i1 = 1.f / fmaxf((float)c1[r], 1.f);
    float i2 = 1.f / fmaxf((float)c2[r], 1.f);
    xr[tid] = x_a[r * Hh + tid];
    a1[tid] = (Sx1[r * Hh + tid] + E1[r * Hh + tid]) * i1;
    a2[tid] = (Sx2[r * Hh + tid] + E2[r * Hh + tid]) * i2;
    __syncthreads();
    float acc = 0.f;
    for (int k = 0; k < 128; k++) {
        acc = fmaf(xr[k], Wself[k * Hh + tid], acc);
        acc = fmaf(a1[k], Wm1[k * Hh + tid], acc);
        acc = fmaf(a2[k], Wm2[k * Hh + tid], acc);
    }
    if (do_relu) acc = fmaxf(acc, 0.f);
    x_a[r * Hh + tid] = acc;
}

// ---------------------------------------------------------------------------
__global__ __launch_bounds__(128)
void k_qkv(const float* __restrict__ h, float* __restrict__ qkv,
           const float* __restrict__ W, const float* __restrict__ b)
{
    int r = blockIdx.x, tid = threadIdx.x;
    __shared__ float hr[128];
    hr[tid] = h[r * Hh + tid];
    __syncthreads();
    #pragma unroll
    for (int c0 = 0; c0 < 3; c0++) {
        int c = c0 * 128 + tid;
        float acc = b[c];
        for (int k = 0; k < 128; k++) acc = fmaf(hr[k], W[k * 384 + c], acc);
        qkv[r * 384 + c] = acc;
    }
}

DEV float blocksum128(float v, float* red)
{
    #pragma unroll
    for (int o = 32; o; o >>= 1) v += __shfl_xor(v, o);
    int wid = threadIdx.x >> 6;
    __syncthreads();
    if ((threadIdx.x & 63) == 0) red[wid] = v;
    __syncthreads();
    return red[0] + red[1];
}

DEV float blocksum256(float v, float* red)
{
    #pragma unroll
    for (int o = 32; o; o >>= 1) v += __shfl_xor(v, o);
    int wid = threadIdx.x >> 6;
    __syncthreads();
    if ((threadIdx.x & 63) == 0) red[wid] = v;
    __syncthreads();
    return red[0] + red[1] + red[2] + red[3];
}

// fused attention + out-proj + residual + LN1 + ff1 ; 256 thr, block per q row
__global__ __launch_bounds__(256)
void k_attn_ff1(const float* __restrict__ qkv, float* __restrict__ h,
                float* __restrict__ fbuf,
                const float* __restrict__ Wout, const float* __restrict__ bout,
                const float* __restrict__ ln,
                const float* __restrict__ W1, const float* __restrict__ b1)
{
    int q = blockIdx.x, tid = threadIdx.x;
    __shared__ float sc[NH * Dd];
    __shared__ float o_r[128];
    __shared__ float hr[128];
    __shared__ float red[4];
    int hh = tid >> 4;
    int k0 = (tid & 15) * 4;
    if (tid < 128) {
        const float* qrow = qkv + q * 384 + hh * HD;
        #pragma unroll
        for (int kk = k0; kk < k0 + 4; kk++) {
            const float* krow = qkv + kk * 384 + 128 + hh * HD;
            float s = 0.f;
            #pragma unroll
            for (int d = 0; d < HD; d++) s = fmaf(qrow[d], krow[d], s);
            sc[hh * Dd + kk] = s * 0.25f + (kk <= q ? 0.f : -1e9f);
        }
    }
    __syncthreads();
    float p0 = 0.f, p1 = 0.f, p2 = 0.f, p3 = 0.f;
    if (tid < 128) {
        float mm = -1e30f;
        for (int k = 0; k < Dd; k++) mm = fmaxf(mm, sc[hh * Dd + k]);
        float l = 0.f;
        for (int k = 0; k < Dd; k++) l += __expf(sc[hh * Dd + k] - mm);
        float inv_l = 1.f / l;
        p0 = __expf(sc[hh * Dd + k0]     - mm) * inv_l;
        p1 = __expf(sc[hh * Dd + k0 + 1] - mm) * inv_l;
        p2 = __expf(sc[hh * Dd + k0 + 2] - mm) * inv_l;
        p3 = __expf(sc[hh * Dd + k0 + 3] - mm) * inv_l;
    }
    __syncthreads();
    if (tid < 128) {
        sc[hh * Dd + k0] = p0; sc[hh * Dd + k0 + 1] = p1;
        sc[hh * Dd + k0 + 2] = p2; sc[hh * Dd + k0 + 3] = p3;
    }
    __syncthreads();
    if (tid < 128) {
        int d = tid & 15;
        float o0 = 0.f, o1 = 0.f, o2 = 0.f, o3 = 0.f;
        for (int k = 0; k < Dd; k += 4) {
            o0 = fmaf(sc[hh * Dd + k],     qkv[(k)     * 384 + 256 + hh * HD + d], o0);
            o1 = fmaf(sc[hh * Dd + k + 1], qkv[(k + 1) * 384 + 256 + hh * HD + d], o1);
            o2 = fmaf(sc[hh * Dd + k + 2], qkv[(k + 2) * 384 + 256 + hh * HD + d], o2);
            o3 = fmaf(sc[hh * Dd + k + 3], qkv[(k + 3) * 384 + 256 + hh * HD + d], o3);
        }
        o_r[hh * HD + d] = (o0 + o1) + (o2 + o3);
    }
    __syncthreads();
    float x = 0.f;
    if (tid < 128) {
        float a0 = bout[tid], a1 = 0.f, a2 = 0.f, a3 = 0.f;
        for (int k = 0; k < 128; k += 4) {
            a0 = fmaf(o_r[k],     Wout[(k)     * Hh + tid], a0);
            a1 = fmaf(o_r[k + 1], Wout[(k + 1) * Hh + tid], a1);
            a2 = fmaf(o_r[k + 2], Wout[(k + 2) * Hh + tid], a2);
            a3 = fmaf(o_r[k + 3], Wout[(k + 3) * Hh + tid], a3);
        }
        x = h[q * Hh + tid] + (a0 + a1) + (a2 + a3);
    }
    float mu = blocksum256(x, red) * (1.f / 128.f);
    float dx = (tid < 128) ? (x - mu) : 0.f;
    float var = blocksum256(dx * dx, red) * (1.f / 128.f);
    if (tid < 128) {
        float y = ln[tid] * dx * (1.f / sqrtf(var + 1e-5f)) + ln[128 + tid];
        hr[tid] = y;
        h[q * Hh + tid] = y;
    }
    __syncthreads();
    #pragma unroll 1
    for (int i = 0; i < 8; i++) {
        int c = i * 256 + tid;
        float a = b1[c];
        #pragma unroll 4
        for (int k = 0; k < 128; k++) a = fmaf(hr[k], W1[(size_t)k * FF + c], a);
        fbuf[(size_t)q * FF + c] = fmaxf(a, 0.f);
    }
}

__global__ __launch_bounds__(128)
void k_ff2p(const float* __restrict__ fbuf, float* __restrict__ part,
            const float* __restrict__ W2)
{
    int r = blockIdx.x, pi = blockIdx.y, tid = threadIdx.x;
    int kc = pi * 128;
    const float* f = fbuf + (size_t)r * FF + kc;
    float a0 = 0.f, a1 = 0.f, a2 = 0.f, a3 = 0.f;
    for (int k = 0; k < 128; k += 4) {
        a0 = fmaf(f[k],     W2[(size_t)(kc + k)     * Hh + tid], a0);
        a1 = fmaf(f[k + 1], W2[(size_t)(kc + k + 1) * Hh + tid], a1);
        a2 = fmaf(f[k + 2], W2[(size_t)(kc + k + 2) * Hh + tid], a2);
        a3 = fmaf(f[k + 3], W2[(size_t)(kc + k + 3) * Hh + tid], a3);
    }
    part[(size_t)(r * 16 + pi) * Hh + tid] = (a0 + a1) + (a2 + a3);
}

__global__ __launch_bounds__(128)
void k_ln2qkv(float* __restrict__ h, const float* __restrict__ part,
              const float* __restrict__ b2, const float* __restrict__ ln,
              float* __restrict__ qkv, const float* __restrict__ Wq,
              const float* __restrict__ bq, int do_qkv)
{
    int r = blockIdx.x, tid = threadIdx.x;
    __shared__ float red[2];
    __shared__ float hr[128];
    float acc = b2[tid];
    #pragma unroll
    for (int pi = 0; pi < 16; pi++) acc += part[(size_t)(r * 16 + pi) * Hh + tid];
    float x = h[r * Hh + tid] + acc;
    float mu = blocksum128(x, red) * (1.f / 128.f);
    float dx = x - mu;
    float var = blocksum128(dx * dx, red) * (1.f / 128.f);
    float y = ln[tid] * dx * (1.f / sqrtf(var + 1e-5f)) + ln[128 + tid];
    hr[tid] = y;
    h[r * Hh + tid] = y;
    __syncthreads();
    if (do_qkv) {
        #pragma unroll
        for (int c0 = 0; c0 < 3; c0++) {
            int c = c0 * 128 + tid;
            float a = bq[c];
            for (int k = 0; k < 128; k++) a = fmaf(hr[k], Wq[k * 384 + c], a);
            qkv[r * 384 + c] = a;
        }
    }
}

// ---------------------------------------------------------------------------
__global__ __launch_bounds__(256)
void k_logits(const ushort_t* __restrict__ x_dc, const int* __restrict__ map,
              const float* __restrict__ h, const float* __restrict__ lp,
              const int* __restrict__ cand, float* __restrict__ out)
{
    int d = blockIdx.x;
    int tid = threadIdx.x, lane = tid & 63, w = tid >> 6;
    __shared__ float wv[128];
    if (tid < 128) wv[tid] = h[d * Hh + tid] * lp[tid];
    __syncthreads();
    for (int k = w; k < KK; k += 4) {
        int slot = map[d * VD + cand[d * KK + k]] >> 2;
        const ushort_t* row = x_dc + (size_t)slot * Hh;
        float v = bf(row[lane]) * wv[lane] + bf(row[lane + 64]) * wv[lane + 64];
        #pragma unroll
        for (int o = 32; o; o >>= 1) v += __shfl_xor(v, o);
        if (lane == 0) out[d * KK + k] = v;
    }
}

// ---------------------------------------------------------------------------
extern "C" void kernel_launch(void* const* d_in, const int* in_sizes, int n_in,
                              void* d_out, int out_size, void* d_ws, size_t ws_size,
                              hipStream_t stream)
{
    (void)in_sizes; (void)n_in; (void)out_size; (void)ws_size;

    const int* drug_tokens  = (const int*)d_in[0];
    const int* drug_node_id = (const int*)d_in[1];
    const int* lab_tokens   = (const int*)d_in[3];
    const int* lab_node_id  = (const int*)d_in[4];
    const int* adm_tokens   = (const int*)d_in[6];
    const int* did_tokens   = (const int*)d_in[8];
    const int* did_src      = (const int*)d_in[10];
    const int* did_dst      = (const int*)d_in[11];
    const int* took_tokens  = (const int*)d_in[12];
    const int* took_src     = (const int*)d_in[14];
    const int* took_dst     = (const int*)d_in[15];
    const int* cand_idx     = (const int*)d_in[16];

    const int cidx[NCANON] = {2,5,7,9,13, 17,18,19,20,21,22,23, 24,25,26,27,28,
                              29,30,31,32,33, 34,35, 36,37,38,39,40,41,42,43,44,45,46};
    const int cn[NCANON] = {
        ND*2, NLN*1, Dd*3, ED*2, ET*1,
        VD*EMB, VL*EMB, 3*TV*EMB, 2*TV*EMB, 4*TV*EMB, 2*TV*EMB, 2*TV*EMB,
        2*EMB, 1*EMB, 3*EMB, 2*EMB, 1*EMB,
        5*EMB*Hh, 4*EMB*Hh, 5*EMB*Hh, 3*EMB*Hh, 3*EMB*Hh,
        GL*4*Hh*Hh, GL*3*Hh*Hh,
        L_ENC*Hh*3*Hh, L_ENC*3*Hh, L_ENC*Hh*Hh, L_ENC*Hh, L_ENC*2*Hh,
        L_ENC*Hh*FF, L_ENC*FF, L_ENC*FF*Hh, L_ENC*Hh, L_ENC*2*Hh, Hh
    };
    CanonDesc cd;
    int eoff[NCANON + 1];
    int btot_blocks = 0;
    {
        int e = 0;
        for (int t = 0; t < NCANON; t++) {
            cd.src[t] = d_in[cidx[t]];
            cd.n[t] = cn[t];
            eoff[t] = e;
            cd.doff[t] = e;
            e = (e + cn[t] + 7) & ~7;
            btot_blocks += (cn[t] + 255) / 256;
            cd.bend[t] = btot_blocks;
        }
        eoff[NCANON] = e;
    }

    // ---- workspace carve ----
    char* p = (char*)d_ws;
    auto alloc_f = [&](size_t n) -> float*    { float* r = (float*)p;    p += n * sizeof(float); return r; };
    auto alloc_h = [&](size_t n) -> ushort_t* { ushort_t* r = (ushort_t*)p; p += n * sizeof(ushort_t); return r; };
    auto alloc_i = [&](size_t n) -> int*      { int* r = (int*)p;        p += n * sizeof(int); return r; };

    int* map    = alloc_i(ND);
    int* cnt_dc = alloc_i(UCAP);
    int* cnt_ld = alloc_i(NLN);
    int* cnt_a1 = alloc_i(64);
    int* cnt_a2 = alloc_i(64);
    int* nUB    = alloc_i(8);
    int* cur_t  = alloc_i(UCAP);
    int* cur_d  = alloc_i(NLN);
    int* cur_a1 = alloc_i(64);
    int* cur_a2 = alloc_i(64);
    float* E_did  = alloc_f((size_t)Dd * Hh);
    float* E_took = alloc_f((size_t)Dd * Hh);
    const size_t ZBLOCK = (size_t)ND + UCAP + NLN + 64 + 64 + 8 + UCAP + NLN + 64 + 64
                        + (size_t)Dd * Hh * 2;
    float* Sx_did  = alloc_f((size_t)Dd * Hh);
    float* Sx_took = alloc_f((size_t)Dd * Hh);
    int* roff_t  = alloc_i(UCAP + 8);
    int* roff_d  = alloc_i(NLN + 8);
    int* roff_a1 = alloc_i(72);
    int* roff_a2 = alloc_i(72);
    int* bscr    = alloc_i(1024);
    int* ulist   = alloc_i(UCAP);
    int* blist   = alloc_i(NCAND);
    int* elist_t = alloc_i(ET);
    int* elist_d = alloc_i(ED);
    int* tookA   = alloc_i(ET);
    int* tookB   = alloc_i(ET);
    int* didA    = alloc_i(ED);
    int* didB    = alloc_i(ED);
    ushort_t* wt     = alloc_h(3 * 32768);
    ushort_t* ap     = alloc_h(2 * 8192 + 2 * 4096);   // drug, lab (K=64); did, took (K=32)
    ushort_t* x_dc   = alloc_h((size_t)UCAP * Hh);
    ushort_t* x_l    = alloc_h((size_t)NLN * Hh);
    float*    x_a    = alloc_f((size_t)Dd * Hh);
    ushort_t* e_did  = alloc_h((size_t)ED * Hh);
    ushort_t* e_took = alloc_h((size_t)ET * Hh);
    float*    qkvb   = alloc_f((size_t)Dd * 384);
    float*    fbuf   = alloc_f((size_t)Dd * FF);
    float*    part   = alloc_f((size_t)Dd * 16 * Hh);
    float*    cf     = alloc_f((size_t)eoff[NCANON]);
    int*      dflag  = alloc_i(8);

    ushort_t* ap_drug = ap;
    ushort_t* ap_lab  = ap + 8192;
    ushort_t* ap_did  = ap + 16384;
    ushort_t* ap_took = ap + 16384 + 4096;

    const float* c_drug_floats  = cf + eoff[0];
    const float* c_lab_floats   = cf + eoff[1];
    const float* c_adm_floats   = cf + eoff[2];
    const float* c_did_floats   = cf + eoff[3];
    const float* c_took_floats  = cf + eoff[4];
    const float* c_drug_id_emb  = cf + eoff[5];
    const float* c_lab_id_emb   = cf + eoff[6];
    const float* c_drug_tok_emb = cf + eoff[7];
    const float* c_lab_tok_emb  = cf + eoff[8];
    const float* c_adm_tok_emb  = cf + eoff[9];
    const float* c_did_tok_emb  = cf + eoff[10];
    const float* c_took_tok_emb = cf + eoff[11];
    const float* c_drug_float_w = cf + eoff[12];
    const float* c_lab_float_w  = cf + eoff[13];
    const float* c_adm_float_w  = cf + eoff[14];
    const float* c_did_float_w  = cf + eoff[15];
    const float* c_took_float_w = cf + eoff[16];
    const float* c_drug_align   = cf + eoff[17];
    const float* c_lab_align    = cf + eoff[18];
    const float* c_adm_align    = cf + eoff[19];
    const float* c_did_align    = cf + eoff[20];
    const float* c_took_align   = cf + eoff[21];
    const float* c_gnn_msg      = cf + eoff[22];
    const float* c_gnn_self     = cf + eoff[23];
    const float* c_qkv_w        = cf + eoff[24];
    const float* c_qkv_b        = cf + eoff[25];
    const float* c_out_w        = cf + eoff[26];
    const float* c_out_b        = cf + eoff[27];
    const float* c_ln1          = cf + eoff[28];
    const float* c_ff1_w        = cf + eoff[29];
    const float* c_ff1_b        = cf + eoff[30];
    const float* c_ff2_w        = cf + eoff[31];
    const float* c_ff2_b        = cf + eoff[32];
    const float* c_ln2          = cf + eoff[33];
    const float* c_lp_w         = cf + eoff[34];

    // ---- canonicalize + graph prep ----
    k_probe<<<1, 64, 0, stream>>>((const unsigned*)d_in[41], dflag);
    k_canon<<<btot_blocks, 256, 0, stream>>>(cd, cf, dflag);
    k_wpack<<<dim3(32, 3), 128, 0, stream>>>(c_gnn_self, c_gnn_msg, wt);
    k_apack<<<8, 128, 0, stream>>>(c_drug_align, ap_drug, 50);
    k_apack<<<8, 128, 0, stream>>>(c_lab_align,  ap_lab,  40);
    k_apack<<<4, 128, 0, stream>>>(c_did_align,  ap_did,  30);
    k_apack<<<4, 128, 0, stream>>>(c_took_align, ap_took, 30);
    hipMemsetAsync(map, 0, ZBLOCK * sizeof(int), stream);
    k_mark<<<ET / 256, 256, 0, stream>>>(took_dst, cand_idx, map);
    k_assign<<<(ND + 255) / 256, 256, 0, stream>>>(map, ulist, blist, nUB);
    k_counts<<<128, 256, 0, stream>>>(did_dst, did_src, took_dst, took_src, map,
                                      cnt_ld, cnt_a1, cnt_dc, cnt_a2);
    k_scan_blk<<<NB_T, 256, 0, stream>>>(cnt_dc, roff_t, bscr, UCAP);
    k_scan_top<<<1, 1024, 0, stream>>>(bscr, NB_T);
    k_scan_add<<<NB_T, 256, 0, stream>>>(roff_t, bscr, UCAP, ET);
    k_scan_blk<<<NB_D, 256, 0, stream>>>(cnt_ld, roff_d, bscr, NLN);
    k_scan_top<<<1, 1024, 0, stream>>>(bscr, NB_D);
    k_scan_add<<<NB_D, 256, 0, stream>>>(roff_d, bscr, NLN, ED);
    k_scan64<<<1, 64, 0, stream>>>(cnt_a1, cnt_a2, roff_a1, roff_a2);
    k_fill<<<128, 256, 0, stream>>>(did_src, did_dst, took_src, took_dst, map,
                                    roff_d, roff_t, roff_a1, roff_a2,
                                    cur_d, cur_t, cur_a1, cur_a2,
                                    elist_d, elist_t, didA, didB, tookA, tookB);

    // ---- embeddings (MFMA for the 4 big ones; scalar for adm) ----
    k_embed_m<1,3,2,2,true><<<UCAP / 32, 128, 0, stream>>>(x_dc, 0, nUB, ulist,
        drug_node_id, c_drug_id_emb, drug_tokens, c_drug_tok_emb,
        c_drug_floats, c_drug_float_w, ap_drug);
    k_embed_m<1,2,1,2,false><<<NLN / 32, 128, 0, stream>>>(x_l, NLN, nullptr, nullptr,
        lab_node_id, c_lab_id_emb, lab_tokens, c_lab_tok_emb,
        c_lab_floats, c_lab_float_w, ap_lab);
    k_embed<0,4,3><<<1, 64, 0, stream>>>(x_a, Dd,
        nullptr, nullptr, adm_tokens, c_adm_tok_emb, c_adm_floats, c_adm_float_w, c_adm_align);
    k_embed_m<0,2,2,1,false><<<ED / 32, 128, 0, stream>>>(e_did, ED, nullptr, nullptr,
        nullptr, nullptr, did_tokens, c_did_tok_emb, c_did_floats, c_did_float_w, ap_did);
    k_embed_m<0,2,1,1,false><<<ET / 32, 128, 0, stream>>>(e_took, ET, nullptr, nullptr,
        nullptr, nullptr, took_tokens, c_took_tok_emb, c_took_floats, c_took_float_w, ap_took);

    const size_t HH = (size_t)Hh * Hh;

    // ---- GNN layer 1 (relu) ----
    hipMemsetAsync(Sx_did, 0, 2 * (size_t)Dd * Hh * sizeof(float), stream);
    k_srcsum<true><<<(ED + 31) / 32, 64, 0, stream>>>(didA, didB, x_l, e_did, 16,
                                                      Sx_did, E_did, ED, 32);
    k_srcsum<true><<<(ET + 31) / 32, 64, 0, stream>>>(tookA, tookB, x_dc, e_took, 18,
                                                      Sx_took, E_took, ET, 32);
    k_gup<false><<<UCAP / 32, 128, 0, stream>>>(x_dc, x_a, e_took, roff_t, elist_t, 17,
        nullptr, nUB, 0, wt, 1);
    k_gup<false><<<NLN / 32, 128, 0, stream>>>(x_l, x_a, e_did, roff_d, elist_d, 15,
        nullptr, nullptr, NLN, wt + 32768, 1);
    k_xa<<<Dd, 128, 0, stream>>>(x_a, Sx_did, E_did, Sx_took, E_took, cnt_a1, cnt_a2,
        c_gnn_self + 0 * HH, c_gnn_msg + 2 * HH, c_gnn_msg + 3 * HH, 1);

    // ---- GNN layer 2 ----
    const float* Ws1 = c_gnn_self + 3 * HH;
    const float* Wm1 = c_gnn_msg + 4 * HH;
    hipMemsetAsync(Sx_did, 0, 2 * (size_t)Dd * Hh * sizeof(float), stream);
    k_srcsum<false><<<(ED + 31) / 32, 64, 0, stream>>>(didA, didB, x_l, nullptr, 16,
                                                       Sx_did, nullptr, ED, 32);
    k_srcsum<false><<<(ET + 31) / 32, 64, 0, stream>>>(tookA, tookB, x_dc, nullptr, 18,
                                                       Sx_took, nullptr, ET, 32);
    k_gup<true><<<(NCAND + 31) / 32, 128, 0, stream>>>(x_dc, x_a, e_took, roff_t, elist_t, 17,
        blist, nUB + 1, 0, wt + 65536, 0);
    k_xa<<<Dd, 128, 0, stream>>>(x_a, Sx_did, E_did, Sx_took, E_took, cnt_a1, cnt_a2,
        Ws1 + 0 * HH, Wm1 + 2 * HH, Wm1 + 3 * HH, 0);

    // ---- transformer encoder (3 launches/layer) ----
    k_qkv<<<Dd, 128, 0, stream>>>(x_a, qkvb, c_qkv_w, c_qkv_b);
    for (int i = 0; i < L_ENC; i++) {
        k_attn_ff1<<<Dd, 256, 0, stream>>>(qkvb, x_a, fbuf,
            c_out_w + (size_t)i * HH, c_out_b + (size_t)i * Hh, c_ln1 + (size_t)i * 2 * Hh,
            c_ff1_w + (size_t)i * Hh * FF, c_ff1_b + (size_t)i * FF);
        k_ff2p<<<dim3(Dd, 16), 128, 0, stream>>>(fbuf, part, c_ff2_w + (size_t)i * FF * Hh);
        int nx = (i + 1 < L_ENC) ? 1 : 0;
        k_ln2qkv<<<Dd, 128, 0, stream>>>(x_a, part, c_ff2_b + (size_t)i * Hh,
            c_ln2 + (size_t)i * 2 * Hh, qkvb,
            c_qkv_w + (size_t)(nx ? (i + 1) : 0) * Hh * 384,
            c_qkv_b + (size_t)(nx ? (i + 1) : 0) * 384, nx);
    }

    // ---- logits ----
    k_logits<<<Dd - 1, 256, 0, stream>>>(x_dc, map, x_a, c_lp_w, cand_idx, (float*)d_out);
}

// Round 11
// 1344.461 us; speedup vs baseline: 2.8426x; 1.0709x over previous
//
#include <hip/hip_runtime.h>
#include <hip/hip_bf16.h>

typedef unsigned short ushort_t;
typedef unsigned long long u64;
typedef __attribute__((ext_vector_type(8))) short bf16x8;
typedef __attribute__((ext_vector_type(4))) float f32x4;

#define DEV __device__ __forceinline__

constexpr int Dd  = 64;
constexpr int VD  = 4525;
constexpr int VL  = 753;
constexpr int ND  = Dd * VD;     // 289600
constexpr int NLN = Dd * VL;     // 48192
constexpr int Hh  = 128;
constexpr int EMB = 10;
constexpr int TV  = 100;
constexpr int NH  = 8, HD = 16;
constexpr int L_ENC = 6, FF = 2048;
constexpr int GL  = 2;
constexpr int ED  = 32768, ET = 131072;
constexpr int KK  = 256;
constexpr int NCAND = (Dd - 1) * KK;       // 16128
constexpr int UCAP  = ET + NCAND;          // 147200
constexpr int NCANON = 35;
constexpr int NB_T = (UCAP + 255) / 256;
constexpr int NB_D = (NLN + 255) / 256;
constexpr int NB_A = (ND + 255) / 256;     // 1132 assignment-scan blocks

DEV float bf(ushort_t u) { return __uint_as_float(((unsigned)u) << 16); }
DEV float bflo(unsigned u) { return __uint_as_float(u << 16); }
DEV float bfhi(unsigned u) { return __uint_as_float(u & 0xffff0000u); }
DEV ushort_t f2bf(float f) {
    unsigned u = __float_as_uint(f);
    u += 0x7fffu + ((u >> 16) & 1u);
    return (ushort_t)(u >> 16);
}

// ---------------------------------------------------------------------------
__global__ __launch_bounds__(64)
void k_probe(const unsigned* __restrict__ w, int* __restrict__ flag)
{
    int tid = threadIdx.x;
    int c = 0;
    #pragma unroll
    for (int i = 0; i < 16; i++) c += (w[tid * 16 + i] >> 14) & 1;
    #pragma unroll
    for (int o = 32; o; o >>= 1) c += __shfl_xor(c, o);
    if (tid == 0) *flag = (c > 256) ? 1 : 0;
}

struct CanonDesc {
    const void* src[NCANON];
    int doff[NCANON];
    int bend[NCANON];
    int n[NCANON];
};

__global__ __launch_bounds__(256)
void k_canon(CanonDesc cd, float* __restrict__ dst, const int* __restrict__ flag)
{
    int b = blockIdx.x;
    int t = 0;
    while (t < NCANON && b >= cd.bend[t]) t++;
    if (t >= NCANON) return;
    int bstart = (t == 0) ? 0 : cd.bend[t - 1];
    int i = (b - bstart) * 256 + threadIdx.x;
    if (i >= cd.n[t]) return;
    float v = (*flag) ? ((const float*)cd.src[t])[i]
                      : bf(((const ushort_t*)cd.src[t])[i]);
    dst[cd.doff[t] + i] = v;
}

// pack [Wself;Wmsg] (256x128 fp32) into MFMA B-operand bf16 layout
__global__ __launch_bounds__(128)
void k_wpack(const float* __restrict__ gself, const float* __restrict__ gmsg,
             ushort_t* __restrict__ wt)
{
    const int selfIdx[3] = {1, 2, 4};
    const int msgIdx[3]  = {1, 0, 5};
    int pr = blockIdx.y, chunk = blockIdx.x, nn = threadIdx.x;
    const float* Ws = gself + (size_t)selfIdx[pr] * Hh * Hh;
    const float* Wm = gmsg  + (size_t)msgIdx[pr]  * Hh * Hh;
    ushort_t* dst = wt + (((size_t)pr * 32 + chunk) * 128 + nn) * 8;
    #pragma unroll
    for (int j = 0; j < 8; j++) {
        int k = chunk * 8 + j;
        float v = (k < 128) ? Ws[k * Hh + nn] : Wm[(k - 128) * Hh + nn];
        dst[j] = f2bf(v);
    }
}

// pack an align matrix [L x 128] fp32 -> MFMA B layout bf16, K padded w/ zeros
__global__ __launch_bounds__(128)
void k_apack(const float* __restrict__ A, ushort_t* __restrict__ dst, int L)
{
    int c = blockIdx.x, nn = threadIdx.x;
    ushort_t* d = dst + ((size_t)c * 128 + nn) * 8;
    #pragma unroll
    for (int j = 0; j < 8; j++) {
        int k = c * 8 + j;
        d[j] = (k < L) ? f2bf(A[(size_t)k * Hh + nn]) : (ushort_t)0;
    }
}

// ---------------------------------------------------------------------------
__global__ __launch_bounds__(256)
void k_mark(const int* __restrict__ took_dst, const int* __restrict__ cand,
            int* __restrict__ map)
{
    int g = blockIdx.x * 256 + threadIdx.x;
    if (g < ET) atomicOr(&map[took_dst[g]], 1);
    if (g < NCAND) {
        int d = g >> 8;
        atomicOr(&map[d * VD + cand[g]], 2);
    }
}

// ---- contention-free slot assignment ----
// 64-bit packed indicator: isU in low 32 bits, isB in high 32 bits.
// (Round-10 bug: 32-bit packing isB<<18 overflowed at B_total<<18 = 4.2e9.)
__global__ __launch_bounds__(256)
void k_acount(const int* __restrict__ map, u64* __restrict__ bsum)
{
    __shared__ u64 s[256];
    int tid = threadIdx.x;
    int g = blockIdx.x * 256 + tid;
    int m = (g < ND) ? map[g] : 0;
    s[tid] = (u64)(m ? 1u : 0u) | ((u64)((m & 2) ? 1u : 0u) << 32);
    __syncthreads();
    for (int o = 128; o; o >>= 1) {
        if (tid < o) s[tid] += s[tid + o];
        __syncthreads();
    }
    if (tid == 0) bsum[blockIdx.x] = s[0];
}

__global__ __launch_bounds__(1024)
void k_ascan(u64* __restrict__ bsum, int nb, int* __restrict__ nUB)
{
    __shared__ u64 s[1024];
    int tid = threadIdx.x;
    u64 carry = 0;
    for (int base = 0; base < nb; base += 1024) {
        int idx = base + tid;
        u64 v = (idx < nb) ? bsum[idx] : 0;
        s[tid] = v;
        __syncthreads();
        for (int o = 1; o < 1024; o <<= 1) {
            u64 t = (tid >= o) ? s[tid - o] : 0;
            __syncthreads();
            s[tid] += t;
            __syncthreads();
        }
        if (idx < nb) bsum[idx] = carry + s[tid] - v;
        u64 tot = s[1023];
        __syncthreads();
        carry += tot;
    }
    if (tid == 0) {
        nUB[0] = (int)(carry & 0xffffffffu);
        nUB[1] = (int)(carry >> 32);
    }
}

__global__ __launch_bounds__(256)
void k_assign2(int* __restrict__ map, int* __restrict__ ulist, int* __restrict__ blist,
               const u64* __restrict__ bsum)
{
    __shared__ u64 s[256];
    int tid = threadIdx.x;
    int g = blockIdx.x * 256 + tid;
    int m = (g < ND) ? map[g] : 0;
    u64 v = (u64)(m ? 1u : 0u) | ((u64)((m & 2) ? 1u : 0u) << 32);
    s[tid] = v;
    __syncthreads();
    for (int o = 1; o < 256; o <<= 1) {
        u64 t = (tid >= o) ? s[tid - o] : 0;
        __syncthreads();
        s[tid] += t;
        __syncthreads();
    }
    u64 excl = s[tid] - v + bsum[blockIdx.x];
    if (m) {
        int slot = (int)(excl & 0xffffffffu);
        ulist[slot] = g;
        map[g] = (slot << 2) | m;
        if (m & 2) blist[(int)(excl >> 32)] = slot;
    }
}

__global__ __launch_bounds__(256)
void k_counts(const int* __restrict__ did_dst, const int* __restrict__ did_src,
              const int* __restrict__ took_dst, const int* __restrict__ took_src,
              const int* __restrict__ map,
              int* __restrict__ cnt_ld, int* __restrict__ cnt_a1,
              int* __restrict__ cnt_dc, int* __restrict__ cnt_a2)
{
    __shared__ int h1[64], h2[64];
    int tid = threadIdx.x;
    if (tid < 64) { h1[tid] = 0; h2[tid] = 0; }
    __syncthreads();
    int tb = blockIdx.x * 1024;
    #pragma unroll
    for (int o = 0; o < 1024; o += 256) {
        int i = tb + o + tid;
        atomicAdd(&cnt_dc[map[took_dst[i]] >> 2], 1);
        atomicAdd(&h2[took_src[i]], 1);
    }
    {
        int i = blockIdx.x * 256 + tid;
        atomicAdd(&cnt_ld[did_dst[i]], 1);
        atomicAdd(&h1[did_src[i]], 1);
    }
    __syncthreads();
    if (tid < 64) {
        if (h1[tid]) atomicAdd(&cnt_a1[tid], h1[tid]);
        if (h2[tid]) atomicAdd(&cnt_a2[tid], h2[tid]);
    }
}

// ---------------------------------------------------------------------------
__global__ __launch_bounds__(256)
void k_scan_blk(const int* __restrict__ cnt, int* __restrict__ excl,
                int* __restrict__ btot, int n)
{
    __shared__ int s[256];
    int tid = threadIdx.x;
    int g = blockIdx.x * 256 + tid;
    int v = (g < n) ? cnt[g] : 0;
    s[tid] = v;
    __syncthreads();
    for (int o = 1; o < 256; o <<= 1) {
        int t = (tid >= o) ? s[tid - o] : 0;
        __syncthreads();
        s[tid] += t;
        __syncthreads();
    }
    if (g < n) excl[g] = s[tid] - v;
    if (tid == 255) btot[blockIdx.x] = s[255];
}

__global__ __launch_bounds__(1024)
void k_scan_top(int* __restrict__ btot, int nb)
{
    __shared__ int s[1024];
    int tid = threadIdx.x;
    int v = (tid < nb) ? btot[tid] : 0;
    s[tid] = v;
    __syncthreads();
    for (int o = 1; o < 1024; o <<= 1) {
        int t = (tid >= o) ? s[tid - o] : 0;
        __syncthreads();
        s[tid] += t;
        __syncthreads();
    }
    if (tid < nb) btot[tid] = s[tid] - v;
}

__global__ __launch_bounds__(256)
void k_scan_add(int* __restrict__ roff, const int* __restrict__ btot, int n, int total)
{
    int g = blockIdx.x * 256 + threadIdx.x;
    if (g < n) roff[g] += btot[blockIdx.x];
    if (g == 0) roff[n] = total;
}

__global__ __launch_bounds__(64)
void k_scan64(const int* __restrict__ c1, const int* __restrict__ c2,
              int* __restrict__ r1, int* __restrict__ r2)
{
    int tid = threadIdx.x;
    int v1 = c1[tid], v2 = c2[tid];
    int s1 = v1, s2 = v2;
    for (int o = 1; o < 64; o <<= 1) {
        int t1 = __shfl_up(s1, o), t2 = __shfl_up(s2, o);
        if (tid >= o) { s1 += t1; s2 += t2; }
    }
    r1[tid] = s1 - v1;
    r2[tid] = s2 - v2;
}

__global__ __launch_bounds__(256)
void k_fill(const int* __restrict__ did_src, const int* __restrict__ did_dst,
            const int* __restrict__ took_src, const int* __restrict__ took_dst,
            const int* __restrict__ map,
            const int* __restrict__ roff_d, const int* __restrict__ roff_t,
            const int* __restrict__ roff_a1, const int* __restrict__ roff_a2,
            int* __restrict__ cur_d, int* __restrict__ cur_t,
            int* __restrict__ cur_a1, int* __restrict__ cur_a2,
            int* __restrict__ elist_d, int* __restrict__ elist_t,
            int* __restrict__ didA, int* __restrict__ didB,
            int* __restrict__ tookA, int* __restrict__ tookB)
{
    __shared__ int h1[64], h2[64], b1[64], b2[64];
    int tid = threadIdx.x;
    if (tid < 64) { h1[tid] = 0; h2[tid] = 0; }
    __syncthreads();
    int tb = blockIdx.x * 1024;
    int db = blockIdx.x * 256;
    #pragma unroll
    for (int o = 0; o < 1024; o += 256)
        atomicAdd(&h2[took_src[tb + o + tid]], 1);
    atomicAdd(&h1[did_src[db + tid]], 1);
    __syncthreads();
    if (tid < 64) {
        b1[tid] = h1[tid] ? atomicAdd(&cur_a1[tid], h1[tid]) : 0;
        b2[tid] = h2[tid] ? atomicAdd(&cur_a2[tid], h2[tid]) : 0;
        h1[tid] = 0; h2[tid] = 0;
    }
    __syncthreads();
    #pragma unroll
    for (int o = 0; o < 1024; o += 256) {
        int i = tb + o + tid;
        int s = took_src[i];
        int slot = map[took_dst[i]] >> 2;
        int pos = roff_t[slot] + atomicAdd(&cur_t[slot], 1);
        elist_t[pos] = (s << 17) | i;
        int pa = roff_a2[s] + b2[s] + atomicAdd(&h2[s], 1);
        tookA[pa] = (s << 18) | slot;
        tookB[pa] = i;
    }
    {
        int i = db + tid;
        int d = did_dst[i], s = did_src[i];
        int pos = roff_d[d] + atomicAdd(&cur_d[d], 1);
        elist_d[pos] = (s << 15) | i;
        int pa = roff_a1[s] + b1[s] + atomicAdd(&h1[s], 1);
        didA[pa] = (s << 16) | d;
        didB[pa] = i;
    }
}

// ---------------------------------------------------------------------------
template<bool DUAL>
__global__ __launch_bounds__(64)
void k_srcsum(const int* __restrict__ lA, const int* __restrict__ lB,
              const ushort_t* __restrict__ xrows, const ushort_t* __restrict__ erows,
              int shift, float* __restrict__ Sx, float* __restrict__ Se,
              int nedge, int epb)
{
    int lane = threadIdx.x;
    int c0 = lane * 2;
    int base = blockIdx.x * epb;
    int end = min(base + epb, nedge);
    int mask = (1 << shift) - 1;
    float ax0 = 0.f, ax1 = 0.f, ae0 = 0.f, ae1 = 0.f;
    int cur = -1;
    for (int i = base; i < end; i++) {
        int pk = lA[i];
        int s = pk >> shift, row = pk & mask;
        if (s != cur) {
            if (cur >= 0) {
                unsafeAtomicAdd(&Sx[cur * Hh + c0], ax0);
                unsafeAtomicAdd(&Sx[cur * Hh + c0 + 1], ax1);
                if (DUAL) {
                    unsafeAtomicAdd(&Se[cur * Hh + c0], ae0);
                    unsafeAtomicAdd(&Se[cur * Hh + c0 + 1], ae1);
                }
            }
            cur = s; ax0 = ax1 = ae0 = ae1 = 0.f;
        }
        unsigned xx = *reinterpret_cast<const unsigned*>(xrows + (size_t)row * Hh + c0);
        ax0 += bflo(xx); ax1 += bfhi(xx);
        if (DUAL) {
            int e = lB[i];
            unsigned ee = *reinterpret_cast<const unsigned*>(erows + (size_t)e * Hh + c0);
            ae0 += bflo(ee); ae1 += bfhi(ee);
        }
    }
    if (cur >= 0) {
        unsafeAtomicAdd(&Sx[cur * Hh + c0], ax0);
        unsafeAtomicAdd(&Sx[cur * Hh + c0 + 1], ax1);
        if (DUAL) {
            unsafeAtomicAdd(&Se[cur * Hh + c0], ae0);
            unsafeAtomicAdd(&Se[cur * Hh + c0 + 1], ae1);
        }
    }
}

// ---------------------------------------------------------------------------
// scalar embed (kept only for adm; 1 block)
template<int NID, int NTOK, int NF>
__global__ __launch_bounds__(64)
void k_embed(float* __restrict__ out, int n,
             const int* __restrict__ id_idx, const float* __restrict__ id_emb,
             const int* __restrict__ tokens, const float* __restrict__ tok_emb,
             const float* __restrict__ floats_, const float* __restrict__ float_w,
             const float* __restrict__ alignf)
{
    constexpr int L = (NID + NTOK + 1) * EMB;
    int node = blockIdx.x * 64 + threadIdx.x;
    if (node >= n) return;
    float vec[L];
    int p = 0;
    if constexpr (NID != 0) {
        const float* pe = id_emb + (size_t)id_idx[node] * EMB;
        #pragma unroll
        for (int e = 0; e < EMB; e++) vec[p++] = pe[e];
    }
    #pragma unroll
    for (int t = 0; t < NTOK; t++) {
        const float* pe = tok_emb + ((size_t)t * TV + tokens[node * NTOK + t]) * EMB;
        #pragma unroll
        for (int e = 0; e < EMB; e++) vec[p++] = pe[e];
    }
    {
        float fv[NF];
        #pragma unroll
        for (int f = 0; f < NF; f++) fv[f] = floats_[node * NF + f];
        #pragma unroll
        for (int e = 0; e < EMB; e++) {
            float a = 0.f;
            #pragma unroll
            for (int f = 0; f < NF; f++) a = fmaf(fv[f], float_w[f * EMB + e], a);
            vec[p++] = a;
        }
    }
    #pragma unroll 1
    for (int j = 0; j < Hh; j += 4) {
        float a0 = 0.f, a1 = 0.f, a2 = 0.f, a3 = 0.f;
        #pragma unroll
        for (int i = 0; i < L; i++) {
            const float* w = alignf + i * Hh + j;
            a0 = fmaf(vec[i], w[0], a0);
            a1 = fmaf(vec[i], w[1], a1);
            a2 = fmaf(vec[i], w[2], a2);
            a3 = fmaf(vec[i], w[3], a3);
        }
        float4 r4; r4.x = a0; r4.y = a1; r4.z = a2; r4.w = a3;
        *reinterpret_cast<float4*>(out + (size_t)node * Hh + j) = r4;
    }
}

// MFMA embed: 32 nodes/block; 128-thread parallel gather into bf16 LDS A-tile,
// then 32xK @ Kx128 MFMA with pre-packed align B.
template<int NID, int NTOK, int NF, int KCH, bool INDIRECT>
__global__ __launch_bounds__(128)
void k_embed_m(ushort_t* __restrict__ out, int n_static, const int* __restrict__ n_dyn,
               const int* __restrict__ ulist,
               const int* __restrict__ id_idx, const float* __restrict__ id_emb,
               const int* __restrict__ tokens, const float* __restrict__ tok_emb,
               const float* __restrict__ floats_, const float* __restrict__ float_w,
               const ushort_t* __restrict__ Bp)
{
    constexpr int NSEG = NID + NTOK + 1;
    constexpr int K = KCH * 32;
    constexpr int STR = K + 8;
    __shared__ ushort_t As[32 * 264];
    __shared__ int nodeid[32];
    int tid = threadIdx.x;
    int r0 = blockIdx.x * 32;
    int n = INDIRECT ? *n_dyn : n_static;
    if (tid < 32) {
        int slot = r0 + tid;
        nodeid[tid] = (slot < n) ? (INDIRECT ? ulist[slot] : slot) : -1;
    }
    for (int i = tid; i < 32 * STR; i += 128) As[i] = 0;
    __syncthreads();

    for (int pi = tid; pi < 32 * NSEG; pi += 128) {
        int seg = pi >> 5, nl = pi & 31;
        int node = nodeid[nl];
        if (node < 0) continue;
        float v[EMB];
        if (NID != 0 && seg == 0) {
            const float* pe = id_emb + (size_t)id_idx[node] * EMB;
            #pragma unroll
            for (int e = 0; e < EMB; e++) v[e] = pe[e];
        } else if (seg < NID + NTOK) {
            int t = seg - NID;
            const float* pe = tok_emb + ((size_t)t * TV + tokens[node * NTOK + t]) * EMB;
            #pragma unroll
            for (int e = 0; e < EMB; e++) v[e] = pe[e];
        } else {
            float fv[NF];
            #pragma unroll
            for (int f = 0; f < NF; f++) fv[f] = floats_[node * NF + f];
            #pragma unroll
            for (int e = 0; e < EMB; e++) {
                float a = 0.f;
                #pragma unroll
                for (int f = 0; f < NF; f++) a = fmaf(fv[f], float_w[f * EMB + e], a);
                v[e] = a;
            }
        }
        ushort_t* dst = &As[nl * STR + seg * EMB];
        #pragma unroll
        for (int e = 0; e < EMB; e += 2) {
            unsigned pk = (unsigned)f2bf(v[e]) | ((unsigned)f2bf(v[e + 1]) << 16);
            *reinterpret_cast<unsigned*>(dst + e) = pk;
        }
    }
    __syncthreads();

    int wid = tid >> 6, lane = tid & 63;
    int m = lane & 15, quad = lane >> 4;
    f32x4 acc[8];
    #pragma unroll
    for (int t = 0; t < 8; t++) acc[t] = (f32x4){0.f, 0.f, 0.f, 0.f};
    #pragma unroll
    for (int kc = 0; kc < KCH; kc++) {
        bf16x8 a = *reinterpret_cast<const bf16x8*>(&As[(16 * wid + m) * STR + kc * 32 + quad * 8]);
        #pragma unroll
        for (int nt = 0; nt < 8; nt++) {
            bf16x8 b = *reinterpret_cast<const bf16x8*>(Bp + (((kc * 4 + quad) * 128) + nt * 16 + m) * 8);
            acc[nt] = __builtin_amdgcn_mfma_f32_16x16x32_bf16(a, b, acc[nt], 0, 0, 0);
        }
    }
    __syncthreads();
    float* Ds = reinterpret_cast<float*>(As);
    #pragma unroll
    for (int nt = 0; nt < 8; nt++)
        #pragma unroll
        for (int reg = 0; reg < 4; reg++)
            Ds[(16 * wid + quad * 4 + reg) * 132 + nt * 16 + m] = acc[nt][reg];
    __syncthreads();
    for (int idx = tid; idx < 512; idx += 128) {
        int r = idx >> 4, c16 = idx & 15;
        int slot = r0 + r;
        if (slot >= n) continue;
        const float* dsrc = &Ds[r * 132 + c16 * 8];
        uint4 v;
        v.x = (unsigned)f2bf(dsrc[0]) | ((unsigned)f2bf(dsrc[1]) << 16);
        v.y = (unsigned)f2bf(dsrc[2]) | ((unsigned)f2bf(dsrc[3]) << 16);
        v.z = (unsigned)f2bf(dsrc[4]) | ((unsigned)f2bf(dsrc[5]) << 16);
        v.w = (unsigned)f2bf(dsrc[6]) | ((unsigned)f2bf(dsrc[7]) << 16);
        *reinterpret_cast<uint4*>(out + (size_t)slot * Hh + c16 * 8) = v;
    }
}

// ---------------------------------------------------------------------------
// Fused gather + mean + GNN update, MFMA version.
template<bool INDIRECT>
__global__ __launch_bounds__(128)
void k_gup(ushort_t* __restrict__ X, const float* __restrict__ xa,
           const ushort_t* __restrict__ ef,
           const int* __restrict__ roff, const int* __restrict__ elist, int sshift,
           const int* __restrict__ rows_list, const int* __restrict__ n_dyn, int n_static,
           const ushort_t* __restrict__ Wt, int do_relu)
{
    __shared__ ushort_t As[32 * 264];
    __shared__ int rowid[32];
    int tid = threadIdx.x;
    int r0 = blockIdx.x * 32;
    int n = n_dyn ? *n_dyn : n_static;
    if (tid < 32) {
        int row = r0 + tid;
        rowid[tid] = (row < n) ? (INDIRECT ? rows_list[row] : row) : -1;
    }
    __syncthreads();

    for (int idx = tid; idx < 512; idx += 128) {
        int r = idx >> 4, c16 = idx & 15;
        int rr = rowid[r];
        uint4 v = make_uint4(0, 0, 0, 0);
        if (rr >= 0) v = *reinterpret_cast<const uint4*>(X + (size_t)rr * Hh + c16 * 8);
        *reinterpret_cast<uint4*>(&As[r * 264 + c16 * 8]) = v;
    }
    int wid = tid >> 6, lane = tid & 63;
    int c0 = lane * 2;
    int emask = (1 << sshift) - 1;
    for (int r = wid; r < 32; r += 2) {
        int rr = rowid[r];
        float a0 = 0.f, a1 = 0.f, invd = 0.f;
        if (rr >= 0) {
            int e0 = roff[rr], e1 = roff[rr + 1];
            invd = 1.f / fmaxf((float)(e1 - e0), 1.f);
            for (int ei = e0; ei < e1; ei++) {
                int pk = elist[ei];
                int s = pk >> sshift, e = pk & emask;
                const float* xr = xa + s * Hh + c0;
                unsigned ee = *reinterpret_cast<const unsigned*>(ef + (size_t)e * Hh + c0);
                a0 += xr[0] + bflo(ee);
                a1 += xr[1] + bfhi(ee);
            }
        }
        unsigned pk2 = (unsigned)f2bf(a0 * invd) | ((unsigned)f2bf(a1 * invd) << 16);
        *reinterpret_cast<unsigned*>(&As[r * 264 + 128 + c0]) = pk2;
    }
    __syncthreads();

    int m = lane & 15, quad = lane >> 4;
    f32x4 acc[8];
    #pragma unroll
    for (int t = 0; t < 8; t++) acc[t] = (f32x4){0.f, 0.f, 0.f, 0.f};
    #pragma unroll
    for (int kc = 0; kc < 8; kc++) {
        bf16x8 a = *reinterpret_cast<const bf16x8*>(&As[(16 * wid + m) * 264 + kc * 32 + quad * 8]);
        #pragma unroll
        for (int nt = 0; nt < 8; nt++) {
            bf16x8 b = *reinterpret_cast<const bf16x8*>(Wt + (((kc * 4 + quad) * 128) + nt * 16 + m) * 8);
            acc[nt] = __builtin_amdgcn_mfma_f32_16x16x32_bf16(a, b, acc[nt], 0, 0, 0);
        }
    }
    __syncthreads();
    float* Ds = reinterpret_cast<float*>(As);
    #pragma unroll
    for (int nt = 0; nt < 8; nt++)
        #pragma unroll
        for (int reg = 0; reg < 4; reg++)
            Ds[(16 * wid + quad * 4 + reg) * 132 + nt * 16 + m] = acc[nt][reg];
    __syncthreads();
    for (int idx = tid; idx < 512; idx += 128) {
        int r = idx >> 4, c16 = idx & 15;
        int rr = rowid[r];
        if (rr < 0) continue;
        const float* dsrc = &Ds[r * 132 + c16 * 8];
        float o[8];
        #pragma unroll
        for (int c = 0; c < 8; c++) {
            o[c] = dsrc[c];
            if (do_relu) o[c] = fmaxf(o[c], 0.f);
        }
        uint4 v;
        v.x = (unsigned)f2bf(o[0]) | ((unsigned)f2bf(o[1]) << 16);
        v.y = (unsigned)f2bf(o[2]) | ((unsigned)f2bf(o[3]) << 16);
        v.z = (unsigned)f2bf(o[4]) | ((unsigned)f2bf(o[5]) << 16);
        v.w = (unsigned)f2bf(o[6]) | ((unsigned)f2bf(o[7]) << 16);
        *reinterpret_cast<uint4*>(X + (size_t)rr * Hh + c16 * 8) = v;
    }
}

// ---------------------------------------------------------------------------
__global__ __launch_bounds__(128)
void k_xa(float* __restrict__ x_a,
          const float* __restrict__ Sx1, const float* __restrict__ E1,
          const float* __restrict__ Sx2, const float* __restrict__ E2,
          const int* __restrict__ c1, const int* __restrict__ c2,
          const float* __restrict__ Wself, const float* __restrict__ Wm1,
          const float* __restrict__ Wm2, int do_relu)
{
    int r = blockIdx.x, tid = threadIdx.x;
    __shared__ float xr[128], a1[128], a2[128];
    float i1 = 1.f / fmaxf((float)c1[r], 1.f);
    float i2 = 1.f / fmaxf((float)c2[r], 1.f);
    xr[tid] = x_a[r * Hh + tid];
    a1[tid] = (Sx1[r * Hh + tid] + E1[r * Hh + tid]) * i1;
    a2[tid] = (Sx2[r * Hh + tid] + E2[r * Hh + tid]) * i2;
    __syncthreads();
    float acc = 0.f;
    for (int k = 0; k < 128; k++) {
        acc = fmaf(xr[k], Wself[k * Hh + tid], acc);
        acc = fmaf(a1[k], Wm1[k * Hh + tid], acc);
        acc = fmaf(a2[k], Wm2[k * Hh + tid], acc);
    }
    if (do_relu) acc = fmaxf(acc, 0.f);
    x_a[r * Hh + tid] = acc;
}

// ---------------------------------------------------------------------------
__global__ __launch_bounds__(128)
void k_qkv(const float* __restrict__ h, float* __restrict__ qkv,
           const float* __restrict__ W, const float* __restrict__ b)
{
    int r = blockIdx.x, tid = threadIdx.x;
    __shared__ float hr[128];
    hr[tid] = h[r * Hh + tid];
    __syncthreads();
    #pragma unroll
    for (int c0 = 0; c0 < 3; c0++) {
        int c = c0 * 128 + tid;
        float acc = b[c];
        for (int k = 0; k < 128; k++) acc = fmaf(hr[k], W[k * 384 + c], acc);
        qkv[r * 384 + c] = acc;
    }
}

DEV float blocksum128(float v, float* red)
{
    #pragma unroll
    for (int o = 32; o; o >>= 1) v += __shfl_xor(v, o);
    int wid = threadIdx.x >> 6;
    __syncthreads();
    if ((threadIdx.x & 63) == 0) red[wid] = v;
    __syncthreads();
    return red[0] + red[1];
}

DEV float blocksum256(float v, float* red)
{
    #pragma unroll
    for (int o = 32; o; o >>= 1) v += __shfl_xor(v, o);
    int wid = threadIdx.x >> 6;
    __syncthreads();
    if ((threadIdx.x & 63) == 0) red[wid] = v;
    __syncthreads();
    return red[0] + red[1] + red[2] + red[3];
}

// fused attention + out-proj + residual + LN1 + ff1 ; 256 thr, block per q row
__global__ __launch_bounds__(256)
void k_attn_ff1(const float* __restrict__ qkv, float* __restrict__ h,
                float* __restrict__ fbuf,
                const float* __restrict__ Wout, const float* __restrict__ bout,
                const float* __restrict__ ln,
                const float* __restrict__ W1, const float* __restrict__ b1)
{
    int q = blockIdx.x, tid = threadIdx.x;
    __shared__ float sc[NH * Dd];
    __shared__ float o_r[128];
    __shared__ float hr[128];
    __shared__ float red[4];
    int hh = tid >> 4;
    int k0 = (tid & 15) * 4;
    if (tid < 128) {
        const float* qrow = qkv + q * 384 + hh * HD;
        #pragma unroll
        for (int kk = k0; kk < k0 + 4; kk++) {
            const float* krow = qkv + kk * 384 + 128 + hh * HD;
            float s = 0.f;
            #pragma unroll
            for (int d = 0; d < HD; d++) s = fmaf(qrow[d], krow[d], s);
            sc[hh * Dd + kk] = s * 0.25f + (kk <= q ? 0.f : -1e9f);
        }
    }
    __syncthreads();
    float p0 = 0.f, p1 = 0.f, p2 = 0.f, p3 = 0.f;
    if (tid < 128) {
        float mm = -1e30f;
        for (int k = 0; k < Dd; k++) mm = fmaxf(mm, sc[hh * Dd + k]);
        float l = 0.f;
        for (int k = 0; k < Dd; k++) l += __expf(sc[hh * Dd + k] - mm);
        float inv_l = 1.f / l;
        p0 = __expf(sc[hh * Dd + k0]     - mm) * inv_l;
        p1 = __expf(sc[hh * Dd + k0 + 1] - mm) * inv_l;
        p2 = __expf(sc[hh * Dd + k0 + 2] - mm) * inv_l;
        p3 = __expf(sc[hh * Dd + k0 + 3] - mm) * inv_l;
    }
    __syncthreads();
    if (tid < 128) {
        sc[hh * Dd + k0] = p0; sc[hh * Dd + k0 + 1] = p1;
        sc[hh * Dd + k0 + 2] = p2; sc[hh * Dd + k0 + 3] = p3;
    }
    __syncthreads();
    if (tid < 128) {
        int d = tid & 15;
        float o0 = 0.f, o1 = 0.f, o2 = 0.f, o3 = 0.f;
        for (int k = 0; k < Dd; k += 4) {
            o0 = fmaf(sc[hh * Dd + k],     qkv[(k)     * 384 + 256 + hh * HD + d], o0);
            o1 = fmaf(sc[hh * Dd + k + 1], qkv[(k + 1) * 384 + 256 + hh * HD + d], o1);
            o2 = fmaf(sc[hh * Dd + k + 2], qkv[(k + 2) * 384 + 256 + hh * HD + d], o2);
            o3 = fmaf(sc[hh * Dd + k + 3], qkv[(k + 3) * 384 + 256 + hh * HD + d], o3);
        }
        o_r[hh * HD + d] = (o0 + o1) + (o2 + o3);
    }
    __syncthreads();
    float x = 0.f;
    if (tid < 128) {
        float a0 = bout[tid], a1 = 0.f, a2 = 0.f, a3 = 0.f;
        for (int k = 0; k < 128; k += 4) {
            a0 = fmaf(o_r[k],     Wout[(k)     * Hh + tid], a0);
            a1 = fmaf(o_r[k + 1], Wout[(k + 1) * Hh + tid], a1);
            a2 = fmaf(o_r[k + 2], Wout[(k + 2) * Hh + tid], a2);
            a3 = fmaf(o_r[k + 3], Wout[(k + 3) * Hh + tid], a3);
        }
        x = h[q * Hh + tid] + (a0 + a1) + (a2 + a3);
    }
    float mu = blocksum256(x, red) * (1.f / 128.f);
    float dx = (tid < 128) ? (x - mu) : 0.f;
    float var = blocksum256(dx * dx, red) * (1.f / 128.f);
    if (tid < 128) {
        float y = ln[tid] * dx * (1.f / sqrtf(var + 1e-5f)) + ln[128 + tid];
        hr[tid] = y;
        h[q * Hh + tid] = y;
    }
    __syncthreads();
    #pragma unroll 1
    for (int i = 0; i < 8; i++) {
        int c = i * 256 + tid;
        float a = b1[c];
        #pragma unroll 4
        for (int k = 0; k < 128; k++) a = fmaf(hr[k], W1[(size_t)k * FF + c], a);
        fbuf[(size_t)q * FF + c] = fmaxf(a, 0.f);
    }
}

__global__ __launch_bounds__(128)
void k_ff2p(const float* __restrict__ fbuf, float* __restrict__ part,
            const float* __restrict__ W2)
{
    int r = blockIdx.x, pi = blockIdx.y, tid = threadIdx.x;
    int kc = pi * 128;
    const float* f = fbuf + (size_t)r * FF + kc;
    float a0 = 0.f, a1 = 0.f, a2 = 0.f, a3 = 0.f;
    for (int k = 0; k < 128; k += 4) {
        a0 = fmaf(f[k],     W2[(size_t)(kc + k)     * Hh + tid], a0);
        a1 = fmaf(f[k + 1], W2[(size_t)(kc + k + 1) * Hh + tid], a1);
        a2 = fmaf(f[k + 2], W2[(size_t)(kc + k + 2) * Hh + tid], a2);
        a3 = fmaf(f[k + 3], W2[(size_t)(kc + k + 3) * Hh + tid], a3);
    }
    part[(size_t)(r * 16 + pi) * Hh + tid] = (a0 + a1) + (a2 + a3);
}

__global__ __launch_bounds__(128)
void k_ln2qkv(float* __restrict__ h, const float* __restrict__ part,
              const float* __restrict__ b2, const float* __restrict__ ln,
              float* __restrict__ qkv, const float* __restrict__ Wq,
              const float* __restrict__ bq, int do_qkv)
{
    int r = blockIdx.x, tid = threadIdx.x;
    __shared__ float red[2];
    __shared__ float hr[128];
    float acc = b2[tid];
    #pragma unroll
    for (int pi = 0; pi < 16; pi++) acc += part[(size_t)(r * 16 + pi) * Hh + tid];
    float x = h[r * Hh + tid] + acc;
    float mu = blocksum128(x, red) * (1.f / 128.f);
    float dx = x - mu;
    float var = blocksum128(dx * dx, red) * (1.f / 128.f);
    float y = ln[tid] * dx * (1.f / sqrtf(var + 1e-5f)) + ln[128 + tid];
    hr[tid] = y;
    h[r * Hh + tid] = y;
    __syncthreads();
    if (do_qkv) {
        #pragma unroll
        for (int c0 = 0; c0 < 3; c0++) {
            int c = c0 * 128 + tid;
            float a = bq[c];
            for (int k = 0; k < 128; k++) a = fmaf(hr[k], Wq[k * 384 + c], a);
            qkv[r * 384 + c] = a;
        }
    }
}

// ---------------------------------------------------------------------------
__global__ __launch_bounds__(256)
void k_logits(const ushort_t* __restrict__ x_dc, const int* __restrict__ map,
              const float* __restrict__ h, const float* __restrict__ lp,
              const int* __restrict__ cand, float* __restrict__ out)
{
    int d = blockIdx.x;
    int tid = threadIdx.x, lane = tid & 63, w = tid >> 6;
    __shared__ float wv[128];
    if (tid < 128) wv[tid] = h[d * Hh + tid] * lp[tid];
    __syncthreads();
    for (int k = w; k < KK; k += 4) {
        int slot = map[d * VD + cand[d * KK + k]] >> 2;
        const ushort_t* row = x_dc + (size_t)slot * Hh;
        float v = bf(row[lane]) * wv[lane] + bf(row[lane + 64]) * wv[lane + 64];
        #pragma unroll
        for (int o = 32; o; o >>= 1) v += __shfl_xor(v, o);
        if (lane == 0) out[d * KK + k] = v;
    }
}

// ---------------------------------------------------------------------------
extern "C" void kernel_launch(void* const* d_in, const int* in_sizes, int n_in,
                              void* d_out, int out_size, void* d_ws, size_t ws_size,
                              hipStream_t stream)
{
    (void)in_sizes; (void)n_in; (void)out_size; (void)ws_size;

    const int* drug_tokens  = (const int*)d_in[0];
    const int* drug_node_id = (const int*)d_in[1];
    const int* lab_tokens   = (const int*)d_in[3];
    const int* lab_node_id  = (const int*)d_in[4];
    const int* adm_tokens   = (const int*)d_in[6];
    const int* did_tokens   = (const int*)d_in[8];
    const int* did_src      = (const int*)d_in[10];
    const int* did_dst      = (const int*)d_in[11];
    const int* took_tokens  = (const int*)d_in[12];
    const int* took_src     = (const int*)d_in[14];
    const int* took_dst     = (const int*)d_in[15];
    const int* cand_idx     = (const int*)d_in[16];

    const int cidx[NCANON] = {2,5,7,9,13, 17,18,19,20,21,22,23, 24,25,26,27,28,
                              29,30,31,32,33, 34,35, 36,37,38,39,40,41,42,43,44,45,46};
    const int cn[NCANON] = {
        ND*2, NLN*1, Dd*3, ED*2, ET*1,
        VD*EMB, VL*EMB, 3*TV*EMB, 2*TV*EMB, 4*TV*EMB, 2*TV*EMB, 2*TV*EMB,
        2*EMB, 1*EMB, 3*EMB, 2*EMB, 1*EMB,
        5*EMB*Hh, 4*EMB*Hh, 5*EMB*Hh, 3*EMB*Hh, 3*EMB*Hh,
        GL*4*Hh*Hh, GL*3*Hh*Hh,
        L_ENC*Hh*3*Hh, L_ENC*3*Hh, L_ENC*Hh*Hh, L_ENC*Hh, L_ENC*2*Hh,
        L_ENC*Hh*FF, L_ENC*FF, L_ENC*FF*Hh, L_ENC*Hh, L_ENC*2*Hh, Hh
    };
    CanonDesc cd;
    int eoff[NCANON + 1];
    int btot_blocks = 0;
    {
        int e = 0;
        for (int t = 0; t < NCANON; t++) {
            cd.src[t] = d_in[cidx[t]];
            cd.n[t] = cn[t];
            eoff[t] = e;
            cd.doff[t] = e;
            e = (e + cn[t] + 7) & ~7;
            btot_blocks += (cn[t] + 255) / 256;
            cd.bend[t] = btot_blocks;
        }
        eoff[NCANON] = e;
    }

    // ---- workspace carve ----
    char* p = (char*)d_ws;
    auto alloc_f = [&](size_t n) -> float*    { float* r = (float*)p;    p += n * sizeof(float); return r; };
    auto alloc_h = [&](size_t n) -> ushort_t* { ushort_t* r = (ushort_t*)p; p += n * sizeof(ushort_t); return r; };
    auto alloc_i = [&](size_t n) -> int*      { int* r = (int*)p;        p += n * sizeof(int); return r; };

    int* map    = alloc_i(ND);
    int* cnt_dc = alloc_i(UCAP);
    int* cnt_ld = alloc_i(NLN);
    int* cnt_a1 = alloc_i(64);
    int* cnt_a2 = alloc_i(64);
    int* nUB    = alloc_i(8);
    int* cur_t  = alloc_i(UCAP);
    int* cur_d  = alloc_i(NLN);
    int* cur_a1 = alloc_i(64);
    int* cur_a2 = alloc_i(64);
    float* E_did  = alloc_f((size_t)Dd * Hh);
    float* E_took = alloc_f((size_t)Dd * Hh);
    const size_t ZBLOCK = (size_t)ND + UCAP + NLN + 64 + 64 + 8 + UCAP + NLN + 64 + 64
                        + (size_t)Dd * Hh * 2;
    float* Sx_did  = alloc_f((size_t)Dd * Hh);
    float* Sx_took = alloc_f((size_t)Dd * Hh);
    int* roff_t  = alloc_i(UCAP + 8);
    int* roff_d  = alloc_i(NLN + 8);
    int* roff_a1 = alloc_i(72);
    int* roff_a2 = alloc_i(72);
    int* bscr    = alloc_i(1024);
    u64* absum   = (u64*)alloc_i(2 * (NB_A + 8));
    int* ulist   = alloc_i(UCAP);
    int* blist   = alloc_i(NCAND);
    int* elist_t = alloc_i(ET);
    int* elist_d = alloc_i(ED);
    int* tookA   = alloc_i(ET);
    int* tookB   = alloc_i(ET);
    int* didA    = alloc_i(ED);
    int* didB    = alloc_i(ED);
    ushort_t* wt     = alloc_h(3 * 32768);
    ushort_t* ap     = alloc_h(2 * 8192 + 2 * 4096);
    ushort_t* x_dc   = alloc_h((size_t)UCAP * Hh);
    ushort_t* x_l    = alloc_h((size_t)NLN * Hh);
    float*    x_a    = alloc_f((size_t)Dd * Hh);
    ushort_t* e_did  = alloc_h((size_t)ED * Hh);
    ushort_t* e_took = alloc_h((size_t)ET * Hh);
    float*    qkvb   = alloc_f((size_t)Dd * 384);
    float*    fbuf   = alloc_f((size_t)Dd * FF);
    float*    part   = alloc_f((size_t)Dd * 16 * Hh);
    float*    cf     = alloc_f((size_t)eoff[NCANON]);
    int*      dflag  = alloc_i(8);

    ushort_t* ap_drug = ap;
    ushort_t* ap_lab  = ap + 8192;
    ushort_t* ap_did  = ap + 16384;
    ushort_t* ap_took = ap + 16384 + 4096;

    const float* c_drug_floats  = cf + eoff[0];
    const float* c_lab_floats   = cf + eoff[1];
    const float* c_adm_floats   = cf + eoff[2];
    const float* c_did_floats   = cf + eoff[3];
    const float* c_took_floats  = cf + eoff[4];
    const float* c_drug_id_emb  = cf + eoff[5];
    const float* c_lab_id_emb   = cf + eoff[6];
    const float* c_drug_tok_emb = cf + eoff[7];
    const float* c_lab_tok_emb  = cf + eoff[8];
    const float* c_adm_tok_emb  = cf + eoff[9];
    const float* c_did_tok_emb  = cf + eoff[10];
    const float* c_took_tok_emb = cf + eoff[11];
    const float* c_drug_float_w = cf + eoff[12];
    const float* c_lab_float_w  = cf + eoff[13];
    const float* c_adm_float_w  = cf + eoff[14];
    const float* c_did_float_w  = cf + eoff[15];
    const float* c_took_float_w = cf + eoff[16];
    const float* c_drug_align   = cf + eoff[17];
    const float* c_lab_align    = cf + eoff[18];
    const float* c_adm_align    = cf + eoff[19];
    const float* c_did_align    = cf + eoff[20];
    const float* c_took_align   = cf + eoff[21];
    const float* c_gnn_msg      = cf + eoff[22];
    const float* c_gnn_self     = cf + eoff[23];
    const float* c_qkv_w        = cf + eoff[24];
    const float* c_qkv_b        = cf + eoff[25];
    const float* c_out_w        = cf + eoff[26];
    const float* c_out_b        = cf + eoff[27];
    const float* c_ln1          = cf + eoff[28];
    const float* c_ff1_w        = cf + eoff[29];
    const float* c_ff1_b        = cf + eoff[30];
    const float* c_ff2_w        = cf + eoff[31];
    const float* c_ff2_b        = cf + eoff[32];
    const float* c_ln2          = cf + eoff[33];
    const float* c_lp_w         = cf + eoff[34];

    // ---- canonicalize + graph prep ----
    k_probe<<<1, 64, 0, stream>>>((const unsigned*)d_in[41], dflag);
    k_canon<<<btot_blocks, 256, 0, stream>>>(cd, cf, dflag);
    k_wpack<<<dim3(32, 3), 128, 0, stream>>>(c_gnn_self, c_gnn_msg, wt);
    k_apack<<<8, 128, 0, stream>>>(c_drug_align, ap_drug, 50);
    k_apack<<<8, 128, 0, stream>>>(c_lab_align,  ap_lab,  40);
    k_apack<<<4, 128, 0, stream>>>(c_did_align,  ap_did,  30);
    k_apack<<<4, 128, 0, stream>>>(c_took_align, ap_took, 30);
    hipMemsetAsync(map, 0, ZBLOCK * sizeof(int), stream);
    k_mark<<<ET / 256, 256, 0, stream>>>(took_dst, cand_idx, map);
    k_acount<<<NB_A, 256, 0, stream>>>(map, absum);
    k_ascan<<<1, 1024, 0, stream>>>(absum, NB_A, nUB);
    k_assign2<<<NB_A, 256, 0, stream>>>(map, ulist, blist, absum);
    k_counts<<<128, 256, 0, stream>>>(did_dst, did_src, took_dst, took_src, map,
                                      cnt_ld, cnt_a1, cnt_dc, cnt_a2);
    k_scan_blk<<<NB_T, 256, 0, stream>>>(cnt_dc, roff_t, bscr, UCAP);
    k_scan_top<<<1, 1024, 0, stream>>>(bscr, NB_T);
    k_scan_add<<<NB_T, 256, 0, stream>>>(roff_t, bscr, UCAP, ET);
    k_scan_blk<<<NB_D, 256, 0, stream>>>(cnt_ld, roff_d, bscr, NLN);
    k_scan_top<<<1, 1024, 0, stream>>>(bscr, NB_D);
    k_scan_add<<<NB_D, 256, 0, stream>>>(roff_d, bscr, NLN, ED);
    k_scan64<<<1, 64, 0, stream>>>(cnt_a1, cnt_a2, roff_a1, roff_a2);
    k_fill<<<128, 256, 0, stream>>>(did_src, did_dst, took_src, took_dst, map,
                                    roff_d, roff_t, roff_a1, roff_a2,
                                    cur_d, cur_t, cur_a1, cur_a2,
                                    elist_d, elist_t, didA, didB, tookA, tookB);

    // ---- embeddings (MFMA for the 4 big ones; scalar for adm) ----
    k_embed_m<1,3,2,2,true><<<UCAP / 32, 128, 0, stream>>>(x_dc, 0, nUB, ulist,
        drug_node_id, c_drug_id_emb, drug_tokens, c_drug_tok_emb,
        c_drug_floats, c_drug_float_w, ap_drug);
    k_embed_m<1,2,1,2,false><<<NLN / 32, 128, 0, stream>>>(x_l, NLN, nullptr, nullptr,
        lab_node_id, c_lab_id_emb, lab_tokens, c_lab_tok_emb,
        c_lab_floats, c_lab_float_w, ap_lab);
    k_embed<0,4,3><<<1, 64, 0, stream>>>(x_a, Dd,
        nullptr, nullptr, adm_tokens, c_adm_tok_emb, c_adm_floats, c_adm_float_w, c_adm_align);
    k_embed_m<0,2,2,1,false><<<ED / 32, 128, 0, stream>>>(e_did, ED, nullptr, nullptr,
        nullptr, nullptr, did_tokens, c_did_tok_emb, c_did_floats, c_did_float_w, ap_did);
    k_embed_m<0,2,1,1,false><<<ET / 32, 128, 0, stream>>>(e_took, ET, nullptr, nullptr,
        nullptr, nullptr, took_tokens, c_took_tok_emb, c_took_floats, c_took_float_w, ap_took);

    const size_t HH = (size_t)Hh * Hh;

    // ---- GNN layer 1 (relu) ----
    hipMemsetAsync(Sx_did, 0, 2 * (size_t)Dd * Hh * sizeof(float), stream);
    k_srcsum<true><<<(ED + 31) / 32, 64, 0, stream>>>(didA, didB, x_l, e_did, 16,
                                                      Sx_did, E_did, ED, 32);
    k_srcsum<true><<<(ET + 31) / 32, 64, 0, stream>>>(tookA, tookB, x_dc, e_took, 18,
                                                      Sx_took, E_took, ET, 32);
    k_gup<false><<<UCAP / 32, 128, 0, stream>>>(x_dc, x_a, e_took, roff_t, elist_t, 17,
        nullptr, nUB, 0, wt, 1);
    k_gup<false><<<NLN / 32, 128, 0, stream>>>(x_l, x_a, e_did, roff_d, elist_d, 15,
        nullptr, nullptr, NLN, wt + 32768, 1);
    k_xa<<<Dd, 128, 0, stream>>>(x_a, Sx_did, E_did, Sx_took, E_took, cnt_a1, cnt_a2,
        c_gnn_self + 0 * HH, c_gnn_msg + 2 * HH, c_gnn_msg + 3 * HH, 1);

    // ---- GNN layer 2 ----
    const float* Ws1 = c_gnn_self + 3 * HH;
    const float* Wm1 = c_gnn_msg + 4 * HH;
    hipMemsetAsync(Sx_did, 0, 2 * (size_t)Dd * Hh * sizeof(float), stream);
    k_srcsum<false><<<(ED + 31) / 32, 64, 0, stream>>>(didA, didB, x_l, nullptr, 16,
                                                       Sx_did, nullptr, ED, 32);
    k_srcsum<false><<<(ET + 31) / 32, 64, 0, stream>>>(tookA, tookB, x_dc, nullptr, 18,
                                                       Sx_took, nullptr, ET, 32);
    k_gup<true><<<(NCAND + 31) / 32, 128, 0, stream>>>(x_dc, x_a, e_took, roff_t, elist_t, 17,
        blist, nUB + 1, 0, wt + 65536, 0);
    k_xa<<<Dd, 128, 0, stream>>>(x_a, Sx_did, E_did, Sx_took, E_took, cnt_a1, cnt_a2,
        Ws1 + 0 * HH, Wm1 + 2 * HH, Wm1 + 3 * HH, 0);

    // ---- transformer encoder (3 launches/layer) ----
    k_qkv<<<Dd, 128, 0, stream>>>(x_a, qkvb, c_qkv_w, c_qkv_b);
    for (int i = 0; i < L_ENC; i++) {
        k_attn_ff1<<<Dd, 256, 0, stream>>>(qkvb, x_a, fbuf,
            c_out_w + (size_t)i * HH, c_out_b + (size_t)i * Hh, c_ln1 + (size_t)i * 2 * Hh,
            c_ff1_w + (size_t)i * Hh * FF, c_ff1_b + (size_t)i * FF);
        k_ff2p<<<dim3(Dd, 16), 128, 0, stream>>>(fbuf, part, c_ff2_w + (size_t)i * FF * Hh);
        int nx = (i + 1 < L_ENC) ? 1 : 0;
        k_ln2qkv<<<Dd, 128, 0, stream>>>(x_a, part, c_ff2_b + (size_t)i * Hh,
            c_ln2 + (size_t)i * 2 * Hh, qkvb,
            c_qkv_w + (size_t)(nx ? (i + 1) : 0) * Hh * 384,
            c_qkv_b + (size_t)(nx ? (i + 1) : 0) * 384, nx);
    }

    // ---- logits ----
    k_logits<<<Dd - 1, 256, 0, stream>>>(x_dc, map, x_a, c_lp_w, cand_idx, (float*)d_out);
}

// Round 12
// 814.845 us; speedup vs baseline: 4.6902x; 1.6500x over previous
//
#include <hip/hip_runtime.h>
#include <hip/hip_bf16.h>

typedef unsigned short ushort_t;
typedef unsigned long long u64;
typedef __attribute__((ext_vector_type(8))) short bf16x8;
typedef __attribute__((ext_vector_type(4))) float f32x4;

#define DEV __device__ __forceinline__

constexpr int Dd  = 64;
constexpr int VD  = 4525;
constexpr int VL  = 753;
constexpr int ND  = Dd * VD;     // 289600
constexpr int NLN = Dd * VL;     // 48192
constexpr int Hh  = 128;
constexpr int EMB = 10;
constexpr int TV  = 100;
constexpr int NH  = 8, HD = 16;
constexpr int L_ENC = 6, FF = 2048;
constexpr int GL  = 2;
constexpr int ED  = 32768, ET = 131072;
constexpr int KK  = 256;
constexpr int NCAND = (Dd - 1) * KK;       // 16128
constexpr int UCAP  = ET + NCAND;          // 147200
constexpr int NCANON = 35;
constexpr int NB_T = (UCAP + 255) / 256;
constexpr int NB_D = (NLN + 255) / 256;
constexpr int NB_A = (ND + 255) / 256;

DEV float bf(ushort_t u) { return __uint_as_float(((unsigned)u) << 16); }
DEV float bflo(unsigned u) { return __uint_as_float(u << 16); }
DEV float bfhi(unsigned u) { return __uint_as_float(u & 0xffff0000u); }
DEV ushort_t f2bf(float f) {
    unsigned u = __float_as_uint(f);
    u += 0x7fffu + ((u >> 16) & 1u);
    return (ushort_t)(u >> 16);
}

// ---------------------------------------------------------------------------
__global__ __launch_bounds__(64)
void k_probe(const unsigned* __restrict__ w, int* __restrict__ flag)
{
    int tid = threadIdx.x;
    int c = 0;
    #pragma unroll
    for (int i = 0; i < 16; i++) c += (w[tid * 16 + i] >> 14) & 1;
    #pragma unroll
    for (int o = 32; o; o >>= 1) c += __shfl_xor(c, o);
    if (tid == 0) *flag = (c > 256) ? 1 : 0;
}

struct CanonDesc {
    const void* src[NCANON];
    int doff[NCANON];
    int bend[NCANON];
    int n[NCANON];
};

__global__ __launch_bounds__(256)
void k_canon(CanonDesc cd, float* __restrict__ dst, const int* __restrict__ flag)
{
    int b = blockIdx.x;
    int t = 0;
    while (t < NCANON && b >= cd.bend[t]) t++;
    if (t >= NCANON) return;
    int bstart = (t == 0) ? 0 : cd.bend[t - 1];
    int i = (b - bstart) * 256 + threadIdx.x;
    if (i >= cd.n[t]) return;
    float v = (*flag) ? ((const float*)cd.src[t])[i]
                      : bf(((const ushort_t*)cd.src[t])[i]);
    dst[cd.doff[t] + i] = v;
}

__global__ __launch_bounds__(128)
void k_wpack(const float* __restrict__ gself, const float* __restrict__ gmsg,
             ushort_t* __restrict__ wt)
{
    const int selfIdx[3] = {1, 2, 4};
    const int msgIdx[3]  = {1, 0, 5};
    int pr = blockIdx.y, chunk = blockIdx.x, nn = threadIdx.x;
    const float* Ws = gself + (size_t)selfIdx[pr] * Hh * Hh;
    const float* Wm = gmsg  + (size_t)msgIdx[pr]  * Hh * Hh;
    ushort_t* dst = wt + (((size_t)pr * 32 + chunk) * 128 + nn) * 8;
    #pragma unroll
    for (int j = 0; j < 8; j++) {
        int k = chunk * 8 + j;
        float v = (k < 128) ? Ws[k * Hh + nn] : Wm[(k - 128) * Hh + nn];
        dst[j] = f2bf(v);
    }
}

__global__ __launch_bounds__(128)
void k_apack(const float* __restrict__ A, ushort_t* __restrict__ dst, int L)
{
    int c = blockIdx.x, nn = threadIdx.x;
    ushort_t* d = dst + ((size_t)c * 128 + nn) * 8;
    #pragma unroll
    for (int j = 0; j < 8; j++) {
        int k = c * 8 + j;
        d[j] = (k < L) ? f2bf(A[(size_t)k * Hh + nn]) : (ushort_t)0;
    }
}

// ---------------------------------------------------------------------------
__global__ __launch_bounds__(256)
void k_mark(const int* __restrict__ took_dst, const int* __restrict__ cand,
            int* __restrict__ map)
{
    int g = blockIdx.x * 256 + threadIdx.x;
    if (g < ET) atomicOr(&map[took_dst[g]], 1);
    if (g < NCAND) {
        int d = g >> 8;
        atomicOr(&map[d * VD + cand[g]], 2);
    }
}

// contention-free slot assignment (u64: isU low 32, isB high 32)
__global__ __launch_bounds__(256)
void k_acount(const int* __restrict__ map, u64* __restrict__ bsum)
{
    __shared__ u64 s[256];
    int tid = threadIdx.x;
    int g = blockIdx.x * 256 + tid;
    int m = (g < ND) ? map[g] : 0;
    s[tid] = (u64)(m ? 1u : 0u) | ((u64)((m & 2) ? 1u : 0u) << 32);
    __syncthreads();
    for (int o = 128; o; o >>= 1) {
        if (tid < o) s[tid] += s[tid + o];
        __syncthreads();
    }
    if (tid == 0) bsum[blockIdx.x] = s[0];
}

__global__ __launch_bounds__(1024)
void k_ascan(u64* __restrict__ bsum, int nb, int* __restrict__ nUB)
{
    __shared__ u64 s[1024];
    int tid = threadIdx.x;
    u64 carry = 0;
    for (int base = 0; base < nb; base += 1024) {
        int idx = base + tid;
        u64 v = (idx < nb) ? bsum[idx] : 0;
        s[tid] = v;
        __syncthreads();
        for (int o = 1; o < 1024; o <<= 1) {
            u64 t = (tid >= o) ? s[tid - o] : 0;
            __syncthreads();
            s[tid] += t;
            __syncthreads();
        }
        if (idx < nb) bsum[idx] = carry + s[tid] - v;
        u64 tot = s[1023];
        __syncthreads();
        carry += tot;
    }
    if (tid == 0) {
        nUB[0] = (int)(carry & 0xffffffffu);
        nUB[1] = (int)(carry >> 32);
    }
}

__global__ __launch_bounds__(256)
void k_assign2(int* __restrict__ map, int* __restrict__ ulist, int* __restrict__ blist,
               const u64* __restrict__ bsum)
{
    __shared__ u64 s[256];
    int tid = threadIdx.x;
    int g = blockIdx.x * 256 + tid;
    int m = (g < ND) ? map[g] : 0;
    u64 v = (u64)(m ? 1u : 0u) | ((u64)((m & 2) ? 1u : 0u) << 32);
    s[tid] = v;
    __syncthreads();
    for (int o = 1; o < 256; o <<= 1) {
        u64 t = (tid >= o) ? s[tid - o] : 0;
        __syncthreads();
        s[tid] += t;
        __syncthreads();
    }
    u64 excl = s[tid] - v + bsum[blockIdx.x];
    if (m) {
        int slot = (int)(excl & 0xffffffffu);
        ulist[slot] = g;
        map[g] = (slot << 2) | m;
        if (m & 2) blist[(int)(excl >> 32)] = slot;
    }
}

__global__ __launch_bounds__(256)
void k_counts(const int* __restrict__ did_dst, const int* __restrict__ did_src,
              const int* __restrict__ took_dst, const int* __restrict__ took_src,
              const int* __restrict__ map,
              int* __restrict__ cnt_ld, int* __restrict__ cnt_a1,
              int* __restrict__ cnt_dc, int* __restrict__ cnt_a2)
{
    __shared__ int h1[64], h2[64];
    int tid = threadIdx.x;
    if (tid < 64) { h1[tid] = 0; h2[tid] = 0; }
    __syncthreads();
    int tb = blockIdx.x * 1024;
    #pragma unroll
    for (int o = 0; o < 1024; o += 256) {
        int i = tb + o + tid;
        atomicAdd(&cnt_dc[map[took_dst[i]] >> 2], 1);
        atomicAdd(&h2[took_src[i]], 1);
    }
    {
        int i = blockIdx.x * 256 + tid;
        atomicAdd(&cnt_ld[did_dst[i]], 1);
        atomicAdd(&h1[did_src[i]], 1);
    }
    __syncthreads();
    if (tid < 64) {
        if (h1[tid]) atomicAdd(&cnt_a1[tid], h1[tid]);
        if (h2[tid]) atomicAdd(&cnt_a2[tid], h2[tid]);
    }
}

// ---------------------------------------------------------------------------
__global__ __launch_bounds__(256)
void k_scan_blk(const int* __restrict__ cnt, int* __restrict__ excl,
                int* __restrict__ btot, int n)
{
    __shared__ int s[256];
    int tid = threadIdx.x;
    int g = blockIdx.x * 256 + tid;
    int v = (g < n) ? cnt[g] : 0;
    s[tid] = v;
    __syncthreads();
    for (int o = 1; o < 256; o <<= 1) {
        int t = (tid >= o) ? s[tid - o] : 0;
        __syncthreads();
        s[tid] += t;
        __syncthreads();
    }
    if (g < n) excl[g] = s[tid] - v;
    if (tid == 255) btot[blockIdx.x] = s[255];
}

__global__ __launch_bounds__(1024)
void k_scan_top(int* __restrict__ btot, int nb)
{
    __shared__ int s[1024];
    int tid = threadIdx.x;
    int v = (tid < nb) ? btot[tid] : 0;
    s[tid] = v;
    __syncthreads();
    for (int o = 1; o < 1024; o <<= 1) {
        int t = (tid >= o) ? s[tid - o] : 0;
        __syncthreads();
        s[tid] += t;
        __syncthreads();
    }
    if (tid < nb) btot[tid] = s[tid] - v;
}

__global__ __launch_bounds__(256)
void k_scan_add(int* __restrict__ roff, const int* __restrict__ btot, int n, int total)
{
    int g = blockIdx.x * 256 + threadIdx.x;
    if (g < n) roff[g] += btot[blockIdx.x];
    if (g == 0) roff[n] = total;
}

__global__ __launch_bounds__(64)
void k_scan64(const int* __restrict__ c1, const int* __restrict__ c2,
              int* __restrict__ r1, int* __restrict__ r2)
{
    int tid = threadIdx.x;
    int v1 = c1[tid], v2 = c2[tid];
    int s1 = v1, s2 = v2;
    for (int o = 1; o < 64; o <<= 1) {
        int t1 = __shfl_up(s1, o), t2 = __shfl_up(s2, o);
        if (tid >= o) { s1 += t1; s2 += t2; }
    }
    r1[tid] = s1 - v1;
    r2[tid] = s2 - v2;
}

__global__ __launch_bounds__(256)
void k_fill(const int* __restrict__ did_src, const int* __restrict__ did_dst,
            const int* __restrict__ took_src, const int* __restrict__ took_dst,
            const int* __restrict__ map,
            const int* __restrict__ roff_d, const int* __restrict__ roff_t,
            const int* __restrict__ roff_a1, const int* __restrict__ roff_a2,
            int* __restrict__ cur_d, int* __restrict__ cur_t,
            int* __restrict__ cur_a1, int* __restrict__ cur_a2,
            int* __restrict__ elist_d, int* __restrict__ elist_t,
            int* __restrict__ didA, int* __restrict__ didB,
            int* __restrict__ tookA, int* __restrict__ tookB)
{
    __shared__ int h1[64], h2[64], b1[64], b2[64];
    int tid = threadIdx.x;
    if (tid < 64) { h1[tid] = 0; h2[tid] = 0; }
    __syncthreads();
    int tb = blockIdx.x * 1024;
    int db = blockIdx.x * 256;
    #pragma unroll
    for (int o = 0; o < 1024; o += 256)
        atomicAdd(&h2[took_src[tb + o + tid]], 1);
    atomicAdd(&h1[did_src[db + tid]], 1);
    __syncthreads();
    if (tid < 64) {
        b1[tid] = h1[tid] ? atomicAdd(&cur_a1[tid], h1[tid]) : 0;
        b2[tid] = h2[tid] ? atomicAdd(&cur_a2[tid], h2[tid]) : 0;
        h1[tid] = 0; h2[tid] = 0;
    }
    __syncthreads();
    #pragma unroll
    for (int o = 0; o < 1024; o += 256) {
        int i = tb + o + tid;
        int s = took_src[i];
        int slot = map[took_dst[i]] >> 2;
        int pos = roff_t[slot] + atomicAdd(&cur_t[slot], 1);
        elist_t[pos] = (s << 17) | i;
        int pa = roff_a2[s] + b2[s] + atomicAdd(&h2[s], 1);
        tookA[pa] = (s << 18) | slot;
        tookB[pa] = i;
    }
    {
        int i = db + tid;
        int d = did_dst[i], s = did_src[i];
        int pos = roff_d[d] + atomicAdd(&cur_d[d], 1);
        elist_d[pos] = (s << 15) | i;
        int pa = roff_a1[s] + b1[s] + atomicAdd(&h1[s], 1);
        didA[pa] = (s << 16) | d;
        didB[pa] = i;
    }
}

// ---------------------------------------------------------------------------
template<bool DUAL>
__global__ __launch_bounds__(64)
void k_srcsum(const int* __restrict__ lA, const int* __restrict__ lB,
              const ushort_t* __restrict__ xrows, const ushort_t* __restrict__ erows,
              int shift, float* __restrict__ Sx, float* __restrict__ Se,
              int nedge, int epb)
{
    int lane = threadIdx.x;
    int c0 = lane * 2;
    int base = blockIdx.x * epb;
    int end = min(base + epb, nedge);
    int mask = (1 << shift) - 1;
    float ax0 = 0.f, ax1 = 0.f, ae0 = 0.f, ae1 = 0.f;
    int cur = -1;
    for (int i = base; i < end; i++) {
        int pk = lA[i];
        int s = pk >> shift, row = pk & mask;
        if (s != cur) {
            if (cur >= 0) {
                unsafeAtomicAdd(&Sx[cur * Hh + c0], ax0);
                unsafeAtomicAdd(&Sx[cur * Hh + c0 + 1], ax1);
                if (DUAL) {
                    unsafeAtomicAdd(&Se[cur * Hh + c0], ae0);
                    unsafeAtomicAdd(&Se[cur * Hh + c0 + 1], ae1);
                }
            }
            cur = s; ax0 = ax1 = ae0 = ae1 = 0.f;
        }
        unsigned xx = *reinterpret_cast<const unsigned*>(xrows + (size_t)row * Hh + c0);
        ax0 += bflo(xx); ax1 += bfhi(xx);
        if (DUAL) {
            int e = lB[i];
            unsigned ee = *reinterpret_cast<const unsigned*>(erows + (size_t)e * Hh + c0);
            ae0 += bflo(ee); ae1 += bfhi(ee);
        }
    }
    if (cur >= 0) {
        unsafeAtomicAdd(&Sx[cur * Hh + c0], ax0);
        unsafeAtomicAdd(&Sx[cur * Hh + c0 + 1], ax1);
        if (DUAL) {
            unsafeAtomicAdd(&Se[cur * Hh + c0], ae0);
            unsafeAtomicAdd(&Se[cur * Hh + c0 + 1], ae1);
        }
    }
}

// ---------------------------------------------------------------------------
// scalar embed (adm only; 1 block)
template<int NID, int NTOK, int NF>
__global__ __launch_bounds__(64)
void k_embed(float* __restrict__ out, int n,
             const int* __restrict__ id_idx, const float* __restrict__ id_emb,
             const int* __restrict__ tokens, const float* __restrict__ tok_emb,
             const float* __restrict__ floats_, const float* __restrict__ float_w,
             const float* __restrict__ alignf)
{
    constexpr int L = (NID + NTOK + 1) * EMB;
    int node = blockIdx.x * 64 + threadIdx.x;
    if (node >= n) return;
    float vec[L];
    int p = 0;
    if constexpr (NID != 0) {
        const float* pe = id_emb + (size_t)id_idx[node] * EMB;
        #pragma unroll
        for (int e = 0; e < EMB; e++) vec[p++] = pe[e];
    }
    #pragma unroll
    for (int t = 0; t < NTOK; t++) {
        const float* pe = tok_emb + ((size_t)t * TV + tokens[node * NTOK + t]) * EMB;
        #pragma unroll
        for (int e = 0; e < EMB; e++) vec[p++] = pe[e];
    }
    {
        float fv[NF];
        #pragma unroll
        for (int f = 0; f < NF; f++) fv[f] = floats_[node * NF + f];
        #pragma unroll
        for (int e = 0; e < EMB; e++) {
            float a = 0.f;
            #pragma unroll
            for (int f = 0; f < NF; f++) a = fmaf(fv[f], float_w[f * EMB + e], a);
            vec[p++] = a;
        }
    }
    #pragma unroll 1
    for (int j = 0; j < Hh; j += 4) {
        float a0 = 0.f, a1 = 0.f, a2 = 0.f, a3 = 0.f;
        #pragma unroll
        for (int i = 0; i < L; i++) {
            const float* w = alignf + i * Hh + j;
            a0 = fmaf(vec[i], w[0], a0);
            a1 = fmaf(vec[i], w[1], a1);
            a2 = fmaf(vec[i], w[2], a2);
            a3 = fmaf(vec[i], w[3], a3);
        }
        float4 r4; r4.x = a0; r4.y = a1; r4.z = a2; r4.w = a3;
        *reinterpret_cast<float4*>(out + (size_t)node * Hh + j) = r4;
    }
}

// MFMA embed
template<int NID, int NTOK, int NF, int KCH, bool INDIRECT>
__global__ __launch_bounds__(128)
void k_embed_m(ushort_t* __restrict__ out, int n_static, const int* __restrict__ n_dyn,
               const int* __restrict__ ulist,
               const int* __restrict__ id_idx, const float* __restrict__ id_emb,
               const int* __restrict__ tokens, const float* __restrict__ tok_emb,
               const float* __restrict__ floats_, const float* __restrict__ float_w,
               const ushort_t* __restrict__ Bp)
{
    constexpr int NSEG = NID + NTOK + 1;
    constexpr int K = KCH * 32;
    constexpr int STR = K + 8;
    __shared__ ushort_t As[32 * 264];
    __shared__ int nodeid[32];
    int tid = threadIdx.x;
    int r0 = blockIdx.x * 32;
    int n = INDIRECT ? *n_dyn : n_static;
    if (tid < 32) {
        int slot = r0 + tid;
        nodeid[tid] = (slot < n) ? (INDIRECT ? ulist[slot] : slot) : -1;
    }
    for (int i = tid; i < 32 * STR; i += 128) As[i] = 0;
    __syncthreads();

    for (int pi = tid; pi < 32 * NSEG; pi += 128) {
        int seg = pi >> 5, nl = pi & 31;
        int node = nodeid[nl];
        if (node < 0) continue;
        float v[EMB];
        if (NID != 0 && seg == 0) {
            const float* pe = id_emb + (size_t)id_idx[node] * EMB;
            #pragma unroll
            for (int e = 0; e < EMB; e++) v[e] = pe[e];
        } else if (seg < NID + NTOK) {
            int t = seg - NID;
            const float* pe = tok_emb + ((size_t)t * TV + tokens[node * NTOK + t]) * EMB;
            #pragma unroll
            for (int e = 0; e < EMB; e++) v[e] = pe[e];
        } else {
            float fv[NF];
            #pragma unroll
            for (int f = 0; f < NF; f++) fv[f] = floats_[node * NF + f];
            #pragma unroll
            for (int e = 0; e < EMB; e++) {
                float a = 0.f;
                #pragma unroll
                for (int f = 0; f < NF; f++) a = fmaf(fv[f], float_w[f * EMB + e], a);
                v[e] = a;
            }
        }
        ushort_t* dst = &As[nl * STR + seg * EMB];
        #pragma unroll
        for (int e = 0; e < EMB; e += 2) {
            unsigned pk = (unsigned)f2bf(v[e]) | ((unsigned)f2bf(v[e + 1]) << 16);
            *reinterpret_cast<unsigned*>(dst + e) = pk;
        }
    }
    __syncthreads();

    int wid = tid >> 6, lane = tid & 63;
    int m = lane & 15, quad = lane >> 4;
    f32x4 acc[8];
    #pragma unroll
    for (int t = 0; t < 8; t++) acc[t] = (f32x4){0.f, 0.f, 0.f, 0.f};
    #pragma unroll
    for (int kc = 0; kc < KCH; kc++) {
        bf16x8 a = *reinterpret_cast<const bf16x8*>(&As[(16 * wid + m) * STR + kc * 32 + quad * 8]);
        #pragma unroll
        for (int nt = 0; nt < 8; nt++) {
            bf16x8 b = *reinterpret_cast<const bf16x8*>(Bp + (((kc * 4 + quad) * 128) + nt * 16 + m) * 8);
            acc[nt] = __builtin_amdgcn_mfma_f32_16x16x32_bf16(a, b, acc[nt], 0, 0, 0);
        }
    }
    __syncthreads();
    float* Ds = reinterpret_cast<float*>(As);
    #pragma unroll
    for (int nt = 0; nt < 8; nt++)
        #pragma unroll
        for (int reg = 0; reg < 4; reg++)
            Ds[(16 * wid + quad * 4 + reg) * 132 + nt * 16 + m] = acc[nt][reg];
    __syncthreads();
    for (int idx = tid; idx < 512; idx += 128) {
        int r = idx >> 4, c16 = idx & 15;
        int slot = r0 + r;
        if (slot >= n) continue;
        const float* dsrc = &Ds[r * 132 + c16 * 8];
        uint4 v;
        v.x = (unsigned)f2bf(dsrc[0]) | ((unsigned)f2bf(dsrc[1]) << 16);
        v.y = (unsigned)f2bf(dsrc[2]) | ((unsigned)f2bf(dsrc[3]) << 16);
        v.z = (unsigned)f2bf(dsrc[4]) | ((unsigned)f2bf(dsrc[5]) << 16);
        v.w = (unsigned)f2bf(dsrc[6]) | ((unsigned)f2bf(dsrc[7]) << 16);
        *reinterpret_cast<uint4*>(out + (size_t)slot * Hh + c16 * 8) = v;
    }
}

// ---------------------------------------------------------------------------
// Fused gather + mean + GNN update, MFMA version.
template<bool INDIRECT>
__global__ __launch_bounds__(128)
void k_gup(ushort_t* __restrict__ X, const float* __restrict__ xa,
           const ushort_t* __restrict__ ef,
           const int* __restrict__ roff, const int* __restrict__ elist, int sshift,
           const int* __restrict__ rows_list, const int* __restrict__ n_dyn, int n_static,
           const ushort_t* __restrict__ Wt, int do_relu)
{
    __shared__ ushort_t As[32 * 264];
    __shared__ int rowid[32];
    int tid = threadIdx.x;
    int r0 = blockIdx.x * 32;
    int n = n_dyn ? *n_dyn : n_static;
    if (tid < 32) {
        int row = r0 + tid;
        rowid[tid] = (row < n) ? (INDIRECT ? rows_list[row] : row) : -1;
    }
    __syncthreads();

    for (int idx = tid; idx < 512; idx += 128) {
        int r = idx >> 4, c16 = idx & 15;
        int rr = rowid[r];
        uint4 v = make_uint4(0, 0, 0, 0);
        if (rr >= 0) v = *reinterpret_cast<const uint4*>(X + (size_t)rr * Hh + c16 * 8);
        *reinterpret_cast<uint4*>(&As[r * 264 + c16 * 8]) = v;
    }
    int wid = tid >> 6, lane = tid & 63;
    int c0 = lane * 2;
    int emask = (1 << sshift) - 1;
    for (int r = wid; r < 32; r += 2) {
        int rr = rowid[r];
        float a0 = 0.f, a1 = 0.f, invd = 0.f;
        if (rr >= 0) {
            int e0 = roff[rr], e1 = roff[rr + 1];
            invd = 1.f / fmaxf((float)(e1 - e0), 1.f);
            for (int ei = e0; ei < e1; ei++) {
                int pk = elist[ei];
                int s = pk >> sshift, e = pk & emask;
                const float* xr = xa + s * Hh + c0;
                unsigned ee = *reinterpret_cast<const unsigned*>(ef + (size_t)e * Hh + c0);
                a0 += xr[0] + bflo(ee);
                a1 += xr[1] + bfhi(ee);
            }
        }
        unsigned pk2 = (unsigned)f2bf(a0 * invd) | ((unsigned)f2bf(a1 * invd) << 16);
        *reinterpret_cast<unsigned*>(&As[r * 264 + 128 + c0]) = pk2;
    }
    __syncthreads();

    int m = lane & 15, quad = lane >> 4;
    f32x4 acc[8];
    #pragma unroll
    for (int t = 0; t < 8; t++) acc[t] = (f32x4){0.f, 0.f, 0.f, 0.f};
    #pragma unroll
    for (int kc = 0; kc < 8; kc++) {
        bf16x8 a = *reinterpret_cast<const bf16x8*>(&As[(16 * wid + m) * 264 + kc * 32 + quad * 8]);
        #pragma unroll
        for (int nt = 0; nt < 8; nt++) {
            bf16x8 b = *reinterpret_cast<const bf16x8*>(Wt + (((kc * 4 + quad) * 128) + nt * 16 + m) * 8);
            acc[nt] = __builtin_amdgcn_mfma_f32_16x16x32_bf16(a, b, acc[nt], 0, 0, 0);
        }
    }
    __syncthreads();
    float* Ds = reinterpret_cast<float*>(As);
    #pragma unroll
    for (int nt = 0; nt < 8; nt++)
        #pragma unroll
        for (int reg = 0; reg < 4; reg++)
            Ds[(16 * wid + quad * 4 + reg) * 132 + nt * 16 + m] = acc[nt][reg];
    __syncthreads();
    for (int idx = tid; idx < 512; idx += 128) {
        int r = idx >> 4, c16 = idx & 15;
        int rr = rowid[r];
        if (rr < 0) continue;
        const float* dsrc = &Ds[r * 132 + c16 * 8];
        float o[8];
        #pragma unroll
        for (int c = 0; c < 8; c++) {
            o[c] = dsrc[c];
            if (do_relu) o[c] = fmaxf(o[c], 0.f);
        }
        uint4 v;
        v.x = (unsigned)f2bf(o[0]) | ((unsigned)f2bf(o[1]) << 16);
        v.y = (unsigned)f2bf(o[2]) | ((unsigned)f2bf(o[3]) << 16);
        v.z = (unsigned)f2bf(o[4]) | ((unsigned)f2bf(o[5]) << 16);
        v.w = (unsigned)f2bf(o[6]) | ((unsigned)f2bf(o[7]) << 16);
        *reinterpret_cast<uint4*>(X + (size_t)rr * Hh + c16 * 8) = v;
    }
}

// ---------------------------------------------------------------------------
__global__ __launch_bounds__(128)
void k_xa(float* __restrict__ x_a,
          const float* __restrict__ Sx1, const float* __restrict__ E1,
          const float* __restrict__ Sx2, const float* __restrict__ E2,
          const int* __restrict__ c1, const int* __restrict__ c2,
          const float* __restrict__ Wself, const float* __restrict__ Wm1,
          const float* __restrict__ Wm2, int do_relu)
{
    int r = blockIdx.x, tid = threadIdx.x;
    __shared__ float xr[128], a1[128], a2[128];
    float i1 = 1.f / fmaxf((float)c1[r], 1.f);
    float i2 = 1.f / fmaxf((float)c2[r], 1.f);
    xr[tid] = x_a[r * Hh + tid];
    a1[tid] = (Sx1[r * Hh + tid] + E1[r * Hh + tid]) * i1;
    a2[tid] = (Sx2[r * Hh + tid] + E2[r * Hh + tid]) * i2;
    __syncthreads();
    float acc = 0.f;
    for (int k = 0; k < 128; k++) {
        acc = fmaf(xr[k], Wself[k * Hh + tid], acc);
        acc = fmaf(a1[k], Wm1[k * Hh + tid], acc);
        acc = fmaf(a2[k], Wm2[k * Hh + tid], acc);
    }
    if (do_relu) acc = fmaxf(acc, 0.f);
    x_a[r * Hh + tid] = acc;
}

// ---------------------------------------------------------------------------
// Transformer — re-parallelized: any weight-streaming phase gets >=192 blocks.
// qkv: grid (Dd, 3) — block computes 128 cols of one of Q/K/V for one row.
__global__ __launch_bounds__(128)
void k_qkv3(const float* __restrict__ h, float* __restrict__ qkv,
            const float* __restrict__ W, const float* __restrict__ b)
{
    int r = blockIdx.x, part = blockIdx.y, tid = threadIdx.x;
    int c = part * 128 + tid;
    __shared__ float hr[128];
    hr[tid] = h[r * Hh + tid];
    __syncthreads();
    float a0 = b[c], a1 = 0.f, a2 = 0.f, a3 = 0.f;
    for (int k = 0; k < 128; k += 4) {
        a0 = fmaf(hr[k],     W[(k)     * 384 + c], a0);
        a1 = fmaf(hr[k + 1], W[(k + 1) * 384 + c], a1);
        a2 = fmaf(hr[k + 2], W[(k + 2) * 384 + c], a2);
        a3 = fmaf(hr[k + 3], W[(k + 3) * 384 + c], a3);
    }
    qkv[r * 384 + c] = (a0 + a1) + (a2 + a3);
}

// attention: grid (NH, Dd), 64 lanes — shuffle softmax (round-4 verified design)
__global__ __launch_bounds__(64)
void k_attn2(const float* __restrict__ qkv, float* __restrict__ attn_o)
{
    int hh = blockIdx.x, q = blockIdx.y;
    int lane = threadIdx.x;
    const float* qv = qkv + q * 384 + hh * HD;
    const float* kv = qkv + lane * 384 + 128 + hh * HD;
    float s = 0.f;
    #pragma unroll
    for (int d2 = 0; d2 < HD; d2++) s = fmaf(qv[d2], kv[d2], s);
    s = s * 0.25f + (lane <= q ? 0.f : -1e9f);
    float m = s;
    #pragma unroll
    for (int o = 32; o; o >>= 1) m = fmaxf(m, __shfl_xor(m, o));
    float e = __expf(s - m);
    float tot = e;
    #pragma unroll
    for (int o = 32; o; o >>= 1) tot += __shfl_xor(tot, o);
    float att = e / tot;
    __shared__ float satt[64];
    satt[lane] = att;
    __syncthreads();
    if (lane < HD) {
        float o0 = 0.f, o1 = 0.f, o2 = 0.f, o3 = 0.f;
        for (int k2 = 0; k2 < Dd; k2 += 4) {
            o0 = fmaf(satt[k2],     qkv[(k2)     * 384 + 256 + hh * HD + lane], o0);
            o1 = fmaf(satt[k2 + 1], qkv[(k2 + 1) * 384 + 256 + hh * HD + lane], o1);
            o2 = fmaf(satt[k2 + 2], qkv[(k2 + 2) * 384 + 256 + hh * HD + lane], o2);
            o3 = fmaf(satt[k2 + 3], qkv[(k2 + 3) * 384 + 256 + hh * HD + lane], o3);
        }
        attn_o[q * Hh + hh * HD + lane] = (o0 + o1) + (o2 + o3);
    }
}

DEV float blocksum128(float v, float* red)
{
    #pragma unroll
    for (int o = 32; o; o >>= 1) v += __shfl_xor(v, o);
    int wid = threadIdx.x >> 6;
    __syncthreads();
    if ((threadIdx.x & 63) == 0) red[wid] = v;
    __syncthreads();
    return red[0] + red[1];
}

// out-proj + residual + LN1 (64 blocks; Wout is only 64 KB)
__global__ __launch_bounds__(128)
void k_outln(const float* __restrict__ attn_o, float* __restrict__ h,
             const float* __restrict__ Wout, const float* __restrict__ bout,
             const float* __restrict__ ln)
{
    int r = blockIdx.x, tid = threadIdx.x;
    __shared__ float ar[128];
    __shared__ float red[2];
    ar[tid] = attn_o[r * Hh + tid];
    __syncthreads();
    float a0 = bout[tid], a1 = 0.f, a2 = 0.f, a3 = 0.f;
    for (int k = 0; k < 128; k += 4) {
        a0 = fmaf(ar[k],     Wout[(k)     * Hh + tid], a0);
        a1 = fmaf(ar[k + 1], Wout[(k + 1) * Hh + tid], a1);
        a2 = fmaf(ar[k + 2], Wout[(k + 2) * Hh + tid], a2);
        a3 = fmaf(ar[k + 3], Wout[(k + 3) * Hh + tid], a3);
    }
    float x = h[r * Hh + tid] + (a0 + a1) + (a2 + a3);
    float mu = blocksum128(x, red) * (1.f / 128.f);
    float dx = x - mu;
    float var = blocksum128(dx * dx, red) * (1.f / 128.f);
    h[r * Hh + tid] = ln[tid] * dx * (1.f / sqrtf(var + 1e-5f)) + ln[128 + tid];
}

// ff1: grid (Dd, 8) = 512 blocks — W1 streamed by 512 concurrent blocks.
__global__ __launch_bounds__(256)
void k_ff1b(const float* __restrict__ h, float* __restrict__ fbuf,
            const float* __restrict__ W1, const float* __restrict__ b1)
{
    int r = blockIdx.x, tid = threadIdx.x;
    int c = blockIdx.y * 256 + tid;
    __shared__ float hr[128];
    if (tid < 128) hr[tid] = h[r * Hh + tid];
    __syncthreads();
    float a0 = b1[c], a1 = 0.f, a2 = 0.f, a3 = 0.f;
    for (int k = 0; k < 128; k += 4) {
        a0 = fmaf(hr[k],     W1[(size_t)(k)     * FF + c], a0);
        a1 = fmaf(hr[k + 1], W1[(size_t)(k + 1) * FF + c], a1);
        a2 = fmaf(hr[k + 2], W1[(size_t)(k + 2) * FF + c], a2);
        a3 = fmaf(hr[k + 3], W1[(size_t)(k + 3) * FF + c], a3);
    }
    fbuf[(size_t)r * FF + c] = fmaxf((a0 + a1) + (a2 + a3), 0.f);
}

__global__ __launch_bounds__(128)
void k_ff2p(const float* __restrict__ fbuf, float* __restrict__ part,
            const float* __restrict__ W2)
{
    int r = blockIdx.x, pi = blockIdx.y, tid = threadIdx.x;
    int kc = pi * 128;
    const float* f = fbuf + (size_t)r * FF + kc;
    float a0 = 0.f, a1 = 0.f, a2 = 0.f, a3 = 0.f;
    for (int k = 0; k < 128; k += 4) {
        a0 = fmaf(f[k],     W2[(size_t)(kc + k)     * Hh + tid], a0);
        a1 = fmaf(f[k + 1], W2[(size_t)(kc + k + 1) * Hh + tid], a1);
        a2 = fmaf(f[k + 2], W2[(size_t)(kc + k + 2) * Hh + tid], a2);
        a3 = fmaf(f[k + 3], W2[(size_t)(kc + k + 3) * Hh + tid], a3);
    }
    part[(size_t)(r * 16 + pi) * Hh + tid] = (a0 + a1) + (a2 + a3);
}

__global__ __launch_bounds__(128)
void k_ln2(float* __restrict__ h, const float* __restrict__ part,
           const float* __restrict__ b2, const float* __restrict__ ln)
{
    int r = blockIdx.x, tid = threadIdx.x;
    __shared__ float red[2];
    float acc = b2[tid];
    #pragma unroll
    for (int pi = 0; pi < 16; pi++) acc += part[(size_t)(r * 16 + pi) * Hh + tid];
    float x = h[r * Hh + tid] + acc;
    float mu = blocksum128(x, red) * (1.f / 128.f);
    float dx = x - mu;
    float var = blocksum128(dx * dx, red) * (1.f / 128.f);
    h[r * Hh + tid] = ln[tid] * dx * (1.f / sqrtf(var + 1e-5f)) + ln[128 + tid];
}

// ---------------------------------------------------------------------------
__global__ __launch_bounds__(256)
void k_logits(const ushort_t* __restrict__ x_dc, const int* __restrict__ map,
              const float* __restrict__ h, const float* __restrict__ lp,
              const int* __restrict__ cand, float* __restrict__ out)
{
    int d = blockIdx.x;
    int tid = threadIdx.x, lane = tid & 63, w = tid >> 6;
    __shared__ float wv[128];
    if (tid < 128) wv[tid] = h[d * Hh + tid] * lp[tid];
    __syncthreads();
    for (int k = w; k < KK; k += 4) {
        int slot = map[d * VD + cand[d * KK + k]] >> 2;
        const ushort_t* row = x_dc + (size_t)slot * Hh;
        float v = bf(row[lane]) * wv[lane] + bf(row[lane + 64]) * wv[lane + 64];
        #pragma unroll
        for (int o = 32; o; o >>= 1) v += __shfl_xor(v, o);
        if (lane == 0) out[d * KK + k] = v;
    }
}

// ---------------------------------------------------------------------------
extern "C" void kernel_launch(void* const* d_in, const int* in_sizes, int n_in,
                              void* d_out, int out_size, void* d_ws, size_t ws_size,
                              hipStream_t stream)
{
    (void)in_sizes; (void)n_in; (void)out_size; (void)ws_size;

    const int* drug_tokens  = (const int*)d_in[0];
    const int* drug_node_id = (const int*)d_in[1];
    const int* lab_tokens   = (const int*)d_in[3];
    const int* lab_node_id  = (const int*)d_in[4];
    const int* adm_tokens   = (const int*)d_in[6];
    const int* did_tokens   = (const int*)d_in[8];
    const int* did_src      = (const int*)d_in[10];
    const int* did_dst      = (const int*)d_in[11];
    const int* took_tokens  = (const int*)d_in[12];
    const int* took_src     = (const int*)d_in[14];
    const int* took_dst     = (const int*)d_in[15];
    const int* cand_idx     = (const int*)d_in[16];

    const int cidx[NCANON] = {2,5,7,9,13, 17,18,19,20,21,22,23, 24,25,26,27,28,
                              29,30,31,32,33, 34,35, 36,37,38,39,40,41,42,43,44,45,46};
    const int cn[NCANON] = {
        ND*2, NLN*1, Dd*3, ED*2, ET*1,
        VD*EMB, VL*EMB, 3*TV*EMB, 2*TV*EMB, 4*TV*EMB, 2*TV*EMB, 2*TV*EMB,
        2*EMB, 1*EMB, 3*EMB, 2*EMB, 1*EMB,
        5*EMB*Hh, 4*EMB*Hh, 5*EMB*Hh, 3*EMB*Hh, 3*EMB*Hh,
        GL*4*Hh*Hh, GL*3*Hh*Hh,
        L_ENC*Hh*3*Hh, L_ENC*3*Hh, L_ENC*Hh*Hh, L_ENC*Hh, L_ENC*2*Hh,
        L_ENC*Hh*FF, L_ENC*FF, L_ENC*FF*Hh, L_ENC*Hh, L_ENC*2*Hh, Hh
    };
    CanonDesc cd;
    int eoff[NCANON + 1];
    int btot_blocks = 0;
    {
        int e = 0;
        for (int t = 0; t < NCANON; t++) {
            cd.src[t] = d_in[cidx[t]];
            cd.n[t] = cn[t];
            eoff[t] = e;
            cd.doff[t] = e;
            e = (e + cn[t] + 7) & ~7;
            btot_blocks += (cn[t] + 255) / 256;
            cd.bend[t] = btot_blocks;
        }
        eoff[NCANON] = e;
    }

    // ---- workspace carve ----
    char* p = (char*)d_ws;
    auto alloc_f = [&](size_t n) -> float*    { float* r = (float*)p;    p += n * sizeof(float); return r; };
    auto alloc_h = [&](size_t n) -> ushort_t* { ushort_t* r = (ushort_t*)p; p += n * sizeof(ushort_t); return r; };
    auto alloc_i = [&](size_t n) -> int*      { int* r = (int*)p;        p += n * sizeof(int); return r; };

    int* map    = alloc_i(ND);
    int* cnt_dc = alloc_i(UCAP);
    int* cnt_ld = alloc_i(NLN);
    int* cnt_a1 = alloc_i(64);
    int* cnt_a2 = alloc_i(64);
    int* nUB    = alloc_i(8);
    int* cur_t  = alloc_i(UCAP);
    int* cur_d  = alloc_i(NLN);
    int* cur_a1 = alloc_i(64);
    int* cur_a2 = alloc_i(64);
    float* E_did  = alloc_f((size_t)Dd * Hh);
    float* E_took = alloc_f((size_t)Dd * Hh);
    const size_t ZBLOCK = (size_t)ND + UCAP + NLN + 64 + 64 + 8 + UCAP + NLN + 64 + 64
                        + (size_t)Dd * Hh * 2;
    float* Sx_did  = alloc_f((size_t)Dd * Hh);
    float* Sx_took = alloc_f((size_t)Dd * Hh);
    int* roff_t  = alloc_i(UCAP + 8);
    int* roff_d  = alloc_i(NLN + 8);
    int* roff_a1 = alloc_i(72);
    int* roff_a2 = alloc_i(72);
    int* bscr    = alloc_i(1024);
    u64* absum   = (u64*)alloc_i(2 * (NB_A + 8));
    int* ulist   = alloc_i(UCAP);
    int* blist   = alloc_i(NCAND);
    int* elist_t = alloc_i(ET);
    int* elist_d = alloc_i(ED);
    int* tookA   = alloc_i(ET);
    int* tookB   = alloc_i(ET);
    int* didA    = alloc_i(ED);
    int* didB    = alloc_i(ED);
    ushort_t* wt     = alloc_h(3 * 32768);
    ushort_t* ap     = alloc_h(2 * 8192 + 2 * 4096);
    ushort_t* x_dc   = alloc_h((size_t)UCAP * Hh);
    ushort_t* x_l    = alloc_h((size_t)NLN * Hh);
    float*    x_a    = alloc_f((size_t)Dd * Hh);
    ushort_t* e_did  = alloc_h((size_t)ED * Hh);
    ushort_t* e_took = alloc_h((size_t)ET * Hh);
    float*    qkvb   = alloc_f((size_t)Dd * 384);
    float*    attn_o = alloc_f((size_t)Dd * Hh);
    float*    fbuf   = alloc_f((size_t)Dd * FF);
    float*    part   = alloc_f((size_t)Dd * 16 * Hh);
    float*    cf     = alloc_f((size_t)eoff[NCANON]);
    int*      dflag  = alloc_i(8);

    ushort_t* ap_drug = ap;
    ushort_t* ap_lab  = ap + 8192;
    ushort_t* ap_did  = ap + 16384;
    ushort_t* ap_took = ap + 16384 + 4096;

    const float* c_drug_floats  = cf + eoff[0];
    const float* c_lab_floats   = cf + eoff[1];
    const float* c_adm_floats   = cf + eoff[2];
    const float* c_did_floats   = cf + eoff[3];
    const float* c_took_floats  = cf + eoff[4];
    const float* c_drug_id_emb  = cf + eoff[5];
    const float* c_lab_id_emb   = cf + eoff[6];
    const float* c_drug_tok_emb = cf + eoff[7];
    const float* c_lab_tok_emb  = cf + eoff[8];
    const float* c_adm_tok_emb  = cf + eoff[9];
    const float* c_did_tok_emb  = cf + eoff[10];
    const float* c_took_tok_emb = cf + eoff[11];
    const float* c_drug_float_w = cf + eoff[12];
    const float* c_lab_float_w  = cf + eoff[13];
    const float* c_adm_float_w  = cf + eoff[14];
    const float* c_did_float_w  = cf + eoff[15];
    const float* c_took_float_w = cf + eoff[16];
    const float* c_drug_align   = cf + eoff[17];
    const float* c_lab_align    = cf + eoff[18];
    const float* c_adm_align    = cf + eoff[19];
    const float* c_did_align    = cf + eoff[20];
    const float* c_took_align   = cf + eoff[21];
    const float* c_gnn_msg      = cf + eoff[22];
    const float* c_gnn_self     = cf + eoff[23];
    const float* c_qkv_w        = cf + eoff[24];
    const float* c_qkv_b        = cf + eoff[25];
    const float* c_out_w        = cf + eoff[26];
    const float* c_out_b        = cf + eoff[27];
    const float* c_ln1          = cf + eoff[28];
    const float* c_ff1_w        = cf + eoff[29];
    const float* c_ff1_b        = cf + eoff[30];
    const float* c_ff2_w        = cf + eoff[31];
    const float* c_ff2_b        = cf + eoff[32];
    const float* c_ln2          = cf + eoff[33];
    const float* c_lp_w         = cf + eoff[34];

    // ---- canonicalize + graph prep ----
    k_probe<<<1, 64, 0, stream>>>((const unsigned*)d_in[41], dflag);
    k_canon<<<btot_blocks, 256, 0, stream>>>(cd, cf, dflag);
    k_wpack<<<dim3(32, 3), 128, 0, stream>>>(c_gnn_self, c_gnn_msg, wt);
    k_apack<<<8, 128, 0, stream>>>(c_drug_align, ap_drug, 50);
    k_apack<<<8, 128, 0, stream>>>(c_lab_align,  ap_lab,  40);
    k_apack<<<4, 128, 0, stream>>>(c_did_align,  ap_did,  30);
    k_apack<<<4, 128, 0, stream>>>(c_took_align, ap_took, 30);
    hipMemsetAsync(map, 0, ZBLOCK * sizeof(int), stream);
    k_mark<<<ET / 256, 256, 0, stream>>>(took_dst, cand_idx, map);
    k_acount<<<NB_A, 256, 0, stream>>>(map, absum);
    k_ascan<<<1, 1024, 0, stream>>>(absum, NB_A, nUB);
    k_assign2<<<NB_A, 256, 0, stream>>>(map, ulist, blist, absum);
    k_counts<<<128, 256, 0, stream>>>(did_dst, did_src, took_dst, took_src, map,
                                      cnt_ld, cnt_a1, cnt_dc, cnt_a2);
    k_scan_blk<<<NB_T, 256, 0, stream>>>(cnt_dc, roff_t, bscr, UCAP);
    k_scan_top<<<1, 1024, 0, stream>>>(bscr, NB_T);
    k_scan_add<<<NB_T, 256, 0, stream>>>(roff_t, bscr, UCAP, ET);
    k_scan_blk<<<NB_D, 256, 0, stream>>>(cnt_ld, roff_d, bscr, NLN);
    k_scan_top<<<1, 1024, 0, stream>>>(bscr, NB_D);
    k_scan_add<<<NB_D, 256, 0, stream>>>(roff_d, bscr, NLN, ED);
    k_scan64<<<1, 64, 0, stream>>>(cnt_a1, cnt_a2, roff_a1, roff_a2);
    k_fill<<<128, 256, 0, stream>>>(did_src, did_dst, took_src, took_dst, map,
                                    roff_d, roff_t, roff_a1, roff_a2,
                                    cur_d, cur_t, cur_a1, cur_a2,
                                    elist_d, elist_t, didA, didB, tookA, tookB);

    // ---- embeddings ----
    k_embed_m<1,3,2,2,true><<<UCAP / 32, 128, 0, stream>>>(x_dc, 0, nUB, ulist,
        drug_node_id, c_drug_id_emb, drug_tokens, c_drug_tok_emb,
        c_drug_floats, c_drug_float_w, ap_drug);
    k_embed_m<1,2,1,2,false><<<NLN / 32, 128, 0, stream>>>(x_l, NLN, nullptr, nullptr,
        lab_node_id, c_lab_id_emb, lab_tokens, c_lab_tok_emb,
        c_lab_floats, c_lab_float_w, ap_lab);
    k_embed<0,4,3><<<1, 64, 0, stream>>>(x_a, Dd,
        nullptr, nullptr, adm_tokens, c_adm_tok_emb, c_adm_floats, c_adm_float_w, c_adm_align);
    k_embed_m<0,2,2,1,false><<<ED / 32, 128, 0, stream>>>(e_did, ED, nullptr, nullptr,
        nullptr, nullptr, did_tokens, c_did_tok_emb, c_did_floats, c_did_float_w, ap_did);
    k_embed_m<0,2,1,1,false><<<ET / 32, 128, 0, stream>>>(e_took, ET, nullptr, nullptr,
        nullptr, nullptr, took_tokens, c_took_tok_emb, c_took_floats, c_took_float_w, ap_took);

    const size_t HH = (size_t)Hh * Hh;

    // ---- GNN layer 1 (relu) ----
    hipMemsetAsync(Sx_did, 0, 2 * (size_t)Dd * Hh * sizeof(float), stream);
    k_srcsum<true><<<(ED + 31) / 32, 64, 0, stream>>>(didA, didB, x_l, e_did, 16,
                                                      Sx_did, E_did, ED, 32);
    k_srcsum<true><<<(ET + 31) / 32, 64, 0, stream>>>(tookA, tookB, x_dc, e_took, 18,
                                                      Sx_took, E_took, ET, 32);
    k_gup<false><<<UCAP / 32, 128, 0, stream>>>(x_dc, x_a, e_took, roff_t, elist_t, 17,
        nullptr, nUB, 0, wt, 1);
    k_gup<false><<<NLN / 32, 128, 0, stream>>>(x_l, x_a, e_did, roff_d, elist_d, 15,
        nullptr, nullptr, NLN, wt + 32768, 1);
    k_xa<<<Dd, 128, 0, stream>>>(x_a, Sx_did, E_did, Sx_took, E_took, cnt_a1, cnt_a2,
        c_gnn_self + 0 * HH, c_gnn_msg + 2 * HH, c_gnn_msg + 3 * HH, 1);

    // ---- GNN layer 2 ----
    const float* Ws1 = c_gnn_self + 3 * HH;
    const float* Wm1 = c_gnn_msg + 4 * HH;
    hipMemsetAsync(Sx_did, 0, 2 * (size_t)Dd * Hh * sizeof(float), stream);
    k_srcsum<false><<<(ED + 31) / 32, 64, 0, stream>>>(didA, didB, x_l, nullptr, 16,
                                                       Sx_did, nullptr, ED, 32);
    k_srcsum<false><<<(ET + 31) / 32, 64, 0, stream>>>(tookA, tookB, x_dc, nullptr, 18,
                                                       Sx_took, nullptr, ET, 32);
    k_gup<true><<<(NCAND + 31) / 32, 128, 0, stream>>>(x_dc, x_a, e_took, roff_t, elist_t, 17,
        blist, nUB + 1, 0, wt + 65536, 0);
    k_xa<<<Dd, 128, 0, stream>>>(x_a, Sx_did, E_did, Sx_took, E_took, cnt_a1, cnt_a2,
        Ws1 + 0 * HH, Wm1 + 2 * HH, Wm1 + 3 * HH, 0);

    // ---- transformer encoder (6 launches/layer, all weight phases >=192 blocks) ----
    for (int i = 0; i < L_ENC; i++) {
        k_qkv3<<<dim3(Dd, 3), 128, 0, stream>>>(x_a, qkvb,
            c_qkv_w + (size_t)i * Hh * 384, c_qkv_b + (size_t)i * 384);
        k_attn2<<<dim3(NH, Dd), 64, 0, stream>>>(qkvb, attn_o);
        k_outln<<<Dd, 128, 0, stream>>>(attn_o, x_a, c_out_w + (size_t)i * HH,
                                        c_out_b + (size_t)i * Hh, c_ln1 + (size_t)i * 2 * Hh);
        k_ff1b<<<dim3(Dd, FF / 256), 256, 0, stream>>>(x_a, fbuf,
            c_ff1_w + (size_t)i * Hh * FF, c_ff1_b + (size_t)i * FF);
        k_ff2p<<<dim3(Dd, 16), 128, 0, stream>>>(fbuf, part, c_ff2_w + (size_t)i * FF * Hh);
        k_ln2<<<Dd, 128, 0, stream>>>(x_a, part, c_ff2_b + (size_t)i * Hh,
                                      c_ln2 + (size_t)i * 2 * Hh);
    }

    // ---- logits ----
    k_logits<<<Dd - 1, 256, 0, stream>>>(x_dc, map, x_a, c_lp_w, cand_idx, (float*)d_out);
}

// Round 13
// 729.740 us; speedup vs baseline: 5.2372x; 1.1166x over previous
//
#include <hip/hip_runtime.h>
#include <hip/hip_bf16.h>

typedef unsigned short ushort_t;
typedef unsigned long long u64;
typedef __attribute__((ext_vector_type(8))) short bf16x8;
typedef __attribute__((ext_vector_type(4))) float f32x4;

#define DEV __device__ __forceinline__

constexpr int Dd  = 64;
constexpr int VD  = 4525;
constexpr int VL  = 753;
constexpr int ND  = Dd * VD;     // 289600
constexpr int NLN = Dd * VL;     // 48192
constexpr int Hh  = 128;
constexpr int EMB = 10;
constexpr int TV  = 100;
constexpr int NH  = 8, HD = 16;
constexpr int L_ENC = 6, FF = 2048;
constexpr int GL  = 2;
constexpr int ED  = 32768, ET = 131072;
constexpr int KK  = 256;
constexpr int NCAND = (Dd - 1) * KK;       // 16128
constexpr int UCAP  = ET + NCAND;          // 147200
constexpr int NCANON = 35;
constexpr int NB_T = (UCAP + 255) / 256;
constexpr int NB_D = (NLN + 255) / 256;
constexpr int NB_A = (ND + 255) / 256;

DEV float bf(ushort_t u) { return __uint_as_float(((unsigned)u) << 16); }
DEV float bflo(unsigned u) { return __uint_as_float(u << 16); }
DEV float bfhi(unsigned u) { return __uint_as_float(u & 0xffff0000u); }
DEV ushort_t f2bf(float f) {
    unsigned u = __float_as_uint(f);
    u += 0x7fffu + ((u >> 16) & 1u);
    return (ushort_t)(u >> 16);
}

// ---------------------------------------------------------------------------
__global__ __launch_bounds__(64)
void k_probe(const unsigned* __restrict__ w, int* __restrict__ flag)
{
    int tid = threadIdx.x;
    int c = 0;
    #pragma unroll
    for (int i = 0; i < 16; i++) c += (w[tid * 16 + i] >> 14) & 1;
    #pragma unroll
    for (int o = 32; o; o >>= 1) c += __shfl_xor(c, o);
    if (tid == 0) *flag = (c > 256) ? 1 : 0;
}

struct CanonDesc {
    const void* src[NCANON];
    int doff[NCANON];
    int bend[NCANON];
    int n[NCANON];
};

__global__ __launch_bounds__(256)
void k_canon(CanonDesc cd, float* __restrict__ dst, const int* __restrict__ flag)
{
    int b = blockIdx.x;
    int t = 0;
    while (t < NCANON && b >= cd.bend[t]) t++;
    if (t >= NCANON) return;
    int bstart = (t == 0) ? 0 : cd.bend[t - 1];
    int i = (b - bstart) * 256 + threadIdx.x;
    if (i >= cd.n[t]) return;
    float v = (*flag) ? ((const float*)cd.src[t])[i]
                      : bf(((const ushort_t*)cd.src[t])[i]);
    dst[cd.doff[t] + i] = v;
}

__global__ __launch_bounds__(128)
void k_wpack(const float* __restrict__ gself, const float* __restrict__ gmsg,
             ushort_t* __restrict__ wt)
{
    const int selfIdx[3] = {1, 2, 4};
    const int msgIdx[3]  = {1, 0, 5};
    int pr = blockIdx.y, chunk = blockIdx.x, nn = threadIdx.x;
    const float* Ws = gself + (size_t)selfIdx[pr] * Hh * Hh;
    const float* Wm = gmsg  + (size_t)msgIdx[pr]  * Hh * Hh;
    ushort_t* dst = wt + (((size_t)pr * 32 + chunk) * 128 + nn) * 8;
    #pragma unroll
    for (int j = 0; j < 8; j++) {
        int k = chunk * 8 + j;
        float v = (k < 128) ? Ws[k * Hh + nn] : Wm[(k - 128) * Hh + nn];
        dst[j] = f2bf(v);
    }
}

__global__ __launch_bounds__(128)
void k_apack(const float* __restrict__ A, ushort_t* __restrict__ dst, int L)
{
    int c = blockIdx.x, nn = threadIdx.x;
    ushort_t* d = dst + ((size_t)c * 128 + nn) * 8;
    #pragma unroll
    for (int j = 0; j < 8; j++) {
        int k = c * 8 + j;
        d[j] = (k < L) ? f2bf(A[(size_t)k * Hh + nn]) : (ushort_t)0;
    }
}

// ---------------------------------------------------------------------------
__global__ __launch_bounds__(256)
void k_mark(const int* __restrict__ took_dst, const int* __restrict__ cand,
            int* __restrict__ map)
{
    int g = blockIdx.x * 256 + threadIdx.x;
    if (g < ET) atomicOr(&map[took_dst[g]], 1);
    if (g < NCAND) {
        int d = g >> 8;
        atomicOr(&map[d * VD + cand[g]], 2);
    }
}

// contention-free slot assignment (u64: isU low 32, isB high 32)
__global__ __launch_bounds__(256)
void k_acount(const int* __restrict__ map, u64* __restrict__ bsum)
{
    __shared__ u64 s[256];
    int tid = threadIdx.x;
    int g = blockIdx.x * 256 + tid;
    int m = (g < ND) ? map[g] : 0;
    s[tid] = (u64)(m ? 1u : 0u) | ((u64)((m & 2) ? 1u : 0u) << 32);
    __syncthreads();
    for (int o = 128; o; o >>= 1) {
        if (tid < o) s[tid] += s[tid + o];
        __syncthreads();
    }
    if (tid == 0) bsum[blockIdx.x] = s[0];
}

__global__ __launch_bounds__(1024)
void k_ascan(u64* __restrict__ bsum, int nb, int* __restrict__ nUB)
{
    __shared__ u64 s[1024];
    int tid = threadIdx.x;
    u64 carry = 0;
    for (int base = 0; base < nb; base += 1024) {
        int idx = base + tid;
        u64 v = (idx < nb) ? bsum[idx] : 0;
        s[tid] = v;
        __syncthreads();
        for (int o = 1; o < 1024; o <<= 1) {
            u64 t = (tid >= o) ? s[tid - o] : 0;
            __syncthreads();
            s[tid] += t;
            __syncthreads();
        }
        if (idx < nb) bsum[idx] = carry + s[tid] - v;
        u64 tot = s[1023];
        __syncthreads();
        carry += tot;
    }
    if (tid == 0) {
        nUB[0] = (int)(carry & 0xffffffffu);
        nUB[1] = (int)(carry >> 32);
    }
}

__global__ __launch_bounds__(256)
void k_assign2(int* __restrict__ map, int* __restrict__ ulist, int* __restrict__ blist,
               const u64* __restrict__ bsum)
{
    __shared__ u64 s[256];
    int tid = threadIdx.x;
    int g = blockIdx.x * 256 + tid;
    int m = (g < ND) ? map[g] : 0;
    u64 v = (u64)(m ? 1u : 0u) | ((u64)((m & 2) ? 1u : 0u) << 32);
    s[tid] = v;
    __syncthreads();
    for (int o = 1; o < 256; o <<= 1) {
        u64 t = (tid >= o) ? s[tid - o] : 0;
        __syncthreads();
        s[tid] += t;
        __syncthreads();
    }
    u64 excl = s[tid] - v + bsum[blockIdx.x];
    if (m) {
        int slot = (int)(excl & 0xffffffffu);
        ulist[slot] = g;
        map[g] = (slot << 2) | m;
        if (m & 2) blist[(int)(excl >> 32)] = slot;
    }
}

__global__ __launch_bounds__(256)
void k_counts(const int* __restrict__ did_dst, const int* __restrict__ did_src,
              const int* __restrict__ took_dst, const int* __restrict__ took_src,
              const int* __restrict__ map,
              int* __restrict__ cnt_ld, int* __restrict__ cnt_a1,
              int* __restrict__ cnt_dc, int* __restrict__ cnt_a2)
{
    __shared__ int h1[64], h2[64];
    int tid = threadIdx.x;
    if (tid < 64) { h1[tid] = 0; h2[tid] = 0; }
    __syncthreads();
    int tb = blockIdx.x * 1024;
    #pragma unroll
    for (int o = 0; o < 1024; o += 256) {
        int i = tb + o + tid;
        atomicAdd(&cnt_dc[map[took_dst[i]] >> 2], 1);
        atomicAdd(&h2[took_src[i]], 1);
    }
    {
        int i = blockIdx.x * 256 + tid;
        atomicAdd(&cnt_ld[did_dst[i]], 1);
        atomicAdd(&h1[did_src[i]], 1);
    }
    __syncthreads();
    if (tid < 64) {
        if (h1[tid]) atomicAdd(&cnt_a1[tid], h1[tid]);
        if (h2[tid]) atomicAdd(&cnt_a2[tid], h2[tid]);
    }
}

// ---------------------------------------------------------------------------
__global__ __launch_bounds__(256)
void k_scan_blk(const int* __restrict__ cnt, int* __restrict__ excl,
                int* __restrict__ btot, int n)
{
    __shared__ int s[256];
    int tid = threadIdx.x;
    int g = blockIdx.x * 256 + tid;
    int v = (g < n) ? cnt[g] : 0;
    s[tid] = v;
    __syncthreads();
    for (int o = 1; o < 256; o <<= 1) {
        int t = (tid >= o) ? s[tid - o] : 0;
        __syncthreads();
        s[tid] += t;
        __syncthreads();
    }
    if (g < n) excl[g] = s[tid] - v;
    if (tid == 255) btot[blockIdx.x] = s[255];
}

__global__ __launch_bounds__(1024)
void k_scan_top(int* __restrict__ btot, int nb)
{
    __shared__ int s[1024];
    int tid = threadIdx.x;
    int v = (tid < nb) ? btot[tid] : 0;
    s[tid] = v;
    __syncthreads();
    for (int o = 1; o < 1024; o <<= 1) {
        int t = (tid >= o) ? s[tid - o] : 0;
        __syncthreads();
        s[tid] += t;
        __syncthreads();
    }
    if (tid < nb) btot[tid] = s[tid] - v;
}

__global__ __launch_bounds__(256)
void k_scan_add(int* __restrict__ roff, const int* __restrict__ btot, int n, int total)
{
    int g = blockIdx.x * 256 + threadIdx.x;
    if (g < n) roff[g] += btot[blockIdx.x];
    if (g == 0) roff[n] = total;
}

__global__ __launch_bounds__(64)
void k_scan64(const int* __restrict__ c1, const int* __restrict__ c2,
              int* __restrict__ r1, int* __restrict__ r2)
{
    int tid = threadIdx.x;
    int v1 = c1[tid], v2 = c2[tid];
    int s1 = v1, s2 = v2;
    for (int o = 1; o < 64; o <<= 1) {
        int t1 = __shfl_up(s1, o), t2 = __shfl_up(s2, o);
        if (tid >= o) { s1 += t1; s2 += t2; }
    }
    r1[tid] = s1 - v1;
    r2[tid] = s2 - v2;
}

__global__ __launch_bounds__(256)
void k_fill(const int* __restrict__ did_src, const int* __restrict__ did_dst,
            const int* __restrict__ took_src, const int* __restrict__ took_dst,
            const int* __restrict__ map,
            const int* __restrict__ roff_d, const int* __restrict__ roff_t,
            const int* __restrict__ roff_a1, const int* __restrict__ roff_a2,
            int* __restrict__ cur_d, int* __restrict__ cur_t,
            int* __restrict__ cur_a1, int* __restrict__ cur_a2,
            int* __restrict__ elist_d, int* __restrict__ elist_t,
            int* __restrict__ didA, int* __restrict__ didB,
            int* __restrict__ tookA, int* __restrict__ tookB)
{
    __shared__ int h1[64], h2[64], b1[64], b2[64];
    int tid = threadIdx.x;
    if (tid < 64) { h1[tid] = 0; h2[tid] = 0; }
    __syncthreads();
    int tb = blockIdx.x * 1024;
    int db = blockIdx.x * 256;
    #pragma unroll
    for (int o = 0; o < 1024; o += 256)
        atomicAdd(&h2[took_src[tb + o + tid]], 1);
    atomicAdd(&h1[did_src[db + tid]], 1);
    __syncthreads();
    if (tid < 64) {
        b1[tid] = h1[tid] ? atomicAdd(&cur_a1[tid], h1[tid]) : 0;
        b2[tid] = h2[tid] ? atomicAdd(&cur_a2[tid], h2[tid]) : 0;
        h1[tid] = 0; h2[tid] = 0;
    }
    __syncthreads();
    #pragma unroll
    for (int o = 0; o < 1024; o += 256) {
        int i = tb + o + tid;
        int s = took_src[i];
        int slot = map[took_dst[i]] >> 2;
        int pos = roff_t[slot] + atomicAdd(&cur_t[slot], 1);
        elist_t[pos] = (s << 17) | i;
        int pa = roff_a2[s] + b2[s] + atomicAdd(&h2[s], 1);
        tookA[pa] = (s << 18) | slot;
        tookB[pa] = i;
    }
    {
        int i = db + tid;
        int d = did_dst[i], s = did_src[i];
        int pos = roff_d[d] + atomicAdd(&cur_d[d], 1);
        elist_d[pos] = (s << 15) | i;
        int pa = roff_a1[s] + b1[s] + atomicAdd(&h1[s], 1);
        didA[pa] = (s << 16) | d;
        didB[pa] = i;
    }
}

// ---------------------------------------------------------------------------
template<bool DUAL>
__global__ __launch_bounds__(64)
void k_srcsum(const int* __restrict__ lA, const int* __restrict__ lB,
              const ushort_t* __restrict__ xrows, const ushort_t* __restrict__ erows,
              int shift, float* __restrict__ Sx, float* __restrict__ Se,
              int nedge, int epb)
{
    int lane = threadIdx.x;
    int c0 = lane * 2;
    int base = blockIdx.x * epb;
    int end = min(base + epb, nedge);
    int mask = (1 << shift) - 1;
    float ax0 = 0.f, ax1 = 0.f, ae0 = 0.f, ae1 = 0.f;
    int cur = -1;
    for (int i = base; i < end; i++) {
        int pk = lA[i];
        int s = pk >> shift, row = pk & mask;
        if (s != cur) {
            if (cur >= 0) {
                unsafeAtomicAdd(&Sx[cur * Hh + c0], ax0);
                unsafeAtomicAdd(&Sx[cur * Hh + c0 + 1], ax1);
                if (DUAL) {
                    unsafeAtomicAdd(&Se[cur * Hh + c0], ae0);
                    unsafeAtomicAdd(&Se[cur * Hh + c0 + 1], ae1);
                }
            }
            cur = s; ax0 = ax1 = ae0 = ae1 = 0.f;
        }
        unsigned xx = *reinterpret_cast<const unsigned*>(xrows + (size_t)row * Hh + c0);
        ax0 += bflo(xx); ax1 += bfhi(xx);
        if (DUAL) {
            int e = lB[i];
            unsigned ee = *reinterpret_cast<const unsigned*>(erows + (size_t)e * Hh + c0);
            ae0 += bflo(ee); ae1 += bfhi(ee);
        }
    }
    if (cur >= 0) {
        unsafeAtomicAdd(&Sx[cur * Hh + c0], ax0);
        unsafeAtomicAdd(&Sx[cur * Hh + c0 + 1], ax1);
        if (DUAL) {
            unsafeAtomicAdd(&Se[cur * Hh + c0], ae0);
            unsafeAtomicAdd(&Se[cur * Hh + c0 + 1], ae1);
        }
    }
}

// ---------------------------------------------------------------------------
// adm embed, parallelized: 64 blocks (1 row each) x 128 threads; bit-identical
// fp32 math to the old scalar path (same fma order). Was: 1 block, 87 us.
__global__ __launch_bounds__(128)
void k_embed_adm(float* __restrict__ out,
                 const int* __restrict__ tokens, const float* __restrict__ tok_emb,
                 const float* __restrict__ floats_, const float* __restrict__ float_w,
                 const float* __restrict__ alignf)
{
    int r = blockIdx.x, tid = threadIdx.x;
    __shared__ float vec[50];
    if (tid < 40) {
        int seg = tid / 10, e = tid % 10;
        vec[tid] = tok_emb[((size_t)seg * TV + tokens[r * 4 + seg]) * EMB + e];
    } else if (tid < 50) {
        int e = tid - 40;
        float a = 0.f;
        #pragma unroll
        for (int f = 0; f < 3; f++) a = fmaf(floats_[r * 3 + f], float_w[f * EMB + e], a);
        vec[tid] = a;
    }
    __syncthreads();
    float acc = 0.f;
    #pragma unroll 5
    for (int k = 0; k < 50; k++) acc = fmaf(vec[k], alignf[k * Hh + tid], acc);
    out[r * Hh + tid] = acc;
}

// MFMA embed
template<int NID, int NTOK, int NF, int KCH, bool INDIRECT>
__global__ __launch_bounds__(128)
void k_embed_m(ushort_t* __restrict__ out, int n_static, const int* __restrict__ n_dyn,
               const int* __restrict__ ulist,
               const int* __restrict__ id_idx, const float* __restrict__ id_emb,
               const int* __restrict__ tokens, const float* __restrict__ tok_emb,
               const float* __restrict__ floats_, const float* __restrict__ float_w,
               const ushort_t* __restrict__ Bp)
{
    constexpr int NSEG = NID + NTOK + 1;
    constexpr int K = KCH * 32;
    constexpr int STR = K + 8;
    __shared__ ushort_t As[32 * 264];
    __shared__ int nodeid[32];
    int tid = threadIdx.x;
    int r0 = blockIdx.x * 32;
    int n = INDIRECT ? *n_dyn : n_static;
    if (tid < 32) {
        int slot = r0 + tid;
        nodeid[tid] = (slot < n) ? (INDIRECT ? ulist[slot] : slot) : -1;
    }
    for (int i = tid; i < 32 * STR; i += 128) As[i] = 0;
    __syncthreads();

    for (int pi = tid; pi < 32 * NSEG; pi += 128) {
        int seg = pi >> 5, nl = pi & 31;
        int node = nodeid[nl];
        if (node < 0) continue;
        float v[EMB];
        if (NID != 0 && seg == 0) {
            const float* pe = id_emb + (size_t)id_idx[node] * EMB;
            #pragma unroll
            for (int e = 0; e < EMB; e++) v[e] = pe[e];
        } else if (seg < NID + NTOK) {
            int t = seg - NID;
            const float* pe = tok_emb + ((size_t)t * TV + tokens[node * NTOK + t]) * EMB;
            #pragma unroll
            for (int e = 0; e < EMB; e++) v[e] = pe[e];
        } else {
            float fv[NF];
            #pragma unroll
            for (int f = 0; f < NF; f++) fv[f] = floats_[node * NF + f];
            #pragma unroll
            for (int e = 0; e < EMB; e++) {
                float a = 0.f;
                #pragma unroll
                for (int f = 0; f < NF; f++) a = fmaf(fv[f], float_w[f * EMB + e], a);
                v[e] = a;
            }
        }
        ushort_t* dst = &As[nl * STR + seg * EMB];
        #pragma unroll
        for (int e = 0; e < EMB; e += 2) {
            unsigned pk = (unsigned)f2bf(v[e]) | ((unsigned)f2bf(v[e + 1]) << 16);
            *reinterpret_cast<unsigned*>(dst + e) = pk;
        }
    }
    __syncthreads();

    int wid = tid >> 6, lane = tid & 63;
    int m = lane & 15, quad = lane >> 4;
    f32x4 acc[8];
    #pragma unroll
    for (int t = 0; t < 8; t++) acc[t] = (f32x4){0.f, 0.f, 0.f, 0.f};
    #pragma unroll
    for (int kc = 0; kc < KCH; kc++) {
        bf16x8 a = *reinterpret_cast<const bf16x8*>(&As[(16 * wid + m) * STR + kc * 32 + quad * 8]);
        #pragma unroll
        for (int nt = 0; nt < 8; nt++) {
            bf16x8 b = *reinterpret_cast<const bf16x8*>(Bp + (((kc * 4 + quad) * 128) + nt * 16 + m) * 8);
            acc[nt] = __builtin_amdgcn_mfma_f32_16x16x32_bf16(a, b, acc[nt], 0, 0, 0);
        }
    }
    __syncthreads();
    float* Ds = reinterpret_cast<float*>(As);
    #pragma unroll
    for (int nt = 0; nt < 8; nt++)
        #pragma unroll
        for (int reg = 0; reg < 4; reg++)
            Ds[(16 * wid + quad * 4 + reg) * 132 + nt * 16 + m] = acc[nt][reg];
    __syncthreads();
    for (int idx = tid; idx < 512; idx += 128) {
        int r = idx >> 4, c16 = idx & 15;
        int slot = r0 + r;
        if (slot >= n) continue;
        const float* dsrc = &Ds[r * 132 + c16 * 8];
        uint4 v;
        v.x = (unsigned)f2bf(dsrc[0]) | ((unsigned)f2bf(dsrc[1]) << 16);
        v.y = (unsigned)f2bf(dsrc[2]) | ((unsigned)f2bf(dsrc[3]) << 16);
        v.z = (unsigned)f2bf(dsrc[4]) | ((unsigned)f2bf(dsrc[5]) << 16);
        v.w = (unsigned)f2bf(dsrc[6]) | ((unsigned)f2bf(dsrc[7]) << 16);
        *reinterpret_cast<uint4*>(out + (size_t)slot * Hh + c16 * 8) = v;
    }
}

// ---------------------------------------------------------------------------
// Fused gather + mean + GNN update, MFMA version.
template<bool INDIRECT>
__global__ __launch_bounds__(128)
void k_gup(ushort_t* __restrict__ X, const float* __restrict__ xa,
           const ushort_t* __restrict__ ef,
           const int* __restrict__ roff, const int* __restrict__ elist, int sshift,
           const int* __restrict__ rows_list, const int* __restrict__ n_dyn, int n_static,
           const ushort_t* __restrict__ Wt, int do_relu)
{
    __shared__ ushort_t As[32 * 264];
    __shared__ int rowid[32];
    int tid = threadIdx.x;
    int r0 = blockIdx.x * 32;
    int n = n_dyn ? *n_dyn : n_static;
    if (tid < 32) {
        int row = r0 + tid;
        rowid[tid] = (row < n) ? (INDIRECT ? rows_list[row] : row) : -1;
    }
    __syncthreads();

    for (int idx = tid; idx < 512; idx += 128) {
        int r = idx >> 4, c16 = idx & 15;
        int rr = rowid[r];
        uint4 v = make_uint4(0, 0, 0, 0);
        if (rr >= 0) v = *reinterpret_cast<const uint4*>(X + (size_t)rr * Hh + c16 * 8);
        *reinterpret_cast<uint4*>(&As[r * 264 + c16 * 8]) = v;
    }
    int wid = tid >> 6, lane = tid & 63;
    int c0 = lane * 2;
    int emask = (1 << sshift) - 1;
    for (int r = wid; r < 32; r += 2) {
        int rr = rowid[r];
        float a0 = 0.f, a1 = 0.f, invd = 0.f;
        if (rr >= 0) {
            int e0 = roff[rr], e1 = roff[rr + 1];
            invd = 1.f / fmaxf((float)(e1 - e0), 1.f);
            for (int ei = e0; ei < e1; ei++) {
                int pk = elist[ei];
                int s = pk >> sshift, e = pk & emask;
                const float* xr = xa + s * Hh + c0;
                unsigned ee = *reinterpret_cast<const unsigned*>(ef + (size_t)e * Hh + c0);
                a0 += xr[0] + bflo(ee);
                a1 += xr[1] + bfhi(ee);
            }
        }
        unsigned pk2 = (unsigned)f2bf(a0 * invd) | ((unsigned)f2bf(a1 * invd) << 16);
        *reinterpret_cast<unsigned*>(&As[r * 264 + 128 + c0]) = pk2;
    }
    __syncthreads();

    int m = lane & 15, quad = lane >> 4;
    f32x4 acc[8];
    #pragma unroll
    for (int t = 0; t < 8; t++) acc[t] = (f32x4){0.f, 0.f, 0.f, 0.f};
    #pragma unroll
    for (int kc = 0; kc < 8; kc++) {
        bf16x8 a = *reinterpret_cast<const bf16x8*>(&As[(16 * wid + m) * 264 + kc * 32 + quad * 8]);
        #pragma unroll
        for (int nt = 0; nt < 8; nt++) {
            bf16x8 b = *reinterpret_cast<const bf16x8*>(Wt + (((kc * 4 + quad) * 128) + nt * 16 + m) * 8);
            acc[nt] = __builtin_amdgcn_mfma_f32_16x16x32_bf16(a, b, acc[nt], 0, 0, 0);
        }
    }
    __syncthreads();
    float* Ds = reinterpret_cast<float*>(As);
    #pragma unroll
    for (int nt = 0; nt < 8; nt++)
        #pragma unroll
        for (int reg = 0; reg < 4; reg++)
            Ds[(16 * wid + quad * 4 + reg) * 132 + nt * 16 + m] = acc[nt][reg];
    __syncthreads();
    for (int idx = tid; idx < 512; idx += 128) {
        int r = idx >> 4, c16 = idx & 15;
        int rr = rowid[r];
        if (rr < 0) continue;
        const float* dsrc = &Ds[r * 132 + c16 * 8];
        float o[8];
        #pragma unroll
        for (int c = 0; c < 8; c++) {
            o[c] = dsrc[c];
            if (do_relu) o[c] = fmaxf(o[c], 0.f);
        }
        uint4 v;
        v.x = (unsigned)f2bf(o[0]) | ((unsigned)f2bf(o[1]) << 16);
        v.y = (unsigned)f2bf(o[2]) | ((unsigned)f2bf(o[3]) << 16);
        v.z = (unsigned)f2bf(o[4]) | ((unsigned)f2bf(o[5]) << 16);
        v.w = (unsigned)f2bf(o[6]) | ((unsigned)f2bf(o[7]) << 16);
        *reinterpret_cast<uint4*>(X + (size_t)rr * Hh + c16 * 8) = v;
    }
}

// ---------------------------------------------------------------------------
__global__ __launch_bounds__(128)
void k_xa(float* __restrict__ x_a,
          const float* __restrict__ Sx1, const float* __restrict__ E1,
          const float* __restrict__ Sx2, const float* __restrict__ E2,
          const int* __restrict__ c1, const int* __restrict__ c2,
          const float* __restrict__ Wself, const float* __restrict__ Wm1,
          const float* __restrict__ Wm2, int do_relu)
{
    int r = blockIdx.x, tid = threadIdx.x;
    __shared__ float xr[128], a1[128], a2[128];
    float i1 = 1.f / fmaxf((float)c1[r], 1.f);
    float i2 = 1.f / fmaxf((float)c2[r], 1.f);
    xr[tid] = x_a[r * Hh + tid];
    a1[tid] = (Sx1[r * Hh + tid] + E1[r * Hh + tid]) * i1;
    a2[tid] = (Sx2[r * Hh + tid] + E2[r * Hh + tid]) * i2;
    __syncthreads();
    float acc = 0.f;
    for (int k = 0; k < 128; k++) {
        acc = fmaf(xr[k], Wself[k * Hh + tid], acc);
        acc = fmaf(a1[k], Wm1[k * Hh + tid], acc);
        acc = fmaf(a2[k], Wm2[k * Hh + tid], acc);
    }
    if (do_relu) acc = fmaxf(acc, 0.f);
    x_a[r * Hh + tid] = acc;
}

// ---------------------------------------------------------------------------
// Transformer
__global__ __launch_bounds__(128)
void k_qkv3(const float* __restrict__ h, float* __restrict__ qkv,
            const float* __restrict__ W, const float* __restrict__ b)
{
    int r = blockIdx.x, part = blockIdx.y, tid = threadIdx.x;
    int c = part * 128 + tid;
    __shared__ float hr[128];
    hr[tid] = h[r * Hh + tid];
    __syncthreads();
    float a0 = b[c], a1 = 0.f, a2 = 0.f, a3 = 0.f;
    for (int k = 0; k < 128; k += 4) {
        a0 = fmaf(hr[k],     W[(k)     * 384 + c], a0);
        a1 = fmaf(hr[k + 1], W[(k + 1) * 384 + c], a1);
        a2 = fmaf(hr[k + 2], W[(k + 2) * 384 + c], a2);
        a3 = fmaf(hr[k + 3], W[(k + 3) * 384 + c], a3);
    }
    qkv[r * 384 + c] = (a0 + a1) + (a2 + a3);
}

__global__ __launch_bounds__(64)
void k_attn2(const float* __restrict__ qkv, float* __restrict__ attn_o)
{
    int hh = blockIdx.x, q = blockIdx.y;
    int lane = threadIdx.x;
    const float* qv = qkv + q * 384 + hh * HD;
    const float* kv = qkv + lane * 384 + 128 + hh * HD;
    float s = 0.f;
    #pragma unroll
    for (int d2 = 0; d2 < HD; d2++) s = fmaf(qv[d2], kv[d2], s);
    s = s * 0.25f + (lane <= q ? 0.f : -1e9f);
    float m = s;
    #pragma unroll
    for (int o = 32; o; o >>= 1) m = fmaxf(m, __shfl_xor(m, o));
    float e = __expf(s - m);
    float tot = e;
    #pragma unroll
    for (int o = 32; o; o >>= 1) tot += __shfl_xor(tot, o);
    float att = e / tot;
    __shared__ float satt[64];
    satt[lane] = att;
    __syncthreads();
    if (lane < HD) {
        float o0 = 0.f, o1 = 0.f, o2 = 0.f, o3 = 0.f;
        for (int k2 = 0; k2 < Dd; k2 += 4) {
            o0 = fmaf(satt[k2],     qkv[(k2)     * 384 + 256 + hh * HD + lane], o0);
            o1 = fmaf(satt[k2 + 1], qkv[(k2 + 1) * 384 + 256 + hh * HD + lane], o1);
            o2 = fmaf(satt[k2 + 2], qkv[(k2 + 2) * 384 + 256 + hh * HD + lane], o2);
            o3 = fmaf(satt[k2 + 3], qkv[(k2 + 3) * 384 + 256 + hh * HD + lane], o3);
        }
        attn_o[q * Hh + hh * HD + lane] = (o0 + o1) + (o2 + o3);
    }
}

DEV float blocksum128(float v, float* red)
{
    #pragma unroll
    for (int o = 32; o; o >>= 1) v += __shfl_xor(v, o);
    int wid = threadIdx.x >> 6;
    __syncthreads();
    if ((threadIdx.x & 63) == 0) red[wid] = v;
    __syncthreads();
    return red[0] + red[1];
}

__global__ __launch_bounds__(128)
void k_outln(const float* __restrict__ attn_o, float* __restrict__ h,
             const float* __restrict__ Wout, const float* __restrict__ bout,
             const float* __restrict__ ln)
{
    int r = blockIdx.x, tid = threadIdx.x;
    __shared__ float ar[128];
    __shared__ float red[2];
    ar[tid] = attn_o[r * Hh + tid];
    __syncthreads();
    float a0 = bout[tid], a1 = 0.f, a2 = 0.f, a3 = 0.f;
    for (int k = 0; k < 128; k += 4) {
        a0 = fmaf(ar[k],     Wout[(k)     * Hh + tid], a0);
        a1 = fmaf(ar[k + 1], Wout[(k + 1) * Hh + tid], a1);
        a2 = fmaf(ar[k + 2], Wout[(k + 2) * Hh + tid], a2);
        a3 = fmaf(ar[k + 3], Wout[(k + 3) * Hh + tid], a3);
    }
    float x = h[r * Hh + tid] + (a0 + a1) + (a2 + a3);
    float mu = blocksum128(x, red) * (1.f / 128.f);
    float dx = x - mu;
    float var = blocksum128(dx * dx, red) * (1.f / 128.f);
    h[r * Hh + tid] = ln[tid] * dx * (1.f / sqrtf(var + 1e-5f)) + ln[128 + tid];
}

__global__ __launch_bounds__(256)
void k_ff1b(const float* __restrict__ h, float* __restrict__ fbuf,
            const float* __restrict__ W1, const float* __restrict__ b1)
{
    int r = blockIdx.x, tid = threadIdx.x;
    int c = blockIdx.y * 256 + tid;
    __shared__ float hr[128];
    if (tid < 128) hr[tid] = h[r * Hh + tid];
    __syncthreads();
    float a0 = b1[c], a1 = 0.f, a2 = 0.f, a3 = 0.f;
    for (int k = 0; k < 128; k += 4) {
        a0 = fmaf(hr[k],     W1[(size_t)(k)     * FF + c], a0);
        a1 = fmaf(hr[k + 1], W1[(size_t)(k + 1) * FF + c], a1);
        a2 = fmaf(hr[k + 2], W1[(size_t)(k + 2) * FF + c], a2);
        a3 = fmaf(hr[k + 3], W1[(size_t)(k + 3) * FF + c], a3);
    }
    fbuf[(size_t)r * FF + c] = fmaxf((a0 + a1) + (a2 + a3), 0.f);
}

__global__ __launch_bounds__(128)
void k_ff2p(const float* __restrict__ fbuf, float* __restrict__ part,
            const float* __restrict__ W2)
{
    int r = blockIdx.x, pi = blockIdx.y, tid = threadIdx.x;
    int kc = pi * 128;
    const float* f = fbuf + (size_t)r * FF + kc;
    float a0 = 0.f, a1 = 0.f, a2 = 0.f, a3 = 0.f;
    for (int k = 0; k < 128; k += 4) {
        a0 = fmaf(f[k],     W2[(size_t)(kc + k)     * Hh + tid], a0);
        a1 = fmaf(f[k + 1], W2[(size_t)(kc + k + 1) * Hh + tid], a1);
        a2 = fmaf(f[k + 2], W2[(size_t)(kc + k + 2) * Hh + tid], a2);
        a3 = fmaf(f[k + 3], W2[(size_t)(kc + k + 3) * Hh + tid], a3);
    }
    part[(size_t)(r * 16 + pi) * Hh + tid] = (a0 + a1) + (a2 + a3);
}

__global__ __launch_bounds__(128)
void k_ln2(float* __restrict__ h, const float* __restrict__ part,
           const float* __restrict__ b2, const float* __restrict__ ln)
{
    int r = blockIdx.x, tid = threadIdx.x;
    __shared__ float red[2];
    float acc = b2[tid];
    #pragma unroll
    for (int pi = 0; pi < 16; pi++) acc += part[(size_t)(r * 16 + pi) * Hh + tid];
    float x = h[r * Hh + tid] + acc;
    float mu = blocksum128(x, red) * (1.f / 128.f);
    float dx = x - mu;
    float var = blocksum128(dx * dx, red) * (1.f / 128.f);
    h[r * Hh + tid] = ln[tid] * dx * (1.f / sqrtf(var + 1e-5f)) + ln[128 + tid];
}

// ---------------------------------------------------------------------------
__global__ __launch_bounds__(256)
void k_logits(const ushort_t* __restrict__ x_dc, const int* __restrict__ map,
              const float* __restrict__ h, const float* __restrict__ lp,
              const int* __restrict__ cand, float* __restrict__ out)
{
    int d = blockIdx.x;
    int tid = threadIdx.x, lane = tid & 63, w = tid >> 6;
    __shared__ float wv[128];
    if (tid < 128) wv[tid] = h[d * Hh + tid] * lp[tid];
    __syncthreads();
    for (int k = w; k < KK; k += 4) {
        int slot = map[d * VD + cand[d * KK + k]] >> 2;
        const ushort_t* row = x_dc + (size_t)slot * Hh;
        float v = bf(row[lane]) * wv[lane] + bf(row[lane + 64]) * wv[lane + 64];
        #pragma unroll
        for (int o = 32; o; o >>= 1) v += __shfl_xor(v, o);
        if (lane == 0) out[d * KK + k] = v;
    }
}

// ---------------------------------------------------------------------------
extern "C" void kernel_launch(void* const* d_in, const int* in_sizes, int n_in,
                              void* d_out, int out_size, void* d_ws, size_t ws_size,
                              hipStream_t stream)
{
    (void)in_sizes; (void)n_in; (void)out_size; (void)ws_size;

    const int* drug_tokens  = (const int*)d_in[0];
    const int* drug_node_id = (const int*)d_in[1];
    const int* lab_tokens   = (const int*)d_in[3];
    const int* lab_node_id  = (const int*)d_in[4];
    const int* adm_tokens   = (const int*)d_in[6];
    const int* did_tokens   = (const int*)d_in[8];
    const int* did_src      = (const int*)d_in[10];
    const int* did_dst      = (const int*)d_in[11];
    const int* took_tokens  = (const int*)d_in[12];
    const int* took_src     = (const int*)d_in[14];
    const int* took_dst     = (const int*)d_in[15];
    const int* cand_idx     = (const int*)d_in[16];

    const int cidx[NCANON] = {2,5,7,9,13, 17,18,19,20,21,22,23, 24,25,26,27,28,
                              29,30,31,32,33, 34,35, 36,37,38,39,40,41,42,43,44,45,46};
    const int cn[NCANON] = {
        ND*2, NLN*1, Dd*3, ED*2, ET*1,
        VD*EMB, VL*EMB, 3*TV*EMB, 2*TV*EMB, 4*TV*EMB, 2*TV*EMB, 2*TV*EMB,
        2*EMB, 1*EMB, 3*EMB, 2*EMB, 1*EMB,
        5*EMB*Hh, 4*EMB*Hh, 5*EMB*Hh, 3*EMB*Hh, 3*EMB*Hh,
        GL*4*Hh*Hh, GL*3*Hh*Hh,
        L_ENC*Hh*3*Hh, L_ENC*3*Hh, L_ENC*Hh*Hh, L_ENC*Hh, L_ENC*2*Hh,
        L_ENC*Hh*FF, L_ENC*FF, L_ENC*FF*Hh, L_ENC*Hh, L_ENC*2*Hh, Hh
    };
    CanonDesc cd;
    int eoff[NCANON + 1];
    int btot_blocks = 0;
    {
        int e = 0;
        for (int t = 0; t < NCANON; t++) {
            cd.src[t] = d_in[cidx[t]];
            cd.n[t] = cn[t];
            eoff[t] = e;
            cd.doff[t] = e;
            e = (e + cn[t] + 7) & ~7;
            btot_blocks += (cn[t] + 255) / 256;
            cd.bend[t] = btot_blocks;
        }
        eoff[NCANON] = e;
    }

    // ---- workspace carve ----
    char* p = (char*)d_ws;
    auto alloc_f = [&](size_t n) -> float*    { float* r = (float*)p;    p += n * sizeof(float); return r; };
    auto alloc_h = [&](size_t n) -> ushort_t* { ushort_t* r = (ushort_t*)p; p += n * sizeof(ushort_t); return r; };
    auto alloc_i = [&](size_t n) -> int*      { int* r = (int*)p;        p += n * sizeof(int); return r; };

    int* map    = alloc_i(ND);
    int* cnt_dc = alloc_i(UCAP);
    int* cnt_ld = alloc_i(NLN);
    int* cnt_a1 = alloc_i(64);
    int* cnt_a2 = alloc_i(64);
    int* nUB    = alloc_i(8);
    int* cur_t  = alloc_i(UCAP);
    int* cur_d  = alloc_i(NLN);
    int* cur_a1 = alloc_i(64);
    int* cur_a2 = alloc_i(64);
    float* E_did  = alloc_f((size_t)Dd * Hh);
    float* E_took = alloc_f((size_t)Dd * Hh);
    const size_t ZBLOCK = (size_t)ND + UCAP + NLN + 64 + 64 + 8 + UCAP + NLN + 64 + 64
                        + (size_t)Dd * Hh * 2;
    float* Sx_did  = alloc_f((size_t)Dd * Hh);
    float* Sx_took = alloc_f((size_t)Dd * Hh);
    int* roff_t  = alloc_i(UCAP + 8);
    int* roff_d  = alloc_i(NLN + 8);
    int* roff_a1 = alloc_i(72);
    int* roff_a2 = alloc_i(72);
    int* bscr    = alloc_i(1024);
    u64* absum   = (u64*)alloc_i(2 * (NB_A + 8));
    int* ulist   = alloc_i(UCAP);
    int* blist   = alloc_i(NCAND);
    int* elist_t = alloc_i(ET);
    int* elist_d = alloc_i(ED);
    int* tookA   = alloc_i(ET);
    int* tookB   = alloc_i(ET);
    int* didA    = alloc_i(ED);
    int* didB    = alloc_i(ED);
    ushort_t* wt     = alloc_h(3 * 32768);
    ushort_t* ap     = alloc_h(2 * 8192 + 2 * 4096);
    ushort_t* x_dc   = alloc_h((size_t)UCAP * Hh);
    ushort_t* x_l    = alloc_h((size_t)NLN * Hh);
    float*    x_a    = alloc_f((size_t)Dd * Hh);
    ushort_t* e_did  = alloc_h((size_t)ED * Hh);
    ushort_t* e_took = alloc_h((size_t)ET * Hh);
    float*    qkvb   = alloc_f((size_t)Dd * 384);
    float*    attn_o = alloc_f((size_t)Dd * Hh);
    float*    fbuf   = alloc_f((size_t)Dd * FF);
    float*    part   = alloc_f((size_t)Dd * 16 * Hh);
    float*    cf     = alloc_f((size_t)eoff[NCANON]);
    int*      dflag  = alloc_i(8);

    ushort_t* ap_drug = ap;
    ushort_t* ap_lab  = ap + 8192;
    ushort_t* ap_did  = ap + 16384;
    ushort_t* ap_took = ap + 16384 + 4096;

    const float* c_drug_floats  = cf + eoff[0];
    const float* c_lab_floats   = cf + eoff[1];
    const float* c_adm_floats   = cf + eoff[2];
    const float* c_did_floats   = cf + eoff[3];
    const float* c_took_floats  = cf + eoff[4];
    const float* c_drug_id_emb  = cf + eoff[5];
    const float* c_lab_id_emb   = cf + eoff[6];
    const float* c_drug_tok_emb = cf + eoff[7];
    const float* c_lab_tok_emb  = cf + eoff[8];
    const float* c_adm_tok_emb  = cf + eoff[9];
    const float* c_did_tok_emb  = cf + eoff[10];
    const float* c_took_tok_emb = cf + eoff[11];
    const float* c_drug_float_w = cf + eoff[12];
    const float* c_lab_float_w  = cf + eoff[13];
    const float* c_adm_float_w  = cf + eoff[14];
    const float* c_did_float_w  = cf + eoff[15];
    const float* c_took_float_w = cf + eoff[16];
    const float* c_drug_align   = cf + eoff[17];
    const float* c_lab_align    = cf + eoff[18];
    const float* c_adm_align    = cf + eoff[19];
    const float* c_did_align    = cf + eoff[20];
    const float* c_took_align   = cf + eoff[21];
    const float* c_gnn_msg      = cf + eoff[22];
    const float* c_gnn_self     = cf + eoff[23];
    const float* c_qkv_w        = cf + eoff[24];
    const float* c_qkv_b        = cf + eoff[25];
    const float* c_out_w        = cf + eoff[26];
    const float* c_out_b        = cf + eoff[27];
    const float* c_ln1          = cf + eoff[28];
    const float* c_ff1_w        = cf + eoff[29];
    const float* c_ff1_b        = cf + eoff[30];
    const float* c_ff2_w        = cf + eoff[31];
    const float* c_ff2_b        = cf + eoff[32];
    const float* c_ln2          = cf + eoff[33];
    const float* c_lp_w         = cf + eoff[34];

    // ---- canonicalize + graph prep ----
    k_probe<<<1, 64, 0, stream>>>((const unsigned*)d_in[41], dflag);
    k_canon<<<btot_blocks, 256, 0, stream>>>(cd, cf, dflag);
    k_wpack<<<dim3(32, 3), 128, 0, stream>>>(c_gnn_self, c_gnn_msg, wt);
    k_apack<<<8, 128, 0, stream>>>(c_drug_align, ap_drug, 50);
    k_apack<<<8, 128, 0, stream>>>(c_lab_align,  ap_lab,  40);
    k_apack<<<4, 128, 0, stream>>>(c_did_align,  ap_did,  30);
    k_apack<<<4, 128, 0, stream>>>(c_took_align, ap_took, 30);
    hipMemsetAsync(map, 0, ZBLOCK * sizeof(int), stream);
    k_mark<<<ET / 256, 256, 0, stream>>>(took_dst, cand_idx, map);
    k_acount<<<NB_A, 256, 0, stream>>>(map, absum);
    k_ascan<<<1, 1024, 0, stream>>>(absum, NB_A, nUB);
    k_assign2<<<NB_A, 256, 0, stream>>>(map, ulist, blist, absum);
    k_counts<<<128, 256, 0, stream>>>(did_dst, did_src, took_dst, took_src, map,
                                      cnt_ld, cnt_a1, cnt_dc, cnt_a2);
    k_scan_blk<<<NB_T, 256, 0, stream>>>(cnt_dc, roff_t, bscr, UCAP);
    k_scan_top<<<1, 1024, 0, stream>>>(bscr, NB_T);
    k_scan_add<<<NB_T, 256, 0, stream>>>(roff_t, bscr, UCAP, ET);
    k_scan_blk<<<NB_D, 256, 0, stream>>>(cnt_ld, roff_d, bscr, NLN);
    k_scan_top<<<1, 1024, 0, stream>>>(bscr, NB_D);
    k_scan_add<<<NB_D, 256, 0, stream>>>(roff_d, bscr, NLN, ED);
    k_scan64<<<1, 64, 0, stream>>>(cnt_a1, cnt_a2, roff_a1, roff_a2);
    k_fill<<<128, 256, 0, stream>>>(did_src, did_dst, took_src, took_dst, map,
                                    roff_d, roff_t, roff_a1, roff_a2,
                                    cur_d, cur_t, cur_a1, cur_a2,
                                    elist_d, elist_t, didA, didB, tookA, tookB);

    // ---- embeddings ----
    k_embed_m<1,3,2,2,true><<<UCAP / 32, 128, 0, stream>>>(x_dc, 0, nUB, ulist,
        drug_node_id, c_drug_id_emb, drug_tokens, c_drug_tok_emb,
        c_drug_floats, c_drug_float_w, ap_drug);
    k_embed_m<1,2,1,2,false><<<NLN / 32, 128, 0, stream>>>(x_l, NLN, nullptr, nullptr,
        lab_node_id, c_lab_id_emb, lab_tokens, c_lab_tok_emb,
        c_lab_floats, c_lab_float_w, ap_lab);
    k_embed_adm<<<Dd, 128, 0, stream>>>(x_a, adm_tokens, c_adm_tok_emb,
                                        c_adm_floats, c_adm_float_w, c_adm_align);
    k_embed_m<0,2,2,1,false><<<ED / 32, 128, 0, stream>>>(e_did, ED, nullptr, nullptr,
        nullptr, nullptr, did_tokens, c_did_tok_emb, c_did_floats, c_did_float_w, ap_did);
    k_embed_m<0,2,1,1,false><<<ET / 32, 128, 0, stream>>>(e_took, ET, nullptr, nullptr,
        nullptr, nullptr, took_tokens, c_took_tok_emb, c_took_floats, c_took_float_w, ap_took);

    const size_t HH = (size_t)Hh * Hh;

    // ---- GNN layer 1 (relu) ----
    hipMemsetAsync(Sx_did, 0, 2 * (size_t)Dd * Hh * sizeof(float), stream);
    k_srcsum<true><<<(ED + 31) / 32, 64, 0, stream>>>(didA, didB, x_l, e_did, 16,
                                                      Sx_did, E_did, ED, 32);
    k_srcsum<true><<<(ET + 31) / 32, 64, 0, stream>>>(tookA, tookB, x_dc, e_took, 18,
                                                      Sx_took, E_took, ET, 32);
    k_gup<false><<<UCAP / 32, 128, 0, stream>>>(x_dc, x_a, e_took, roff_t, elist_t, 17,
        nullptr, nUB, 0, wt, 1);
    k_gup<false><<<NLN / 32, 128, 0, stream>>>(x_l, x_a, e_did, roff_d, elist_d, 15,
        nullptr, nullptr, NLN, wt + 32768, 1);
    k_xa<<<Dd, 128, 0, stream>>>(x_a, Sx_did, E_did, Sx_took, E_took, cnt_a1, cnt_a2,
        c_gnn_self + 0 * HH, c_gnn_msg + 2 * HH, c_gnn_msg + 3 * HH, 1);

    // ---- GNN layer 2 ----
    const float* Ws1 = c_gnn_self + 3 * HH;
    const float* Wm1 = c_gnn_msg + 4 * HH;
    hipMemsetAsync(Sx_did, 0, 2 * (size_t)Dd * Hh * sizeof(float), stream);
    k_srcsum<false><<<(ED + 31) / 32, 64, 0, stream>>>(didA, didB, x_l, nullptr, 16,
                                                       Sx_did, nullptr, ED, 32);
    k_srcsum<false><<<(ET + 31) / 32, 64, 0, stream>>>(tookA, tookB, x_dc, nullptr, 18,
                                                       Sx_took, nullptr, ET, 32);
    k_gup<true><<<(NCAND + 31) / 32, 128, 0, stream>>>(x_dc, x_a, e_took, roff_t, elist_t, 17,
        blist, nUB + 1, 0, wt + 65536, 0);
    k_xa<<<Dd, 128, 0, stream>>>(x_a, Sx_did, E_did, Sx_took, E_took, cnt_a1, cnt_a2,
        Ws1 + 0 * HH, Wm1 + 2 * HH, Wm1 + 3 * HH, 0);

    // ---- transformer encoder ----
    for (int i = 0; i < L_ENC; i++) {
        k_qkv3<<<dim3(Dd, 3), 128, 0, stream>>>(x_a, qkvb,
            c_qkv_w + (size_t)i * Hh * 384, c_qkv_b + (size_t)i * 384);
        k_attn2<<<dim3(NH, Dd), 64, 0, stream>>>(qkvb, attn_o);
        k_outln<<<Dd, 128, 0, stream>>>(attn_o, x_a, c_out_w + (size_t)i * HH,
                                        c_out_b + (size_t)i * Hh, c_ln1 + (size_t)i * 2 * Hh);
        k_ff1b<<<dim3(Dd, FF / 256), 256, 0, stream>>>(x_a, fbuf,
            c_ff1_w + (size_t)i * Hh * FF, c_ff1_b + (size_t)i * FF);
        k_ff2p<<<dim3(Dd, 16), 128, 0, stream>>>(fbuf, part, c_ff2_w + (size_t)i * FF * Hh);
        k_ln2<<<Dd, 128, 0, stream>>>(x_a, part, c_ff2_b + (size_t)i * Hh,
                                      c_ln2 + (size_t)i * 2 * Hh);
    }

    // ---- logits ----
    k_logits<<<Dd - 1, 256, 0, stream>>>(x_dc, map, x_a, c_lp_w, cand_idx, (float*)d_out);
}

// Round 14
// 674.265 us; speedup vs baseline: 5.6680x; 1.0823x over previous
//
#include <hip/hip_runtime.h>
#include <hip/hip_bf16.h>

typedef unsigned short ushort_t;
typedef unsigned long long u64;
typedef __attribute__((ext_vector_type(8))) short bf16x8;
typedef __attribute__((ext_vector_type(4))) float f32x4;

#define DEV __device__ __forceinline__

constexpr int Dd  = 64;
constexpr int VD  = 4525;
constexpr int VL  = 753;
constexpr int ND  = Dd * VD;     // 289600
constexpr int NLN = Dd * VL;     // 48192
constexpr int Hh  = 128;
constexpr int EMB = 10;
constexpr int TV  = 100;
constexpr int NH  = 8, HD = 16;
constexpr int L_ENC = 6, FF = 2048;
constexpr int GL  = 2;
constexpr int ED  = 32768, ET = 131072;
constexpr int KK  = 256;
constexpr int NCAND = (Dd - 1) * KK;       // 16128
constexpr int UCAP  = ET + NCAND;          // 147200
constexpr int NCANON = 35;
constexpr int NB_T = (UCAP + 255) / 256;
constexpr int NB_D = (NLN + 255) / 256;
constexpr int NB_A = (ND + 255) / 256;

DEV float bf(ushort_t u) { return __uint_as_float(((unsigned)u) << 16); }
DEV float bflo(unsigned u) { return __uint_as_float(u << 16); }
DEV float bfhi(unsigned u) { return __uint_as_float(u & 0xffff0000u); }
DEV ushort_t f2bf(float f) {
    unsigned u = __float_as_uint(f);
    u += 0x7fffu + ((u >> 16) & 1u);
    return (ushort_t)(u >> 16);
}

// ---------------------------------------------------------------------------
__global__ __launch_bounds__(64)
void k_probe(const unsigned* __restrict__ w, int* __restrict__ flag)
{
    int tid = threadIdx.x;
    int c = 0;
    #pragma unroll
    for (int i = 0; i < 16; i++) c += (w[tid * 16 + i] >> 14) & 1;
    #pragma unroll
    for (int o = 32; o; o >>= 1) c += __shfl_xor(c, o);
    if (tid == 0) *flag = (c > 256) ? 1 : 0;
}

struct CanonDesc {
    const void* src[NCANON];
    int doff[NCANON];
    int bend[NCANON];
    int n[NCANON];
};

__global__ __launch_bounds__(256)
void k_canon(CanonDesc cd, float* __restrict__ dst, const int* __restrict__ flag)
{
    int b = blockIdx.x;
    int t = 0;
    while (t < NCANON && b >= cd.bend[t]) t++;
    if (t >= NCANON) return;
    int bstart = (t == 0) ? 0 : cd.bend[t - 1];
    int i = (b - bstart) * 256 + threadIdx.x;
    if (i >= cd.n[t]) return;
    float v = (*flag) ? ((const float*)cd.src[t])[i]
                      : bf(((const ushort_t*)cd.src[t])[i]);
    dst[cd.doff[t] + i] = v;
}

// merged weight packing: sel 0..2 = GNN [Wself;Wmsg] pairs; sel 3..6 = align mats
__global__ __launch_bounds__(128)
void k_packall(const float* __restrict__ gself, const float* __restrict__ gmsg,
               const float* __restrict__ a_drug, const float* __restrict__ a_lab,
               const float* __restrict__ a_did, const float* __restrict__ a_took,
               ushort_t* __restrict__ wt, ushort_t* __restrict__ ap)
{
    int sel = blockIdx.y, chunk = blockIdx.x, nn = threadIdx.x;
    if (sel < 3) {
        const int selfIdx[3] = {1, 2, 4};
        const int msgIdx[3]  = {1, 0, 5};
        const float* Ws = gself + (size_t)selfIdx[sel] * Hh * Hh;
        const float* Wm = gmsg  + (size_t)msgIdx[sel]  * Hh * Hh;
        ushort_t* dst = wt + (((size_t)sel * 32 + chunk) * 128 + nn) * 8;
        #pragma unroll
        for (int j = 0; j < 8; j++) {
            int k = chunk * 8 + j;
            float v = (k < 128) ? Ws[k * Hh + nn] : Wm[(k - 128) * Hh + nn];
            dst[j] = f2bf(v);
        }
    } else {
        int ai = sel - 3;
        const int nchunk[4] = {8, 8, 4, 4};
        if (chunk >= nchunk[ai]) return;
        const int Ls[4] = {50, 40, 30, 30};
        const int aoff[4] = {0, 8192, 16384, 16384 + 4096};
        const float* A = (ai == 0) ? a_drug : (ai == 1) ? a_lab : (ai == 2) ? a_did : a_took;
        ushort_t* d = ap + aoff[ai] + ((size_t)chunk * 128 + nn) * 8;
        int L = Ls[ai];
        #pragma unroll
        for (int j = 0; j < 8; j++) {
            int k = chunk * 8 + j;
            d[j] = (k < L) ? f2bf(A[(size_t)k * Hh + nn]) : (ushort_t)0;
        }
    }
}

// ---------------------------------------------------------------------------
__global__ __launch_bounds__(256)
void k_mark(const int* __restrict__ took_dst, const int* __restrict__ cand,
            int* __restrict__ map)
{
    int g = blockIdx.x * 256 + threadIdx.x;
    if (g < ET) atomicOr(&map[took_dst[g]], 1);
    if (g < NCAND) {
        int d = g >> 8;
        atomicOr(&map[d * VD + cand[g]], 2);
    }
}

// contention-free slot assignment (u64: isU low 32, isB high 32)
__global__ __launch_bounds__(256)
void k_acount(const int* __restrict__ map, u64* __restrict__ bsum)
{
    __shared__ u64 s[256];
    int tid = threadIdx.x;
    int g = blockIdx.x * 256 + tid;
    int m = (g < ND) ? map[g] : 0;
    s[tid] = (u64)(m ? 1u : 0u) | ((u64)((m & 2) ? 1u : 0u) << 32);
    __syncthreads();
    for (int o = 128; o; o >>= 1) {
        if (tid < o) s[tid] += s[tid + o];
        __syncthreads();
    }
    if (tid == 0) bsum[blockIdx.x] = s[0];
}

__global__ __launch_bounds__(1024)
void k_ascan(u64* __restrict__ bsum, int nb, int* __restrict__ nUB)
{
    __shared__ u64 s[1024];
    int tid = threadIdx.x;
    u64 carry = 0;
    for (int base = 0; base < nb; base += 1024) {
        int idx = base + tid;
        u64 v = (idx < nb) ? bsum[idx] : 0;
        s[tid] = v;
        __syncthreads();
        for (int o = 1; o < 1024; o <<= 1) {
            u64 t = (tid >= o) ? s[tid - o] : 0;
            __syncthreads();
            s[tid] += t;
            __syncthreads();
        }
        if (idx < nb) bsum[idx] = carry + s[tid] - v;
        u64 tot = s[1023];
        __syncthreads();
        carry += tot;
    }
    if (tid == 0) {
        nUB[0] = (int)(carry & 0xffffffffu);
        nUB[1] = (int)(carry >> 32);
    }
}

__global__ __launch_bounds__(256)
void k_assign2(int* __restrict__ map, int* __restrict__ ulist, int* __restrict__ blist,
               const u64* __restrict__ bsum)
{
    __shared__ u64 s[256];
    int tid = threadIdx.x;
    int g = blockIdx.x * 256 + tid;
    int m = (g < ND) ? map[g] : 0;
    u64 v = (u64)(m ? 1u : 0u) | ((u64)((m & 2) ? 1u : 0u) << 32);
    s[tid] = v;
    __syncthreads();
    for (int o = 1; o < 256; o <<= 1) {
        u64 t = (tid >= o) ? s[tid - o] : 0;
        __syncthreads();
        s[tid] += t;
        __syncthreads();
    }
    u64 excl = s[tid] - v + bsum[blockIdx.x];
    if (m) {
        int slot = (int)(excl & 0xffffffffu);
        ulist[slot] = g;
        map[g] = (slot << 2) | m;
        if (m & 2) blist[(int)(excl >> 32)] = slot;
    }
}

__global__ __launch_bounds__(256)
void k_counts(const int* __restrict__ did_dst, const int* __restrict__ did_src,
              const int* __restrict__ took_dst, const int* __restrict__ took_src,
              const int* __restrict__ map,
              int* __restrict__ cnt_ld, int* __restrict__ cnt_a1,
              int* __restrict__ cnt_dc, int* __restrict__ cnt_a2)
{
    __shared__ int h1[64], h2[64];
    int tid = threadIdx.x;
    if (tid < 64) { h1[tid] = 0; h2[tid] = 0; }
    __syncthreads();
    int tb = blockIdx.x * 1024;
    #pragma unroll
    for (int o = 0; o < 1024; o += 256) {
        int i = tb + o + tid;
        atomicAdd(&cnt_dc[map[took_dst[i]] >> 2], 1);
        atomicAdd(&h2[took_src[i]], 1);
    }
    {
        int i = blockIdx.x * 256 + tid;
        atomicAdd(&cnt_ld[did_dst[i]], 1);
        atomicAdd(&h1[did_src[i]], 1);
    }
    __syncthreads();
    if (tid < 64) {
        if (h1[tid]) atomicAdd(&cnt_a1[tid], h1[tid]);
        if (h2[tid]) atomicAdd(&cnt_a2[tid], h2[tid]);
    }
}

// ---------------------------------------------------------------------------
// merged CSR scans (T chunk first, then D chunk)
__global__ __launch_bounds__(256)
void k_scan_blk2(const int* __restrict__ cnt_dc, int* __restrict__ roff_t,
                 const int* __restrict__ cnt_ld, int* __restrict__ roff_d,
                 int* __restrict__ bscrT, int* __restrict__ bscrD)
{
    __shared__ int s[256];
    int tid = threadIdx.x;
    const int* cnt; int* excl; int* btot; int n; int blk;
    if (blockIdx.x < NB_T) { cnt = cnt_dc; excl = roff_t; btot = bscrT; n = UCAP; blk = blockIdx.x; }
    else { cnt = cnt_ld; excl = roff_d; btot = bscrD; n = NLN; blk = blockIdx.x - NB_T; }
    int g = blk * 256 + tid;
    int v = (g < n) ? cnt[g] : 0;
    s[tid] = v;
    __syncthreads();
    for (int o = 1; o < 256; o <<= 1) {
        int t = (tid >= o) ? s[tid - o] : 0;
        __syncthreads();
        s[tid] += t;
        __syncthreads();
    }
    if (g < n) excl[g] = s[tid] - v;
    if (tid == 255) btot[blk] = s[255];
}

// block 0: top-scan bscrT; block 1: top-scan bscrD; block 2: scan64(cnt_a1,cnt_a2)
__global__ __launch_bounds__(1024)
void k_scan_top2(int* __restrict__ bscrT, int* __restrict__ bscrD,
                 const int* __restrict__ c1, const int* __restrict__ c2,
                 int* __restrict__ r1, int* __restrict__ r2)
{
    int tid = threadIdx.x;
    if (blockIdx.x == 2) {
        if (tid < 64) {
            int v1 = c1[tid], v2 = c2[tid];
            int s1 = v1, s2 = v2;
            for (int o = 1; o < 64; o <<= 1) {
                int t1 = __shfl_up(s1, o), t2 = __shfl_up(s2, o);
                if (tid >= o) { s1 += t1; s2 += t2; }
            }
            r1[tid] = s1 - v1;
            r2[tid] = s2 - v2;
        }
        return;
    }
    __shared__ int s[1024];
    int* btot = (blockIdx.x == 0) ? bscrT : bscrD;
    int nb = (blockIdx.x == 0) ? NB_T : NB_D;
    int v = (tid < nb) ? btot[tid] : 0;
    s[tid] = v;
    __syncthreads();
    for (int o = 1; o < 1024; o <<= 1) {
        int t = (tid >= o) ? s[tid - o] : 0;
        __syncthreads();
        s[tid] += t;
        __syncthreads();
    }
    if (tid < nb) btot[tid] = s[tid] - v;
}

__global__ __launch_bounds__(256)
void k_scan_add2(int* __restrict__ roff_t, const int* __restrict__ bscrT,
                 int* __restrict__ roff_d, const int* __restrict__ bscrD)
{
    int tid = threadIdx.x;
    if (blockIdx.x < NB_T) {
        int g = blockIdx.x * 256 + tid;
        if (g < UCAP) roff_t[g] += bscrT[blockIdx.x];
        if (g == 0) roff_t[UCAP] = ET;
    } else {
        int blk = blockIdx.x - NB_T;
        int g = blk * 256 + tid;
        if (g < NLN) roff_d[g] += bscrD[blk];
        if (g == 0) roff_d[NLN] = ED;
    }
}

__global__ __launch_bounds__(256)
void k_fill(const int* __restrict__ did_src, const int* __restrict__ did_dst,
            const int* __restrict__ took_src, const int* __restrict__ took_dst,
            const int* __restrict__ map,
            const int* __restrict__ roff_d, const int* __restrict__ roff_t,
            const int* __restrict__ roff_a1, const int* __restrict__ roff_a2,
            int* __restrict__ cur_d, int* __restrict__ cur_t,
            int* __restrict__ cur_a1, int* __restrict__ cur_a2,
            int* __restrict__ elist_d, int* __restrict__ elist_t,
            int* __restrict__ didA, int* __restrict__ didB,
            int* __restrict__ tookA, int* __restrict__ tookB)
{
    __shared__ int h1[64], h2[64], b1[64], b2[64];
    int tid = threadIdx.x;
    if (tid < 64) { h1[tid] = 0; h2[tid] = 0; }
    __syncthreads();
    int tb = blockIdx.x * 1024;
    int db = blockIdx.x * 256;
    #pragma unroll
    for (int o = 0; o < 1024; o += 256)
        atomicAdd(&h2[took_src[tb + o + tid]], 1);
    atomicAdd(&h1[did_src[db + tid]], 1);
    __syncthreads();
    if (tid < 64) {
        b1[tid] = h1[tid] ? atomicAdd(&cur_a1[tid], h1[tid]) : 0;
        b2[tid] = h2[tid] ? atomicAdd(&cur_a2[tid], h2[tid]) : 0;
        h1[tid] = 0; h2[tid] = 0;
    }
    __syncthreads();
    #pragma unroll
    for (int o = 0; o < 1024; o += 256) {
        int i = tb + o + tid;
        int s = took_src[i];
        int slot = map[took_dst[i]] >> 2;
        int pos = roff_t[slot] + atomicAdd(&cur_t[slot], 1);
        elist_t[pos] = (s << 17) | i;
        int pa = roff_a2[s] + b2[s] + atomicAdd(&h2[s], 1);
        tookA[pa] = (s << 18) | slot;
        tookB[pa] = i;
    }
    {
        int i = db + tid;
        int d = did_dst[i], s = did_src[i];
        int pos = roff_d[d] + atomicAdd(&cur_d[d], 1);
        elist_d[pos] = (s << 15) | i;
        int pa = roff_a1[s] + b1[s] + atomicAdd(&h1[s], 1);
        didA[pa] = (s << 16) | d;
        didB[pa] = i;
    }
}

// ---------------------------------------------------------------------------
template<bool DUAL>
__global__ __launch_bounds__(64)
void k_srcsum(const int* __restrict__ lA, const int* __restrict__ lB,
              const ushort_t* __restrict__ xrows, const ushort_t* __restrict__ erows,
              int shift, float* __restrict__ Sx, float* __restrict__ Se,
              int nedge, int epb)
{
    int lane = threadIdx.x;
    int c0 = lane * 2;
    int base = blockIdx.x * epb;
    int end = min(base + epb, nedge);
    int mask = (1 << shift) - 1;
    float ax0 = 0.f, ax1 = 0.f, ae0 = 0.f, ae1 = 0.f;
    int cur = -1;
    for (int i = base; i < end; i++) {
        int pk = lA[i];
        int s = pk >> shift, row = pk & mask;
        if (s != cur) {
            if (cur >= 0) {
                unsafeAtomicAdd(&Sx[cur * Hh + c0], ax0);
                unsafeAtomicAdd(&Sx[cur * Hh + c0 + 1], ax1);
                if (DUAL) {
                    unsafeAtomicAdd(&Se[cur * Hh + c0], ae0);
                    unsafeAtomicAdd(&Se[cur * Hh + c0 + 1], ae1);
                }
            }
            cur = s; ax0 = ax1 = ae0 = ae1 = 0.f;
        }
        unsigned xx = *reinterpret_cast<const unsigned*>(xrows + (size_t)row * Hh + c0);
        ax0 += bflo(xx); ax1 += bfhi(xx);
        if (DUAL) {
            int e = lB[i];
            unsigned ee = *reinterpret_cast<const unsigned*>(erows + (size_t)e * Hh + c0);
            ae0 += bflo(ee); ae1 += bfhi(ee);
        }
    }
    if (cur >= 0) {
        unsafeAtomicAdd(&Sx[cur * Hh + c0], ax0);
        unsafeAtomicAdd(&Sx[cur * Hh + c0 + 1], ax1);
        if (DUAL) {
            unsafeAtomicAdd(&Se[cur * Hh + c0], ae0);
            unsafeAtomicAdd(&Se[cur * Hh + c0 + 1], ae1);
        }
    }
}

// ---------------------------------------------------------------------------
// adm embed (64 blocks x 128 thr, bit-identical math)
__global__ __launch_bounds__(128)
void k_embed_adm(float* __restrict__ out,
                 const int* __restrict__ tokens, const float* __restrict__ tok_emb,
                 const float* __restrict__ floats_, const float* __restrict__ float_w,
                 const float* __restrict__ alignf)
{
    int r = blockIdx.x, tid = threadIdx.x;
    __shared__ float vec[50];
    if (tid < 40) {
        int seg = tid / 10, e = tid % 10;
        vec[tid] = tok_emb[((size_t)seg * TV + tokens[r * 4 + seg]) * EMB + e];
    } else if (tid < 50) {
        int e = tid - 40;
        float a = 0.f;
        #pragma unroll
        for (int f = 0; f < 3; f++) a = fmaf(floats_[r * 3 + f], float_w[f * EMB + e], a);
        vec[tid] = a;
    }
    __syncthreads();
    float acc = 0.f;
    #pragma unroll 5
    for (int k = 0; k < 50; k++) acc = fmaf(vec[k], alignf[k * Hh + tid], acc);
    out[r * Hh + tid] = acc;
}

// MFMA embed
template<int NID, int NTOK, int NF, int KCH, bool INDIRECT>
__global__ __launch_bounds__(128)
void k_embed_m(ushort_t* __restrict__ out, int n_static, const int* __restrict__ n_dyn,
               const int* __restrict__ ulist,
               const int* __restrict__ id_idx, const float* __restrict__ id_emb,
               const int* __restrict__ tokens, const float* __restrict__ tok_emb,
               const float* __restrict__ floats_, const float* __restrict__ float_w,
               const ushort_t* __restrict__ Bp)
{
    constexpr int NSEG = NID + NTOK + 1;
    constexpr int K = KCH * 32;
    constexpr int STR = K + 8;
    __shared__ ushort_t As[32 * 264];
    __shared__ int nodeid[32];
    int tid = threadIdx.x;
    int r0 = blockIdx.x * 32;
    int n = INDIRECT ? *n_dyn : n_static;
    if (tid < 32) {
        int slot = r0 + tid;
        nodeid[tid] = (slot < n) ? (INDIRECT ? ulist[slot] : slot) : -1;
    }
    for (int i = tid; i < 32 * STR; i += 128) As[i] = 0;
    __syncthreads();

    for (int pi = tid; pi < 32 * NSEG; pi += 128) {
        int seg = pi >> 5, nl = pi & 31;
        int node = nodeid[nl];
        if (node < 0) continue;
        float v[EMB];
        if (NID != 0 && seg == 0) {
            const float* pe = id_emb + (size_t)id_idx[node] * EMB;
            #pragma unroll
            for (int e = 0; e < EMB; e++) v[e] = pe[e];
        } else if (seg < NID + NTOK) {
            int t = seg - NID;
            const float* pe = tok_emb + ((size_t)t * TV + tokens[node * NTOK + t]) * EMB;
            #pragma unroll
            for (int e = 0; e < EMB; e++) v[e] = pe[e];
        } else {
            float fv[NF];
            #pragma unroll
            for (int f = 0; f < NF; f++) fv[f] = floats_[node * NF + f];
            #pragma unroll
            for (int e = 0; e < EMB; e++) {
                float a = 0.f;
                #pragma unroll
                for (int f = 0; f < NF; f++) a = fmaf(fv[f], float_w[f * EMB + e], a);
                v[e] = a;
            }
        }
        ushort_t* dst = &As[nl * STR + seg * EMB];
        #pragma unroll
        for (int e = 0; e < EMB; e += 2) {
            unsigned pk = (unsigned)f2bf(v[e]) | ((unsigned)f2bf(v[e + 1]) << 16);
            *reinterpret_cast<unsigned*>(dst + e) = pk;
        }
    }
    __syncthreads();

    int wid = tid >> 6, lane = tid & 63;
    int m = lane & 15, quad = lane >> 4;
    f32x4 acc[8];
    #pragma unroll
    for (int t = 0; t < 8; t++) acc[t] = (f32x4){0.f, 0.f, 0.f, 0.f};
    #pragma unroll
    for (int kc = 0; kc < KCH; kc++) {
        bf16x8 a = *reinterpret_cast<const bf16x8*>(&As[(16 * wid + m) * STR + kc * 32 + quad * 8]);
        #pragma unroll
        for (int nt = 0; nt < 8; nt++) {
            bf16x8 b = *reinterpret_cast<const bf16x8*>(Bp + (((kc * 4 + quad) * 128) + nt * 16 + m) * 8);
            acc[nt] = __builtin_amdgcn_mfma_f32_16x16x32_bf16(a, b, acc[nt], 0, 0, 0);
        }
    }
    __syncthreads();
    float* Ds = reinterpret_cast<float*>(As);
    #pragma unroll
    for (int nt = 0; nt < 8; nt++)
        #pragma unroll
        for (int reg = 0; reg < 4; reg++)
            Ds[(16 * wid + quad * 4 + reg) * 132 + nt * 16 + m] = acc[nt][reg];
    __syncthreads();
    for (int idx = tid; idx < 512; idx += 128) {
        int r = idx >> 4, c16 = idx & 15;
        int slot = r0 + r;
        if (slot >= n) continue;
        const float* dsrc = &Ds[r * 132 + c16 * 8];
        uint4 v;
        v.x = (unsigned)f2bf(dsrc[0]) | ((unsigned)f2bf(dsrc[1]) << 16);
        v.y = (unsigned)f2bf(dsrc[2]) | ((unsigned)f2bf(dsrc[3]) << 16);
        v.z = (unsigned)f2bf(dsrc[4]) | ((unsigned)f2bf(dsrc[5]) << 16);
        v.w = (unsigned)f2bf(dsrc[6]) | ((unsigned)f2bf(dsrc[7]) << 16);
        *reinterpret_cast<uint4*>(out + (size_t)slot * Hh + c16 * 8) = v;
    }
}

// ---------------------------------------------------------------------------
// Fused gather + mean + GNN update, MFMA version.
// Direct path stages roff window + contiguous elist range in LDS (parallel
// loads) so the per-row gather chain is only the xa/ef row loads. Order
// preserved -> bit-identical sums.
template<bool INDIRECT>
__global__ __launch_bounds__(128)
void k_gup(ushort_t* __restrict__ X, const float* __restrict__ xa,
           const ushort_t* __restrict__ ef,
           const int* __restrict__ roff, const int* __restrict__ elist, int sshift,
           const int* __restrict__ rows_list, const int* __restrict__ n_dyn, int n_static,
           const ushort_t* __restrict__ Wt, int do_relu)
{
    __shared__ ushort_t As[32 * 264];
    __shared__ int rowid[32];
    __shared__ int off[33];
    __shared__ int el[1024];
    int tid = threadIdx.x;
    int r0 = blockIdx.x * 32;
    int n = n_dyn ? *n_dyn : n_static;
    if (tid < 32) {
        int row = r0 + tid;
        rowid[tid] = (row < n) ? (INDIRECT ? rows_list[row] : row) : -1;
    }
    if (!INDIRECT && tid < 33) off[tid] = roff[r0 + tid];
    __syncthreads();

    for (int idx = tid; idx < 512; idx += 128) {
        int r = idx >> 4, c16 = idx & 15;
        int rr = rowid[r];
        uint4 v = make_uint4(0, 0, 0, 0);
        if (rr >= 0) v = *reinterpret_cast<const uint4*>(X + (size_t)rr * Hh + c16 * 8);
        *reinterpret_cast<uint4*>(&As[r * 264 + c16 * 8]) = v;
    }
    int eb = 0, ne = 0;
    bool fast = false;
    if (!INDIRECT) {
        eb = off[0];
        ne = off[32] - eb;
        fast = (ne <= 1024);
        if (fast) for (int j = tid; j < ne; j += 128) el[j] = elist[eb + j];
    }
    __syncthreads();

    int wid = tid >> 6, lane = tid & 63;
    int c0 = lane * 2;
    int emask = (1 << sshift) - 1;
    for (int r = wid; r < 32; r += 2) {
        int rr = rowid[r];
        float a0 = 0.f, a1 = 0.f, invd = 0.f;
        if (rr >= 0) {
            int e0, e1;
            if (!INDIRECT) { e0 = off[r]; e1 = off[r + 1]; }
            else { e0 = roff[rr]; e1 = roff[rr + 1]; }
            invd = 1.f / fmaxf((float)(e1 - e0), 1.f);
            for (int ei = e0; ei < e1; ei++) {
                int pk = (!INDIRECT && fast) ? el[ei - eb] : elist[ei];
                int s = pk >> sshift, e = pk & emask;
                const float* xr = xa + s * Hh + c0;
                unsigned ee = *reinterpret_cast<const unsigned*>(ef + (size_t)e * Hh + c0);
                a0 += xr[0] + bflo(ee);
                a1 += xr[1] + bfhi(ee);
            }
        }
        unsigned pk2 = (unsigned)f2bf(a0 * invd) | ((unsigned)f2bf(a1 * invd) << 16);
        *reinterpret_cast<unsigned*>(&As[r * 264 + 128 + c0]) = pk2;
    }
    __syncthreads();

    int m = lane & 15, quad = lane >> 4;
    f32x4 acc[8];
    #pragma unroll
    for (int t = 0; t < 8; t++) acc[t] = (f32x4){0.f, 0.f, 0.f, 0.f};
    #pragma unroll
    for (int kc = 0; kc < 8; kc++) {
        bf16x8 a = *reinterpret_cast<const bf16x8*>(&As[(16 * wid + m) * 264 + kc * 32 + quad * 8]);
        #pragma unroll
        for (int nt = 0; nt < 8; nt++) {
            bf16x8 b = *reinterpret_cast<const bf16x8*>(Wt + (((kc * 4 + quad) * 128) + nt * 16 + m) * 8);
            acc[nt] = __builtin_amdgcn_mfma_f32_16x16x32_bf16(a, b, acc[nt], 0, 0, 0);
        }
    }
    __syncthreads();
    float* Ds = reinterpret_cast<float*>(As);
    #pragma unroll
    for (int nt = 0; nt < 8; nt++)
        #pragma unroll
        for (int reg = 0; reg < 4; reg++)
            Ds[(16 * wid + quad * 4 + reg) * 132 + nt * 16 + m] = acc[nt][reg];
    __syncthreads();
    for (int idx = tid; idx < 512; idx += 128) {
        int r = idx >> 4, c16 = idx & 15;
        int rr = rowid[r];
        if (rr < 0) continue;
        const float* dsrc = &Ds[r * 132 + c16 * 8];
        float o[8];
        #pragma unroll
        for (int c = 0; c < 8; c++) {
            o[c] = dsrc[c];
            if (do_relu) o[c] = fmaxf(o[c], 0.f);
        }
        uint4 v;
        v.x = (unsigned)f2bf(o[0]) | ((unsigned)f2bf(o[1]) << 16);
        v.y = (unsigned)f2bf(o[2]) | ((unsigned)f2bf(o[3]) << 16);
        v.z = (unsigned)f2bf(o[4]) | ((unsigned)f2bf(o[5]) << 16);
        v.w = (unsigned)f2bf(o[6]) | ((unsigned)f2bf(o[7]) << 16);
        *reinterpret_cast<uint4*>(X + (size_t)rr * Hh + c16 * 8) = v;
    }
}

// ---------------------------------------------------------------------------
__global__ __launch_bounds__(128)
void k_xa(float* __restrict__ x_a,
          const float* __restrict__ Sx1, const float* __restrict__ E1,
          const float* __restrict__ Sx2, const float* __restrict__ E2,
          const int* __restrict__ c1, const int* __restrict__ c2,
          const float* __restrict__ Wself, const float* __restrict__ Wm1,
          const float* __restrict__ Wm2, int do_relu)
{
    int r = blockIdx.x, tid = threadIdx.x;
    __shared__ float xr[128], a1[128], a2[128];
    float i1 = 1.f / fmaxf((float)c1[r], 1.f);
    float i2 = 1.f / fmaxf((float)c2[r], 1.f);
    xr[tid] = x_a[r * Hh + tid];
    a1[tid] = (Sx1[r * Hh + tid] + E1[r * Hh + tid]) * i1;
    a2[tid] = (Sx2[r * Hh + tid] + E2[r * Hh + tid]) * i2;
    __syncthreads();
    float acc = 0.f;
    for (int k = 0; k < 128; k++) {
        acc = fmaf(xr[k], Wself[k * Hh + tid], acc);
        acc = fmaf(a1[k], Wm1[k * Hh + tid], acc);
        acc = fmaf(a2[k], Wm2[k * Hh + tid], acc);
    }
    if (do_relu) acc = fmaxf(acc, 0.f);
    x_a[r * Hh + tid] = acc;
}

// ---------------------------------------------------------------------------
// Transformer
DEV float blocksum128(float v, float* red)
{
    #pragma unroll
    for (int o = 32; o; o >>= 1) v += __shfl_xor(v, o);
    int wid = threadIdx.x >> 6;
    __syncthreads();
    if ((threadIdx.x & 63) == 0) red[wid] = v;
    __syncthreads();
    return red[0] + red[1];
}

DEV float blocksum256(float v, float* red)
{
    #pragma unroll
    for (int o = 32; o; o >>= 1) v += __shfl_xor(v, o);
    int wid = threadIdx.x >> 6;
    __syncthreads();
    if ((threadIdx.x & 63) == 0) red[wid] = v;
    __syncthreads();
    return red[0] + red[1] + red[2] + red[3];
}

__global__ __launch_bounds__(128)
void k_qkv3(const float* __restrict__ h, float* __restrict__ qkv,
            const float* __restrict__ W, const float* __restrict__ b)
{
    int r = blockIdx.x, part = blockIdx.y, tid = threadIdx.x;
    int c = part * 128 + tid;
    __shared__ float hr[128];
    hr[tid] = h[r * Hh + tid];
    __syncthreads();
    float a0 = b[c], a1 = 0.f, a2 = 0.f, a3 = 0.f;
    for (int k = 0; k < 128; k += 4) {
        a0 = fmaf(hr[k],     W[(k)     * 384 + c], a0);
        a1 = fmaf(hr[k + 1], W[(k + 1) * 384 + c], a1);
        a2 = fmaf(hr[k + 2], W[(k + 2) * 384 + c], a2);
        a3 = fmaf(hr[k + 3], W[(k + 3) * 384 + c], a3);
    }
    qkv[r * 384 + c] = (a0 + a1) + (a2 + a3);
}

__global__ __launch_bounds__(64)
void k_attn2(const float* __restrict__ qkv, float* __restrict__ attn_o)
{
    int hh = blockIdx.x, q = blockIdx.y;
    int lane = threadIdx.x;
    const float* qv = qkv + q * 384 + hh * HD;
    const float* kv = qkv + lane * 384 + 128 + hh * HD;
    float s = 0.f;
    #pragma unroll
    for (int d2 = 0; d2 < HD; d2++) s = fmaf(qv[d2], kv[d2], s);
    s = s * 0.25f + (lane <= q ? 0.f : -1e9f);
    float m = s;
    #pragma unroll
    for (int o = 32; o; o >>= 1) m = fmaxf(m, __shfl_xor(m, o));
    float e = __expf(s - m);
    float tot = e;
    #pragma unroll
    for (int o = 32; o; o >>= 1) tot += __shfl_xor(tot, o);
    float att = e / tot;
    __shared__ float satt[64];
    satt[lane] = att;
    __syncthreads();
    if (lane < HD) {
        float o0 = 0.f, o1 = 0.f, o2 = 0.f, o3 = 0.f;
        for (int k2 = 0; k2 < Dd; k2 += 4) {
            o0 = fmaf(satt[k2],     qkv[(k2)     * 384 + 256 + hh * HD + lane], o0);
            o1 = fmaf(satt[k2 + 1], qkv[(k2 + 1) * 384 + 256 + hh * HD + lane], o1);
            o2 = fmaf(satt[k2 + 2], qkv[(k2 + 2) * 384 + 256 + hh * HD + lane], o2);
            o3 = fmaf(satt[k2 + 3], qkv[(k2 + 3) * 384 + 256 + hh * HD + lane], o3);
        }
        attn_o[q * Hh + hh * HD + lane] = (o0 + o1) + (o2 + o3);
    }
}

// fused out-proj + residual + LN1 + ff1 slice; grid (Dd, 8) = 512 blocks.
// The out-proj/LN phase is recomputed redundantly per y-block (identical fp
// ops -> identical values); only y==0 writes h.
__global__ __launch_bounds__(256)
void k_outff(const float* __restrict__ attn_o, float* __restrict__ h,
             float* __restrict__ fbuf,
             const float* __restrict__ Wout, const float* __restrict__ bout,
             const float* __restrict__ ln,
             const float* __restrict__ W1, const float* __restrict__ b1)
{
    int r = blockIdx.x, tid = threadIdx.x;
    __shared__ float ar[128];
    __shared__ float hr[128];
    __shared__ float red[4];
    if (tid < 128) ar[tid] = attn_o[r * Hh + tid];
    __syncthreads();
    float x = 0.f;
    if (tid < 128) {
        float a0 = bout[tid], a1 = 0.f, a2 = 0.f, a3 = 0.f;
        for (int k = 0; k < 128; k += 4) {
            a0 = fmaf(ar[k],     Wout[(k)     * Hh + tid], a0);
            a1 = fmaf(ar[k + 1], Wout[(k + 1) * Hh + tid], a1);
            a2 = fmaf(ar[k + 2], Wout[(k + 2) * Hh + tid], a2);
            a3 = fmaf(ar[k + 3], Wout[(k + 3) * Hh + tid], a3);
        }
        x = h[r * Hh + tid] + (a0 + a1) + (a2 + a3);
    }
    float mu = blocksum256(x, red) * (1.f / 128.f);
    float dx = (tid < 128) ? (x - mu) : 0.f;
    float var = blocksum256(dx * dx, red) * (1.f / 128.f);
    if (tid < 128) {
        float y = ln[tid] * dx * (1.f / sqrtf(var + 1e-5f)) + ln[128 + tid];
        hr[tid] = y;
        if (blockIdx.y == 0) h[r * Hh + tid] = y;
    }
    __syncthreads();
    int c = blockIdx.y * 256 + tid;
    float a0 = b1[c], a1 = 0.f, a2 = 0.f, a3 = 0.f;
    for (int k = 0; k < 128; k += 4) {
        a0 = fmaf(hr[k],     W1[(size_t)(k)     * FF + c], a0);
        a1 = fmaf(hr[k + 1], W1[(size_t)(k + 1) * FF + c], a1);
        a2 = fmaf(hr[k + 2], W1[(size_t)(k + 2) * FF + c], a2);
        a3 = fmaf(hr[k + 3], W1[(size_t)(k + 3) * FF + c], a3);
    }
    fbuf[(size_t)r * FF + c] = fmaxf((a0 + a1) + (a2 + a3), 0.f);
}

__global__ __launch_bounds__(128)
void k_ff2p(const float* __restrict__ fbuf, float* __restrict__ part,
            const float* __restrict__ W2)
{
    int r = blockIdx.x, pi = blockIdx.y, tid = threadIdx.x;
    int kc = pi * 128;
    const float* f = fbuf + (size_t)r * FF + kc;
    float a0 = 0.f, a1 = 0.f, a2 = 0.f, a3 = 0.f;
    for (int k = 0; k < 128; k += 4) {
        a0 = fmaf(f[k],     W2[(size_t)(kc + k)     * Hh + tid], a0);
        a1 = fmaf(f[k + 1], W2[(size_t)(kc + k + 1) * Hh + tid], a1);
        a2 = fmaf(f[k + 2], W2[(size_t)(kc + k + 2) * Hh + tid], a2);
        a3 = fmaf(f[k + 3], W2[(size_t)(kc + k + 3) * Hh + tid], a3);
    }
    part[(size_t)(r * 16 + pi) * Hh + tid] = (a0 + a1) + (a2 + a3);
}

// fused LN2 + next-layer qkv part; grid (Dd, 3). LN2 recomputed redundantly
// per y-block (identical fp ops); only y==0 writes h.
__global__ __launch_bounds__(128)
void k_ln2qkv3(float* __restrict__ h, const float* __restrict__ part,
               const float* __restrict__ b2, const float* __restrict__ ln,
               float* __restrict__ qkv, const float* __restrict__ Wq,
               const float* __restrict__ bq)
{
    int r = blockIdx.x, pid = blockIdx.y, tid = threadIdx.x;
    __shared__ float red[2];
    __shared__ float hr[128];
    float acc = b2[tid];
    #pragma unroll
    for (int pi = 0; pi < 16; pi++) acc += part[(size_t)(r * 16 + pi) * Hh + tid];
    float x = h[r * Hh + tid] + acc;
    float mu = blocksum128(x, red) * (1.f / 128.f);
    float dx = x - mu;
    float var = blocksum128(dx * dx, red) * (1.f / 128.f);
    float y = ln[tid] * dx * (1.f / sqrtf(var + 1e-5f)) + ln[128 + tid];
    hr[tid] = y;
    if (pid == 0) h[r * Hh + tid] = y;
    __syncthreads();
    int c = pid * 128 + tid;
    float a0 = bq[c], a1 = 0.f, a2 = 0.f, a3 = 0.f;
    for (int k = 0; k < 128; k += 4) {
        a0 = fmaf(hr[k],     Wq[(k)     * 384 + c], a0);
        a1 = fmaf(hr[k + 1], Wq[(k + 1) * 384 + c], a1);
        a2 = fmaf(hr[k + 2], Wq[(k + 2) * 384 + c], a2);
        a3 = fmaf(hr[k + 3], Wq[(k + 3) * 384 + c], a3);
    }
    qkv[r * 384 + c] = (a0 + a1) + (a2 + a3);
}

__global__ __launch_bounds__(128)
void k_ln2(float* __restrict__ h, const float* __restrict__ part,
           const float* __restrict__ b2, const float* __restrict__ ln)
{
    int r = blockIdx.x, tid = threadIdx.x;
    __shared__ float red[2];
    float acc = b2[tid];
    #pragma unroll
    for (int pi = 0; pi < 16; pi++) acc += part[(size_t)(r * 16 + pi) * Hh + tid];
    float x = h[r * Hh + tid] + acc;
    float mu = blocksum128(x, red) * (1.f / 128.f);
    float dx = x - mu;
    float var = blocksum128(dx * dx, red) * (1.f / 128.f);
    h[r * Hh + tid] = ln[tid] * dx * (1.f / sqrtf(var + 1e-5f)) + ln[128 + tid];
}

// ---------------------------------------------------------------------------
__global__ __launch_bounds__(256)
void k_logits(const ushort_t* __restrict__ x_dc, const int* __restrict__ map,
              const float* __restrict__ h, const float* __restrict__ lp,
              const int* __restrict__ cand, float* __restrict__ out)
{
    int d = blockIdx.x;
    int tid = threadIdx.x, lane = tid & 63, w = tid >> 6;
    __shared__ float wv[128];
    if (tid < 128) wv[tid] = h[d * Hh + tid] * lp[tid];
    __syncthreads();
    for (int k = w; k < KK; k += 4) {
        int slot = map[d * VD + cand[d * KK + k]] >> 2;
        const ushort_t* row = x_dc + (size_t)slot * Hh;
        float v = bf(row[lane]) * wv[lane] + bf(row[lane + 64]) * wv[lane + 64];
        #pragma unroll
        for (int o = 32; o; o >>= 1) v += __shfl_xor(v, o);
        if (lane == 0) out[d * KK + k] = v;
    }
}

// ---------------------------------------------------------------------------
extern "C" void kernel_launch(void* const* d_in, const int* in_sizes, int n_in,
                              void* d_out, int out_size, void* d_ws, size_t ws_size,
                              hipStream_t stream)
{
    (void)in_sizes; (void)n_in; (void)out_size; (void)ws_size;

    const int* drug_tokens  = (const int*)d_in[0];
    const int* drug_node_id = (const int*)d_in[1];
    const int* lab_tokens   = (const int*)d_in[3];
    const int* lab_node_id  = (const int*)d_in[4];
    const int* adm_tokens   = (const int*)d_in[6];
    const int* did_tokens   = (const int*)d_in[8];
    const int* did_src      = (const int*)d_in[10];
    const int* did_dst      = (const int*)d_in[11];
    const int* took_tokens  = (const int*)d_in[12];
    const int* took_src     = (const int*)d_in[14];
    const int* took_dst     = (const int*)d_in[15];
    const int* cand_idx     = (const int*)d_in[16];

    const int cidx[NCANON] = {2,5,7,9,13, 17,18,19,20,21,22,23, 24,25,26,27,28,
                              29,30,31,32,33, 34,35, 36,37,38,39,40,41,42,43,44,45,46};
    const int cn[NCANON] = {
        ND*2, NLN*1, Dd*3, ED*2, ET*1,
        VD*EMB, VL*EMB, 3*TV*EMB, 2*TV*EMB, 4*TV*EMB, 2*TV*EMB, 2*TV*EMB,
        2*EMB, 1*EMB, 3*EMB, 2*EMB, 1*EMB,
        5*EMB*Hh, 4*EMB*Hh, 5*EMB*Hh, 3*EMB*Hh, 3*EMB*Hh,
        GL*4*Hh*Hh, GL*3*Hh*Hh,
        L_ENC*Hh*3*Hh, L_ENC*3*Hh, L_ENC*Hh*Hh, L_ENC*Hh, L_ENC*2*Hh,
        L_ENC*Hh*FF, L_ENC*FF, L_ENC*FF*Hh, L_ENC*Hh, L_ENC*2*Hh, Hh
    };
    CanonDesc cd;
    int eoff[NCANON + 1];
    int btot_blocks = 0;
    {
        int e = 0;
        for (int t = 0; t < NCANON; t++) {
            cd.src[t] = d_in[cidx[t]];
            cd.n[t] = cn[t];
            eoff[t] = e;
            cd.doff[t] = e;
            e = (e + cn[t] + 7) & ~7;
            btot_blocks += (cn[t] + 255) / 256;
            cd.bend[t] = btot_blocks;
        }
        eoff[NCANON] = e;
    }

    // ---- workspace carve ----
    char* p = (char*)d_ws;
    auto alloc_f = [&](size_t n) -> float*    { float* r = (float*)p;    p += n * sizeof(float); return r; };
    auto alloc_h = [&](size_t n) -> ushort_t* { ushort_t* r = (ushort_t*)p; p += n * sizeof(ushort_t); return r; };
    auto alloc_i = [&](size_t n) -> int*      { int* r = (int*)p;        p += n * sizeof(int); return r; };

    int* map    = alloc_i(ND);
    int* cnt_dc = alloc_i(UCAP);
    int* cnt_ld = alloc_i(NLN);
    int* cnt_a1 = alloc_i(64);
    int* cnt_a2 = alloc_i(64);
    int* nUB    = alloc_i(8);
    int* cur_t  = alloc_i(UCAP);
    int* cur_d  = alloc_i(NLN);
    int* cur_a1 = alloc_i(64);
    int* cur_a2 = alloc_i(64);
    float* E_did  = alloc_f((size_t)Dd * Hh);
    float* E_took = alloc_f((size_t)Dd * Hh);
    const size_t ZBLOCK = (size_t)ND + UCAP + NLN + 64 + 64 + 8 + UCAP + NLN + 64 + 64
                        + (size_t)Dd * Hh * 2;
    float* Sx_did  = alloc_f((size_t)Dd * Hh);
    float* Sx_took = alloc_f((size_t)Dd * Hh);
    int* roff_t  = alloc_i(UCAP + 8);
    int* roff_d  = alloc_i(NLN + 8);
    int* roff_a1 = alloc_i(72);
    int* roff_a2 = alloc_i(72);
    int* bscr    = alloc_i(2048);
    u64* absum   = (u64*)alloc_i(2 * (NB_A + 8));
    int* ulist   = alloc_i(UCAP);
    int* blist   = alloc_i(NCAND);
    int* elist_t = alloc_i(ET);
    int* elist_d = alloc_i(ED);
    int* tookA   = alloc_i(ET);
    int* tookB   = alloc_i(ET);
    int* didA    = alloc_i(ED);
    int* didB    = alloc_i(ED);
    ushort_t* wt     = alloc_h(3 * 32768);
    ushort_t* ap     = alloc_h(2 * 8192 + 2 * 4096);
    ushort_t* x_dc   = alloc_h((size_t)UCAP * Hh);
    ushort_t* x_l    = alloc_h((size_t)NLN * Hh);
    float*    x_a    = alloc_f((size_t)Dd * Hh);
    ushort_t* e_did  = alloc_h((size_t)ED * Hh);
    ushort_t* e_took = alloc_h((size_t)ET * Hh);
    float*    qkvb   = alloc_f((size_t)Dd * 384);
    float*    attn_o = alloc_f((size_t)Dd * Hh);
    float*    fbuf   = alloc_f((size_t)Dd * FF);
    float*    part   = alloc_f((size_t)Dd * 16 * Hh);
    float*    cf     = alloc_f((size_t)eoff[NCANON]);
    int*      dflag  = alloc_i(8);

    int* bscrT = bscr;
    int* bscrD = bscr + 1024;
    ushort_t* ap_drug = ap;
    ushort_t* ap_lab  = ap + 8192;
    ushort_t* ap_did  = ap + 16384;
    ushort_t* ap_took = ap + 16384 + 4096;

    const float* c_drug_floats  = cf + eoff[0];
    const float* c_lab_floats   = cf + eoff[1];
    const float* c_adm_floats   = cf + eoff[2];
    const float* c_did_floats   = cf + eoff[3];
    const float* c_took_floats  = cf + eoff[4];
    const float* c_drug_id_emb  = cf + eoff[5];
    const float* c_lab_id_emb   = cf + eoff[6];
    const float* c_drug_tok_emb = cf + eoff[7];
    const float* c_lab_tok_emb  = cf + eoff[8];
    const float* c_adm_tok_emb  = cf + eoff[9];
    const float* c_did_tok_emb  = cf + eoff[10];
    const float* c_took_tok_emb = cf + eoff[11];
    const float* c_drug_float_w = cf + eoff[12];
    const float* c_lab_float_w  = cf + eoff[13];
    const float* c_adm_float_w  = cf + eoff[14];
    const float* c_did_float_w  = cf + eoff[15];
    const float* c_took_float_w = cf + eoff[16];
    const float* c_drug_align   = cf + eoff[17];
    const float* c_lab_align    = cf + eoff[18];
    const float* c_adm_align    = cf + eoff[19];
    const float* c_did_align    = cf + eoff[20];
    const float* c_took_align   = cf + eoff[21];
    const float* c_gnn_msg      = cf + eoff[22];
    const float* c_gnn_self     = cf + eoff[23];
    const float* c_qkv_w        = cf + eoff[24];
    const float* c_qkv_b        = cf + eoff[25];
    const float* c_out_w        = cf + eoff[26];
    const float* c_out_b        = cf + eoff[27];
    const float* c_ln1          = cf + eoff[28];
    const float* c_ff1_w        = cf + eoff[29];
    const float* c_ff1_b        = cf + eoff[30];
    const float* c_ff2_w        = cf + eoff[31];
    const float* c_ff2_b        = cf + eoff[32];
    const float* c_ln2          = cf + eoff[33];
    const float* c_lp_w         = cf + eoff[34];

    // ---- canonicalize + graph prep ----
    k_probe<<<1, 64, 0, stream>>>((const unsigned*)d_in[41], dflag);
    k_canon<<<btot_blocks, 256, 0, stream>>>(cd, cf, dflag);
    k_packall<<<dim3(32, 7), 128, 0, stream>>>(c_gnn_self, c_gnn_msg,
        c_drug_align, c_lab_align, c_did_align, c_took_align, wt, ap);
    hipMemsetAsync(map, 0, ZBLOCK * sizeof(int), stream);
    k_mark<<<ET / 256, 256, 0, stream>>>(took_dst, cand_idx, map);
    k_acount<<<NB_A, 256, 0, stream>>>(map, absum);
    k_ascan<<<1, 1024, 0, stream>>>(absum, NB_A, nUB);
    k_assign2<<<NB_A, 256, 0, stream>>>(map, ulist, blist, absum);
    k_counts<<<128, 256, 0, stream>>>(did_dst, did_src, took_dst, took_src, map,
                                      cnt_ld, cnt_a1, cnt_dc, cnt_a2);
    k_scan_blk2<<<NB_T + NB_D, 256, 0, stream>>>(cnt_dc, roff_t, cnt_ld, roff_d, bscrT, bscrD);
    k_scan_top2<<<3, 1024, 0, stream>>>(bscrT, bscrD, cnt_a1, cnt_a2, roff_a1, roff_a2);
    k_scan_add2<<<NB_T + NB_D, 256, 0, stream>>>(roff_t, bscrT, roff_d, bscrD);
    k_fill<<<128, 256, 0, stream>>>(did_src, did_dst, took_src, took_dst, map,
                                    roff_d, roff_t, roff_a1, roff_a2,
                                    cur_d, cur_t, cur_a1, cur_a2,
                                    elist_d, elist_t, didA, didB, tookA, tookB);

    // ---- embeddings ----
    k_embed_m<1,3,2,2,true><<<UCAP / 32, 128, 0, stream>>>(x_dc, 0, nUB, ulist,
        drug_node_id, c_drug_id_emb, drug_tokens, c_drug_tok_emb,
        c_drug_floats, c_drug_float_w, ap_drug);
    k_embed_m<1,2,1,2,false><<<NLN / 32, 128, 0, stream>>>(x_l, NLN, nullptr, nullptr,
        lab_node_id, c_lab_id_emb, lab_tokens, c_lab_tok_emb,
        c_lab_floats, c_lab_float_w, ap_lab);
    k_embed_adm<<<Dd, 128, 0, stream>>>(x_a, adm_tokens, c_adm_tok_emb,
                                        c_adm_floats, c_adm_float_w, c_adm_align);
    k_embed_m<0,2,2,1,false><<<ED / 32, 128, 0, stream>>>(e_did, ED, nullptr, nullptr,
        nullptr, nullptr, did_tokens, c_did_tok_emb, c_did_floats, c_did_float_w, ap_did);
    k_embed_m<0,2,1,1,false><<<ET / 32, 128, 0, stream>>>(e_took, ET, nullptr, nullptr,
        nullptr, nullptr, took_tokens, c_took_tok_emb, c_took_floats, c_took_float_w, ap_took);

    const size_t HH = (size_t)Hh * Hh;

    // ---- GNN layer 1 (relu) ----
    hipMemsetAsync(Sx_did, 0, 2 * (size_t)Dd * Hh * sizeof(float), stream);
    k_srcsum<true><<<(ED + 31) / 32, 64, 0, stream>>>(didA, didB, x_l, e_did, 16,
                                                      Sx_did, E_did, ED, 32);
    k_srcsum<true><<<(ET + 31) / 32, 64, 0, stream>>>(tookA, tookB, x_dc, e_took, 18,
                                                      Sx_took, E_took, ET, 32);
    k_gup<false><<<UCAP / 32, 128, 0, stream>>>(x_dc, x_a, e_took, roff_t, elist_t, 17,
        nullptr, nUB, 0, wt, 1);
    k_gup<false><<<NLN / 32, 128, 0, stream>>>(x_l, x_a, e_did, roff_d, elist_d, 15,
        nullptr, nullptr, NLN, wt + 32768, 1);
    k_xa<<<Dd, 128, 0, stream>>>(x_a, Sx_did, E_did, Sx_took, E_took, cnt_a1, cnt_a2,
        c_gnn_self + 0 * HH, c_gnn_msg + 2 * HH, c_gnn_msg + 3 * HH, 1);

    // ---- GNN layer 2 ----
    const float* Ws1 = c_gnn_self + 3 * HH;
    const float* Wm1 = c_gnn_msg + 4 * HH;
    hipMemsetAsync(Sx_did, 0, 2 * (size_t)Dd * Hh * sizeof(float), stream);
    k_srcsum<false><<<(ED + 31) / 32, 64, 0, stream>>>(didA, didB, x_l, nullptr, 16,
                                                       Sx_did, nullptr, ED, 32);
    k_srcsum<false><<<(ET + 31) / 32, 64, 0, stream>>>(tookA, tookB, x_dc, nullptr, 18,
                                                       Sx_took, nullptr, ET, 32);
    k_gup<true><<<(NCAND + 31) / 32, 128, 0, stream>>>(x_dc, x_a, e_took, roff_t, elist_t, 17,
        blist, nUB + 1, 0, wt + 65536, 0);
    k_xa<<<Dd, 128, 0, stream>>>(x_a, Sx_did, E_did, Sx_took, E_took, cnt_a1, cnt_a2,
        Ws1 + 0 * HH, Wm1 + 2 * HH, Wm1 + 3 * HH, 0);

    // ---- transformer encoder (4 launches/layer + initial qkv) ----
    k_qkv3<<<dim3(Dd, 3), 128, 0, stream>>>(x_a, qkvb, c_qkv_w, c_qkv_b);
    for (int i = 0; i < L_ENC; i++) {
        k_attn2<<<dim3(NH, Dd), 64, 0, stream>>>(qkvb, attn_o);
        k_outff<<<dim3(Dd, 8), 256, 0, stream>>>(attn_o, x_a, fbuf,
            c_out_w + (size_t)i * HH, c_out_b + (size_t)i * Hh, c_ln1 + (size_t)i * 2 * Hh,
            c_ff1_w + (size_t)i * Hh * FF, c_ff1_b + (size_t)i * FF);
        k_ff2p<<<dim3(Dd, 16), 128, 0, stream>>>(fbuf, part, c_ff2_w + (size_t)i * FF * Hh);
        if (i + 1 < L_ENC) {
            k_ln2qkv3<<<dim3(Dd, 3), 128, 0, stream>>>(x_a, part,
                c_ff2_b + (size_t)i * Hh, c_ln2 + (size_t)i * 2 * Hh, qkvb,
                c_qkv_w + (size_t)(i + 1) * Hh * 384, c_qkv_b + (size_t)(i + 1) * 384);
        } else {
            k_ln2<<<Dd, 128, 0, stream>>>(x_a, part, c_ff2_b + (size_t)i * Hh,
                                          c_ln2 + (size_t)i * 2 * Hh);
        }
    }

    // ---- logits ----
    k_logits<<<Dd - 1, 256, 0, stream>>>(x_dc, map, x_a, c_lp_w, cand_idx, (float*)d_out);
}